// Round 9
// baseline (2880.764 us; speedup 1.0000x reference)
//
#include <hip/hip_runtime.h>
#include <hip/hip_bf16.h>

#define NPAD 16640
#define TOK  16385
#define CDIM 512
#define NHEAD 8
#define DHEAD 64
#define NLAND 256
#define LFAC  65
#define PAD0  255
#define NCHUNK 65   // chunks of 256 rows: 65*256 = 16640

typedef __attribute__((ext_vector_type(8))) short sh8;
typedef __attribute__((ext_vector_type(4))) float f4;

__device__ __forceinline__ float wave_sum(float v){
  #pragma unroll
  for(int o=32;o;o>>=1) v += __shfl_xor(v,o);
  return v;
}
__device__ __forceinline__ float wave_max(float v){
  #pragma unroll
  for(int o=32;o;o>>=1) v = fmaxf(v, __shfl_xor(v,o));
  return v;
}

// bf16 RNE pack helpers
__device__ __forceinline__ unsigned bfbits(float x){
  unsigned u = __float_as_uint(x);
  return (u + 0x7fffu + ((u >> 16) & 1u)) >> 16;
}
__device__ __forceinline__ float bf2f(short s){
  return __uint_as_float(((unsigned)(unsigned short)s) << 16);
}
__device__ __forceinline__ sh8 pack8f(float4 a, float4 b){
  sh8 r;
  r[0]=(short)bfbits(a.x); r[1]=(short)bfbits(a.y); r[2]=(short)bfbits(a.z); r[3]=(short)bfbits(a.w);
  r[4]=(short)bfbits(b.x); r[5]=(short)bfbits(b.y); r[6]=(short)bfbits(b.z); r[7]=(short)bfbits(b.w);
  return r;
}
#define MFMA16(a,b,c) __builtin_amdgcn_mfma_f32_16x16x32_bf16(a,b,c,0,0,0)

// ---------------- row copy (cls token) ----------------
__global__ void k_copyrow(float* dst, const float* __restrict__ src){
  dst[threadIdx.x] = src[threadIdx.x];
}

// ---------------- layernorm + front pad ----------------
__global__ __launch_bounds__(256) void k_ln_pad(const float* __restrict__ A,
    const float* __restrict__ g, const float* __restrict__ b, float* __restrict__ B){
  int w = threadIdx.x >> 6, lane = threadIdx.x & 63;
  int row = blockIdx.x*4 + w;
  float* out = B + (size_t)row*CDIM;
  if(row < PAD0){
    #pragma unroll
    for(int i=0;i<8;i++) out[lane + i*64] = 0.f;
    return;
  }
  const float* x = A + (size_t)(row-PAD0)*CDIM;
  int c0 = lane*4, c1 = 256 + lane*4;
  float4 v0 = *(const float4*)(x + c0);
  float4 v1 = *(const float4*)(x + c1);
  float xs[8] = {v0.x,v0.y,v0.z,v0.w,v1.x,v1.y,v1.z,v1.w};
  float s = 0;
  #pragma unroll
  for(int i=0;i<8;i++) s += xs[i];
  s = wave_sum(s);
  float mu = s * (1.f/512.f);
  float vs = 0;
  #pragma unroll
  for(int i=0;i<8;i++){ float d = xs[i]-mu; vs += d*d; }
  vs = wave_sum(vs) * (1.f/512.f);
  float rs = rsqrtf(vs + 1e-5f);
  float4 g0 = *(const float4*)(g + c0); float4 g1 = *(const float4*)(g + c1);
  float4 b0 = *(const float4*)(b + c0); float4 b1 = *(const float4*)(b + c1);
  float4 o0, o1;
  o0.x = (xs[0]-mu)*rs*g0.x + b0.x; o0.y = (xs[1]-mu)*rs*g0.y + b0.y;
  o0.z = (xs[2]-mu)*rs*g0.z + b0.z; o0.w = (xs[3]-mu)*rs*g0.w + b0.w;
  o1.x = (xs[4]-mu)*rs*g1.x + b1.x; o1.y = (xs[5]-mu)*rs*g1.y + b1.y;
  o1.z = (xs[6]-mu)*rs*g1.z + b1.z; o1.w = (xs[7]-mu)*rs*g1.w + b1.w;
  *(float4*)(out + c0) = o0;
  *(float4*)(out + c1) = o1;
}

// ---------------- MFMA GEMM: C[M,N] = A[M,K] @ WT[N,K]^T, bf16 inputs ----------------
template<int MODE>
__global__ __launch_bounds__(256) void k_gemm_mfma(const float* __restrict__ A, int lda,
    const float* __restrict__ WT, int K, const float* __restrict__ bias,
    float* out0, float* out1, float* out2, int M){
  __shared__ short As[128*32];
  __shared__ short Bs[128*32];
  int t = threadIdx.x, lane = t & 63, wv = t >> 6, g = lane >> 4, l15 = lane & 15;
  int row0 = blockIdx.y*128, n0 = blockIdx.x*128;
  int wm = (wv>>1)*64, wn = (wv&1)*64;
  f4 acc[4][4] = {};
  for(int k0 = 0; k0 < K; k0 += 32){
    #pragma unroll
    for(int u=0; u<2; u++){
      int gi = t + u*256;               // 512 granules of 8 elems
      int m = gi >> 2, kb = (gi & 3) * 8;
      float4 va = make_float4(0,0,0,0), vb = make_float4(0,0,0,0);
      int gr = row0 + m;
      if(gr < M){
        va = *(const float4*)(A + (size_t)gr*lda + k0 + kb);
        vb = *(const float4*)(A + (size_t)gr*lda + k0 + kb + 4);
      }
      int swz = (((m&3) ^ ((m>>2)&3)) << 4);
      *(sh8*)((char*)As + m*64 + ((kb*2) ^ swz)) = pack8f(va, vb);
      float4 wa = *(const float4*)(WT + (size_t)(n0+m)*K + k0 + kb);
      float4 wb = *(const float4*)(WT + (size_t)(n0+m)*K + k0 + kb + 4);
      *(sh8*)((char*)Bs + m*64 + ((kb*2) ^ swz)) = pack8f(wa, wb);
    }
    __syncthreads();
    sh8 af[4], bf[4];
    #pragma unroll
    for(int mt=0; mt<4; mt++){
      int r = wm + mt*16 + l15;
      af[mt] = *(sh8*)((char*)As + r*64 + ((g*16) ^ (((r&3)^((r>>2)&3))<<4)));
    }
    #pragma unroll
    for(int nt=0; nt<4; nt++){
      int r = wn + nt*16 + l15;
      bf[nt] = *(sh8*)((char*)Bs + r*64 + ((g*16) ^ (((r&3)^((r>>2)&3))<<4)));
    }
    #pragma unroll
    for(int mt=0; mt<4; mt++)
      #pragma unroll
      for(int nt=0; nt<4; nt++)
        acc[mt][nt] = MFMA16(af[mt], bf[nt], acc[mt][nt]);
    __syncthreads();
  }
  #pragma unroll
  for(int mt=0; mt<4; mt++){
    #pragma unroll
    for(int r=0; r<4; r++){
      int gm = row0 + wm + mt*16 + g*4 + r;
      if(gm >= M) continue;
      #pragma unroll
      for(int nt=0; nt<4; nt++){
        int gn = n0 + wn + nt*16 + l15;
        float v = acc[mt][nt][r];
        if(MODE == 0){
          v += bias[gn];
          out0[(size_t)gm*CDIM + gn] = v > 0.f ? v : 0.f;
        } else if(MODE == 1){
          int p = gn >> 9, rr = gn & 511;
          int hh = rr >> 6, dd = rr & 63;
          if(p == 0) v *= 0.125f;
          float* dst = (p==0) ? out0 : (p==1 ? out1 : out2);
          dst[((size_t)hh*NPAD + gm)*DHEAD + dd] = v;
        } else {
          out0[(size_t)gm*CDIM + gn] += v + bias[gn];
        }
      }
    }
  }
}

// ---------------- landmark means ----------------
__global__ void k_landmark(const float* __restrict__ src, float* __restrict__ dst){
  int bidx = blockIdx.x;               // h*256 + m
  int h = bidx >> 8, m = bidx & 255, d = threadIdx.x;
  const float* p = src + ((size_t)h*NPAD + (size_t)m*LFAC)*DHEAD + d;
  float s = 0;
  for(int j=0;j<LFAC;j++) s += p[(size_t)j*DHEAD];
  dst[(size_t)bidx*DHEAD + d] = s * (1.f/LFAC);
}

// ---------------- a2 = softmax(ql @ kl^T), f32 + bf16 copies ----------------
__global__ __launch_bounds__(256) void k_a2(const float* __restrict__ ql,
    const float* __restrict__ kl, float* __restrict__ a2, short* __restrict__ a2bf){
  __shared__ __hip_bfloat16 klt[64*256];  // [d][m]
  int h = blockIdx.y;
  int t = threadIdx.x;
  const float* klh = kl + (size_t)h*NLAND*DHEAD;
  for(int r=0;r<64;r++){
    int idx = r*256 + t;
    int d = idx >> 8, m = idx & 255;
    klt[idx] = __float2bfloat16(klh[m*DHEAD + d]);
  }
  __syncthreads();
  int w = t >> 6, lane = t & 63;
  const float* qlh = ql + (size_t)h*NLAND*DHEAD;
  for(int rr=0; rr<16; rr++){
    int m = blockIdx.x*64 + w*16 + rr;
    const float* q = qlh + (size_t)m*DHEAD;
    float s[4] = {0,0,0,0};
    #pragma unroll
    for(int d=0; d<64; d++){
      float qv = q[d];
      #pragma unroll
      for(int qd=0; qd<4; qd++)
        s[qd] += qv * __bfloat162float(klt[d*256 + qd*64 + lane]);
    }
    float e[4], den = 0.f;
    #pragma unroll
    for(int qd=0; qd<4; qd++){ e[qd] = __expf(s[qd]); den += e[qd]; }
    den = wave_sum(den);
    float inv = 1.f/den;
    size_t rowo = ((size_t)h*NLAND + m)*NLAND;
    #pragma unroll
    for(int qd=0; qd<4; qd++){
      float v = e[qd]*inv;
      a2[rowo + qd*64 + lane] = v;
      a2bf[rowo + qd*64 + lane] = (short)bfbits(v);
    }
  }
}

// ---------------- pinv init ----------------
__global__ void k_colmax(const float* __restrict__ a2, float* __restrict__ hmax){
  __shared__ float red[4];
  int h = blockIdx.x, t = threadIdx.x;
  const float* p = a2 + (size_t)h*65536 + t;
  float s = 0;
  for(int m=0;m<256;m++) s += p[(size_t)m*256];
  float mx = wave_max(s);
  if((t & 63) == 0) red[t>>6] = mx;
  __syncthreads();
  if(t == 0) hmax[h] = fmaxf(fmaxf(red[0],red[1]), fmaxf(red[2],red[3]));
}
__global__ void k_scal(const float* __restrict__ hmax, float* __restrict__ scal){
  int t = threadIdx.x;
  float v = (t < 8) ? hmax[t] : -1e30f;
  v = wave_max(v);
  if(t == 0) scal[0] = v;
}
// z0 (bf16, both forms) = a2^T / s
__global__ void k_zinit2(const float* __restrict__ a2, const float* __restrict__ scal,
                         short* __restrict__ zrm, short* __restrict__ ztr){
  int h = blockIdx.y;
  int idx = blockIdx.x*256 + threadIdx.x;   // 0..65535
  int m = idx >> 8, j = idx & 255;
  float inv = 1.f / scal[0];
  size_t off = (size_t)h*65536;
  zrm[off + idx] = (short)bfbits(a2[off + (size_t)j*256 + m] * inv);
  ztr[off + idx] = (short)bfbits(a2[off + idx] * inv);
}

// ---------------- pinv stage: D = beta * A @ B, full 256x256 B staged in LDS ----
// Sequential n-groups: only acc[4][4] (64 VGPR) live at a time — stays under
// the VGPR budget (round-8's dual-acc design spilled: WRITE_SIZE 52MB scratch).
// NEGB: B := alpha*I - B via sign-flip XOR + predicated diagonal fix.
// WR bit0: Dtr (short4 coalesced), bit1: Drm (bf16), bit2: Df32 (f32 rm).
template<int NEGB, int WR>
__device__ __forceinline__ void pstage3(const short* __restrict__ Aarr,
    const short* __restrict__ Btr, float alpha, float beta,
    short* __restrict__ Dtr, short* __restrict__ Drm, float* __restrict__ Df32,
    short* Bq, int wv, int g, int l15, int t){
  __syncthreads();                 // prev stage's Bq reads + stores done
  #pragma unroll
  for(int i=0;i<16;i++){
    int gi = t + i*512;            // 8192 granules of 8 elems
    int n = gi >> 5, kb = (gi & 31) * 8;
    sh8 v = *(const sh8*)(Btr + (size_t)n*256 + kb);
    if(NEGB){
      #pragma unroll
      for(int j=0;j<4;j++) ((unsigned*)&v)[j] ^= 0x80008000u;
      #pragma unroll
      for(int e=0;e<8;e++)
        if(n == kb+e) v[e] = (short)bfbits(alpha + bf2f(v[e]));
    }
    *(sh8*)((char*)Bq + n*512 + ((kb*2) ^ ((n&7)<<4))) = v;
  }
  __syncthreads();
  int mbase = (wv>>1)*64;          // 4 m-groups of 64 rows
  #pragma unroll
  for(int ng=0; ng<2; ng++){
    int nbase = (wv&1)*64 + ng*128;
    f4 acc[4][4] = {};
    #pragma unroll
    for(int ks=0; ks<8; ks++){
      int k0 = ks*32 + g*8;
      sh8 a[4];
      #pragma unroll
      for(int mt=0; mt<4; mt++)
        a[mt] = *(const sh8*)(Aarr + (size_t)(mbase + mt*16 + l15)*256 + k0);
      #pragma unroll
      for(int nt=0; nt<4; nt++){
        int n = nbase + nt*16 + l15;
        sh8 b = *(sh8*)((char*)Bq + n*512 + ((ks*64 + g*16) ^ ((n&7)<<4)));
        #pragma unroll
        for(int mt=0; mt<4; mt++) acc[mt][nt] = MFMA16(a[mt], b, acc[mt][nt]);
      }
    }
    #pragma unroll
    for(int mt=0; mt<4; mt++){
      int m0 = mbase + mt*16 + g*4;
      #pragma unroll
      for(int nt=0; nt<4; nt++){
        int n0 = nbase + nt*16 + l15;
        f4 v = acc[mt][nt];
        v[0]*=beta; v[1]*=beta; v[2]*=beta; v[3]*=beta;
        if(WR & 1){
          short4 pk;
          pk.x=(short)bfbits(v[0]); pk.y=(short)bfbits(v[1]);
          pk.z=(short)bfbits(v[2]); pk.w=(short)bfbits(v[3]);
          *(short4*)(Dtr + (size_t)n0*256 + m0) = pk;
        }
        if(WR & 2){
          #pragma unroll
          for(int r=0;r<4;r++) Drm[(size_t)(m0+r)*256 + n0] = (short)bfbits(v[r]);
        }
        if(WR & 4){
          #pragma unroll
          for(int r=0;r<4;r++) Df32[(size_t)(m0+r)*256 + n0] = v[r];
        }
      }
    }
  }
}

// 512 threads = 8 waves = exactly 2 waves/EU -> declare it so the register
// allocator gets the full 256-VGPR budget (default target capped us at 128
// and spilled in rounds 7-8).
__global__ __launch_bounds__(512, 2) void k_pinv3(const short* __restrict__ a2bf,
    short* __restrict__ Xrm, short* __restrict__ Xtr,
    short* __restrict__ Ttr, short* __restrict__ Utr,
    short* __restrict__ zrm0, short* __restrict__ ztr0,
    short* __restrict__ zrm1, short* __restrict__ ztr1,
    float* __restrict__ zf32){
  __shared__ short Bq[256*256];    // 128KB
  int h = blockIdx.x;
  size_t off = (size_t)h*65536;
  const short* a2h = a2bf + off;
  short* Xr = Xrm + off; short* Xt = Xtr + off;
  short* Tt = Ttr + off; short* Ut = Utr + off;
  short* zr[2] = {zrm0 + off, zrm1 + off};
  short* zt[2] = {ztr0 + off, ztr1 + off};
  float* zf = zf32 + off;
  int t = threadIdx.x, lane = t & 63, wv = t >> 6, g = lane >> 4, l15 = lane & 15;
  int cur = 0;
  for(int it=0; it<6; it++){
    // X = a2 @ z
    pstage3<0,3>(a2h, zt[cur], 0.f, 1.f, Xt, Xr, nullptr, Bq, wv, g, l15, t);
    // T = X @ (7I - X)
    pstage3<1,1>(Xr, Xt, 7.f, 1.f, Tt, nullptr, nullptr, Bq, wv, g, l15, t);
    // U = X @ (15I - T)
    pstage3<1,1>(Xr, Tt, 15.f, 1.f, Ut, nullptr, nullptr, Bq, wv, g, l15, t);
    // zn = 0.25 * z @ (13I - U)
    if(it < 5)
      pstage3<1,3>(zr[cur], Ut, 13.f, 0.25f, zt[cur^1], zr[cur^1], nullptr,
                   Bq, wv, g, l15, t);
    else
      pstage3<1,4>(zr[cur], Ut, 13.f, 0.25f, nullptr, nullptr, zf,
                   Bq, wv, g, l15, t);
    cur ^= 1;
  }
}

// ---------------- batched f32 GEMM 64x64 tile (used for w2^T) ----------------
template<int TRANS, int OUTT>
__global__ __launch_bounds__(256) void k_sgemm2(const float* __restrict__ A,
    const float* __restrict__ B, float* __restrict__ C,
    int M, int N, int K, long sA, long sB, long sC, float alpha, float beta){
  __shared__ float As[32][68];
  __shared__ float Bs[32][68];
  int bh = blockIdx.z;
  const float* Ah = A + (size_t)bh*sA;
  const float* Bh = B + (size_t)bh*sB;
  float* Ch = C + (size_t)bh*sC;
  int m0 = blockIdx.y*64, n0 = blockIdx.x*64;
  int t = threadIdx.x, tx = t & 15, ty = t >> 4;
  float acc[4][4] = {};
  for(int k0=0; k0<K; k0+=32){
    #pragma unroll
    for(int u=0; u<2; u++){
      int idx = t + u*256;
      int r = idx >> 3, cb = (idx & 7) * 4;
      float4 va = *(const float4*)(Ah + (size_t)(m0+r)*K + k0 + cb);
      As[cb+0][r]=va.x; As[cb+1][r]=va.y; As[cb+2][r]=va.z; As[cb+3][r]=va.w;
      int kr = idx >> 4, nb = (idx & 15) * 4;
      float4 w = *(const float4*)(Bh + (size_t)(k0+kr)*N + n0 + nb);
      if(TRANS){
        int gk = k0 + kr;
        w.x = ((gk==n0+nb+0)?alpha:0.f) - w.x;
        w.y = ((gk==n0+nb+1)?alpha:0.f) - w.y;
        w.z = ((gk==n0+nb+2)?alpha:0.f) - w.z;
        w.w = ((gk==n0+nb+3)?alpha:0.f) - w.w;
      }
      *(float4*)&Bs[kr][nb] = w;
    }
    __syncthreads();
    #pragma unroll
    for(int k=0;k<32;k++){
      float a[4], b[4];
      *(float4*)a = *(const float4*)&As[k][ty*4];
      *(float4*)b = *(const float4*)&Bs[k][tx*4];
      #pragma unroll
      for(int i=0;i<4;i++)
        #pragma unroll
        for(int j=0;j<4;j++) acc[i][j] += a[i]*b[j];
    }
    __syncthreads();
  }
  #pragma unroll
  for(int i=0;i<4;i++){
    #pragma unroll
    for(int j=0;j<4;j++){
      int gm = m0 + ty*4 + i, gn = n0 + tx*4 + j;
      float v = acc[i][j] * beta;
      if(OUTT) Ch[(size_t)gn*M + gm] = v;
      else     Ch[(size_t)gm*N + gn] = v;
    }
  }
}

// ---------------- MFMA flash a1 ----------------
__global__ __launch_bounds__(256) void k_a1_mfma(const float* __restrict__ Qb,
    const float* __restrict__ kl, const float* __restrict__ w2t, float* __restrict__ F){
  __shared__ short klL[128*64];
  __shared__ short w2L[64*128];
  __shared__ short pL[4][16*128];
  int h = blockIdx.y, n0 = blockIdx.x*128;
  int t = threadIdx.x, lane = t & 63, wv = t >> 6, g = lane >> 4, l15 = lane & 15;
  const float* klh = kl + (size_t)h*NLAND*DHEAD;
  const float* w2h = w2t + (size_t)h*DHEAD*NLAND;
  const float* qbase = Qb + (size_t)h*NPAD*DHEAD;
  sh8 aQ[2][2];
  #pragma unroll
  for(int st=0; st<2; st++)
    #pragma unroll
    for(int kk=0; kk<2; kk++){
      const float* p = qbase + (size_t)(n0 + wv*32 + st*16 + l15)*DHEAD + kk*32 + g*8;
      aQ[st][kk] = pack8f(*(const float4*)p, *(const float4*)(p+4));
    }
  f4 accO[2][4] = {};
  float den[2][4] = {};
  short* pw = pL[wv];
  for(int half=0; half<2; half++){
    __syncthreads();
    #pragma unroll
    for(int it=0; it<4; it++){
      int gi = t + it*256;
      int m = gi >> 3, db = (gi & 7) * 8;
      const float* p = klh + (size_t)(half*128 + m)*DHEAD + db;
      *(sh8*)((char*)klL + m*128 + ((db*2) ^ ((m&7)<<4))) =
          pack8f(*(const float4*)p, *(const float4*)(p+4));
      int d = gi >> 4, mb = (gi & 15) * 8;
      const float* p2 = w2h + (size_t)d*NLAND + half*128 + mb;
      *(sh8*)((char*)w2L + d*256 + ((mb*2) ^ ((d&7)<<4))) =
          pack8f(*(const float4*)p2, *(const float4*)(p2+4));
    }
    __syncthreads();
    #pragma unroll
    for(int st=0; st<2; st++){
      #pragma unroll
      for(int mt=0; mt<8; mt++){
        f4 s = {};
        #pragma unroll
        for(int kk=0; kk<2; kk++){
          int m = mt*16 + l15;
          sh8 b = *(sh8*)((char*)klL + m*128 + ((kk*64 + g*16) ^ ((m&7)<<4)));
          s = MFMA16(aQ[st][kk], b, s);
        }
        #pragma unroll
        for(int r=0; r<4; r++){
          float e = __expf(s[r]);
          den[st][r] += e;
          int n = g*4 + r;
          *(short*)((char*)pw + n*256 + (((mt*16+l15)*2) ^ ((n&7)<<4))) = (short)bfbits(e);
        }
      }
      __syncthreads();
      #pragma unroll
      for(int ks=0; ks<4; ks++){
        sh8 aP = *(sh8*)((char*)pw + l15*256 + ((ks*64 + g*16) ^ ((l15&7)<<4)));
        #pragma unroll
        for(int dt=0; dt<4; dt++){
          int d = dt*16 + l15;
          sh8 bW = *(sh8*)((char*)w2L + d*256 + ((ks*64 + g*16) ^ ((d&7)<<4)));
          accO[st][dt] = MFMA16(aP, bW, accO[st][dt]);
        }
      }
      __syncthreads();
    }
  }
  #pragma unroll
  for(int st=0; st<2; st++)
    #pragma unroll
    for(int r=0; r<4; r++){
      float d_ = den[st][r];
      d_ += __shfl_xor(d_,1); d_ += __shfl_xor(d_,2);
      d_ += __shfl_xor(d_,4); d_ += __shfl_xor(d_,8);
      den[st][r] = 1.f/d_;
    }
  #pragma unroll
  for(int st=0; st<2; st++)
    #pragma unroll
    for(int dt=0; dt<4; dt++)
      #pragma unroll
      for(int r=0; r<4; r++){
        int row = n0 + wv*32 + st*16 + g*4 + r;
        F[(size_t)row*CDIM + h*DHEAD + dt*16 + l15] = accO[st][dt][r]*den[st][r];
      }
}

// ---------------- MFMA flash a3v (256 threads) ----------------
__global__ __launch_bounds__(256) void k_a3v_mfma(const float* __restrict__ ql,
    const float* __restrict__ Kb, const float* __restrict__ Vb,
    float* __restrict__ numP, float* __restrict__ denP){
  __shared__ short kL[128*64];
  __shared__ short vL[64*128];
  __shared__ short pL[4][16*128];
  int h = blockIdx.x, c = blockIdx.y;
  int t = threadIdx.x, lane = t & 63, wv = t >> 6, g = lane >> 4, l15 = lane & 15;
  const float* qlh = ql + (size_t)h*NLAND*DHEAD;
  sh8 aQ[4][2];
  #pragma unroll
  for(int st=0; st<4; st++)
    #pragma unroll
    for(int kk=0; kk<2; kk++){
      const float* p = qlh + (size_t)(wv*64 + st*16 + l15)*DHEAD + kk*32 + g*8;
      aQ[st][kk] = pack8f(*(const float4*)p, *(const float4*)(p+4));
    }
  f4 accO[4][4] = {};
  float den[4][4] = {};
  short* pw = pL[wv];
  for(int half=0; half<2; half++){
    const float* Kh = Kb + ((size_t)h*NPAD + (size_t)c*256 + half*128)*DHEAD;
    const float* Vh = Vb + ((size_t)h*NPAD + (size_t)c*256 + half*128)*DHEAD;
    __syncthreads();
    #pragma unroll
    for(int it=0; it<4; it++){
      int gi = t + it*256;
      int m = gi >> 3, db = (gi & 7) * 8;
      const float* p = Kh + (size_t)m*DHEAD + db;
      *(sh8*)((char*)kL + m*128 + ((db*2) ^ ((m&7)<<4))) =
          pack8f(*(const float4*)p, *(const float4*)(p+4));
    }
    #pragma unroll
    for(int it=0; it<8; it++){
      int idx = t + it*256;
      int m = idx & 127, d0 = (idx >> 7) * 4;
      float4 v = *(const float4*)(Vh + (size_t)m*DHEAD + d0);
      float vv[4] = {v.x, v.y, v.z, v.w};
      #pragma unroll
      for(int i=0;i<4;i++){
        int d = d0 + i;
        *(short*)((char*)vL + d*256 + ((m*2) ^ ((d&7)<<4))) = (short)bfbits(vv[i]);
      }
    }
    __syncthreads();
    #pragma unroll
    for(int st=0; st<4; st++){
      #pragma unroll
      for(int mt=0; mt<8; mt++){
        f4 s = {};
        #pragma unroll
        for(int kk=0; kk<2; kk++){
          int m = mt*16 + l15;
          sh8 b = *(sh8*)((char*)kL + m*128 + ((kk*64 + g*16) ^ ((m&7)<<4)));
          s = MFMA16(aQ[st][kk], b, s);
        }
        #pragma unroll
        for(int r=0; r<4; r++){
          float e = __expf(s[r]);
          den[st][r] += e;
          int n = g*4 + r;
          *(short*)((char*)pw + n*256 + (((mt*16+l15)*2) ^ ((n&7)<<4))) = (short)bfbits(e);
        }
      }
      __syncthreads();
      #pragma unroll
      for(int ks=0; ks<4; ks++){
        sh8 aP = *(sh8*)((char*)pw + l15*256 + ((ks*64 + g*16) ^ ((l15&7)<<4)));
        #pragma unroll
        for(int dt=0; dt<4; dt++){
          int d = dt*16 + l15;
          sh8 bV = *(sh8*)((char*)vL + d*256 + ((ks*64 + g*16) ^ ((d&7)<<4)));
          accO[st][dt] = MFMA16(aP, bV, accO[st][dt]);
        }
      }
      __syncthreads();
    }
  }
  #pragma unroll
  for(int st=0; st<4; st++)
    #pragma unroll
    for(int r=0; r<4; r++){
      float d_ = den[st][r];
      d_ += __shfl_xor(d_,1); d_ += __shfl_xor(d_,2);
      d_ += __shfl_xor(d_,4); d_ += __shfl_xor(d_,8);
      den[st][r] = d_;
    }
  size_t base = ((size_t)h*NCHUNK + c)*NLAND;
  #pragma unroll
  for(int st=0; st<4; st++){
    #pragma unroll
    for(int r=0; r<4; r++){
      int row = wv*64 + st*16 + g*4 + r;
      if(l15 == 0) denP[base + row] = den[st][r];
      #pragma unroll
      for(int dt=0; dt<4; dt++)
        numP[(base + row)*DHEAD + dt*16 + l15] = accO[st][dt][r];
    }
  }
}

__global__ void k_a3v_comb(const float* __restrict__ numP, const float* __restrict__ denP,
                           float* __restrict__ a3v){
  int bidx = blockIdx.x;           // h*256 + m
  int h = bidx >> 8, m = bidx & 255;
  int d = threadIdx.x;
  float s = 0.f, den = 0.f;
  for(int c=0;c<NCHUNK;c++){
    s += numP[(((size_t)h*NCHUNK + c)*NLAND + m)*DHEAD + d];
    den += denP[((size_t)h*NCHUNK + c)*NLAND + m];
  }
  a3v[((size_t)h*NLAND + m)*DHEAD + d] = s / den;
}

// ---------------- residual depthwise conv (k=33), FIR-tiled ----------------
__global__ __launch_bounds__(256) void k_resconv(const float* __restrict__ Vb,
    const float* __restrict__ rw, float* __restrict__ F){
  __shared__ float vs[160][64];
  int n0 = blockIdx.x*128, h = blockIdx.y;
  int t = threadIdx.x;
  const float* vh = Vb + (size_t)h*NPAD*DHEAD;
  #pragma unroll
  for(int i=0;i<10;i++){
    int idx = t + i*256;
    int r = idx >> 4, dq = (idx & 15)*4;
    int n = n0 - 16 + r;
    float4 v = (n>=0 && n<NPAD) ? *(const float4*)(vh + (size_t)n*DHEAD + dq)
                                : make_float4(0.f,0.f,0.f,0.f);
    *(float4*)&vs[r][dq] = v;
  }
  float w[33];
  #pragma unroll
  for(int j=0;j<33;j++) w[j] = rw[h*33+j];
  __syncthreads();
  int d = t & 63, half = t >> 6;
  float acc[32];
  #pragma unroll
  for(int r=0;r<32;r++) acc[r] = 0.f;
  #pragma unroll
  for(int p=0;p<64;p++){
    float vv = vs[half*32 + p][d];
    #pragma unroll
    for(int j=0;j<33;j++){
      int r = p - j;
      if(r >= 0 && r < 32) acc[r] += w[j]*vv;
    }
  }
  #pragma unroll
  for(int r=0;r<32;r++){
    int n = n0 + half*32 + r;
    F[(size_t)n*CDIM + h*DHEAD + d] += acc[r];
  }
}

// ---------------- transpose (weights only) ----------------
__global__ void k_transpose(const float* __restrict__ in, float* __restrict__ out,
                            int R, int C){
  __shared__ float tile[32][33];
  int r0 = blockIdx.x*32, c0 = blockIdx.y*32;
  int tx = threadIdx.x, ty = threadIdx.y;
  #pragma unroll
  for(int r=0;r<4;r++) tile[ty + r*8][tx] = in[(size_t)(r0 + ty + r*8)*C + c0 + tx];
  __syncthreads();
  #pragma unroll
  for(int r=0;r<4;r++) out[(size_t)(c0 + ty + r*8)*R + r0 + tx] = tile[tx][ty + r*8];
}

// ---------------- PPEG direct on row-major [n][c] ----------------
__global__ __launch_bounds__(256) void k_ppeg2(const float* __restrict__ X,
    const float* __restrict__ w7, const float* __restrict__ b7,
    const float* __restrict__ w5, const float* __restrict__ b5,
    const float* __restrict__ w3, const float* __restrict__ b3,
    float* __restrict__ Y){
  __shared__ float patch[484][20];
  int cg = blockIdx.y;
  int ti = blockIdx.x >> 3, tj = blockIdx.x & 7;
  int t = threadIdx.x;
  int i0 = ti*16 - 3, j0 = tj*16 - 3;
  for(int idx = t; idx < 1936; idx += 256){
    int p = idx >> 2, cq = (idx & 3) * 4;
    int gi = i0 + p/22, gj = j0 + p%22;
    float4 v = make_float4(0.f,0.f,0.f,0.f);
    if(gi>=0 && gi<128 && gj>=0 && gj<128)
      v = *(const float4*)(X + (size_t)(gi*128+gj)*CDIM + cg*16 + cq);
    *(float4*)&patch[p][cq] = v;
  }
  int c = t & 15, sg = t >> 4;
  int cglob = cg*16 + c;
  float wr[83];
  #pragma unroll
  for(int k=0;k<49;k++) wr[k] = w7[cglob*49+k];
  #pragma unroll
  for(int k=0;k<25;k++) wr[49+k] = w5[cglob*25+k];
  #pragma unroll
  for(int k=0;k<9;k++)  wr[74+k] = w3[cglob*9+k];
  float bsum = b7[cglob] + b5[cglob] + b3[cglob];
  __syncthreads();
  float acc[16];
  #pragma unroll
  for(int j=0;j<16;j++) acc[j] = patch[(sg+3)*22 + (j+3)][c] + bsum;
  #pragma unroll
  for(int a=0;a<7;a++)
    #pragma unroll
    for(int x=0;x<22;x++){
      float vv = patch[(sg+a)*22 + x][c];
      #pragma unroll
      for(int bq=0;bq<7;bq++){
        int j = x - bq;
        if(j>=0 && j<16) acc[j] += wr[a*7+bq]*vv;
      }
    }
  #pragma unroll
  for(int a=0;a<5;a++)
    #pragma unroll
    for(int x=1;x<21;x++){
      float vv = patch[(sg+a+1)*22 + x][c];
      #pragma unroll
      for(int bq=0;bq<5;bq++){
        int j = x - 1 - bq;
        if(j>=0 && j<16) acc[j] += wr[49+a*5+bq]*vv;
      }
    }
  #pragma unroll
  for(int a=0;a<3;a++)
    #pragma unroll
    for(int x=2;x<20;x++){
      float vv = patch[(sg+a+2)*22 + x][c];
      #pragma unroll
      for(int bq=0;bq<3;bq++){
        int j = x - 2 - bq;
        if(j>=0 && j<16) acc[j] += wr[74+a*3+bq]*vv;
      }
    }
  #pragma unroll
  for(int j=0;j<16;j++)
    Y[(size_t)((ti*16+sg)*128 + tj*16+j)*CDIM + cglob] = acc[j];
}

// ---------------- final LN(row0) + fc2 ----------------
__global__ __launch_bounds__(512) void k_final(const float* __restrict__ A,
    const float* __restrict__ g, const float* __restrict__ b,
    const float* __restrict__ w, const float* __restrict__ bias,
    float* __restrict__ outp){
  __shared__ float red[8];
  int t = threadIdx.x, wv = t >> 6;
  float x = A[t];
  float s = wave_sum(x);
  if((t & 63) == 0) red[wv] = s;
  __syncthreads();
  float mu = 0;
  #pragma unroll
  for(int i=0;i<8;i++) mu += red[i];
  mu *= (1.f/512.f);
  __syncthreads();
  float dx = x - mu;
  s = wave_sum(dx*dx);
  if((t & 63) == 0) red[wv] = s;
  __syncthreads();
  float var = 0;
  #pragma unroll
  for(int i=0;i<8;i++) var += red[i];
  var *= (1.f/512.f);
  float xn = dx * rsqrtf(var + 1e-5f) * g[t] + b[t];
  __syncthreads();
  for(int o=0;o<4;o++){
    s = wave_sum(xn * w[t*4 + o]);
    if((t & 63) == 0) red[wv] = s;
    __syncthreads();
    if(t == 0){
      float r = 0;
      #pragma unroll
      for(int i=0;i<8;i++) r += red[i];
      outp[o] = r + bias[o];
    }
    __syncthreads();
  }
}

extern "C" void kernel_launch(void* const* d_in, const int* in_sizes, int n_in,
                              void* d_out, int out_size, void* d_ws, size_t ws_size,
                              hipStream_t stream) {
  (void)in_sizes; (void)n_in; (void)out_size; (void)ws_size;
  const float* data_x = (const float*)d_in[0];
  const float* fc1_w  = (const float*)d_in[1];
  const float* fc1_b  = (const float*)d_in[2];
  const float* cls_tk = (const float*)d_in[3];
  const float* ng[2]  = {(const float*)d_in[4],  (const float*)d_in[16]};
  const float* nb[2]  = {(const float*)d_in[5],  (const float*)d_in[17]};
  const float* qkvw[2]= {(const float*)d_in[6],  (const float*)d_in[18]};
  const float* outw[2]= {(const float*)d_in[7],  (const float*)d_in[19]};
  const float* outb[2]= {(const float*)d_in[8],  (const float*)d_in[20]};
  const float* resw[2]= {(const float*)d_in[9],  (const float*)d_in[21]};
  const float* w7 = (const float*)d_in[10]; const float* pb7 = (const float*)d_in[11];
  const float* w5 = (const float*)d_in[12]; const float* pb5 = (const float*)d_in[13];
  const float* w3 = (const float*)d_in[14]; const float* pb3 = (const float*)d_in[15];
  const float* norm_g = (const float*)d_in[22];
  const float* norm_b = (const float*)d_in[23];
  const float* fc2_w  = (const float*)d_in[24];
  const float* fc2_b  = (const float*)d_in[25];

  float* ws = (float*)d_ws;
  float* Ab   = ws;                         // 16385*512 (layer-0 h base)
  float* Bb   = Ab + (size_t)TOK*CDIM;      // L0 ln-out; post-ppeg h base
  float* Qb   = Bb + (size_t)NPAD*CDIM;
  float* Kb   = Qb + (size_t)NPAD*CDIM;
  float* Vb   = Kb + (size_t)NPAD*CDIM;
  float* Fb   = Vb + (size_t)NPAD*CDIM;     // L1 ln-out; a3v numP scratch; pre-proj F
  float* qlb  = Fb + (size_t)NPAD*CDIM;     // 8*256*64
  float* klb  = qlb + NHEAD*NLAND*DHEAD;
  float* a2b  = klb + NHEAD*NLAND*DHEAD;    // 8*256*256 f32
  float* z0b  = a2b + NHEAD*NLAND*NLAND;    // zf32 (final z, f32)
  float* z1b  = z0b + NHEAD*NLAND*NLAND;    // carved: zrm1/ztr1 bf16
  float* Xb_  = z1b + NHEAD*NLAND*NLAND;    // carved: Xrm/Xtr bf16
  float* Tb_  = Xb_ + NHEAD*NLAND*NLAND;    // carved: Ttr/Utr bf16
  float* Ub_  = Tb_ + NHEAD*NLAND*NLAND;    // carved: zrm0/ztr0 bf16
  float* a3vb = Ub_ + NHEAD*NLAND*NLAND;    // 8*256*64
  float* w2tb = a3vb + NHEAD*NLAND*DHEAD;   // 8*64*256 (transposed w2)
  float* denP = w2tb + NHEAD*DHEAD*NLAND;   // 8*65*256
  float* hmax = denP + NHEAD*NCHUNK*NLAND;  // 8
  float* scal = hmax + 8;                   // 1
  float* fc1T = scal + 8;                   // 512*1024
  float* qkvT0= fc1T + 512*1024;            // 1536*512
  float* qkvT1= qkvT0 + 1536*512;
  float* outT0= qkvT1 + 1536*512;           // 512*512
  float* outT1= outT0 + 512*512;
  float* a2bfF= outT1 + 512*512;            // 8*65536 bf16 = 262144 floats
  float* qkvT[2] = {qkvT0, qkvT1};
  float* outT[2] = {outT0, outT1};

  const int HB = NHEAD*NLAND*NLAND;         // 524288 shorts per bf16 array
  short* xrm  = (short*)Xb_;  short* xtr  = xrm  + HB;
  short* ttr  = (short*)Tb_;  short* utr  = ttr  + HB;
  short* zrm0 = (short*)Ub_;  short* ztr0 = zrm0 + HB;
  short* zrm1 = (short*)z1b;  short* ztr1 = zrm1 + HB;
  short* a2bf = (short*)a2bfF;

  // weight transposes (WT[n][k])
  k_transpose<<<dim3(32,16), dim3(32,8), 0, stream>>>(fc1_w, fc1T, 1024, 512);
  k_transpose<<<dim3(16,48), dim3(32,8), 0, stream>>>(qkvw[0], qkvT0, 512, 1536);
  k_transpose<<<dim3(16,48), dim3(32,8), 0, stream>>>(qkvw[1], qkvT1, 512, 1536);
  k_transpose<<<dim3(16,16), dim3(32,8), 0, stream>>>(outw[0], outT0, 512, 512);
  k_transpose<<<dim3(16,16), dim3(32,8), 0, stream>>>(outw[1], outT1, 512, 512);

  k_copyrow<<<1, 512, 0, stream>>>(Ab, cls_tk);
  k_gemm_mfma<0><<<dim3(4, 128), 256, 0, stream>>>(data_x, 1024, fc1T, 1024, fc1_b,
                                                   Ab + CDIM, nullptr, nullptr, 16384);
  float* base[2]  = {Ab, Bb};
  float* lnout[2] = {Bb, Fb};
  for(int L=0; L<2; L++){
    k_ln_pad<<<NPAD/4, 256, 0, stream>>>(base[L], ng[L], nb[L], lnout[L]);
    k_gemm_mfma<1><<<dim3(12, 130), 256, 0, stream>>>(lnout[L], CDIM, qkvT[L], CDIM, nullptr,
                                                      Qb, Kb, Vb, NPAD);
    k_landmark<<<NHEAD*NLAND, 64, 0, stream>>>(Qb, qlb);
    k_landmark<<<NHEAD*NLAND, 64, 0, stream>>>(Kb, klb);
    k_a2<<<dim3(4, NHEAD), 256, 0, stream>>>(qlb, klb, a2b, a2bf);
    k_colmax<<<NHEAD, 256, 0, stream>>>(a2b, hmax);
    k_scal<<<1, 64, 0, stream>>>(hmax, scal);
    k_zinit2<<<dim3(256, NHEAD), 256, 0, stream>>>(a2b, scal, zrm0, ztr0);
    k_pinv3<<<8, 512, 0, stream>>>(a2bf, xrm, xtr, ttr, utr,
                                   zrm0, ztr0, zrm1, ztr1, z0b);
    k_a3v_mfma<<<dim3(NHEAD, NCHUNK), 256, 0, stream>>>(qlb, Kb, Vb, Fb, denP);
    k_a3v_comb<<<NHEAD*NLAND, 64, 0, stream>>>(Fb, denP, a3vb);
    k_sgemm2<0,1><<<dim3(1,4,NHEAD), 256, 0, stream>>>(z0b, a3vb, w2tb, 256,64,256,
                                                       65536,16384,16384, 0.f, 1.f);
    k_a1_mfma<<<dim3(130, NHEAD), 256, 0, stream>>>(Qb, klb, w2tb, Fb);
    k_resconv<<<dim3(130, NHEAD), 256, 0, stream>>>(Vb, resw[L], Fb);
    k_gemm_mfma<2><<<dim3(4, 129), 256, 0, stream>>>(Fb + (size_t)PAD0*CDIM, CDIM,
                                                     outT[L], CDIM, outb[L],
                                                     base[L], nullptr, nullptr, TOK);
    if(L == 0){
      k_ppeg2<<<dim3(64, 32), 256, 0, stream>>>(Ab + CDIM, w7, pb7, w5, pb5, w3, pb3,
                                                Bb + CDIM);
      k_copyrow<<<1, 512, 0, stream>>>(Bb, Ab);
    }
  }
  k_final<<<1, 512, 0, stream>>>(Bb, norm_g, norm_b, fc2_w, fc2_b, (float*)d_out);
}

// Round 10
// 1767.992 us; speedup vs baseline: 1.6294x; 1.6294x over previous
//
#include <hip/hip_runtime.h>
#include <hip/hip_bf16.h>

#define NPAD 16640
#define TOK  16385
#define CDIM 512
#define NHEAD 8
#define DHEAD 64
#define NLAND 256
#define LFAC  65
#define PAD0  255
#define NCHUNK 65   // chunks of 256 rows: 65*256 = 16640

typedef __attribute__((ext_vector_type(8))) short sh8;
typedef __attribute__((ext_vector_type(4))) float f4;

__device__ __forceinline__ float wave_sum(float v){
  #pragma unroll
  for(int o=32;o;o>>=1) v += __shfl_xor(v,o);
  return v;
}
__device__ __forceinline__ float wave_max(float v){
  #pragma unroll
  for(int o=32;o;o>>=1) v = fmaxf(v, __shfl_xor(v,o));
  return v;
}

// bf16 RNE pack helpers
__device__ __forceinline__ unsigned bfbits(float x){
  unsigned u = __float_as_uint(x);
  return (u + 0x7fffu + ((u >> 16) & 1u)) >> 16;
}
__device__ __forceinline__ sh8 pack8f(float4 a, float4 b){
  sh8 r;
  r[0]=(short)bfbits(a.x); r[1]=(short)bfbits(a.y); r[2]=(short)bfbits(a.z); r[3]=(short)bfbits(a.w);
  r[4]=(short)bfbits(b.x); r[5]=(short)bfbits(b.y); r[6]=(short)bfbits(b.z); r[7]=(short)bfbits(b.w);
  return r;
}
#define MFMA16(a,b,c) __builtin_amdgcn_mfma_f32_16x16x32_bf16(a,b,c,0,0,0)

// ---------------- row copy (cls token) ----------------
__global__ void k_copyrow(float* dst, const float* __restrict__ src){
  dst[threadIdx.x] = src[threadIdx.x];
}

// ---------------- layernorm + front pad ----------------
__global__ __launch_bounds__(256) void k_ln_pad(const float* __restrict__ A,
    const float* __restrict__ g, const float* __restrict__ b, float* __restrict__ B){
  int w = threadIdx.x >> 6, lane = threadIdx.x & 63;
  int row = blockIdx.x*4 + w;
  float* out = B + (size_t)row*CDIM;
  if(row < PAD0){
    #pragma unroll
    for(int i=0;i<8;i++) out[lane + i*64] = 0.f;
    return;
  }
  const float* x = A + (size_t)(row-PAD0)*CDIM;
  int c0 = lane*4, c1 = 256 + lane*4;
  float4 v0 = *(const float4*)(x + c0);
  float4 v1 = *(const float4*)(x + c1);
  float xs[8] = {v0.x,v0.y,v0.z,v0.w,v1.x,v1.y,v1.z,v1.w};
  float s = 0;
  #pragma unroll
  for(int i=0;i<8;i++) s += xs[i];
  s = wave_sum(s);
  float mu = s * (1.f/512.f);
  float vs = 0;
  #pragma unroll
  for(int i=0;i<8;i++){ float d = xs[i]-mu; vs += d*d; }
  vs = wave_sum(vs) * (1.f/512.f);
  float rs = rsqrtf(vs + 1e-5f);
  float4 g0 = *(const float4*)(g + c0); float4 g1 = *(const float4*)(g + c1);
  float4 b0 = *(const float4*)(b + c0); float4 b1 = *(const float4*)(b + c1);
  float4 o0, o1;
  o0.x = (xs[0]-mu)*rs*g0.x + b0.x; o0.y = (xs[1]-mu)*rs*g0.y + b0.y;
  o0.z = (xs[2]-mu)*rs*g0.z + b0.z; o0.w = (xs[3]-mu)*rs*g0.w + b0.w;
  o1.x = (xs[4]-mu)*rs*g1.x + b1.x; o1.y = (xs[5]-mu)*rs*g1.y + b1.y;
  o1.z = (xs[6]-mu)*rs*g1.z + b1.z; o1.w = (xs[7]-mu)*rs*g1.w + b1.w;
  *(float4*)(out + c0) = o0;
  *(float4*)(out + c1) = o1;
}

// ---------------- MFMA GEMM: C[M,N] = A[M,K] @ WT[N,K]^T, bf16 inputs ----------------
template<int MODE>
__global__ __launch_bounds__(256) void k_gemm_mfma(const float* __restrict__ A, int lda,
    const float* __restrict__ WT, int K, const float* __restrict__ bias,
    float* out0, float* out1, float* out2, int M){
  __shared__ short As[128*32];
  __shared__ short Bs[128*32];
  int t = threadIdx.x, lane = t & 63, wv = t >> 6, g = lane >> 4, l15 = lane & 15;
  int row0 = blockIdx.y*128, n0 = blockIdx.x*128;
  int wm = (wv>>1)*64, wn = (wv&1)*64;
  f4 acc[4][4] = {};
  for(int k0 = 0; k0 < K; k0 += 32){
    #pragma unroll
    for(int u=0; u<2; u++){
      int gi = t + u*256;               // 512 granules of 8 elems
      int m = gi >> 2, kb = (gi & 3) * 8;
      float4 va = make_float4(0,0,0,0), vb = make_float4(0,0,0,0);
      int gr = row0 + m;
      if(gr < M){
        va = *(const float4*)(A + (size_t)gr*lda + k0 + kb);
        vb = *(const float4*)(A + (size_t)gr*lda + k0 + kb + 4);
      }
      int swz = (((m&3) ^ ((m>>2)&3)) << 4);
      *(sh8*)((char*)As + m*64 + ((kb*2) ^ swz)) = pack8f(va, vb);
      float4 wa = *(const float4*)(WT + (size_t)(n0+m)*K + k0 + kb);
      float4 wb = *(const float4*)(WT + (size_t)(n0+m)*K + k0 + kb + 4);
      *(sh8*)((char*)Bs + m*64 + ((kb*2) ^ swz)) = pack8f(wa, wb);
    }
    __syncthreads();
    sh8 af[4], bf[4];
    #pragma unroll
    for(int mt=0; mt<4; mt++){
      int r = wm + mt*16 + l15;
      af[mt] = *(sh8*)((char*)As + r*64 + ((g*16) ^ (((r&3)^((r>>2)&3))<<4)));
    }
    #pragma unroll
    for(int nt=0; nt<4; nt++){
      int r = wn + nt*16 + l15;
      bf[nt] = *(sh8*)((char*)Bs + r*64 + ((g*16) ^ (((r&3)^((r>>2)&3))<<4)));
    }
    #pragma unroll
    for(int mt=0; mt<4; mt++)
      #pragma unroll
      for(int nt=0; nt<4; nt++)
        acc[mt][nt] = MFMA16(af[mt], bf[nt], acc[mt][nt]);
    __syncthreads();
  }
  #pragma unroll
  for(int mt=0; mt<4; mt++){
    #pragma unroll
    for(int r=0; r<4; r++){
      int gm = row0 + wm + mt*16 + g*4 + r;
      if(gm >= M) continue;
      #pragma unroll
      for(int nt=0; nt<4; nt++){
        int gn = n0 + wn + nt*16 + l15;
        float v = acc[mt][nt][r];
        if(MODE == 0){
          v += bias[gn];
          out0[(size_t)gm*CDIM + gn] = v > 0.f ? v : 0.f;
        } else if(MODE == 1){
          int p = gn >> 9, rr = gn & 511;
          int hh = rr >> 6, dd = rr & 63;
          if(p == 0) v *= 0.125f;
          float* dst = (p==0) ? out0 : (p==1 ? out1 : out2);
          dst[((size_t)hh*NPAD + gm)*DHEAD + dd] = v;
        } else {
          out0[(size_t)gm*CDIM + gn] += v + bias[gn];
        }
      }
    }
  }
}

// ---------------- landmark means ----------------
__global__ void k_landmark(const float* __restrict__ src, float* __restrict__ dst){
  int bidx = blockIdx.x;               // h*256 + m
  int h = bidx >> 8, m = bidx & 255, d = threadIdx.x;
  const float* p = src + ((size_t)h*NPAD + (size_t)m*LFAC)*DHEAD + d;
  float s = 0;
  for(int j=0;j<LFAC;j++) s += p[(size_t)j*DHEAD];
  dst[(size_t)bidx*DHEAD + d] = s * (1.f/LFAC);
}

// ---------------- a2 = softmax(ql @ kl^T) ----------------
__global__ __launch_bounds__(256) void k_a2(const float* __restrict__ ql,
    const float* __restrict__ kl, float* __restrict__ a2){
  __shared__ __hip_bfloat16 klt[64*256];  // [d][m]
  int h = blockIdx.y;
  int t = threadIdx.x;
  const float* klh = kl + (size_t)h*NLAND*DHEAD;
  for(int r=0;r<64;r++){
    int idx = r*256 + t;
    int d = idx >> 8, m = idx & 255;
    klt[idx] = __float2bfloat16(klh[m*DHEAD + d]);
  }
  __syncthreads();
  int w = t >> 6, lane = t & 63;
  const float* qlh = ql + (size_t)h*NLAND*DHEAD;
  for(int rr=0; rr<16; rr++){
    int m = blockIdx.x*64 + w*16 + rr;
    const float* q = qlh + (size_t)m*DHEAD;
    float s[4] = {0,0,0,0};
    #pragma unroll
    for(int d=0; d<64; d++){
      float qv = q[d];
      #pragma unroll
      for(int qd=0; qd<4; qd++)
        s[qd] += qv * __bfloat162float(klt[d*256 + qd*64 + lane]);
    }
    float e[4], den = 0.f;
    #pragma unroll
    for(int qd=0; qd<4; qd++){ e[qd] = __expf(s[qd]); den += e[qd]; }
    den = wave_sum(den);
    float inv = 1.f/den;
    float* arow = a2 + ((size_t)h*NLAND + m)*NLAND;
    #pragma unroll
    for(int qd=0; qd<4; qd++) arow[qd*64 + lane] = e[qd]*inv;
  }
}

// ---------------- pinv init ----------------
__global__ void k_colmax(const float* __restrict__ a2, float* __restrict__ hmax){
  __shared__ float red[4];
  int h = blockIdx.x, t = threadIdx.x;
  const float* p = a2 + (size_t)h*65536 + t;
  float s = 0;
  for(int m=0;m<256;m++) s += p[(size_t)m*256];
  float mx = wave_max(s);
  if((t & 63) == 0) red[t>>6] = mx;
  __syncthreads();
  if(t == 0) hmax[h] = fmaxf(fmaxf(red[0],red[1]), fmaxf(red[2],red[3]));
}
__global__ void k_scal(const float* __restrict__ hmax, float* __restrict__ scal){
  int t = threadIdx.x;
  float v = (t < 8) ? hmax[t] : -1e30f;
  v = wave_max(v);
  if(t == 0) scal[0] = v;
}
__global__ void k_zinit(const float* __restrict__ a2, const float* __restrict__ scal,
                        float* __restrict__ z){
  int h = blockIdx.y;
  int idx = blockIdx.x*256 + threadIdx.x;
  int m = idx >> 8, j = idx & 255;
  z[(size_t)h*65536 + idx] = a2[(size_t)h*65536 + (size_t)j*256 + m] / scal[0];
}

// ---------------- batched f32 GEMM 64x64 tile, 4x4/thread ----------------
// TRANS: B := alpha*I - B on load.  OUTT: write C transposed.  C = beta * (A@B')
template<int TRANS, int OUTT>
__global__ __launch_bounds__(256) void k_sgemm2(const float* __restrict__ A,
    const float* __restrict__ B, float* __restrict__ C,
    int M, int N, int K, long sA, long sB, long sC, float alpha, float beta){
  __shared__ float As[32][68];
  __shared__ float Bs[32][68];
  int bh = blockIdx.z;
  const float* Ah = A + (size_t)bh*sA;
  const float* Bh = B + (size_t)bh*sB;
  float* Ch = C + (size_t)bh*sC;
  int m0 = blockIdx.y*64, n0 = blockIdx.x*64;
  int t = threadIdx.x, tx = t & 15, ty = t >> 4;
  float acc[4][4] = {};
  for(int k0=0; k0<K; k0+=32){
    #pragma unroll
    for(int u=0; u<2; u++){
      int idx = t + u*256;
      int r = idx >> 3, cb = (idx & 7) * 4;
      float4 va = *(const float4*)(Ah + (size_t)(m0+r)*K + k0 + cb);
      As[cb+0][r]=va.x; As[cb+1][r]=va.y; As[cb+2][r]=va.z; As[cb+3][r]=va.w;
      int kr = idx >> 4, nb = (idx & 15) * 4;
      float4 w = *(const float4*)(Bh + (size_t)(k0+kr)*N + n0 + nb);
      if(TRANS){
        int gk = k0 + kr;
        w.x = ((gk==n0+nb+0)?alpha:0.f) - w.x;
        w.y = ((gk==n0+nb+1)?alpha:0.f) - w.y;
        w.z = ((gk==n0+nb+2)?alpha:0.f) - w.z;
        w.w = ((gk==n0+nb+3)?alpha:0.f) - w.w;
      }
      *(float4*)&Bs[kr][nb] = w;
    }
    __syncthreads();
    #pragma unroll
    for(int k=0;k<32;k++){
      float a[4], b[4];
      *(float4*)a = *(const float4*)&As[k][ty*4];
      *(float4*)b = *(const float4*)&Bs[k][tx*4];
      #pragma unroll
      for(int i=0;i<4;i++)
        #pragma unroll
        for(int j=0;j<4;j++) acc[i][j] += a[i]*b[j];
    }
    __syncthreads();
  }
  #pragma unroll
  for(int i=0;i<4;i++){
    #pragma unroll
    for(int j=0;j<4;j++){
      int gm = m0 + ty*4 + i, gn = n0 + tx*4 + j;
      float v = acc[i][j] * beta;
      if(OUTT) Ch[(size_t)gn*M + gm] = v;
      else     Ch[(size_t)gm*N + gn] = v;
    }
  }
}

// ---------------- MFMA flash a1 ----------------
__global__ __launch_bounds__(256) void k_a1_mfma(const float* __restrict__ Qb,
    const float* __restrict__ kl, const float* __restrict__ w2t, float* __restrict__ F){
  __shared__ short klL[128*64];
  __shared__ short w2L[64*128];
  __shared__ short pL[4][16*128];
  int h = blockIdx.y, n0 = blockIdx.x*128;
  int t = threadIdx.x, lane = t & 63, wv = t >> 6, g = lane >> 4, l15 = lane & 15;
  const float* klh = kl + (size_t)h*NLAND*DHEAD;
  const float* w2h = w2t + (size_t)h*DHEAD*NLAND;
  const float* qbase = Qb + (size_t)h*NPAD*DHEAD;
  sh8 aQ[2][2];
  #pragma unroll
  for(int st=0; st<2; st++)
    #pragma unroll
    for(int kk=0; kk<2; kk++){
      const float* p = qbase + (size_t)(n0 + wv*32 + st*16 + l15)*DHEAD + kk*32 + g*8;
      aQ[st][kk] = pack8f(*(const float4*)p, *(const float4*)(p+4));
    }
  f4 accO[2][4] = {};
  float den[2][4] = {};
  short* pw = pL[wv];
  for(int half=0; half<2; half++){
    __syncthreads();
    #pragma unroll
    for(int it=0; it<4; it++){
      int gi = t + it*256;
      int m = gi >> 3, db = (gi & 7) * 8;
      const float* p = klh + (size_t)(half*128 + m)*DHEAD + db;
      *(sh8*)((char*)klL + m*128 + ((db*2) ^ ((m&7)<<4))) =
          pack8f(*(const float4*)p, *(const float4*)(p+4));
      int d = gi >> 4, mb = (gi & 15) * 8;
      const float* p2 = w2h + (size_t)d*NLAND + half*128 + mb;
      *(sh8*)((char*)w2L + d*256 + ((mb*2) ^ ((d&7)<<4))) =
          pack8f(*(const float4*)p2, *(const float4*)(p2+4));
    }
    __syncthreads();
    #pragma unroll
    for(int st=0; st<2; st++){
      #pragma unroll
      for(int mt=0; mt<8; mt++){
        f4 s = {};
        #pragma unroll
        for(int kk=0; kk<2; kk++){
          int m = mt*16 + l15;
          sh8 b = *(sh8*)((char*)klL + m*128 + ((kk*64 + g*16) ^ ((m&7)<<4)));
          s = MFMA16(aQ[st][kk], b, s);
        }
        #pragma unroll
        for(int r=0; r<4; r++){
          float e = __expf(s[r]);
          den[st][r] += e;
          int n = g*4 + r;
          *(short*)((char*)pw + n*256 + (((mt*16+l15)*2) ^ ((n&7)<<4))) = (short)bfbits(e);
        }
      }
      __syncthreads();
      #pragma unroll
      for(int ks=0; ks<4; ks++){
        sh8 aP = *(sh8*)((char*)pw + l15*256 + ((ks*64 + g*16) ^ ((l15&7)<<4)));
        #pragma unroll
        for(int dt=0; dt<4; dt++){
          int d = dt*16 + l15;
          sh8 bW = *(sh8*)((char*)w2L + d*256 + ((ks*64 + g*16) ^ ((d&7)<<4)));
          accO[st][dt] = MFMA16(aP, bW, accO[st][dt]);
        }
      }
      __syncthreads();
    }
  }
  #pragma unroll
  for(int st=0; st<2; st++)
    #pragma unroll
    for(int r=0; r<4; r++){
      float d_ = den[st][r];
      d_ += __shfl_xor(d_,1); d_ += __shfl_xor(d_,2);
      d_ += __shfl_xor(d_,4); d_ += __shfl_xor(d_,8);
      den[st][r] = 1.f/d_;
    }
  #pragma unroll
  for(int st=0; st<2; st++)
    #pragma unroll
    for(int dt=0; dt<4; dt++)
      #pragma unroll
      for(int r=0; r<4; r++){
        int row = n0 + wv*32 + st*16 + g*4 + r;
        F[(size_t)row*CDIM + h*DHEAD + dt*16 + l15] = accO[st][dt][r]*den[st][r];
      }
}

// ---------------- MFMA flash a3v (256 threads) ----------------
__global__ __launch_bounds__(256) void k_a3v_mfma(const float* __restrict__ ql,
    const float* __restrict__ Kb, const float* __restrict__ Vb,
    float* __restrict__ numP, float* __restrict__ denP){
  __shared__ short kL[128*64];
  __shared__ short vL[64*128];
  __shared__ short pL[4][16*128];
  int h = blockIdx.x, c = blockIdx.y;
  int t = threadIdx.x, lane = t & 63, wv = t >> 6, g = lane >> 4, l15 = lane & 15;
  const float* qlh = ql + (size_t)h*NLAND*DHEAD;
  sh8 aQ[4][2];
  #pragma unroll
  for(int st=0; st<4; st++)
    #pragma unroll
    for(int kk=0; kk<2; kk++){
      const float* p = qlh + (size_t)(wv*64 + st*16 + l15)*DHEAD + kk*32 + g*8;
      aQ[st][kk] = pack8f(*(const float4*)p, *(const float4*)(p+4));
    }
  f4 accO[4][4] = {};
  float den[4][4] = {};
  short* pw = pL[wv];
  for(int half=0; half<2; half++){
    const float* Kh = Kb + ((size_t)h*NPAD + (size_t)c*256 + half*128)*DHEAD;
    const float* Vh = Vb + ((size_t)h*NPAD + (size_t)c*256 + half*128)*DHEAD;
    __syncthreads();
    #pragma unroll
    for(int it=0; it<4; it++){
      int gi = t + it*256;
      int m = gi >> 3, db = (gi & 7) * 8;
      const float* p = Kh + (size_t)m*DHEAD + db;
      *(sh8*)((char*)kL + m*128 + ((db*2) ^ ((m&7)<<4))) =
          pack8f(*(const float4*)p, *(const float4*)(p+4));
    }
    #pragma unroll
    for(int it=0; it<8; it++){
      int idx = t + it*256;
      int m = idx & 127, d0 = (idx >> 7) * 4;
      float4 v = *(const float4*)(Vh + (size_t)m*DHEAD + d0);
      float vv[4] = {v.x, v.y, v.z, v.w};
      #pragma unroll
      for(int i=0;i<4;i++){
        int d = d0 + i;
        *(short*)((char*)vL + d*256 + ((m*2) ^ ((d&7)<<4))) = (short)bfbits(vv[i]);
      }
    }
    __syncthreads();
    #pragma unroll
    for(int st=0; st<4; st++){
      #pragma unroll
      for(int mt=0; mt<8; mt++){
        f4 s = {};
        #pragma unroll
        for(int kk=0; kk<2; kk++){
          int m = mt*16 + l15;
          sh8 b = *(sh8*)((char*)kL + m*128 + ((kk*64 + g*16) ^ ((m&7)<<4)));
          s = MFMA16(aQ[st][kk], b, s);
        }
        #pragma unroll
        for(int r=0; r<4; r++){
          float e = __expf(s[r]);
          den[st][r] += e;
          int n = g*4 + r;
          *(short*)((char*)pw + n*256 + (((mt*16+l15)*2) ^ ((n&7)<<4))) = (short)bfbits(e);
        }
      }
      __syncthreads();
      #pragma unroll
      for(int ks=0; ks<4; ks++){
        sh8 aP = *(sh8*)((char*)pw + l15*256 + ((ks*64 + g*16) ^ ((l15&7)<<4)));
        #pragma unroll
        for(int dt=0; dt<4; dt++){
          int d = dt*16 + l15;
          sh8 bV = *(sh8*)((char*)vL + d*256 + ((ks*64 + g*16) ^ ((d&7)<<4)));
          accO[st][dt] = MFMA16(aP, bV, accO[st][dt]);
        }
      }
      __syncthreads();
    }
  }
  #pragma unroll
  for(int st=0; st<4; st++)
    #pragma unroll
    for(int r=0; r<4; r++){
      float d_ = den[st][r];
      d_ += __shfl_xor(d_,1); d_ += __shfl_xor(d_,2);
      d_ += __shfl_xor(d_,4); d_ += __shfl_xor(d_,8);
      den[st][r] = d_;
    }
  size_t base = ((size_t)h*NCHUNK + c)*NLAND;
  #pragma unroll
  for(int st=0; st<4; st++){
    #pragma unroll
    for(int r=0; r<4; r++){
      int row = wv*64 + st*16 + g*4 + r;
      if(l15 == 0) denP[base + row] = den[st][r];
      #pragma unroll
      for(int dt=0; dt<4; dt++)
        numP[(base + row)*DHEAD + dt*16 + l15] = accO[st][dt][r];
    }
  }
}

__global__ void k_a3v_comb(const float* __restrict__ numP, const float* __restrict__ denP,
                           float* __restrict__ a3v){
  int bidx = blockIdx.x;           // h*256 + m
  int h = bidx >> 8, m = bidx & 255;
  int d = threadIdx.x;
  float s = 0.f, den = 0.f;
  for(int c=0;c<NCHUNK;c++){
    s += numP[(((size_t)h*NCHUNK + c)*NLAND + m)*DHEAD + d];
    den += denP[((size_t)h*NCHUNK + c)*NLAND + m];
  }
  a3v[((size_t)h*NLAND + m)*DHEAD + d] = s / den;
}

// ---------------- residual depthwise conv (k=33), FIR-tiled ----------------
__global__ __launch_bounds__(256) void k_resconv(const float* __restrict__ Vb,
    const float* __restrict__ rw, float* __restrict__ F){
  __shared__ float vs[160][64];
  int n0 = blockIdx.x*128, h = blockIdx.y;
  int t = threadIdx.x;
  const float* vh = Vb + (size_t)h*NPAD*DHEAD;
  #pragma unroll
  for(int i=0;i<10;i++){
    int idx = t + i*256;
    int r = idx >> 4, dq = (idx & 15)*4;
    int n = n0 - 16 + r;
    float4 v = (n>=0 && n<NPAD) ? *(const float4*)(vh + (size_t)n*DHEAD + dq)
                                : make_float4(0.f,0.f,0.f,0.f);
    *(float4*)&vs[r][dq] = v;
  }
  float w[33];
  #pragma unroll
  for(int j=0;j<33;j++) w[j] = rw[h*33+j];
  __syncthreads();
  int d = t & 63, half = t >> 6;
  float acc[32];
  #pragma unroll
  for(int r=0;r<32;r++) acc[r] = 0.f;
  #pragma unroll
  for(int p=0;p<64;p++){
    float vv = vs[half*32 + p][d];
    #pragma unroll
    for(int j=0;j<33;j++){
      int r = p - j;
      if(r >= 0 && r < 32) acc[r] += w[j]*vv;
    }
  }
  #pragma unroll
  for(int r=0;r<32;r++){
    int n = n0 + half*32 + r;
    F[(size_t)n*CDIM + h*DHEAD + d] += acc[r];
  }
}

// ---------------- transpose (weights only) ----------------
__global__ void k_transpose(const float* __restrict__ in, float* __restrict__ out,
                            int R, int C){
  __shared__ float tile[32][33];
  int r0 = blockIdx.x*32, c0 = blockIdx.y*32;
  int tx = threadIdx.x, ty = threadIdx.y;
  #pragma unroll
  for(int r=0;r<4;r++) tile[ty + r*8][tx] = in[(size_t)(r0 + ty + r*8)*C + c0 + tx];
  __syncthreads();
  #pragma unroll
  for(int r=0;r<4;r++) out[(size_t)(c0 + ty + r*8)*R + r0 + tx] = tile[tx][ty + r*8];
}

// ---------------- PPEG direct on row-major [n][c] ----------------
__global__ __launch_bounds__(256) void k_ppeg2(const float* __restrict__ X,
    const float* __restrict__ w7, const float* __restrict__ b7,
    const float* __restrict__ w5, const float* __restrict__ b5,
    const float* __restrict__ w3, const float* __restrict__ b3,
    float* __restrict__ Y){
  __shared__ float patch[484][20];
  int cg = blockIdx.y;
  int ti = blockIdx.x >> 3, tj = blockIdx.x & 7;
  int t = threadIdx.x;
  int i0 = ti*16 - 3, j0 = tj*16 - 3;
  for(int idx = t; idx < 1936; idx += 256){
    int p = idx >> 2, cq = (idx & 3) * 4;
    int gi = i0 + p/22, gj = j0 + p%22;
    float4 v = make_float4(0.f,0.f,0.f,0.f);
    if(gi>=0 && gi<128 && gj>=0 && gj<128)
      v = *(const float4*)(X + (size_t)(gi*128+gj)*CDIM + cg*16 + cq);
    *(float4*)&patch[p][cq] = v;
  }
  int c = t & 15, sg = t >> 4;
  int cglob = cg*16 + c;
  float wr[83];
  #pragma unroll
  for(int k=0;k<49;k++) wr[k] = w7[cglob*49+k];
  #pragma unroll
  for(int k=0;k<25;k++) wr[49+k] = w5[cglob*25+k];
  #pragma unroll
  for(int k=0;k<9;k++)  wr[74+k] = w3[cglob*9+k];
  float bsum = b7[cglob] + b5[cglob] + b3[cglob];
  __syncthreads();
  float acc[16];
  #pragma unroll
  for(int j=0;j<16;j++) acc[j] = patch[(sg+3)*22 + (j+3)][c] + bsum;
  #pragma unroll
  for(int a=0;a<7;a++)
    #pragma unroll
    for(int x=0;x<22;x++){
      float vv = patch[(sg+a)*22 + x][c];
      #pragma unroll
      for(int bq=0;bq<7;bq++){
        int j = x - bq;
        if(j>=0 && j<16) acc[j] += wr[a*7+bq]*vv;
      }
    }
  #pragma unroll
  for(int a=0;a<5;a++)
    #pragma unroll
    for(int x=1;x<21;x++){
      float vv = patch[(sg+a+1)*22 + x][c];
      #pragma unroll
      for(int bq=0;bq<5;bq++){
        int j = x - 1 - bq;
        if(j>=0 && j<16) acc[j] += wr[49+a*5+bq]*vv;
      }
    }
  #pragma unroll
  for(int a=0;a<3;a++)
    #pragma unroll
    for(int x=2;x<20;x++){
      float vv = patch[(sg+a+2)*22 + x][c];
      #pragma unroll
      for(int bq=0;bq<3;bq++){
        int j = x - 2 - bq;
        if(j>=0 && j<16) acc[j] += wr[74+a*3+bq]*vv;
      }
    }
  #pragma unroll
  for(int j=0;j<16;j++)
    Y[(size_t)((ti*16+sg)*128 + tj*16+j)*CDIM + cglob] = acc[j];
}

// ---------------- final LN(row0) + fc2 ----------------
__global__ __launch_bounds__(512) void k_final(const float* __restrict__ A,
    const float* __restrict__ g, const float* __restrict__ b,
    const float* __restrict__ w, const float* __restrict__ bias,
    float* __restrict__ outp){
  __shared__ float red[8];
  int t = threadIdx.x, wv = t >> 6;
  float x = A[t];
  float s = wave_sum(x);
  if((t & 63) == 0) red[wv] = s;
  __syncthreads();
  float mu = 0;
  #pragma unroll
  for(int i=0;i<8;i++) mu += red[i];
  mu *= (1.f/512.f);
  __syncthreads();
  float dx = x - mu;
  s = wave_sum(dx*dx);
  if((t & 63) == 0) red[wv] = s;
  __syncthreads();
  float var = 0;
  #pragma unroll
  for(int i=0;i<8;i++) var += red[i];
  var *= (1.f/512.f);
  float xn = dx * rsqrtf(var + 1e-5f) * g[t] + b[t];
  __syncthreads();
  for(int o=0;o<4;o++){
    s = wave_sum(xn * w[t*4 + o]);
    if((t & 63) == 0) red[wv] = s;
    __syncthreads();
    if(t == 0){
      float r = 0;
      #pragma unroll
      for(int i=0;i<8;i++) r += red[i];
      outp[o] = r + bias[o];
    }
    __syncthreads();
  }
}

extern "C" void kernel_launch(void* const* d_in, const int* in_sizes, int n_in,
                              void* d_out, int out_size, void* d_ws, size_t ws_size,
                              hipStream_t stream) {
  (void)in_sizes; (void)n_in; (void)out_size; (void)ws_size;
  const float* data_x = (const float*)d_in[0];
  const float* fc1_w  = (const float*)d_in[1];
  const float* fc1_b  = (const float*)d_in[2];
  const float* cls_tk = (const float*)d_in[3];
  const float* ng[2]  = {(const float*)d_in[4],  (const float*)d_in[16]};
  const float* nb[2]  = {(const float*)d_in[5],  (const float*)d_in[17]};
  const float* qkvw[2]= {(const float*)d_in[6],  (const float*)d_in[18]};
  const float* outw[2]= {(const float*)d_in[7],  (const float*)d_in[19]};
  const float* outb[2]= {(const float*)d_in[8],  (const float*)d_in[20]};
  const float* resw[2]= {(const float*)d_in[9],  (const float*)d_in[21]};
  const float* w7 = (const float*)d_in[10]; const float* pb7 = (const float*)d_in[11];
  const float* w5 = (const float*)d_in[12]; const float* pb5 = (const float*)d_in[13];
  const float* w3 = (const float*)d_in[14]; const float* pb3 = (const float*)d_in[15];
  const float* norm_g = (const float*)d_in[22];
  const float* norm_b = (const float*)d_in[23];
  const float* fc2_w  = (const float*)d_in[24];
  const float* fc2_b  = (const float*)d_in[25];

  float* ws = (float*)d_ws;
  float* Ab   = ws;                         // 16385*512 (layer-0 h base)
  float* Bb   = Ab + (size_t)TOK*CDIM;      // L0 ln-out; post-ppeg h base
  float* Qb   = Bb + (size_t)NPAD*CDIM;
  float* Kb   = Qb + (size_t)NPAD*CDIM;
  float* Vb   = Kb + (size_t)NPAD*CDIM;
  float* Fb   = Vb + (size_t)NPAD*CDIM;     // L1 ln-out; a3v numP scratch; pre-proj F
  float* qlb  = Fb + (size_t)NPAD*CDIM;     // 8*256*64
  float* klb  = qlb + NHEAD*NLAND*DHEAD;
  float* a2b  = klb + NHEAD*NLAND*DHEAD;    // 8*256*256 f32
  float* z0b  = a2b + NHEAD*NLAND*NLAND;
  float* z1b  = z0b + NHEAD*NLAND*NLAND;
  float* Xb_  = z1b + NHEAD*NLAND*NLAND;
  float* Tb_  = Xb_ + NHEAD*NLAND*NLAND;
  float* Ub_  = Tb_ + NHEAD*NLAND*NLAND;
  float* a3vb = Ub_ + NHEAD*NLAND*NLAND;    // 8*256*64
  float* w2tb = a3vb + NHEAD*NLAND*DHEAD;   // 8*64*256 (transposed w2)
  float* denP = w2tb + NHEAD*DHEAD*NLAND;   // 8*65*256
  float* hmax = denP + NHEAD*NCHUNK*NLAND;  // 8
  float* scal = hmax + 8;                   // 1
  float* fc1T = scal + 8;                   // 512*1024
  float* qkvT0= fc1T + 512*1024;            // 1536*512
  float* qkvT1= qkvT0 + 1536*512;
  float* outT0= qkvT1 + 1536*512;           // 512*512
  float* outT1= outT0 + 512*512;
  float* qkvT[2] = {qkvT0, qkvT1};
  float* outT[2] = {outT0, outT1};

  // weight transposes (WT[n][k])
  k_transpose<<<dim3(32,16), dim3(32,8), 0, stream>>>(fc1_w, fc1T, 1024, 512);
  k_transpose<<<dim3(16,48), dim3(32,8), 0, stream>>>(qkvw[0], qkvT0, 512, 1536);
  k_transpose<<<dim3(16,48), dim3(32,8), 0, stream>>>(qkvw[1], qkvT1, 512, 1536);
  k_transpose<<<dim3(16,16), dim3(32,8), 0, stream>>>(outw[0], outT0, 512, 512);
  k_transpose<<<dim3(16,16), dim3(32,8), 0, stream>>>(outw[1], outT1, 512, 512);

  k_copyrow<<<1, 512, 0, stream>>>(Ab, cls_tk);
  k_gemm_mfma<0><<<dim3(4, 128), 256, 0, stream>>>(data_x, 1024, fc1T, 1024, fc1_b,
                                                   Ab + CDIM, nullptr, nullptr, 16384);
  float* base[2]  = {Ab, Bb};
  float* lnout[2] = {Bb, Fb};
  for(int L=0; L<2; L++){
    k_ln_pad<<<NPAD/4, 256, 0, stream>>>(base[L], ng[L], nb[L], lnout[L]);
    k_gemm_mfma<1><<<dim3(12, 130), 256, 0, stream>>>(lnout[L], CDIM, qkvT[L], CDIM, nullptr,
                                                      Qb, Kb, Vb, NPAD);
    k_landmark<<<NHEAD*NLAND, 64, 0, stream>>>(Qb, qlb);
    k_landmark<<<NHEAD*NLAND, 64, 0, stream>>>(Kb, klb);
    k_a2<<<dim3(4, NHEAD), 256, 0, stream>>>(qlb, klb, a2b);
    k_colmax<<<NHEAD, 256, 0, stream>>>(a2b, hmax);
    k_scal<<<1, 64, 0, stream>>>(hmax, scal);
    k_zinit<<<dim3(256, NHEAD), 256, 0, stream>>>(a2b, scal, z0b);
    float* zc = z0b; float* zn = z1b;
    for(int it=0; it<6; it++){
      // X = a2 @ z
      k_sgemm2<0,0><<<dim3(4,4,NHEAD), 256, 0, stream>>>(a2b, zc, Xb_, 256,256,256,
                                                         65536,65536,65536, 0.f, 1.f);
      // T = X @ (7I - X)
      k_sgemm2<1,0><<<dim3(4,4,NHEAD), 256, 0, stream>>>(Xb_, Xb_, Tb_, 256,256,256,
                                                         65536,65536,65536, 7.f, 1.f);
      // U = X @ (15I - T)
      k_sgemm2<1,0><<<dim3(4,4,NHEAD), 256, 0, stream>>>(Xb_, Tb_, Ub_, 256,256,256,
                                                         65536,65536,65536, 15.f, 1.f);
      // zn = 0.25 * z @ (13I - U)
      k_sgemm2<1,0><<<dim3(4,4,NHEAD), 256, 0, stream>>>(zc, Ub_, zn, 256,256,256,
                                                         65536,65536,65536, 13.f, 0.25f);
      float* tmp = zc; zc = zn; zn = tmp;
    }
    // zc == z0b after 6 iterations
    k_a3v_mfma<<<dim3(NHEAD, NCHUNK), 256, 0, stream>>>(qlb, Kb, Vb, Fb, denP);
    k_a3v_comb<<<NHEAD*NLAND, 64, 0, stream>>>(Fb, denP, a3vb);
    k_sgemm2<0,1><<<dim3(1,4,NHEAD), 256, 0, stream>>>(zc, a3vb, w2tb, 256,64,256,
                                                       65536,16384,16384, 0.f, 1.f);
    k_a1_mfma<<<dim3(130, NHEAD), 256, 0, stream>>>(Qb, klb, w2tb, Fb);
    k_resconv<<<dim3(130, NHEAD), 256, 0, stream>>>(Vb, resw[L], Fb);
    k_gemm_mfma<2><<<dim3(4, 129), 256, 0, stream>>>(Fb + (size_t)PAD0*CDIM, CDIM,
                                                     outT[L], CDIM, outb[L],
                                                     base[L], nullptr, nullptr, TOK);
    if(L == 0){
      k_ppeg2<<<dim3(64, 32), 256, 0, stream>>>(Ab + CDIM, w7, pb7, w5, pb5, w3, pb3,
                                                Bb + CDIM);
      k_copyrow<<<1, 512, 0, stream>>>(Bb, Ab);
    }
  }
  k_final<<<1, 512, 0, stream>>>(Bb, norm_g, norm_b, fc2_w, fc2_b, (float*)d_out);
}

// Round 11
// 1645.695 us; speedup vs baseline: 1.7505x; 1.0743x over previous
//
#include <hip/hip_runtime.h>
#include <hip/hip_bf16.h>

#define NPAD 16640
#define TOK  16385
#define CDIM 512
#define NHEAD 8
#define DHEAD 64
#define NLAND 256
#define LFAC  65
#define PAD0  255
#define NCHUNK 65   // chunks of 256 rows: 65*256 = 16640

typedef __attribute__((ext_vector_type(8))) short sh8;
typedef __attribute__((ext_vector_type(4))) float f4;

__device__ __forceinline__ float wave_sum(float v){
  #pragma unroll
  for(int o=32;o;o>>=1) v += __shfl_xor(v,o);
  return v;
}
__device__ __forceinline__ float wave_max(float v){
  #pragma unroll
  for(int o=32;o;o>>=1) v = fmaxf(v, __shfl_xor(v,o));
  return v;
}

// bf16 RNE pack helpers
__device__ __forceinline__ unsigned bfbits(float x){
  unsigned u = __float_as_uint(x);
  return (u + 0x7fffu + ((u >> 16) & 1u)) >> 16;
}
__device__ __forceinline__ float bf2f(short s){
  return __uint_as_float(((unsigned)(unsigned short)s) << 16);
}
__device__ __forceinline__ sh8 pack8f(float4 a, float4 b){
  sh8 r;
  r[0]=(short)bfbits(a.x); r[1]=(short)bfbits(a.y); r[2]=(short)bfbits(a.z); r[3]=(short)bfbits(a.w);
  r[4]=(short)bfbits(b.x); r[5]=(short)bfbits(b.y); r[6]=(short)bfbits(b.z); r[7]=(short)bfbits(b.w);
  return r;
}
#define MFMA16(a,b,c) __builtin_amdgcn_mfma_f32_16x16x32_bf16(a,b,c,0,0,0)

// ---------------- row copy (cls token) ----------------
__global__ void k_copyrow(float* dst, const float* __restrict__ src){
  dst[threadIdx.x] = src[threadIdx.x];
}

// ---------------- layernorm + front pad -> bf16 ----------------
__global__ __launch_bounds__(256) void k_ln_pad(const float* __restrict__ A,
    const float* __restrict__ g, const float* __restrict__ b, short* __restrict__ B){
  int w = threadIdx.x >> 6, lane = threadIdx.x & 63;
  int row = blockIdx.x*4 + w;
  short* out = B + (size_t)row*CDIM;
  int c = lane*8;
  if(row < PAD0){
    sh8 z = {0,0,0,0,0,0,0,0};
    *(sh8*)(out + c) = z;
    return;
  }
  const float* x = A + (size_t)(row-PAD0)*CDIM;
  float4 v0 = *(const float4*)(x + c);
  float4 v1 = *(const float4*)(x + c + 4);
  float xs[8] = {v0.x,v0.y,v0.z,v0.w,v1.x,v1.y,v1.z,v1.w};
  float s = 0;
  #pragma unroll
  for(int i=0;i<8;i++) s += xs[i];
  s = wave_sum(s);
  float mu = s * (1.f/512.f);
  float vs = 0;
  #pragma unroll
  for(int i=0;i<8;i++){ float d = xs[i]-mu; vs += d*d; }
  vs = wave_sum(vs) * (1.f/512.f);
  float rs = rsqrtf(vs + 1e-5f);
  float4 g0 = *(const float4*)(g + c); float4 g1 = *(const float4*)(g + c + 4);
  float4 b0 = *(const float4*)(b + c); float4 b1 = *(const float4*)(b + c + 4);
  float gg[8] = {g0.x,g0.y,g0.z,g0.w,g1.x,g1.y,g1.z,g1.w};
  float bb[8] = {b0.x,b0.y,b0.z,b0.w,b1.x,b1.y,b1.z,b1.w};
  sh8 o;
  #pragma unroll
  for(int i=0;i<8;i++) o[i] = (short)bfbits((xs[i]-mu)*rs*gg[i] + bb[i]);
  *(sh8*)(out + c) = o;
}

// ---------------- MFMA GEMM: C[M,N] = A[M,K] @ WT[N,K]^T ----------------
// A: bf16 (ABF16=1) or f32. WT: bf16. XCD-chunked block swizzle (m-major work
// order: one m-row's n-blocks share one XCD's L2 -> A panel fetched once/XCD).
// MODE 0: fc1 relu(acc+bias)->f32 ; MODE 1: qkv scatter head-major bf16, q*0.125 ;
// MODE 2: proj f32 += acc+bias
template<int MODE, int ABF16>
__global__ __launch_bounds__(256) void k_gemm_mfma(const void* __restrict__ Av, int lda,
    const short* __restrict__ WT, int K, const float* __restrict__ bias,
    void* out0v, void* out1v, void* out2v, int M){
  __shared__ short As[128*32];
  __shared__ short Bs[128*32];
  int t = threadIdx.x, lane = t & 63, wv = t >> 6, g = lane >> 4, l15 = lane & 15;
  // bijective XCD-chunk remap (m204): dispatch b -> XCD b%8; give each XCD a
  // contiguous chunk of m-major work.
  int nwg = gridDim.x * gridDim.y;
  int orig = blockIdx.y * gridDim.x + blockIdx.x;
  int qc = nwg >> 3, rc = nwg & 7, xcd = orig & 7, loc = orig >> 3;
  int wgid = (xcd < rc ? xcd*(qc+1) : rc*(qc+1) + (xcd - rc)*qc) + loc;
  int row0 = (wgid / gridDim.x) * 128, n0 = (wgid % gridDim.x) * 128;
  int wm = (wv>>1)*64, wn = (wv&1)*64;
  f4 acc[4][4] = {};
  for(int k0 = 0; k0 < K; k0 += 32){
    #pragma unroll
    for(int u=0; u<2; u++){
      int gi = t + u*256;               // 512 granules of 8 elems
      int m = gi >> 2, kb = (gi & 3) * 8;
      int swz = (((m&3) ^ ((m>>2)&3)) << 4);
      sh8 av = {0,0,0,0,0,0,0,0};
      int gr = row0 + m;
      if(ABF16){
        const short* A = (const short*)Av;
        if(gr < M) av = *(const sh8*)(A + (size_t)gr*lda + k0 + kb);
      } else {
        const float* A = (const float*)Av;
        if(gr < M){
          float4 va = *(const float4*)(A + (size_t)gr*lda + k0 + kb);
          float4 vb = *(const float4*)(A + (size_t)gr*lda + k0 + kb + 4);
          av = pack8f(va, vb);
        }
      }
      *(sh8*)((char*)As + m*64 + ((kb*2) ^ swz)) = av;
      sh8 wv8 = *(const sh8*)(WT + (size_t)(n0+m)*K + k0 + kb);
      *(sh8*)((char*)Bs + m*64 + ((kb*2) ^ swz)) = wv8;
    }
    __syncthreads();
    sh8 af[4], bf[4];
    #pragma unroll
    for(int mt=0; mt<4; mt++){
      int r = wm + mt*16 + l15;
      af[mt] = *(sh8*)((char*)As + r*64 + ((g*16) ^ (((r&3)^((r>>2)&3))<<4)));
    }
    #pragma unroll
    for(int nt=0; nt<4; nt++){
      int r = wn + nt*16 + l15;
      bf[nt] = *(sh8*)((char*)Bs + r*64 + ((g*16) ^ (((r&3)^((r>>2)&3))<<4)));
    }
    #pragma unroll
    for(int mt=0; mt<4; mt++)
      #pragma unroll
      for(int nt=0; nt<4; nt++)
        acc[mt][nt] = MFMA16(af[mt], bf[nt], acc[mt][nt]);
    __syncthreads();
  }
  #pragma unroll
  for(int mt=0; mt<4; mt++){
    #pragma unroll
    for(int r=0; r<4; r++){
      int gm = row0 + wm + mt*16 + g*4 + r;
      if(gm >= M) continue;
      #pragma unroll
      for(int nt=0; nt<4; nt++){
        int gn = n0 + wn + nt*16 + l15;
        float v = acc[mt][nt][r];
        if(MODE == 0){
          v += bias[gn];
          ((float*)out0v)[(size_t)gm*CDIM + gn] = v > 0.f ? v : 0.f;
        } else if(MODE == 1){
          int p = gn >> 9, rr = gn & 511;
          int hh = rr >> 6, dd = rr & 63;
          if(p == 0) v *= 0.125f;
          short* dst = (p==0) ? (short*)out0v : (p==1 ? (short*)out1v : (short*)out2v);
          dst[((size_t)hh*NPAD + gm)*DHEAD + dd] = (short)bfbits(v);
        } else {
          ((float*)out0v)[(size_t)gm*CDIM + gn] += v + bias[gn];
        }
      }
    }
  }
}

// ---------------- landmark means (bf16 in, f32 out) ----------------
__global__ void k_landmark(const short* __restrict__ src, float* __restrict__ dst){
  int bidx = blockIdx.x;               // h*256 + m
  int h = bidx >> 8, m = bidx & 255, d = threadIdx.x;
  const short* p = src + ((size_t)h*NPAD + (size_t)m*LFAC)*DHEAD + d;
  float s = 0;
  for(int j=0;j<LFAC;j++) s += bf2f(p[(size_t)j*DHEAD]);
  dst[(size_t)bidx*DHEAD + d] = s * (1.f/LFAC);
}

// ---------------- a2 = softmax(ql @ kl^T) ----------------
__global__ __launch_bounds__(256) void k_a2(const float* __restrict__ ql,
    const float* __restrict__ kl, float* __restrict__ a2){
  __shared__ __hip_bfloat16 klt[64*256];  // [d][m]
  int h = blockIdx.y;
  int t = threadIdx.x;
  const float* klh = kl + (size_t)h*NLAND*DHEAD;
  for(int r=0;r<64;r++){
    int idx = r*256 + t;
    int d = idx >> 8, m = idx & 255;
    klt[idx] = __float2bfloat16(klh[m*DHEAD + d]);
  }
  __syncthreads();
  int w = t >> 6, lane = t & 63;
  const float* qlh = ql + (size_t)h*NLAND*DHEAD;
  for(int rr=0; rr<16; rr++){
    int m = blockIdx.x*64 + w*16 + rr;
    const float* q = qlh + (size_t)m*DHEAD;
    float s[4] = {0,0,0,0};
    #pragma unroll
    for(int d=0; d<64; d++){
      float qv = q[d];
      #pragma unroll
      for(int qd=0; qd<4; qd++)
        s[qd] += qv * __bfloat162float(klt[d*256 + qd*64 + lane]);
    }
    float e[4], den = 0.f;
    #pragma unroll
    for(int qd=0; qd<4; qd++){ e[qd] = __expf(s[qd]); den += e[qd]; }
    den = wave_sum(den);
    float inv = 1.f/den;
    float* arow = a2 + ((size_t)h*NLAND + m)*NLAND;
    #pragma unroll
    for(int qd=0; qd<4; qd++) arow[qd*64 + lane] = e[qd]*inv;
  }
}

// ---------------- pinv init ----------------
__global__ void k_colmax(const float* __restrict__ a2, float* __restrict__ hmax){
  __shared__ float red[4];
  int h = blockIdx.x, t = threadIdx.x;
  const float* p = a2 + (size_t)h*65536 + t;
  float s = 0;
  for(int m=0;m<256;m++) s += p[(size_t)m*256];
  float mx = wave_max(s);
  if((t & 63) == 0) red[t>>6] = mx;
  __syncthreads();
  if(t == 0) hmax[h] = fmaxf(fmaxf(red[0],red[1]), fmaxf(red[2],red[3]));
}
__global__ void k_scal(const float* __restrict__ hmax, float* __restrict__ scal){
  int t = threadIdx.x;
  float v = (t < 8) ? hmax[t] : -1e30f;
  v = wave_max(v);
  if(t == 0) scal[0] = v;
}
__global__ void k_zinit(const float* __restrict__ a2, const float* __restrict__ scal,
                        float* __restrict__ z){
  int h = blockIdx.y;
  int idx = blockIdx.x*256 + threadIdx.x;
  int m = idx >> 8, j = idx & 255;
  z[(size_t)h*65536 + idx] = a2[(size_t)h*65536 + (size_t)j*256 + m] / scal[0];
}

// ---------------- batched f32 GEMM 64x64 tile, 4x4/thread ----------------
template<int TRANS, int OUTT>
__global__ __launch_bounds__(256) void k_sgemm2(const float* __restrict__ A,
    const float* __restrict__ B, float* __restrict__ C,
    int M, int N, int K, long sA, long sB, long sC, float alpha, float beta){
  __shared__ float As[32][68];
  __shared__ float Bs[32][68];
  int bh = blockIdx.z;
  const float* Ah = A + (size_t)bh*sA;
  const float* Bh = B + (size_t)bh*sB;
  float* Ch = C + (size_t)bh*sC;
  int m0 = blockIdx.y*64, n0 = blockIdx.x*64;
  int t = threadIdx.x, tx = t & 15, ty = t >> 4;
  float acc[4][4] = {};
  for(int k0=0; k0<K; k0+=32){
    #pragma unroll
    for(int u=0; u<2; u++){
      int idx = t + u*256;
      int r = idx >> 3, cb = (idx & 7) * 4;
      float4 va = *(const float4*)(Ah + (size_t)(m0+r)*K + k0 + cb);
      As[cb+0][r]=va.x; As[cb+1][r]=va.y; As[cb+2][r]=va.z; As[cb+3][r]=va.w;
      int kr = idx >> 4, nb = (idx & 15) * 4;
      float4 w = *(const float4*)(Bh + (size_t)(k0+kr)*N + n0 + nb);
      if(TRANS){
        int gk = k0 + kr;
        w.x = ((gk==n0+nb+0)?alpha:0.f) - w.x;
        w.y = ((gk==n0+nb+1)?alpha:0.f) - w.y;
        w.z = ((gk==n0+nb+2)?alpha:0.f) - w.z;
        w.w = ((gk==n0+nb+3)?alpha:0.f) - w.w;
      }
      *(float4*)&Bs[kr][nb] = w;
    }
    __syncthreads();
    #pragma unroll
    for(int k=0;k<32;k++){
      float a[4], b[4];
      *(float4*)a = *(const float4*)&As[k][ty*4];
      *(float4*)b = *(const float4*)&Bs[k][tx*4];
      #pragma unroll
      for(int i=0;i<4;i++)
        #pragma unroll
        for(int j=0;j<4;j++) acc[i][j] += a[i]*b[j];
    }
    __syncthreads();
  }
  #pragma unroll
  for(int i=0;i<4;i++){
    #pragma unroll
    for(int j=0;j<4;j++){
      int gm = m0 + ty*4 + i, gn = n0 + tx*4 + j;
      float v = acc[i][j] * beta;
      if(OUTT) Ch[(size_t)gn*M + gm] = v;
      else     Ch[(size_t)gm*N + gn] = v;
    }
  }
}

// ---------------- MFMA flash a1 (Q bf16) ----------------
__global__ __launch_bounds__(256) void k_a1_mfma(const short* __restrict__ Qb,
    const float* __restrict__ kl, const float* __restrict__ w2t, float* __restrict__ F){
  __shared__ short klL[128*64];
  __shared__ short w2L[64*128];
  __shared__ short pL[4][16*128];
  int h = blockIdx.y, n0 = blockIdx.x*128;
  int t = threadIdx.x, lane = t & 63, wv = t >> 6, g = lane >> 4, l15 = lane & 15;
  const float* klh = kl + (size_t)h*NLAND*DHEAD;
  const float* w2h = w2t + (size_t)h*DHEAD*NLAND;
  const short* qbase = Qb + (size_t)h*NPAD*DHEAD;
  sh8 aQ[2][2];
  #pragma unroll
  for(int st=0; st<2; st++)
    #pragma unroll
    for(int kk=0; kk<2; kk++)
      aQ[st][kk] = *(const sh8*)(qbase +
          (size_t)(n0 + wv*32 + st*16 + l15)*DHEAD + kk*32 + g*8);
  f4 accO[2][4] = {};
  float den[2][4] = {};
  short* pw = pL[wv];
  for(int half=0; half<2; half++){
    __syncthreads();
    #pragma unroll
    for(int it=0; it<4; it++){
      int gi = t + it*256;
      int m = gi >> 3, db = (gi & 7) * 8;
      const float* p = klh + (size_t)(half*128 + m)*DHEAD + db;
      *(sh8*)((char*)klL + m*128 + ((db*2) ^ ((m&7)<<4))) =
          pack8f(*(const float4*)p, *(const float4*)(p+4));
      int d = gi >> 4, mb = (gi & 15) * 8;
      const float* p2 = w2h + (size_t)d*NLAND + half*128 + mb;
      *(sh8*)((char*)w2L + d*256 + ((mb*2) ^ ((d&7)<<4))) =
          pack8f(*(const float4*)p2, *(const float4*)(p2+4));
    }
    __syncthreads();
    #pragma unroll
    for(int st=0; st<2; st++){
      #pragma unroll
      for(int mt=0; mt<8; mt++){
        f4 s = {};
        #pragma unroll
        for(int kk=0; kk<2; kk++){
          int m = mt*16 + l15;
          sh8 b = *(sh8*)((char*)klL + m*128 + ((kk*64 + g*16) ^ ((m&7)<<4)));
          s = MFMA16(aQ[st][kk], b, s);
        }
        #pragma unroll
        for(int r=0; r<4; r++){
          float e = __expf(s[r]);
          den[st][r] += e;
          int n = g*4 + r;
          *(short*)((char*)pw + n*256 + (((mt*16+l15)*2) ^ ((n&7)<<4))) = (short)bfbits(e);
        }
      }
      __syncthreads();
      #pragma unroll
      for(int ks=0; ks<4; ks++){
        sh8 aP = *(sh8*)((char*)pw + l15*256 + ((ks*64 + g*16) ^ ((l15&7)<<4)));
        #pragma unroll
        for(int dt=0; dt<4; dt++){
          int d = dt*16 + l15;
          sh8 bW = *(sh8*)((char*)w2L + d*256 + ((ks*64 + g*16) ^ ((d&7)<<4)));
          accO[st][dt] = MFMA16(aP, bW, accO[st][dt]);
        }
      }
      __syncthreads();
    }
  }
  #pragma unroll
  for(int st=0; st<2; st++)
    #pragma unroll
    for(int r=0; r<4; r++){
      float d_ = den[st][r];
      d_ += __shfl_xor(d_,1); d_ += __shfl_xor(d_,2);
      d_ += __shfl_xor(d_,4); d_ += __shfl_xor(d_,8);
      den[st][r] = 1.f/d_;
    }
  #pragma unroll
  for(int st=0; st<2; st++)
    #pragma unroll
    for(int dt=0; dt<4; dt++)
      #pragma unroll
      for(int r=0; r<4; r++){
        int row = n0 + wv*32 + st*16 + g*4 + r;
        F[(size_t)row*CDIM + h*DHEAD + dt*16 + l15] = accO[st][dt][r]*den[st][r];
      }
}

// ---------------- MFMA flash a3v (K/V bf16) ----------------
__global__ __launch_bounds__(256) void k_a3v_mfma(const float* __restrict__ ql,
    const short* __restrict__ Kb, const short* __restrict__ Vb,
    float* __restrict__ numP, float* __restrict__ denP){
  __shared__ short kL[128*64];
  __shared__ short vL[64*128];
  __shared__ short pL[4][16*128];
  int h = blockIdx.x, c = blockIdx.y;
  int t = threadIdx.x, lane = t & 63, wv = t >> 6, g = lane >> 4, l15 = lane & 15;
  const float* qlh = ql + (size_t)h*NLAND*DHEAD;
  sh8 aQ[4][2];
  #pragma unroll
  for(int st=0; st<4; st++)
    #pragma unroll
    for(int kk=0; kk<2; kk++){
      const float* p = qlh + (size_t)(wv*64 + st*16 + l15)*DHEAD + kk*32 + g*8;
      aQ[st][kk] = pack8f(*(const float4*)p, *(const float4*)(p+4));
    }
  f4 accO[4][4] = {};
  float den[4][4] = {};
  short* pw = pL[wv];
  for(int half=0; half<2; half++){
    const short* Kh = Kb + ((size_t)h*NPAD + (size_t)c*256 + half*128)*DHEAD;
    const short* Vh = Vb + ((size_t)h*NPAD + (size_t)c*256 + half*128)*DHEAD;
    __syncthreads();
    #pragma unroll
    for(int it=0; it<4; it++){
      int gi = t + it*256;
      int m = gi >> 3, db = (gi & 7) * 8;
      *(sh8*)((char*)kL + m*128 + ((db*2) ^ ((m&7)<<4))) =
          *(const sh8*)(Kh + (size_t)m*DHEAD + db);
    }
    #pragma unroll
    for(int it=0; it<4; it++){
      int idx = t + it*256;                 // 1024 sh8 units
      int m = idx & 127, dg = (idx >> 7) * 8;
      sh8 v = *(const sh8*)(Vh + (size_t)m*DHEAD + dg);
      #pragma unroll
      for(int i=0;i<8;i++){
        int d = dg + i;
        *(short*)((char*)vL + d*256 + ((m*2) ^ ((d&7)<<4))) = v[i];
      }
    }
    __syncthreads();
    #pragma unroll
    for(int st=0; st<4; st++){
      #pragma unroll
      for(int mt=0; mt<8; mt++){
        f4 s = {};
        #pragma unroll
        for(int kk=0; kk<2; kk++){
          int m = mt*16 + l15;
          sh8 b = *(sh8*)((char*)kL + m*128 + ((kk*64 + g*16) ^ ((m&7)<<4)));
          s = MFMA16(aQ[st][kk], b, s);
        }
        #pragma unroll
        for(int r=0; r<4; r++){
          float e = __expf(s[r]);
          den[st][r] += e;
          int n = g*4 + r;
          *(short*)((char*)pw + n*256 + (((mt*16+l15)*2) ^ ((n&7)<<4))) = (short)bfbits(e);
        }
      }
      __syncthreads();
      #pragma unroll
      for(int ks=0; ks<4; ks++){
        sh8 aP = *(sh8*)((char*)pw + l15*256 + ((ks*64 + g*16) ^ ((l15&7)<<4)));
        #pragma unroll
        for(int dt=0; dt<4; dt++){
          int d = dt*16 + l15;
          sh8 bV = *(sh8*)((char*)vL + d*256 + ((ks*64 + g*16) ^ ((d&7)<<4)));
          accO[st][dt] = MFMA16(aP, bV, accO[st][dt]);
        }
      }
      __syncthreads();
    }
  }
  #pragma unroll
  for(int st=0; st<4; st++)
    #pragma unroll
    for(int r=0; r<4; r++){
      float d_ = den[st][r];
      d_ += __shfl_xor(d_,1); d_ += __shfl_xor(d_,2);
      d_ += __shfl_xor(d_,4); d_ += __shfl_xor(d_,8);
      den[st][r] = d_;
    }
  size_t base = ((size_t)h*NCHUNK + c)*NLAND;
  #pragma unroll
  for(int st=0; st<4; st++){
    #pragma unroll
    for(int r=0; r<4; r++){
      int row = wv*64 + st*16 + g*4 + r;
      if(l15 == 0) denP[base + row] = den[st][r];
      #pragma unroll
      for(int dt=0; dt<4; dt++)
        numP[(base + row)*DHEAD + dt*16 + l15] = accO[st][dt][r];
    }
  }
}

__global__ void k_a3v_comb(const float* __restrict__ numP, const float* __restrict__ denP,
                           float* __restrict__ a3v){
  int bidx = blockIdx.x;           // h*256 + m
  int h = bidx >> 8, m = bidx & 255;
  int d = threadIdx.x;
  float s = 0.f, den = 0.f;
  for(int c=0;c<NCHUNK;c++){
    s += numP[(((size_t)h*NCHUNK + c)*NLAND + m)*DHEAD + d];
    den += denP[((size_t)h*NCHUNK + c)*NLAND + m];
  }
  a3v[((size_t)h*NLAND + m)*DHEAD + d] = s / den;
}

// ---------------- residual depthwise conv (k=33), FIR-tiled, V bf16 ----------------
__global__ __launch_bounds__(256) void k_resconv(const short* __restrict__ Vb,
    const float* __restrict__ rw, float* __restrict__ F){
  __shared__ float vs[160][64];
  int n0 = blockIdx.x*128, h = blockIdx.y;
  int t = threadIdx.x;
  const short* vh = Vb + (size_t)h*NPAD*DHEAD;
  #pragma unroll
  for(int i=0;i<5;i++){
    int idx = t + i*256;                // 1280 sh8 units: 160 rows x 8 groups
    int r = idx >> 3, dg = (idx & 7)*8;
    int n = n0 - 16 + r;
    sh8 v = {0,0,0,0,0,0,0,0};
    if(n>=0 && n<NPAD) v = *(const sh8*)(vh + (size_t)n*DHEAD + dg);
    #pragma unroll
    for(int e=0;e<8;e++) vs[r][dg+e] = bf2f(v[e]);
  }
  float w[33];
  #pragma unroll
  for(int j=0;j<33;j++) w[j] = rw[h*33+j];
  __syncthreads();
  int d = t & 63, half = t >> 6;
  float acc[32];
  #pragma unroll
  for(int r=0;r<32;r++) acc[r] = 0.f;
  #pragma unroll
  for(int p=0;p<64;p++){
    float vv = vs[half*32 + p][d];
    #pragma unroll
    for(int j=0;j<33;j++){
      int r = p - j;
      if(r >= 0 && r < 32) acc[r] += w[j]*vv;
    }
  }
  #pragma unroll
  for(int r=0;r<32;r++){
    int n = n0 + half*32 + r;
    F[(size_t)n*CDIM + h*DHEAD + d] += acc[r];
  }
}

// ---------------- weight transpose f32 -> bf16 ----------------
__global__ void k_transposeb(const float* __restrict__ in, short* __restrict__ out,
                             int R, int C){
  __shared__ float tile[32][33];
  int r0 = blockIdx.x*32, c0 = blockIdx.y*32;
  int tx = threadIdx.x, ty = threadIdx.y;
  #pragma unroll
  for(int r=0;r<4;r++) tile[ty + r*8][tx] = in[(size_t)(r0 + ty + r*8)*C + c0 + tx];
  __syncthreads();
  #pragma unroll
  for(int r=0;r<4;r++)
    out[(size_t)(c0 + ty + r*8)*R + r0 + tx] = (short)bfbits(tile[tx][ty + r*8]);
}

// ---------------- PPEG direct on row-major [n][c] (f32) ----------------
__global__ __launch_bounds__(256) void k_ppeg2(const float* __restrict__ X,
    const float* __restrict__ w7, const float* __restrict__ b7,
    const float* __restrict__ w5, const float* __restrict__ b5,
    const float* __restrict__ w3, const float* __restrict__ b3,
    float* __restrict__ Y){
  __shared__ float patch[484][20];
  int cg = blockIdx.y;
  int ti = blockIdx.x >> 3, tj = blockIdx.x & 7;
  int t = threadIdx.x;
  int i0 = ti*16 - 3, j0 = tj*16 - 3;
  for(int idx = t; idx < 1936; idx += 256){
    int p = idx >> 2, cq = (idx & 3) * 4;
    int gi = i0 + p/22, gj = j0 + p%22;
    float4 v = make_float4(0.f,0.f,0.f,0.f);
    if(gi>=0 && gi<128 && gj>=0 && gj<128)
      v = *(const float4*)(X + (size_t)(gi*128+gj)*CDIM + cg*16 + cq);
    *(float4*)&patch[p][cq] = v;
  }
  int c = t & 15, sg = t >> 4;
  int cglob = cg*16 + c;
  float wr[83];
  #pragma unroll
  for(int k=0;k<49;k++) wr[k] = w7[cglob*49+k];
  #pragma unroll
  for(int k=0;k<25;k++) wr[49+k] = w5[cglob*25+k];
  #pragma unroll
  for(int k=0;k<9;k++)  wr[74+k] = w3[cglob*9+k];
  float bsum = b7[cglob] + b5[cglob] + b3[cglob];
  __syncthreads();
  float acc[16];
  #pragma unroll
  for(int j=0;j<16;j++) acc[j] = patch[(sg+3)*22 + (j+3)][c] + bsum;
  #pragma unroll
  for(int a=0;a<7;a++)
    #pragma unroll
    for(int x=0;x<22;x++){
      float vv = patch[(sg+a)*22 + x][c];
      #pragma unroll
      for(int bq=0;bq<7;bq++){
        int j = x - bq;
        if(j>=0 && j<16) acc[j] += wr[a*7+bq]*vv;
      }
    }
  #pragma unroll
  for(int a=0;a<5;a++)
    #pragma unroll
    for(int x=1;x<21;x++){
      float vv = patch[(sg+a+1)*22 + x][c];
      #pragma unroll
      for(int bq=0;bq<5;bq++){
        int j = x - 1 - bq;
        if(j>=0 && j<16) acc[j] += wr[49+a*5+bq]*vv;
      }
    }
  #pragma unroll
  for(int a=0;a<3;a++)
    #pragma unroll
    for(int x=2;x<20;x++){
      float vv = patch[(sg+a+2)*22 + x][c];
      #pragma unroll
      for(int bq=0;bq<3;bq++){
        int j = x - 2 - bq;
        if(j>=0 && j<16) acc[j] += wr[74+a*3+bq]*vv;
      }
    }
  #pragma unroll
  for(int j=0;j<16;j++)
    Y[(size_t)((ti*16+sg)*128 + tj*16+j)*CDIM + cglob] = acc[j];
}

// ---------------- final LN(row0) + fc2 ----------------
__global__ __launch_bounds__(512) void k_final(const float* __restrict__ A,
    const float* __restrict__ g, const float* __restrict__ b,
    const float* __restrict__ w, const float* __restrict__ bias,
    float* __restrict__ outp){
  __shared__ float red[8];
  int t = threadIdx.x, wv = t >> 6;
  float x = A[t];
  float s = wave_sum(x);
  if((t & 63) == 0) red[wv] = s;
  __syncthreads();
  float mu = 0;
  #pragma unroll
  for(int i=0;i<8;i++) mu += red[i];
  mu *= (1.f/512.f);
  __syncthreads();
  float dx = x - mu;
  s = wave_sum(dx*dx);
  if((t & 63) == 0) red[wv] = s;
  __syncthreads();
  float var = 0;
  #pragma unroll
  for(int i=0;i<8;i++) var += red[i];
  var *= (1.f/512.f);
  float xn = dx * rsqrtf(var + 1e-5f) * g[t] + b[t];
  __syncthreads();
  for(int o=0;o<4;o++){
    s = wave_sum(xn * w[t*4 + o]);
    if((t & 63) == 0) red[wv] = s;
    __syncthreads();
    if(t == 0){
      float r = 0;
      #pragma unroll
      for(int i=0;i<8;i++) r += red[i];
      outp[o] = r + bias[o];
    }
    __syncthreads();
  }
}

extern "C" void kernel_launch(void* const* d_in, const int* in_sizes, int n_in,
                              void* d_out, int out_size, void* d_ws, size_t ws_size,
                              hipStream_t stream) {
  (void)in_sizes; (void)n_in; (void)out_size; (void)ws_size;
  const float* data_x = (const float*)d_in[0];
  const float* fc1_w  = (const float*)d_in[1];
  const float* fc1_b  = (const float*)d_in[2];
  const float* cls_tk = (const float*)d_in[3];
  const float* ng[2]  = {(const float*)d_in[4],  (const float*)d_in[16]};
  const float* nb[2]  = {(const float*)d_in[5],  (const float*)d_in[17]};
  const float* qkvw[2]= {(const float*)d_in[6],  (const float*)d_in[18]};
  const float* outw[2]= {(const float*)d_in[7],  (const float*)d_in[19]};
  const float* outb[2]= {(const float*)d_in[8],  (const float*)d_in[20]};
  const float* resw[2]= {(const float*)d_in[9],  (const float*)d_in[21]};
  const float* w7 = (const float*)d_in[10]; const float* pb7 = (const float*)d_in[11];
  const float* w5 = (const float*)d_in[12]; const float* pb5 = (const float*)d_in[13];
  const float* w3 = (const float*)d_in[14]; const float* pb3 = (const float*)d_in[15];
  const float* norm_g = (const float*)d_in[22];
  const float* norm_b = (const float*)d_in[23];
  const float* fc2_w  = (const float*)d_in[24];
  const float* fc2_b  = (const float*)d_in[25];

  float* ws = (float*)d_ws;
  float* Ab   = ws;                         // TOK*512 f32 (layer-0 h base)
  float* Bb   = Ab + (size_t)TOK*CDIM;      // TOK*512 f32 (post-ppeg h base)
  float* Fb   = Bb + (size_t)TOK*CDIM;      // NPAD*512 f32 (F / numP scratch)
  short* lnX  = (short*)(Fb + (size_t)NPAD*CDIM);   // NPAD*512 bf16 (LN out)
  short* Qb   = lnX + (size_t)NPAD*CDIM;    // bf16 head-major
  short* Kb   = Qb  + (size_t)NPAD*CDIM;
  short* Vb   = Kb  + (size_t)NPAD*CDIM;
  float* qlb  = (float*)(Vb + (size_t)NPAD*CDIM);   // 8*256*64 f32
  float* klb  = qlb + NHEAD*NLAND*DHEAD;
  float* a2b  = klb + NHEAD*NLAND*DHEAD;    // 8*65536 f32
  float* z0b  = a2b + NHEAD*NLAND*NLAND;
  float* z1b  = z0b + NHEAD*NLAND*NLAND;
  float* Xb_  = z1b + NHEAD*NLAND*NLAND;
  float* Tb_  = Xb_ + NHEAD*NLAND*NLAND;
  float* Ub_  = Tb_ + NHEAD*NLAND*NLAND;
  float* a3vb = Ub_ + NHEAD*NLAND*NLAND;    // 8*256*64
  float* w2tb = a3vb + NHEAD*NLAND*DHEAD;   // 8*64*256
  float* denP = w2tb + NHEAD*DHEAD*NLAND;   // 8*65*256
  float* hmax = denP + NHEAD*NCHUNK*NLAND;  // 8
  float* scal = hmax + 8;                   // 1
  short* fc1T = (short*)(scal + 8);         // 512*1024 bf16
  short* qkvT0= fc1T + 512*1024;            // 1536*512 bf16
  short* qkvT1= qkvT0 + 1536*512;
  short* outT0= qkvT1 + 1536*512;           // 512*512 bf16
  short* outT1= outT0 + 512*512;
  short* qkvT[2] = {qkvT0, qkvT1};
  short* outT[2] = {outT0, outT1};

  // weight transposes (WT[n][k], bf16)
  k_transposeb<<<dim3(32,16), dim3(32,8), 0, stream>>>(fc1_w, fc1T, 1024, 512);
  k_transposeb<<<dim3(16,48), dim3(32,8), 0, stream>>>(qkvw[0], qkvT0, 512, 1536);
  k_transposeb<<<dim3(16,48), dim3(32,8), 0, stream>>>(qkvw[1], qkvT1, 512, 1536);
  k_transposeb<<<dim3(16,16), dim3(32,8), 0, stream>>>(outw[0], outT0, 512, 512);
  k_transposeb<<<dim3(16,16), dim3(32,8), 0, stream>>>(outw[1], outT1, 512, 512);

  k_copyrow<<<1, 512, 0, stream>>>(Ab, cls_tk);
  k_gemm_mfma<0,0><<<dim3(4, 128), 256, 0, stream>>>(data_x, 1024, fc1T, 1024, fc1_b,
                                                     Ab + CDIM, nullptr, nullptr, 16384);
  float* base[2]  = {Ab, Bb};
  for(int L=0; L<2; L++){
    k_ln_pad<<<NPAD/4, 256, 0, stream>>>(base[L], ng[L], nb[L], lnX);
    k_gemm_mfma<1,1><<<dim3(12, 130), 256, 0, stream>>>(lnX, CDIM, qkvT[L], CDIM, nullptr,
                                                        Qb, Kb, Vb, NPAD);
    k_landmark<<<NHEAD*NLAND, 64, 0, stream>>>(Qb, qlb);
    k_landmark<<<NHEAD*NLAND, 64, 0, stream>>>(Kb, klb);
    k_a2<<<dim3(4, NHEAD), 256, 0, stream>>>(qlb, klb, a2b);
    k_colmax<<<NHEAD, 256, 0, stream>>>(a2b, hmax);
    k_scal<<<1, 64, 0, stream>>>(hmax, scal);
    k_zinit<<<dim3(256, NHEAD), 256, 0, stream>>>(a2b, scal, z0b);
    float* zc = z0b; float* zn = z1b;
    for(int it=0; it<6; it++){
      k_sgemm2<0,0><<<dim3(4,4,NHEAD), 256, 0, stream>>>(a2b, zc, Xb_, 256,256,256,
                                                         65536,65536,65536, 0.f, 1.f);
      k_sgemm2<1,0><<<dim3(4,4,NHEAD), 256, 0, stream>>>(Xb_, Xb_, Tb_, 256,256,256,
                                                         65536,65536,65536, 7.f, 1.f);
      k_sgemm2<1,0><<<dim3(4,4,NHEAD), 256, 0, stream>>>(Xb_, Tb_, Ub_, 256,256,256,
                                                         65536,65536,65536, 15.f, 1.f);
      k_sgemm2<1,0><<<dim3(4,4,NHEAD), 256, 0, stream>>>(zc, Ub_, zn, 256,256,256,
                                                         65536,65536,65536, 13.f, 0.25f);
      float* tmp = zc; zc = zn; zn = tmp;
    }
    // zc == z0b after 6 iterations
    k_a3v_mfma<<<dim3(NHEAD, NCHUNK), 256, 0, stream>>>(qlb, Kb, Vb, Fb, denP);
    k_a3v_comb<<<NHEAD*NLAND, 64, 0, stream>>>(Fb, denP, a3vb);
    k_sgemm2<0,1><<<dim3(1,4,NHEAD), 256, 0, stream>>>(zc, a3vb, w2tb, 256,64,256,
                                                       65536,16384,16384, 0.f, 1.f);
    k_a1_mfma<<<dim3(130, NHEAD), 256, 0, stream>>>(Qb, klb, w2tb, Fb);
    k_resconv<<<dim3(130, NHEAD), 256, 0, stream>>>(Vb, resw[L], Fb);
    k_gemm_mfma<2,0><<<dim3(4, 129), 256, 0, stream>>>(Fb + (size_t)PAD0*CDIM, CDIM,
                                                       outT[L], CDIM, outb[L],
                                                       base[L], nullptr, nullptr, TOK);
    if(L == 0){
      k_ppeg2<<<dim3(64, 32), 256, 0, stream>>>(Ab + CDIM, w7, pb7, w5, pb5, w3, pb3,
                                                Bb + CDIM);
      k_copyrow<<<1, 512, 0, stream>>>(Bb, Ab);
    }
  }
  k_final<<<1, 512, 0, stream>>>(Bb, norm_g, norm_b, fc2_w, fc2_b, (float*)d_out);
}

// Round 12
// 1594.721 us; speedup vs baseline: 1.8064x; 1.0320x over previous
//
#include <hip/hip_runtime.h>
#include <hip/hip_bf16.h>

#define NPAD 16640
#define TOK  16385
#define CDIM 512
#define NHEAD 8
#define DHEAD 64
#define NLAND 256
#define LFAC  65
#define PAD0  255
#define NCHUNK 65   // chunks of 256 rows: 65*256 = 16640

typedef __attribute__((ext_vector_type(8))) short sh8;
typedef __attribute__((ext_vector_type(4))) float f4;

__device__ __forceinline__ float wave_sum(float v){
  #pragma unroll
  for(int o=32;o;o>>=1) v += __shfl_xor(v,o);
  return v;
}
__device__ __forceinline__ float wave_max(float v){
  #pragma unroll
  for(int o=32;o;o>>=1) v = fmaxf(v, __shfl_xor(v,o));
  return v;
}

// bf16 RNE pack helpers
__device__ __forceinline__ unsigned bfbits(float x){
  unsigned u = __float_as_uint(x);
  return (u + 0x7fffu + ((u >> 16) & 1u)) >> 16;
}
__device__ __forceinline__ float bf2f(short s){
  return __uint_as_float(((unsigned)(unsigned short)s) << 16);
}
__device__ __forceinline__ sh8 pack8f(float4 a, float4 b){
  sh8 r;
  r[0]=(short)bfbits(a.x); r[1]=(short)bfbits(a.y); r[2]=(short)bfbits(a.z); r[3]=(short)bfbits(a.w);
  r[4]=(short)bfbits(b.x); r[5]=(short)bfbits(b.y); r[6]=(short)bfbits(b.z); r[7]=(short)bfbits(b.w);
  return r;
}
#define MFMA16(a,b,c) __builtin_amdgcn_mfma_f32_16x16x32_bf16(a,b,c,0,0,0)

// async global->LDS 16B (wave-uniform LDS base + lane*16)
__device__ __forceinline__ void gload16(const void* g, void* l){
  __builtin_amdgcn_global_load_lds(
      (const __attribute__((address_space(1))) void*)g,
      (__attribute__((address_space(3))) void*)l, 16, 0, 0);
}

// ---------------- row copy (cls token) ----------------
__global__ void k_copyrow(float* dst, const float* __restrict__ src){
  dst[threadIdx.x] = src[threadIdx.x];
}

// ---------------- f32 -> bf16 convert ----------------
__global__ __launch_bounds__(256) void k_f2b(const float* __restrict__ in,
    short* __restrict__ out, int n8){
  int i = blockIdx.x*256 + threadIdx.x;
  if(i < n8){
    float4 a = *(const float4*)(in + (size_t)i*8);
    float4 b = *(const float4*)(in + (size_t)i*8 + 4);
    *(sh8*)(out + (size_t)i*8) = pack8f(a, b);
  }
}

// ---------------- layernorm + front pad -> bf16 ----------------
__global__ __launch_bounds__(256) void k_ln_pad(const float* __restrict__ A,
    const float* __restrict__ g, const float* __restrict__ b, short* __restrict__ B){
  int w = threadIdx.x >> 6, lane = threadIdx.x & 63;
  int row = blockIdx.x*4 + w;
  short* out = B + (size_t)row*CDIM;
  int c = lane*8;
  if(row < PAD0){
    sh8 z = {0,0,0,0,0,0,0,0};
    *(sh8*)(out + c) = z;
    return;
  }
  const float* x = A + (size_t)(row-PAD0)*CDIM;
  float4 v0 = *(const float4*)(x + c);
  float4 v1 = *(const float4*)(x + c + 4);
  float xs[8] = {v0.x,v0.y,v0.z,v0.w,v1.x,v1.y,v1.z,v1.w};
  float s = 0;
  #pragma unroll
  for(int i=0;i<8;i++) s += xs[i];
  s = wave_sum(s);
  float mu = s * (1.f/512.f);
  float vs = 0;
  #pragma unroll
  for(int i=0;i<8;i++){ float d = xs[i]-mu; vs += d*d; }
  vs = wave_sum(vs) * (1.f/512.f);
  float rs = rsqrtf(vs + 1e-5f);
  float4 g0 = *(const float4*)(g + c); float4 g1 = *(const float4*)(g + c + 4);
  float4 b0 = *(const float4*)(b + c); float4 b1 = *(const float4*)(b + c + 4);
  float gg[8] = {g0.x,g0.y,g0.z,g0.w,g1.x,g1.y,g1.z,g1.w};
  float bb[8] = {b0.x,b0.y,b0.z,b0.w,b1.x,b1.y,b1.z,b1.w};
  sh8 o;
  #pragma unroll
  for(int i=0;i<8;i++) o[i] = (short)bfbits((xs[i]-mu)*rs*gg[i] + bb[i]);
  *(sh8*)(out + c) = o;
}

// ---------------- gload-staged MFMA GEMM: C[M,N] = A[M,K] @ WT[N,K]^T ----------------
// A bf16, WT bf16. 128x128 tile, BK=32, double-buffered LDS staged via
// global_load_lds (linear LDS dest, pre-swizzled per-lane global source).
// XCD-chunked bijective swizzle, m-major work order.
// MODE 0: fc1 relu(acc+bias)->f32 ; MODE 1: qkv scatter head-major bf16, q*0.125 ;
// MODE 2: proj f32 += acc+bias
template<int MODE>
__global__ __launch_bounds__(256) void k_gemm_g(const short* __restrict__ A, int lda,
    const short* __restrict__ WT, int K, const float* __restrict__ bias,
    void* out0v, void* out1v, void* out2v, int M){
  __shared__ short As[2][128*32];
  __shared__ short Bs[2][128*32];
  int t = threadIdx.x, lane = t & 63, wv = t >> 6, g = lane >> 4, l15 = lane & 15;
  int nwg = gridDim.x * gridDim.y;
  int orig = blockIdx.y * gridDim.x + blockIdx.x;
  int qc = nwg >> 3, rc = nwg & 7, xcd = orig & 7, loc = orig >> 3;
  int wgid = (xcd < rc ? xcd*(qc+1) : rc*(qc+1) + (xcd - rc)*qc) + loc;
  int row0 = (wgid / gridDim.x) * 128, n0 = (wgid % gridDim.x) * 128;
  int wm = (wv>>1)*64, wn = (wv&1)*64;
  int mq = lane >> 2, slot = lane & 3;

  // stage one 128x32 K-tile into buffer `buf` (8 gload16 calls; no waits here)
  auto stage = [&](int buf, int k0){
    #pragma unroll
    for(int c=0;c<2;c++){
      int m = wv*32 + c*16 + mq;
      int swz = (((m&3) ^ ((m>>2)&3)) << 4);
      int gr = row0 + m; if(gr >= M) gr = M-1;
      const char* srcA = (const char*)(A + (size_t)gr*lda + k0) + ((slot*16) ^ swz);
      gload16(srcA, (char*)As[buf] + wv*2048 + c*1024);
      const char* srcB = (const char*)(WT + (size_t)(n0+m)*K + k0) + ((slot*16) ^ swz);
      gload16(srcB, (char*)Bs[buf] + wv*2048 + c*1024);
    }
  };

  f4 acc[4][4] = {};
  int nk = K >> 5;
  stage(0, 0);
  __syncthreads();
  int cur = 0;
  for(int i=0; i<nk; i++){
    if(i+1 < nk) stage(cur^1, (i+1) << 5);
    sh8 af[4], bf[4];
    #pragma unroll
    for(int mt=0; mt<4; mt++){
      int r = wm + mt*16 + l15;
      af[mt] = *(sh8*)((char*)As[cur] + r*64 + ((g*16) ^ (((r&3)^((r>>2)&3))<<4)));
    }
    #pragma unroll
    for(int nt=0; nt<4; nt++){
      int r = wn + nt*16 + l15;
      bf[nt] = *(sh8*)((char*)Bs[cur] + r*64 + ((g*16) ^ (((r&3)^((r>>2)&3))<<4)));
    }
    #pragma unroll
    for(int mt=0; mt<4; mt++)
      #pragma unroll
      for(int nt=0; nt<4; nt++)
        acc[mt][nt] = MFMA16(af[mt], bf[nt], acc[mt][nt]);
    __syncthreads();
    cur ^= 1;
  }
  #pragma unroll
  for(int mt=0; mt<4; mt++){
    #pragma unroll
    for(int r=0; r<4; r++){
      int gm = row0 + wm + mt*16 + g*4 + r;
      if(gm >= M) continue;
      #pragma unroll
      for(int nt=0; nt<4; nt++){
        int gn = n0 + wn + nt*16 + l15;
        float v = acc[mt][nt][r];
        if(MODE == 0){
          v += bias[gn];
          ((float*)out0v)[(size_t)gm*CDIM + gn] = v > 0.f ? v : 0.f;
        } else if(MODE == 1){
          int p = gn >> 9, rr = gn & 511;
          int hh = rr >> 6, dd = rr & 63;
          if(p == 0) v *= 0.125f;
          short* dst = (p==0) ? (short*)out0v : (p==1 ? (short*)out1v : (short*)out2v);
          dst[((size_t)hh*NPAD + gm)*DHEAD + dd] = (short)bfbits(v);
        } else {
          ((float*)out0v)[(size_t)gm*CDIM + gn] += v + bias[gn];
        }
      }
    }
  }
}

// ---------------- landmark means (bf16 in, f32 out) ----------------
__global__ void k_landmark(const short* __restrict__ src, float* __restrict__ dst){
  int bidx = blockIdx.x;               // h*256 + m
  int h = bidx >> 8, m = bidx & 255, d = threadIdx.x;
  const short* p = src + ((size_t)h*NPAD + (size_t)m*LFAC)*DHEAD + d;
  float s = 0;
  for(int j=0;j<LFAC;j++) s += bf2f(p[(size_t)j*DHEAD]);
  dst[(size_t)bidx*DHEAD + d] = s * (1.f/LFAC);
}

// ---------------- a2 = softmax(ql @ kl^T) ----------------
__global__ __launch_bounds__(256) void k_a2(const float* __restrict__ ql,
    const float* __restrict__ kl, float* __restrict__ a2){
  __shared__ __hip_bfloat16 klt[64*256];  // [d][m]
  int h = blockIdx.y;
  int t = threadIdx.x;
  const float* klh = kl + (size_t)h*NLAND*DHEAD;
  for(int r=0;r<64;r++){
    int idx = r*256 + t;
    int d = idx >> 8, m = idx & 255;
    klt[idx] = __float2bfloat16(klh[m*DHEAD + d]);
  }
  __syncthreads();
  int w = t >> 6, lane = t & 63;
  const float* qlh = ql + (size_t)h*NLAND*DHEAD;
  for(int rr=0; rr<16; rr++){
    int m = blockIdx.x*64 + w*16 + rr;
    const float* q = qlh + (size_t)m*DHEAD;
    float s[4] = {0,0,0,0};
    #pragma unroll
    for(int d=0; d<64; d++){
      float qv = q[d];
      #pragma unroll
      for(int qd=0; qd<4; qd++)
        s[qd] += qv * __bfloat162float(klt[d*256 + qd*64 + lane]);
    }
    float e[4], den = 0.f;
    #pragma unroll
    for(int qd=0; qd<4; qd++){ e[qd] = __expf(s[qd]); den += e[qd]; }
    den = wave_sum(den);
    float inv = 1.f/den;
    float* arow = a2 + ((size_t)h*NLAND + m)*NLAND;
    #pragma unroll
    for(int qd=0; qd<4; qd++) arow[qd*64 + lane] = e[qd]*inv;
  }
}

// ---------------- pinv init ----------------
__global__ void k_colmax(const float* __restrict__ a2, float* __restrict__ hmax){
  __shared__ float red[4];
  int h = blockIdx.x, t = threadIdx.x;
  const float* p = a2 + (size_t)h*65536 + t;
  float s = 0;
  for(int m=0;m<256;m++) s += p[(size_t)m*256];
  float mx = wave_max(s);
  if((t & 63) == 0) red[t>>6] = mx;
  __syncthreads();
  if(t == 0) hmax[h] = fmaxf(fmaxf(red[0],red[1]), fmaxf(red[2],red[3]));
}
__global__ void k_scal(const float* __restrict__ hmax, float* __restrict__ scal){
  int t = threadIdx.x;
  float v = (t < 8) ? hmax[t] : -1e30f;
  v = wave_max(v);
  if(t == 0) scal[0] = v;
}
__global__ void k_zinit(const float* __restrict__ a2, const float* __restrict__ scal,
                        float* __restrict__ z){
  int h = blockIdx.y;
  int idx = blockIdx.x*256 + threadIdx.x;
  int m = idx >> 8, j = idx & 255;
  z[(size_t)h*65536 + idx] = a2[(size_t)h*65536 + (size_t)j*256 + m] / scal[0];
}

// ---------------- batched f32 GEMM 64x64 tile, 4x4/thread ----------------
template<int TRANS, int OUTT>
__global__ __launch_bounds__(256) void k_sgemm2(const float* __restrict__ A,
    const float* __restrict__ B, float* __restrict__ C,
    int M, int N, int K, long sA, long sB, long sC, float alpha, float beta){
  __shared__ float As[32][68];
  __shared__ float Bs[32][68];
  int bh = blockIdx.z;
  const float* Ah = A + (size_t)bh*sA;
  const float* Bh = B + (size_t)bh*sB;
  float* Ch = C + (size_t)bh*sC;
  int m0 = blockIdx.y*64, n0 = blockIdx.x*64;
  int t = threadIdx.x, tx = t & 15, ty = t >> 4;
  float acc[4][4] = {};
  for(int k0=0; k0<K; k0+=32){
    #pragma unroll
    for(int u=0; u<2; u++){
      int idx = t + u*256;
      int r = idx >> 3, cb = (idx & 7) * 4;
      float4 va = *(const float4*)(Ah + (size_t)(m0+r)*K + k0 + cb);
      As[cb+0][r]=va.x; As[cb+1][r]=va.y; As[cb+2][r]=va.z; As[cb+3][r]=va.w;
      int kr = idx >> 4, nb = (idx & 15) * 4;
      float4 w = *(const float4*)(Bh + (size_t)(k0+kr)*N + n0 + nb);
      if(TRANS){
        int gk = k0 + kr;
        w.x = ((gk==n0+nb+0)?alpha:0.f) - w.x;
        w.y = ((gk==n0+nb+1)?alpha:0.f) - w.y;
        w.z = ((gk==n0+nb+2)?alpha:0.f) - w.z;
        w.w = ((gk==n0+nb+3)?alpha:0.f) - w.w;
      }
      *(float4*)&Bs[kr][nb] = w;
    }
    __syncthreads();
    #pragma unroll
    for(int k=0;k<32;k++){
      float a[4], b[4];
      *(float4*)a = *(const float4*)&As[k][ty*4];
      *(float4*)b = *(const float4*)&Bs[k][tx*4];
      #pragma unroll
      for(int i=0;i<4;i++)
        #pragma unroll
        for(int j=0;j<4;j++) acc[i][j] += a[i]*b[j];
    }
    __syncthreads();
  }
  #pragma unroll
  for(int i=0;i<4;i++){
    #pragma unroll
    for(int j=0;j<4;j++){
      int gm = m0 + ty*4 + i, gn = n0 + tx*4 + j;
      float v = acc[i][j] * beta;
      if(OUTT) Ch[(size_t)gn*M + gm] = v;
      else     Ch[(size_t)gm*N + gn] = v;
    }
  }
}

// ---------------- MFMA flash a1 (Q bf16, F out bf16) ----------------
__global__ __launch_bounds__(256) void k_a1_mfma(const short* __restrict__ Qb,
    const float* __restrict__ kl, const float* __restrict__ w2t, short* __restrict__ F){
  __shared__ short klL[128*64];
  __shared__ short w2L[64*128];
  __shared__ short pL[4][16*128];
  int h = blockIdx.y, n0 = blockIdx.x*128;
  int t = threadIdx.x, lane = t & 63, wv = t >> 6, g = lane >> 4, l15 = lane & 15;
  const float* klh = kl + (size_t)h*NLAND*DHEAD;
  const float* w2h = w2t + (size_t)h*DHEAD*NLAND;
  const short* qbase = Qb + (size_t)h*NPAD*DHEAD;
  sh8 aQ[2][2];
  #pragma unroll
  for(int st=0; st<2; st++)
    #pragma unroll
    for(int kk=0; kk<2; kk++)
      aQ[st][kk] = *(const sh8*)(qbase +
          (size_t)(n0 + wv*32 + st*16 + l15)*DHEAD + kk*32 + g*8);
  f4 accO[2][4] = {};
  float den[2][4] = {};
  short* pw = pL[wv];
  for(int half=0; half<2; half++){
    __syncthreads();
    #pragma unroll
    for(int it=0; it<4; it++){
      int gi = t + it*256;
      int m = gi >> 3, db = (gi & 7) * 8;
      const float* p = klh + (size_t)(half*128 + m)*DHEAD + db;
      *(sh8*)((char*)klL + m*128 + ((db*2) ^ ((m&7)<<4))) =
          pack8f(*(const float4*)p, *(const float4*)(p+4));
      int d = gi >> 4, mb = (gi & 15) * 8;
      const float* p2 = w2h + (size_t)d*NLAND + half*128 + mb;
      *(sh8*)((char*)w2L + d*256 + ((mb*2) ^ ((d&7)<<4))) =
          pack8f(*(const float4*)p2, *(const float4*)(p2+4));
    }
    __syncthreads();
    #pragma unroll
    for(int st=0; st<2; st++){
      #pragma unroll
      for(int mt=0; mt<8; mt++){
        f4 s = {};
        #pragma unroll
        for(int kk=0; kk<2; kk++){
          int m = mt*16 + l15;
          sh8 b = *(sh8*)((char*)klL + m*128 + ((kk*64 + g*16) ^ ((m&7)<<4)));
          s = MFMA16(aQ[st][kk], b, s);
        }
        #pragma unroll
        for(int r=0; r<4; r++){
          float e = __expf(s[r]);
          den[st][r] += e;
          int n = g*4 + r;
          *(short*)((char*)pw + n*256 + (((mt*16+l15)*2) ^ ((n&7)<<4))) = (short)bfbits(e);
        }
      }
      __syncthreads();
      #pragma unroll
      for(int ks=0; ks<4; ks++){
        sh8 aP = *(sh8*)((char*)pw + l15*256 + ((ks*64 + g*16) ^ ((l15&7)<<4)));
        #pragma unroll
        for(int dt=0; dt<4; dt++){
          int d = dt*16 + l15;
          sh8 bW = *(sh8*)((char*)w2L + d*256 + ((ks*64 + g*16) ^ ((d&7)<<4)));
          accO[st][dt] = MFMA16(aP, bW, accO[st][dt]);
        }
      }
      __syncthreads();
    }
  }
  #pragma unroll
  for(int st=0; st<2; st++)
    #pragma unroll
    for(int r=0; r<4; r++){
      float d_ = den[st][r];
      d_ += __shfl_xor(d_,1); d_ += __shfl_xor(d_,2);
      d_ += __shfl_xor(d_,4); d_ += __shfl_xor(d_,8);
      den[st][r] = 1.f/d_;
    }
  #pragma unroll
  for(int st=0; st<2; st++)
    #pragma unroll
    for(int dt=0; dt<4; dt++)
      #pragma unroll
      for(int r=0; r<4; r++){
        int row = n0 + wv*32 + st*16 + g*4 + r;
        F[(size_t)row*CDIM + h*DHEAD + dt*16 + l15] =
            (short)bfbits(accO[st][dt][r]*den[st][r]);
      }
}

// ---------------- MFMA flash a3v (K/V bf16) ----------------
__global__ __launch_bounds__(256) void k_a3v_mfma(const float* __restrict__ ql,
    const short* __restrict__ Kb, const short* __restrict__ Vb,
    float* __restrict__ numP, float* __restrict__ denP){
  __shared__ short kL[128*64];
  __shared__ short vL[64*128];
  __shared__ short pL[4][16*128];
  int h = blockIdx.x, c = blockIdx.y;
  int t = threadIdx.x, lane = t & 63, wv = t >> 6, g = lane >> 4, l15 = lane & 15;
  const float* qlh = ql + (size_t)h*NLAND*DHEAD;
  sh8 aQ[4][2];
  #pragma unroll
  for(int st=0; st<4; st++)
    #pragma unroll
    for(int kk=0; kk<2; kk++){
      const float* p = qlh + (size_t)(wv*64 + st*16 + l15)*DHEAD + kk*32 + g*8;
      aQ[st][kk] = pack8f(*(const float4*)p, *(const float4*)(p+4));
    }
  f4 accO[4][4] = {};
  float den[4][4] = {};
  short* pw = pL[wv];
  for(int half=0; half<2; half++){
    const short* Kh = Kb + ((size_t)h*NPAD + (size_t)c*256 + half*128)*DHEAD;
    const short* Vh = Vb + ((size_t)h*NPAD + (size_t)c*256 + half*128)*DHEAD;
    __syncthreads();
    #pragma unroll
    for(int it=0; it<4; it++){
      int gi = t + it*256;
      int m = gi >> 3, db = (gi & 7) * 8;
      *(sh8*)((char*)kL + m*128 + ((db*2) ^ ((m&7)<<4))) =
          *(const sh8*)(Kh + (size_t)m*DHEAD + db);
    }
    #pragma unroll
    for(int it=0; it<4; it++){
      int idx = t + it*256;                 // 1024 sh8 units
      int m = idx & 127, dg = (idx >> 7) * 8;
      sh8 v = *(const sh8*)(Vh + (size_t)m*DHEAD + dg);
      #pragma unroll
      for(int i=0;i<8;i++){
        int d = dg + i;
        *(short*)((char*)vL + d*256 + ((m*2) ^ ((d&7)<<4))) = v[i];
      }
    }
    __syncthreads();
    #pragma unroll
    for(int st=0; st<4; st++){
      #pragma unroll
      for(int mt=0; mt<8; mt++){
        f4 s = {};
        #pragma unroll
        for(int kk=0; kk<2; kk++){
          int m = mt*16 + l15;
          sh8 b = *(sh8*)((char*)kL + m*128 + ((kk*64 + g*16) ^ ((m&7)<<4)));
          s = MFMA16(aQ[st][kk], b, s);
        }
        #pragma unroll
        for(int r=0; r<4; r++){
          float e = __expf(s[r]);
          den[st][r] += e;
          int n = g*4 + r;
          *(short*)((char*)pw + n*256 + (((mt*16+l15)*2) ^ ((n&7)<<4))) = (short)bfbits(e);
        }
      }
      __syncthreads();
      #pragma unroll
      for(int ks=0; ks<4; ks++){
        sh8 aP = *(sh8*)((char*)pw + l15*256 + ((ks*64 + g*16) ^ ((l15&7)<<4)));
        #pragma unroll
        for(int dt=0; dt<4; dt++){
          int d = dt*16 + l15;
          sh8 bV = *(sh8*)((char*)vL + d*256 + ((ks*64 + g*16) ^ ((d&7)<<4)));
          accO[st][dt] = MFMA16(aP, bV, accO[st][dt]);
        }
      }
      __syncthreads();
    }
  }
  #pragma unroll
  for(int st=0; st<4; st++)
    #pragma unroll
    for(int r=0; r<4; r++){
      float d_ = den[st][r];
      d_ += __shfl_xor(d_,1); d_ += __shfl_xor(d_,2);
      d_ += __shfl_xor(d_,4); d_ += __shfl_xor(d_,8);
      den[st][r] = d_;
    }
  size_t base = ((size_t)h*NCHUNK + c)*NLAND;
  #pragma unroll
  for(int st=0; st<4; st++){
    #pragma unroll
    for(int r=0; r<4; r++){
      int row = wv*64 + st*16 + g*4 + r;
      if(l15 == 0) denP[base + row] = den[st][r];
      #pragma unroll
      for(int dt=0; dt<4; dt++)
        numP[(base + row)*DHEAD + dt*16 + l15] = accO[st][dt][r];
    }
  }
}

__global__ void k_a3v_comb(const float* __restrict__ numP, const float* __restrict__ denP,
                           float* __restrict__ a3v){
  int bidx = blockIdx.x;           // h*256 + m
  int h = bidx >> 8, m = bidx & 255;
  int d = threadIdx.x;
  float s = 0.f, den = 0.f;
  for(int c=0;c<NCHUNK;c++){
    s += numP[(((size_t)h*NCHUNK + c)*NLAND + m)*DHEAD + d];
    den += denP[((size_t)h*NCHUNK + c)*NLAND + m];
  }
  a3v[((size_t)h*NLAND + m)*DHEAD + d] = s / den;
}

// ---------------- residual depthwise conv (k=33), FIR-tiled, V bf16, F bf16 RMW --
__global__ __launch_bounds__(256) void k_resconv(const short* __restrict__ Vb,
    const float* __restrict__ rw, short* __restrict__ F){
  __shared__ float vs[160][64];
  int n0 = blockIdx.x*128, h = blockIdx.y;
  int t = threadIdx.x;
  const short* vh = Vb + (size_t)h*NPAD*DHEAD;
  #pragma unroll
  for(int i=0;i<5;i++){
    int idx = t + i*256;                // 1280 sh8 units: 160 rows x 8 groups
    int r = idx >> 3, dg = (idx & 7)*8;
    int n = n0 - 16 + r;
    sh8 v = {0,0,0,0,0,0,0,0};
    if(n>=0 && n<NPAD) v = *(const sh8*)(vh + (size_t)n*DHEAD + dg);
    #pragma unroll
    for(int e=0;e<8;e++) vs[r][dg+e] = bf2f(v[e]);
  }
  float w[33];
  #pragma unroll
  for(int j=0;j<33;j++) w[j] = rw[h*33+j];
  __syncthreads();
  int d = t & 63, half = t >> 6;
  float acc[32];
  #pragma unroll
  for(int r=0;r<32;r++) acc[r] = 0.f;
  #pragma unroll
  for(int p=0;p<64;p++){
    float vv = vs[half*32 + p][d];
    #pragma unroll
    for(int j=0;j<33;j++){
      int r = p - j;
      if(r >= 0 && r < 32) acc[r] += w[j]*vv;
    }
  }
  #pragma unroll
  for(int r=0;r<32;r++){
    int n = n0 + half*32 + r;
    size_t idx = (size_t)n*CDIM + h*DHEAD + d;
    F[idx] = (short)bfbits(bf2f(F[idx]) + acc[r]);
  }
}

// ---------------- weight transpose f32 -> bf16 ----------------
__global__ void k_transposeb(const float* __restrict__ in, short* __restrict__ out,
                             int R, int C){
  __shared__ float tile[32][33];
  int r0 = blockIdx.x*32, c0 = blockIdx.y*32;
  int tx = threadIdx.x, ty = threadIdx.y;
  #pragma unroll
  for(int r=0;r<4;r++) tile[ty + r*8][tx] = in[(size_t)(r0 + ty + r*8)*C + c0 + tx];
  __syncthreads();
  #pragma unroll
  for(int r=0;r<4;r++)
    out[(size_t)(c0 + ty + r*8)*R + r0 + tx] = (short)bfbits(tile[tx][ty + r*8]);
}

// ---------------- PPEG direct on row-major [n][c] (f32) ----------------
__global__ __launch_bounds__(256) void k_ppeg2(const float* __restrict__ X,
    const float* __restrict__ w7, const float* __restrict__ b7,
    const float* __restrict__ w5, const float* __restrict__ b5,
    const float* __restrict__ w3, const float* __restrict__ b3,
    float* __restrict__ Y){
  __shared__ float patch[484][20];
  int cg = blockIdx.y;
  int ti = blockIdx.x >> 3, tj = blockIdx.x & 7;
  int t = threadIdx.x;
  int i0 = ti*16 - 3, j0 = tj*16 - 3;
  for(int idx = t; idx < 1936; idx += 256){
    int p = idx >> 2, cq = (idx & 3) * 4;
    int gi = i0 + p/22, gj = j0 + p%22;
    float4 v = make_float4(0.f,0.f,0.f,0.f);
    if(gi>=0 && gi<128 && gj>=0 && gj<128)
      v = *(const float4*)(X + (size_t)(gi*128+gj)*CDIM + cg*16 + cq);
    *(float4*)&patch[p][cq] = v;
  }
  int c = t & 15, sg = t >> 4;
  int cglob = cg*16 + c;
  float wr[83];
  #pragma unroll
  for(int k=0;k<49;k++) wr[k] = w7[cglob*49+k];
  #pragma unroll
  for(int k=0;k<25;k++) wr[49+k] = w5[cglob*25+k];
  #pragma unroll
  for(int k=0;k<9;k++)  wr[74+k] = w3[cglob*9+k];
  float bsum = b7[cglob] + b5[cglob] + b3[cglob];
  __syncthreads();
  float acc[16];
  #pragma unroll
  for(int j=0;j<16;j++) acc[j] = patch[(sg+3)*22 + (j+3)][c] + bsum;
  #pragma unroll
  for(int a=0;a<7;a++)
    #pragma unroll
    for(int x=0;x<22;x++){
      float vv = patch[(sg+a)*22 + x][c];
      #pragma unroll
      for(int bq=0;bq<7;bq++){
        int j = x - bq;
        if(j>=0 && j<16) acc[j] += wr[a*7+bq]*vv;
      }
    }
  #pragma unroll
  for(int a=0;a<5;a++)
    #pragma unroll
    for(int x=1;x<21;x++){
      float vv = patch[(sg+a+1)*22 + x][c];
      #pragma unroll
      for(int bq=0;bq<5;bq++){
        int j = x - 1 - bq;
        if(j>=0 && j<16) acc[j] += wr[49+a*5+bq]*vv;
      }
    }
  #pragma unroll
  for(int a=0;a<3;a++)
    #pragma unroll
    for(int x=2;x<20;x++){
      float vv = patch[(sg+a+2)*22 + x][c];
      #pragma unroll
      for(int bq=0;bq<3;bq++){
        int j = x - 2 - bq;
        if(j>=0 && j<16) acc[j] += wr[74+a*3+bq]*vv;
      }
    }
  #pragma unroll
  for(int j=0;j<16;j++)
    Y[(size_t)((ti*16+sg)*128 + tj*16+j)*CDIM + cglob] = acc[j];
}

// ---------------- final LN(row0) + fc2 ----------------
__global__ __launch_bounds__(512) void k_final(const float* __restrict__ A,
    const float* __restrict__ g, const float* __restrict__ b,
    const float* __restrict__ w, const float* __restrict__ bias,
    float* __restrict__ outp){
  __shared__ float red[8];
  int t = threadIdx.x, wv = t >> 6;
  float x = A[t];
  float s = wave_sum(x);
  if((t & 63) == 0) red[wv] = s;
  __syncthreads();
  float mu = 0;
  #pragma unroll
  for(int i=0;i<8;i++) mu += red[i];
  mu *= (1.f/512.f);
  __syncthreads();
  float dx = x - mu;
  s = wave_sum(dx*dx);
  if((t & 63) == 0) red[wv] = s;
  __syncthreads();
  float var = 0;
  #pragma unroll
  for(int i=0;i<8;i++) var += red[i];
  var *= (1.f/512.f);
  float xn = dx * rsqrtf(var + 1e-5f) * g[t] + b[t];
  __syncthreads();
  for(int o=0;o<4;o++){
    s = wave_sum(xn * w[t*4 + o]);
    if((t & 63) == 0) red[wv] = s;
    __syncthreads();
    if(t == 0){
      float r = 0;
      #pragma unroll
      for(int i=0;i<8;i++) r += red[i];
      outp[o] = r + bias[o];
    }
    __syncthreads();
  }
}

extern "C" void kernel_launch(void* const* d_in, const int* in_sizes, int n_in,
                              void* d_out, int out_size, void* d_ws, size_t ws_size,
                              hipStream_t stream) {
  (void)in_sizes; (void)n_in; (void)out_size; (void)ws_size;
  const float* data_x = (const float*)d_in[0];
  const float* fc1_w  = (const float*)d_in[1];
  const float* fc1_b  = (const float*)d_in[2];
  const float* cls_tk = (const float*)d_in[3];
  const float* ng[2]  = {(const float*)d_in[4],  (const float*)d_in[16]};
  const float* nb[2]  = {(const float*)d_in[5],  (const float*)d_in[17]};
  const float* qkvw[2]= {(const float*)d_in[6],  (const float*)d_in[18]};
  const float* outw[2]= {(const float*)d_in[7],  (const float*)d_in[19]};
  const float* outb[2]= {(const float*)d_in[8],  (const float*)d_in[20]};
  const float* resw[2]= {(const float*)d_in[9],  (const float*)d_in[21]};
  const float* w7 = (const float*)d_in[10]; const float* pb7 = (const float*)d_in[11];
  const float* w5 = (const float*)d_in[12]; const float* pb5 = (const float*)d_in[13];
  const float* w3 = (const float*)d_in[14]; const float* pb3 = (const float*)d_in[15];
  const float* norm_g = (const float*)d_in[22];
  const float* norm_b = (const float*)d_in[23];
  const float* fc2_w  = (const float*)d_in[24];
  const float* fc2_b  = (const float*)d_in[25];

  float* ws = (float*)d_ws;
  float* Ab   = ws;                         // TOK*512 f32 (layer-0 h base)
  float* Bb   = Ab + (size_t)TOK*CDIM;      // TOK*512 f32 (post-ppeg h base)
  float* Fb   = Bb + (size_t)TOK*CDIM;      // NPAD*512 f32 (a3v numP scratch)
  short* Fbf  = (short*)(Fb + (size_t)NPAD*CDIM);   // NPAD*512 bf16 pre-proj F
  short* lnX  = Fbf + (size_t)NPAD*CDIM;    // NPAD*512 bf16 (LN out)
  short* Qb   = lnX + (size_t)NPAD*CDIM;    // bf16 head-major
  short* Kb   = Qb  + (size_t)NPAD*CDIM;
  short* Vb   = Kb  + (size_t)NPAD*CDIM;
  short* dxb  = Vb  + (size_t)NPAD*CDIM;    // 16384*1024 bf16 data_x
  float* qlb  = (float*)(dxb + (size_t)16384*1024);
  float* klb  = qlb + NHEAD*NLAND*DHEAD;
  float* a2b  = klb + NHEAD*NLAND*DHEAD;    // 8*65536 f32
  float* z0b  = a2b + NHEAD*NLAND*NLAND;
  float* z1b  = z0b + NHEAD*NLAND*NLAND;
  float* Xb_  = z1b + NHEAD*NLAND*NLAND;
  float* Tb_  = Xb_ + NHEAD*NLAND*NLAND;
  float* Ub_  = Tb_ + NHEAD*NLAND*NLAND;
  float* a3vb = Ub_ + NHEAD*NLAND*NLAND;    // 8*256*64
  float* w2tb = a3vb + NHEAD*NLAND*DHEAD;   // 8*64*256
  float* denP = w2tb + NHEAD*DHEAD*NLAND;   // 8*65*256
  float* hmax = denP + NHEAD*NCHUNK*NLAND;  // 8
  float* scal = hmax + 8;                   // 1
  short* fc1T = (short*)(scal + 8);         // 512*1024 bf16
  short* qkvT0= fc1T + 512*1024;            // 1536*512 bf16
  short* qkvT1= qkvT0 + 1536*512;
  short* outT0= qkvT1 + 1536*512;           // 512*512 bf16
  short* outT1= outT0 + 512*512;
  short* qkvT[2] = {qkvT0, qkvT1};
  short* outT[2] = {outT0, outT1};

  // weight transposes (WT[n][k], bf16) + data_x bf16
  k_transposeb<<<dim3(32,16), dim3(32,8), 0, stream>>>(fc1_w, fc1T, 1024, 512);
  k_transposeb<<<dim3(16,48), dim3(32,8), 0, stream>>>(qkvw[0], qkvT0, 512, 1536);
  k_transposeb<<<dim3(16,48), dim3(32,8), 0, stream>>>(qkvw[1], qkvT1, 512, 1536);
  k_transposeb<<<dim3(16,16), dim3(32,8), 0, stream>>>(outw[0], outT0, 512, 512);
  k_transposeb<<<dim3(16,16), dim3(32,8), 0, stream>>>(outw[1], outT1, 512, 512);
  k_f2b<<<8192, 256, 0, stream>>>(data_x, dxb, 16384*1024/8);

  k_copyrow<<<1, 512, 0, stream>>>(Ab, cls_tk);
  k_gemm_g<0><<<dim3(4, 128), 256, 0, stream>>>(dxb, 1024, fc1T, 1024, fc1_b,
                                                Ab + CDIM, nullptr, nullptr, 16384);
  float* base[2]  = {Ab, Bb};
  for(int L=0; L<2; L++){
    k_ln_pad<<<NPAD/4, 256, 0, stream>>>(base[L], ng[L], nb[L], lnX);
    k_gemm_g<1><<<dim3(12, 130), 256, 0, stream>>>(lnX, CDIM, qkvT[L], CDIM, nullptr,
                                                   Qb, Kb, Vb, NPAD);
    k_landmark<<<NHEAD*NLAND, 64, 0, stream>>>(Qb, qlb);
    k_landmark<<<NHEAD*NLAND, 64, 0, stream>>>(Kb, klb);
    k_a2<<<dim3(4, NHEAD), 256, 0, stream>>>(qlb, klb, a2b);
    k_colmax<<<NHEAD, 256, 0, stream>>>(a2b, hmax);
    k_scal<<<1, 64, 0, stream>>>(hmax, scal);
    k_zinit<<<dim3(256, NHEAD), 256, 0, stream>>>(a2b, scal, z0b);
    float* zc = z0b; float* zn = z1b;
    for(int it=0; it<6; it++){
      k_sgemm2<0,0><<<dim3(4,4,NHEAD), 256, 0, stream>>>(a2b, zc, Xb_, 256,256,256,
                                                         65536,65536,65536, 0.f, 1.f);
      k_sgemm2<1,0><<<dim3(4,4,NHEAD), 256, 0, stream>>>(Xb_, Xb_, Tb_, 256,256,256,
                                                         65536,65536,65536, 7.f, 1.f);
      k_sgemm2<1,0><<<dim3(4,4,NHEAD), 256, 0, stream>>>(Xb_, Tb_, Ub_, 256,256,256,
                                                         65536,65536,65536, 15.f, 1.f);
      k_sgemm2<1,0><<<dim3(4,4,NHEAD), 256, 0, stream>>>(zc, Ub_, zn, 256,256,256,
                                                         65536,65536,65536, 13.f, 0.25f);
      float* tmp = zc; zc = zn; zn = tmp;
    }
    // zc == z0b after 6 iterations
    k_a3v_mfma<<<dim3(NHEAD, NCHUNK), 256, 0, stream>>>(qlb, Kb, Vb, Fb, denP);
    k_a3v_comb<<<NHEAD*NLAND, 64, 0, stream>>>(Fb, denP, a3vb);
    k_sgemm2<0,1><<<dim3(1,4,NHEAD), 256, 0, stream>>>(zc, a3vb, w2tb, 256,64,256,
                                                       65536,16384,16384, 0.f, 1.f);
    k_a1_mfma<<<dim3(130, NHEAD), 256, 0, stream>>>(Qb, klb, w2tb, Fbf);
    k_resconv<<<dim3(130, NHEAD), 256, 0, stream>>>(Vb, resw[L], Fbf);
    k_gemm_g<2><<<dim3(4, 129), 256, 0, stream>>>(Fbf + (size_t)PAD0*CDIM, CDIM,
                                                  outT[L], CDIM, outb[L],
                                                  base[L], nullptr, nullptr, TOK);
    if(L == 0){
      k_ppeg2<<<dim3(64, 32), 256, 0, stream>>>(Ab + CDIM, w7, pb7, w5, pb5, w3, pb3,
                                                Bb + CDIM);
      k_copyrow<<<1, 512, 0, stream>>>(Bb, Ab);
    }
  }
  k_final<<<1, 512, 0, stream>>>(Bb, norm_g, norm_b, fc2_w, fc2_b, (float*)d_out);
}

// Round 13
// 1178.347 us; speedup vs baseline: 2.4448x; 1.3534x over previous
//
#include <hip/hip_runtime.h>
#include <hip/hip_bf16.h>

#define NPAD 16640
#define TOK  16385
#define CDIM 512
#define NHEAD 8
#define DHEAD 64
#define NLAND 256
#define LFAC  65
#define PAD0  255
#define NCHUNK 65   // chunks of 256 rows: 65*256 = 16640

typedef __attribute__((ext_vector_type(8))) short sh8;
typedef __attribute__((ext_vector_type(4))) float f4;

__device__ __forceinline__ float wave_sum(float v){
  #pragma unroll
  for(int o=32;o;o>>=1) v += __shfl_xor(v,o);
  return v;
}
__device__ __forceinline__ float wave_max(float v){
  #pragma unroll
  for(int o=32;o;o>>=1) v = fmaxf(v, __shfl_xor(v,o));
  return v;
}

// bf16 RNE pack helpers
__device__ __forceinline__ unsigned bfbits(float x){
  unsigned u = __float_as_uint(x);
  return (u + 0x7fffu + ((u >> 16) & 1u)) >> 16;
}
__device__ __forceinline__ float bf2f(short s){
  return __uint_as_float(((unsigned)(unsigned short)s) << 16);
}
__device__ __forceinline__ sh8 pack8f(float4 a, float4 b){
  sh8 r;
  r[0]=(short)bfbits(a.x); r[1]=(short)bfbits(a.y); r[2]=(short)bfbits(a.z); r[3]=(short)bfbits(a.w);
  r[4]=(short)bfbits(b.x); r[5]=(short)bfbits(b.y); r[6]=(short)bfbits(b.z); r[7]=(short)bfbits(b.w);
  return r;
}
#define MFMA16(a,b,c) __builtin_amdgcn_mfma_f32_16x16x32_bf16(a,b,c,0,0,0)

// async global->LDS 16B (wave-uniform LDS base + lane*16)
__device__ __forceinline__ void gload16(const void* g, void* l){
  __builtin_amdgcn_global_load_lds(
      (const __attribute__((address_space(1))) void*)g,
      (__attribute__((address_space(3))) void*)l, 16, 0, 0);
}

// ---------------- row copy (cls token) ----------------
__global__ void k_copyrow(float* dst, const float* __restrict__ src){
  dst[threadIdx.x] = src[threadIdx.x];
}

// ---------------- f32 -> bf16 convert ----------------
__global__ __launch_bounds__(256) void k_f2b(const float* __restrict__ in,
    short* __restrict__ out, int n8){
  int i = blockIdx.x*256 + threadIdx.x;
  if(i < n8){
    float4 a = *(const float4*)(in + (size_t)i*8);
    float4 b = *(const float4*)(in + (size_t)i*8 + 4);
    *(sh8*)(out + (size_t)i*8) = pack8f(a, b);
  }
}

// ---------------- layernorm + front pad -> bf16 ----------------
__global__ __launch_bounds__(256) void k_ln_pad(const float* __restrict__ A,
    const float* __restrict__ g, const float* __restrict__ b, short* __restrict__ B){
  int w = threadIdx.x >> 6, lane = threadIdx.x & 63;
  int row = blockIdx.x*4 + w;
  short* out = B + (size_t)row*CDIM;
  int c = lane*8;
  if(row < PAD0){
    sh8 z = {0,0,0,0,0,0,0,0};
    *(sh8*)(out + c) = z;
    return;
  }
  const float* x = A + (size_t)(row-PAD0)*CDIM;
  float4 v0 = *(const float4*)(x + c);
  float4 v1 = *(const float4*)(x + c + 4);
  float xs[8] = {v0.x,v0.y,v0.z,v0.w,v1.x,v1.y,v1.z,v1.w};
  float s = 0;
  #pragma unroll
  for(int i=0;i<8;i++) s += xs[i];
  s = wave_sum(s);
  float mu = s * (1.f/512.f);
  float vs = 0;
  #pragma unroll
  for(int i=0;i<8;i++){ float d = xs[i]-mu; vs += d*d; }
  vs = wave_sum(vs) * (1.f/512.f);
  float rs = rsqrtf(vs + 1e-5f);
  float4 g0 = *(const float4*)(g + c); float4 g1 = *(const float4*)(g + c + 4);
  float4 b0 = *(const float4*)(b + c); float4 b1 = *(const float4*)(b + c + 4);
  float gg[8] = {g0.x,g0.y,g0.z,g0.w,g1.x,g1.y,g1.z,g1.w};
  float bb[8] = {b0.x,b0.y,b0.z,b0.w,b1.x,b1.y,b1.z,b1.w};
  sh8 o;
  #pragma unroll
  for(int i=0;i<8;i++) o[i] = (short)bfbits((xs[i]-mu)*rs*gg[i] + bb[i]);
  *(sh8*)(out + c) = o;
}

// ---------------- gload-staged MFMA GEMM: C[M,N] = A[M,K] @ WT[N,K]^T ----------------
template<int MODE>
__global__ __launch_bounds__(256) void k_gemm_g(const short* __restrict__ A, int lda,
    const short* __restrict__ WT, int K, const float* __restrict__ bias,
    void* out0v, void* out1v, void* out2v, int M){
  __shared__ short As[2][128*32];
  __shared__ short Bs[2][128*32];
  int t = threadIdx.x, lane = t & 63, wv = t >> 6, g = lane >> 4, l15 = lane & 15;
  int nwg = gridDim.x * gridDim.y;
  int orig = blockIdx.y * gridDim.x + blockIdx.x;
  int qc = nwg >> 3, rc = nwg & 7, xcd = orig & 7, loc = orig >> 3;
  int wgid = (xcd < rc ? xcd*(qc+1) : rc*(qc+1) + (xcd - rc)*qc) + loc;
  int row0 = (wgid / gridDim.x) * 128, n0 = (wgid % gridDim.x) * 128;
  int wm = (wv>>1)*64, wn = (wv&1)*64;
  int mq = lane >> 2, slot = lane & 3;

  auto stage = [&](int buf, int k0){
    #pragma unroll
    for(int c=0;c<2;c++){
      int m = wv*32 + c*16 + mq;
      int swz = (((m&3) ^ ((m>>2)&3)) << 4);
      int gr = row0 + m; if(gr >= M) gr = M-1;
      const char* srcA = (const char*)(A + (size_t)gr*lda + k0) + ((slot*16) ^ swz);
      gload16(srcA, (char*)As[buf] + wv*2048 + c*1024);
      const char* srcB = (const char*)(WT + (size_t)(n0+m)*K + k0) + ((slot*16) ^ swz);
      gload16(srcB, (char*)Bs[buf] + wv*2048 + c*1024);
    }
  };

  f4 acc[4][4] = {};
  int nk = K >> 5;
  stage(0, 0);
  __syncthreads();
  int cur = 0;
  for(int i=0; i<nk; i++){
    if(i+1 < nk) stage(cur^1, (i+1) << 5);
    sh8 af[4], bf[4];
    #pragma unroll
    for(int mt=0; mt<4; mt++){
      int r = wm + mt*16 + l15;
      af[mt] = *(sh8*)((char*)As[cur] + r*64 + ((g*16) ^ (((r&3)^((r>>2)&3))<<4)));
    }
    #pragma unroll
    for(int nt=0; nt<4; nt++){
      int r = wn + nt*16 + l15;
      bf[nt] = *(sh8*)((char*)Bs[cur] + r*64 + ((g*16) ^ (((r&3)^((r>>2)&3))<<4)));
    }
    #pragma unroll
    for(int mt=0; mt<4; mt++)
      #pragma unroll
      for(int nt=0; nt<4; nt++)
        acc[mt][nt] = MFMA16(af[mt], bf[nt], acc[mt][nt]);
    __syncthreads();
    cur ^= 1;
  }
  #pragma unroll
  for(int mt=0; mt<4; mt++){
    #pragma unroll
    for(int r=0; r<4; r++){
      int gm = row0 + wm + mt*16 + g*4 + r;
      if(gm >= M) continue;
      #pragma unroll
      for(int nt=0; nt<4; nt++){
        int gn = n0 + wn + nt*16 + l15;
        float v = acc[mt][nt][r];
        if(MODE == 0){
          v += bias[gn];
          ((float*)out0v)[(size_t)gm*CDIM + gn] = v > 0.f ? v : 0.f;
        } else if(MODE == 1){
          int p = gn >> 9, rr = gn & 511;
          int hh = rr >> 6, dd = rr & 63;
          if(p == 0) v *= 0.125f;
          short* dst = (p==0) ? (short*)out0v : (p==1 ? (short*)out1v : (short*)out2v);
          dst[((size_t)hh*NPAD + gm)*DHEAD + dd] = (short)bfbits(v);
        } else {
          ((float*)out0v)[(size_t)gm*CDIM + gn] += v + bias[gn];
        }
      }
    }
  }
}

// ---------------- landmark means (bf16 in, f32 out) ----------------
__global__ void k_landmark(const short* __restrict__ src, float* __restrict__ dst){
  int bidx = blockIdx.x;               // h*256 + m
  int h = bidx >> 8, m = bidx & 255, d = threadIdx.x;
  const short* p = src + ((size_t)h*NPAD + (size_t)m*LFAC)*DHEAD + d;
  float s = 0;
  for(int j=0;j<LFAC;j++) s += bf2f(p[(size_t)j*DHEAD]);
  dst[(size_t)bidx*DHEAD + d] = s * (1.f/LFAC);
}

// ---------------- a2 = softmax(ql @ kl^T) ----------------
__global__ __launch_bounds__(256) void k_a2(const float* __restrict__ ql,
    const float* __restrict__ kl, float* __restrict__ a2){
  __shared__ __hip_bfloat16 klt[64*256];  // [d][m]
  int h = blockIdx.y;
  int t = threadIdx.x;
  const float* klh = kl + (size_t)h*NLAND*DHEAD;
  for(int r=0;r<64;r++){
    int idx = r*256 + t;
    int d = idx >> 8, m = idx & 255;
    klt[idx] = __float2bfloat16(klh[m*DHEAD + d]);
  }
  __syncthreads();
  int w = t >> 6, lane = t & 63;
  const float* qlh = ql + (size_t)h*NLAND*DHEAD;
  for(int rr=0; rr<16; rr++){
    int m = blockIdx.x*64 + w*16 + rr;
    const float* q = qlh + (size_t)m*DHEAD;
    float s[4] = {0,0,0,0};
    #pragma unroll
    for(int d=0; d<64; d++){
      float qv = q[d];
      #pragma unroll
      for(int qd=0; qd<4; qd++)
        s[qd] += qv * __bfloat162float(klt[d*256 + qd*64 + lane]);
    }
    float e[4], den = 0.f;
    #pragma unroll
    for(int qd=0; qd<4; qd++){ e[qd] = __expf(s[qd]); den += e[qd]; }
    den = wave_sum(den);
    float inv = 1.f/den;
    float* arow = a2 + ((size_t)h*NLAND + m)*NLAND;
    #pragma unroll
    for(int qd=0; qd<4; qd++) arow[qd*64 + lane] = e[qd]*inv;
  }
}

// ---------------- pinv init ----------------
__global__ void k_colmax(const float* __restrict__ a2, float* __restrict__ hmax){
  __shared__ float red[4];
  int h = blockIdx.x, t = threadIdx.x;
  const float* p = a2 + (size_t)h*65536 + t;
  float s = 0;
  for(int m=0;m<256;m++) s += p[(size_t)m*256];
  float mx = wave_max(s);
  if((t & 63) == 0) red[t>>6] = mx;
  __syncthreads();
  if(t == 0) hmax[h] = fmaxf(fmaxf(red[0],red[1]), fmaxf(red[2],red[3]));
}
__global__ void k_scal(const float* __restrict__ hmax, float* __restrict__ scal){
  int t = threadIdx.x;
  float v = (t < 8) ? hmax[t] : -1e30f;
  v = wave_max(v);
  if(t == 0) scal[0] = v;
}
__global__ void k_zinit(const float* __restrict__ a2, const float* __restrict__ scal,
                        float* __restrict__ z){
  int h = blockIdx.y;
  int idx = blockIdx.x*256 + threadIdx.x;
  int m = idx >> 8, j = idx & 255;
  z[(size_t)h*65536 + idx] = a2[(size_t)h*65536 + (size_t)j*256 + m] / scal[0];
}

// ---------------- batched MFMA pinv GEMM: C = beta*(A @ (alpha*I-B)?) ----------------
// 256x256 per head, 64x64 tiles, bf16 products / f32 accum+IO.
template<int TRANS>
__global__ __launch_bounds__(256) void k_pgemm(const float* __restrict__ A,
    const float* __restrict__ B, float* __restrict__ C, float alpha, float beta){
  __shared__ short As[64*32];   // [m][k] swizzled
  __shared__ short Bs[64*32];   // [n][k] swizzled (transposed staging)
  int bh = blockIdx.z;
  const float* Ah = A + (size_t)bh*65536;
  const float* Bh = B + (size_t)bh*65536;
  float* Ch = C + (size_t)bh*65536;
  int m0 = blockIdx.y*64, n0 = blockIdx.x*64;
  int t = threadIdx.x, lane = t & 63, wv = t >> 6, g = lane >> 4, l15 = lane & 15;
  f4 acc[4] = {};
  for(int k0=0; k0<256; k0+=32){
    {
      int m = t >> 2, kb = (t & 3)*8;
      float4 va = *(const float4*)(Ah + (size_t)(m0+m)*256 + k0 + kb);
      float4 vb = *(const float4*)(Ah + (size_t)(m0+m)*256 + k0 + kb + 4);
      int swz = (((m&3)^((m>>2)&3))<<4);
      *(sh8*)((char*)As + m*64 + ((kb*2)^swz)) = pack8f(va, vb);
    }
    {
      int kr = t >> 3, nb = (t & 7)*8;
      float4 wa = *(const float4*)(Bh + (size_t)(k0+kr)*256 + n0 + nb);
      float4 wb = *(const float4*)(Bh + (size_t)(k0+kr)*256 + n0 + nb + 4);
      float w8[8] = {wa.x,wa.y,wa.z,wa.w,wb.x,wb.y,wb.z,wb.w};
      #pragma unroll
      for(int e=0;e<8;e++){
        int n = nb + e;
        float val = w8[e];
        if(TRANS) val = ((k0+kr == n0+n) ? alpha : 0.f) - val;
        int swz = (((n&3)^((n>>2)&3))<<4);
        *(short*)((char*)Bs + n*64 + ((kr*2)^swz)) = (short)bfbits(val);
      }
    }
    __syncthreads();
    int rm = wv*16 + l15;
    sh8 af = *(sh8*)((char*)As + rm*64 + ((g*16) ^ (((rm&3)^((rm>>2)&3))<<4)));
    #pragma unroll
    for(int nt=0; nt<4; nt++){
      int n = nt*16 + l15;
      sh8 bf = *(sh8*)((char*)Bs + n*64 + ((g*16) ^ (((n&3)^((n>>2)&3))<<4)));
      acc[nt] = MFMA16(af, bf, acc[nt]);
    }
    __syncthreads();
  }
  #pragma unroll
  for(int nt=0; nt<4; nt++)
    #pragma unroll
    for(int r=0; r<4; r++)
      Ch[(size_t)(m0 + wv*16 + g*4 + r)*256 + n0 + nt*16 + l15] = acc[nt][r]*beta;
}

// ---------------- batched f32 GEMM 64x64 tile (w2^T only) ----------------
template<int TRANS, int OUTT>
__global__ __launch_bounds__(256) void k_sgemm2(const float* __restrict__ A,
    const float* __restrict__ B, float* __restrict__ C,
    int M, int N, int K, long sA, long sB, long sC, float alpha, float beta){
  __shared__ float As[32][68];
  __shared__ float Bs[32][68];
  int bh = blockIdx.z;
  const float* Ah = A + (size_t)bh*sA;
  const float* Bh = B + (size_t)bh*sB;
  float* Ch = C + (size_t)bh*sC;
  int m0 = blockIdx.y*64, n0 = blockIdx.x*64;
  int t = threadIdx.x, tx = t & 15, ty = t >> 4;
  float acc[4][4] = {};
  for(int k0=0; k0<K; k0+=32){
    #pragma unroll
    for(int u=0; u<2; u++){
      int idx = t + u*256;
      int r = idx >> 3, cb = (idx & 7) * 4;
      float4 va = *(const float4*)(Ah + (size_t)(m0+r)*K + k0 + cb);
      As[cb+0][r]=va.x; As[cb+1][r]=va.y; As[cb+2][r]=va.z; As[cb+3][r]=va.w;
      int kr = idx >> 4, nb = (idx & 15) * 4;
      float4 w = *(const float4*)(Bh + (size_t)(k0+kr)*N + n0 + nb);
      if(TRANS){
        int gk = k0 + kr;
        w.x = ((gk==n0+nb+0)?alpha:0.f) - w.x;
        w.y = ((gk==n0+nb+1)?alpha:0.f) - w.y;
        w.z = ((gk==n0+nb+2)?alpha:0.f) - w.z;
        w.w = ((gk==n0+nb+3)?alpha:0.f) - w.w;
      }
      *(float4*)&Bs[kr][nb] = w;
    }
    __syncthreads();
    #pragma unroll
    for(int k=0;k<32;k++){
      float a[4], b[4];
      *(float4*)a = *(const float4*)&As[k][ty*4];
      *(float4*)b = *(const float4*)&Bs[k][tx*4];
      #pragma unroll
      for(int i=0;i<4;i++)
        #pragma unroll
        for(int j=0;j<4;j++) acc[i][j] += a[i]*b[j];
    }
    __syncthreads();
  }
  #pragma unroll
  for(int i=0;i<4;i++){
    #pragma unroll
    for(int j=0;j<4;j++){
      int gm = m0 + ty*4 + i, gn = n0 + tx*4 + j;
      float v = acc[i][j] * beta;
      if(OUTT) Ch[(size_t)gn*M + gm] = v;
      else     Ch[(size_t)gm*N + gn] = v;
    }
  }
}

// ---------------- MFMA flash a1 (Q bf16, F out bf16) ----------------
__global__ __launch_bounds__(256) void k_a1_mfma(const short* __restrict__ Qb,
    const float* __restrict__ kl, const float* __restrict__ w2t, short* __restrict__ F){
  __shared__ short klL[128*64];
  __shared__ short w2L[64*128];
  __shared__ short pL[4][16*128];
  int h = blockIdx.y, n0 = blockIdx.x*128;
  int t = threadIdx.x, lane = t & 63, wv = t >> 6, g = lane >> 4, l15 = lane & 15;
  const float* klh = kl + (size_t)h*NLAND*DHEAD;
  const float* w2h = w2t + (size_t)h*DHEAD*NLAND;
  const short* qbase = Qb + (size_t)h*NPAD*DHEAD;
  sh8 aQ[2][2];
  #pragma unroll
  for(int st=0; st<2; st++)
    #pragma unroll
    for(int kk=0; kk<2; kk++)
      aQ[st][kk] = *(const sh8*)(qbase +
          (size_t)(n0 + wv*32 + st*16 + l15)*DHEAD + kk*32 + g*8);
  f4 accO[2][4] = {};
  float den[2][4] = {};
  short* pw = pL[wv];
  for(int half=0; half<2; half++){
    __syncthreads();
    #pragma unroll
    for(int it=0; it<4; it++){
      int gi = t + it*256;
      int m = gi >> 3, db = (gi & 7) * 8;
      const float* p = klh + (size_t)(half*128 + m)*DHEAD + db;
      *(sh8*)((char*)klL + m*128 + ((db*2) ^ ((m&7)<<4))) =
          pack8f(*(const float4*)p, *(const float4*)(p+4));
      int d = gi >> 4, mb = (gi & 15) * 8;
      const float* p2 = w2h + (size_t)d*NLAND + half*128 + mb;
      *(sh8*)((char*)w2L + d*256 + ((mb*2) ^ ((d&7)<<4))) =
          pack8f(*(const float4*)p2, *(const float4*)(p2+4));
    }
    __syncthreads();
    #pragma unroll
    for(int st=0; st<2; st++){
      #pragma unroll
      for(int mt=0; mt<8; mt++){
        f4 s = {};
        #pragma unroll
        for(int kk=0; kk<2; kk++){
          int m = mt*16 + l15;
          sh8 b = *(sh8*)((char*)klL + m*128 + ((kk*64 + g*16) ^ ((m&7)<<4)));
          s = MFMA16(aQ[st][kk], b, s);
        }
        #pragma unroll
        for(int r=0; r<4; r++){
          float e = __expf(s[r]);
          den[st][r] += e;
          int n = g*4 + r;
          *(short*)((char*)pw + n*256 + (((mt*16+l15)*2) ^ ((n&7)<<4))) = (short)bfbits(e);
        }
      }
      __syncthreads();
      #pragma unroll
      for(int ks=0; ks<4; ks++){
        sh8 aP = *(sh8*)((char*)pw + l15*256 + ((ks*64 + g*16) ^ ((l15&7)<<4)));
        #pragma unroll
        for(int dt=0; dt<4; dt++){
          int d = dt*16 + l15;
          sh8 bW = *(sh8*)((char*)w2L + d*256 + ((ks*64 + g*16) ^ ((d&7)<<4)));
          accO[st][dt] = MFMA16(aP, bW, accO[st][dt]);
        }
      }
      __syncthreads();
    }
  }
  #pragma unroll
  for(int st=0; st<2; st++)
    #pragma unroll
    for(int r=0; r<4; r++){
      float d_ = den[st][r];
      d_ += __shfl_xor(d_,1); d_ += __shfl_xor(d_,2);
      d_ += __shfl_xor(d_,4); d_ += __shfl_xor(d_,8);
      den[st][r] = 1.f/d_;
    }
  #pragma unroll
  for(int st=0; st<2; st++)
    #pragma unroll
    for(int dt=0; dt<4; dt++)
      #pragma unroll
      for(int r=0; r<4; r++){
        int row = n0 + wv*32 + st*16 + g*4 + r;
        F[(size_t)row*CDIM + h*DHEAD + dt*16 + l15] =
            (short)bfbits(accO[st][dt][r]*den[st][r]);
      }
}

// ---------------- MFMA flash a3v (K/V bf16) ----------------
__global__ __launch_bounds__(256) void k_a3v_mfma(const float* __restrict__ ql,
    const short* __restrict__ Kb, const short* __restrict__ Vb,
    float* __restrict__ numP, float* __restrict__ denP){
  __shared__ short kL[128*64];
  __shared__ short vL[64*128];
  __shared__ short pL[4][16*128];
  int h = blockIdx.x, c = blockIdx.y;
  int t = threadIdx.x, lane = t & 63, wv = t >> 6, g = lane >> 4, l15 = lane & 15;
  const float* qlh = ql + (size_t)h*NLAND*DHEAD;
  sh8 aQ[4][2];
  #pragma unroll
  for(int st=0; st<4; st++)
    #pragma unroll
    for(int kk=0; kk<2; kk++){
      const float* p = qlh + (size_t)(wv*64 + st*16 + l15)*DHEAD + kk*32 + g*8;
      aQ[st][kk] = pack8f(*(const float4*)p, *(const float4*)(p+4));
    }
  f4 accO[4][4] = {};
  float den[4][4] = {};
  short* pw = pL[wv];
  for(int half=0; half<2; half++){
    const short* Kh = Kb + ((size_t)h*NPAD + (size_t)c*256 + half*128)*DHEAD;
    const short* Vh = Vb + ((size_t)h*NPAD + (size_t)c*256 + half*128)*DHEAD;
    __syncthreads();
    #pragma unroll
    for(int it=0; it<4; it++){
      int gi = t + it*256;
      int m = gi >> 3, db = (gi & 7) * 8;
      *(sh8*)((char*)kL + m*128 + ((db*2) ^ ((m&7)<<4))) =
          *(const sh8*)(Kh + (size_t)m*DHEAD + db);
    }
    #pragma unroll
    for(int it=0; it<4; it++){
      int idx = t + it*256;                 // 1024 sh8 units
      int m = idx & 127, dg = (idx >> 7) * 8;
      sh8 v = *(const sh8*)(Vh + (size_t)m*DHEAD + dg);
      #pragma unroll
      for(int i=0;i<8;i++){
        int d = dg + i;
        *(short*)((char*)vL + d*256 + ((m*2) ^ ((d&7)<<4))) = v[i];
      }
    }
    __syncthreads();
    #pragma unroll
    for(int st=0; st<4; st++){
      #pragma unroll
      for(int mt=0; mt<8; mt++){
        f4 s = {};
        #pragma unroll
        for(int kk=0; kk<2; kk++){
          int m = mt*16 + l15;
          sh8 b = *(sh8*)((char*)kL + m*128 + ((kk*64 + g*16) ^ ((m&7)<<4)));
          s = MFMA16(aQ[st][kk], b, s);
        }
        #pragma unroll
        for(int r=0; r<4; r++){
          float e = __expf(s[r]);
          den[st][r] += e;
          int n = g*4 + r;
          *(short*)((char*)pw + n*256 + (((mt*16+l15)*2) ^ ((n&7)<<4))) = (short)bfbits(e);
        }
      }
      __syncthreads();
      #pragma unroll
      for(int ks=0; ks<4; ks++){
        sh8 aP = *(sh8*)((char*)pw + l15*256 + ((ks*64 + g*16) ^ ((l15&7)<<4)));
        #pragma unroll
        for(int dt=0; dt<4; dt++){
          int d = dt*16 + l15;
          sh8 bV = *(sh8*)((char*)vL + d*256 + ((ks*64 + g*16) ^ ((d&7)<<4)));
          accO[st][dt] = MFMA16(aP, bV, accO[st][dt]);
        }
      }
      __syncthreads();
    }
  }
  #pragma unroll
  for(int st=0; st<4; st++)
    #pragma unroll
    for(int r=0; r<4; r++){
      float d_ = den[st][r];
      d_ += __shfl_xor(d_,1); d_ += __shfl_xor(d_,2);
      d_ += __shfl_xor(d_,4); d_ += __shfl_xor(d_,8);
      den[st][r] = d_;
    }
  size_t base = ((size_t)h*NCHUNK + c)*NLAND;
  #pragma unroll
  for(int st=0; st<4; st++){
    #pragma unroll
    for(int r=0; r<4; r++){
      int row = wv*64 + st*16 + g*4 + r;
      if(l15 == 0) denP[base + row] = den[st][r];
      #pragma unroll
      for(int dt=0; dt<4; dt++)
        numP[(base + row)*DHEAD + dt*16 + l15] = accO[st][dt][r];
    }
  }
}

__global__ void k_a3v_comb(const float* __restrict__ numP, const float* __restrict__ denP,
                           float* __restrict__ a3v){
  int bidx = blockIdx.x;           // h*256 + m
  int h = bidx >> 8, m = bidx & 255;
  int d = threadIdx.x;
  float s = 0.f, den = 0.f;
  for(int c=0;c<NCHUNK;c++){
    s += numP[(((size_t)h*NCHUNK + c)*NLAND + m)*DHEAD + d];
    den += denP[((size_t)h*NCHUNK + c)*NLAND + m];
  }
  a3v[((size_t)h*NLAND + m)*DHEAD + d] = s / den;
}

// ---------------- residual depthwise conv (k=33), register-FIR, 64-row tiles ----
// grid (260, 8). Each thread: 16 outputs for fixed d; inputs pulled once from
// LDS into 48 regs; F loads issued upfront (independent) then add+store.
__global__ __launch_bounds__(256) void k_resconv(const short* __restrict__ Vb,
    const float* __restrict__ rw, short* __restrict__ F){
  __shared__ float vs[96][64];
  int n0 = blockIdx.x*64, h = blockIdx.y;
  int t = threadIdx.x;
  const short* vh = Vb + (size_t)h*NPAD*DHEAD;
  #pragma unroll
  for(int i=0;i<3;i++){
    int idx = t + i*256;                // 768 sh8 units: 96 rows x 8 groups
    int r = idx >> 3, dg = (idx & 7)*8;
    int n = n0 - 16 + r;
    sh8 v = {0,0,0,0,0,0,0,0};
    if(n>=0 && n<NPAD) v = *(const sh8*)(vh + (size_t)n*DHEAD + dg);
    #pragma unroll
    for(int e=0;e<8;e++) vs[r][dg+e] = bf2f(v[e]);
  }
  float w[33];
  #pragma unroll
  for(int j=0;j<33;j++) w[j] = rw[h*33+j];
  __syncthreads();
  int d = t & 63, grp = t >> 6;
  // preload F (16 independent ushort loads)
  float f0[16];
  #pragma unroll
  for(int rr=0;rr<16;rr++){
    int n = n0 + grp*16 + rr;
    f0[rr] = bf2f(F[(size_t)n*CDIM + h*DHEAD + d]);
  }
  float in[48];
  #pragma unroll
  for(int x=0;x<48;x++) in[x] = vs[grp*16 + x][d];
  #pragma unroll
  for(int rr=0;rr<16;rr++){
    float acc = 0.f;
    #pragma unroll
    for(int j=0;j<33;j++) acc += w[j]*in[rr+j];
    int n = n0 + grp*16 + rr;
    F[(size_t)n*CDIM + h*DHEAD + d] = (short)bfbits(f0[rr] + acc);
  }
}

// ---------------- weight transpose f32 -> bf16 ----------------
__global__ void k_transposeb(const float* __restrict__ in, short* __restrict__ out,
                             int R, int C){
  __shared__ float tile[32][33];
  int r0 = blockIdx.x*32, c0 = blockIdx.y*32;
  int tx = threadIdx.x, ty = threadIdx.y;
  #pragma unroll
  for(int r=0;r<4;r++) tile[ty + r*8][tx] = in[(size_t)(r0 + ty + r*8)*C + c0 + tx];
  __syncthreads();
  #pragma unroll
  for(int r=0;r<4;r++)
    out[(size_t)(c0 + ty + r*8)*R + r0 + tx] = (short)bfbits(tile[tx][ty + r*8]);
}

// ---------------- PPEG direct on row-major [n][c] (f32) ----------------
__global__ __launch_bounds__(256) void k_ppeg2(const float* __restrict__ X,
    const float* __restrict__ w7, const float* __restrict__ b7,
    const float* __restrict__ w5, const float* __restrict__ b5,
    const float* __restrict__ w3, const float* __restrict__ b3,
    float* __restrict__ Y){
  __shared__ float patch[484][20];
  int cg = blockIdx.y;
  int ti = blockIdx.x >> 3, tj = blockIdx.x & 7;
  int t = threadIdx.x;
  int i0 = ti*16 - 3, j0 = tj*16 - 3;
  for(int idx = t; idx < 1936; idx += 256){
    int p = idx >> 2, cq = (idx & 3) * 4;
    int gi = i0 + p/22, gj = j0 + p%22;
    float4 v = make_float4(0.f,0.f,0.f,0.f);
    if(gi>=0 && gi<128 && gj>=0 && gj<128)
      v = *(const float4*)(X + (size_t)(gi*128+gj)*CDIM + cg*16 + cq);
    *(float4*)&patch[p][cq] = v;
  }
  int c = t & 15, sg = t >> 4;
  int cglob = cg*16 + c;
  float wr[83];
  #pragma unroll
  for(int k=0;k<49;k++) wr[k] = w7[cglob*49+k];
  #pragma unroll
  for(int k=0;k<25;k++) wr[49+k] = w5[cglob*25+k];
  #pragma unroll
  for(int k=0;k<9;k++)  wr[74+k] = w3[cglob*9+k];
  float bsum = b7[cglob] + b5[cglob] + b3[cglob];
  __syncthreads();
  float acc[16];
  #pragma unroll
  for(int j=0;j<16;j++) acc[j] = patch[(sg+3)*22 + (j+3)][c] + bsum;
  #pragma unroll
  for(int a=0;a<7;a++)
    #pragma unroll
    for(int x=0;x<22;x++){
      float vv = patch[(sg+a)*22 + x][c];
      #pragma unroll
      for(int bq=0;bq<7;bq++){
        int j = x - bq;
        if(j>=0 && j<16) acc[j] += wr[a*7+bq]*vv;
      }
    }
  #pragma unroll
  for(int a=0;a<5;a++)
    #pragma unroll
    for(int x=1;x<21;x++){
      float vv = patch[(sg+a+1)*22 + x][c];
      #pragma unroll
      for(int bq=0;bq<5;bq++){
        int j = x - 1 - bq;
        if(j>=0 && j<16) acc[j] += wr[49+a*5+bq]*vv;
      }
    }
  #pragma unroll
  for(int a=0;a<3;a++)
    #pragma unroll
    for(int x=2;x<20;x++){
      float vv = patch[(sg+a+2)*22 + x][c];
      #pragma unroll
      for(int bq=0;bq<3;bq++){
        int j = x - 2 - bq;
        if(j>=0 && j<16) acc[j] += wr[74+a*3+bq]*vv;
      }
    }
  #pragma unroll
  for(int j=0;j<16;j++)
    Y[(size_t)((ti*16+sg)*128 + tj*16+j)*CDIM + cglob] = acc[j];
}

// ---------------- final LN(row0) + fc2 ----------------
__global__ __launch_bounds__(512) void k_final(const float* __restrict__ A,
    const float* __restrict__ g, const float* __restrict__ b,
    const float* __restrict__ w, const float* __restrict__ bias,
    float* __restrict__ outp){
  __shared__ float red[8];
  int t = threadIdx.x, wv = t >> 6;
  float x = A[t];
  float s = wave_sum(x);
  if((t & 63) == 0) red[wv] = s;
  __syncthreads();
  float mu = 0;
  #pragma unroll
  for(int i=0;i<8;i++) mu += red[i];
  mu *= (1.f/512.f);
  __syncthreads();
  float dx = x - mu;
  s = wave_sum(dx*dx);
  if((t & 63) == 0) red[wv] = s;
  __syncthreads();
  float var = 0;
  #pragma unroll
  for(int i=0;i<8;i++) var += red[i];
  var *= (1.f/512.f);
  float xn = dx * rsqrtf(var + 1e-5f) * g[t] + b[t];
  __syncthreads();
  for(int o=0;o<4;o++){
    s = wave_sum(xn * w[t*4 + o]);
    if((t & 63) == 0) red[wv] = s;
    __syncthreads();
    if(t == 0){
      float r = 0;
      #pragma unroll
      for(int i=0;i<8;i++) r += red[i];
      outp[o] = r + bias[o];
    }
    __syncthreads();
  }
}

extern "C" void kernel_launch(void* const* d_in, const int* in_sizes, int n_in,
                              void* d_out, int out_size, void* d_ws, size_t ws_size,
                              hipStream_t stream) {
  (void)in_sizes; (void)n_in; (void)out_size; (void)ws_size;
  const float* data_x = (const float*)d_in[0];
  const float* fc1_w  = (const float*)d_in[1];
  const float* fc1_b  = (const float*)d_in[2];
  const float* cls_tk = (const float*)d_in[3];
  const float* ng[2]  = {(const float*)d_in[4],  (const float*)d_in[16]};
  const float* nb[2]  = {(const float*)d_in[5],  (const float*)d_in[17]};
  const float* qkvw[2]= {(const float*)d_in[6],  (const float*)d_in[18]};
  const float* outw[2]= {(const float*)d_in[7],  (const float*)d_in[19]};
  const float* outb[2]= {(const float*)d_in[8],  (const float*)d_in[20]};
  const float* resw[2]= {(const float*)d_in[9],  (const float*)d_in[21]};
  const float* w7 = (const float*)d_in[10]; const float* pb7 = (const float*)d_in[11];
  const float* w5 = (const float*)d_in[12]; const float* pb5 = (const float*)d_in[13];
  const float* w3 = (const float*)d_in[14]; const float* pb3 = (const float*)d_in[15];
  const float* norm_g = (const float*)d_in[22];
  const float* norm_b = (const float*)d_in[23];
  const float* fc2_w  = (const float*)d_in[24];
  const float* fc2_b  = (const float*)d_in[25];

  float* ws = (float*)d_ws;
  float* Ab   = ws;                         // TOK*512 f32 (layer-0 h base)
  float* Bb   = Ab + (size_t)TOK*CDIM;      // TOK*512 f32 (post-ppeg h base)
  float* Fb   = Bb + (size_t)TOK*CDIM;      // NPAD*512 f32 (a3v numP scratch)
  short* Fbf  = (short*)(Fb + (size_t)NPAD*CDIM);   // NPAD*512 bf16 pre-proj F
  short* lnX  = Fbf + (size_t)NPAD*CDIM;    // NPAD*512 bf16 (LN out)
  short* Qb   = lnX + (size_t)NPAD*CDIM;    // bf16 head-major
  short* Kb   = Qb  + (size_t)NPAD*CDIM;
  short* Vb   = Kb  + (size_t)NPAD*CDIM;
  short* dxb  = Vb  + (size_t)NPAD*CDIM;    // 16384*1024 bf16 data_x
  float* qlb  = (float*)(dxb + (size_t)16384*1024);
  float* klb  = qlb + NHEAD*NLAND*DHEAD;
  float* a2b  = klb + NHEAD*NLAND*DHEAD;    // 8*65536 f32
  float* z0b  = a2b + NHEAD*NLAND*NLAND;
  float* z1b  = z0b + NHEAD*NLAND*NLAND;
  float* Xb_  = z1b + NHEAD*NLAND*NLAND;
  float* Tb_  = Xb_ + NHEAD*NLAND*NLAND;
  float* Ub_  = Tb_ + NHEAD*NLAND*NLAND;
  float* a3vb = Ub_ + NHEAD*NLAND*NLAND;    // 8*256*64
  float* w2tb = a3vb + NHEAD*NLAND*DHEAD;   // 8*64*256
  float* denP = w2tb + NHEAD*DHEAD*NLAND;   // 8*65*256
  float* hmax = denP + NHEAD*NCHUNK*NLAND;  // 8
  float* scal = hmax + 8;                   // 1
  short* fc1T = (short*)(scal + 8);         // 512*1024 bf16
  short* qkvT0= fc1T + 512*1024;            // 1536*512 bf16
  short* qkvT1= qkvT0 + 1536*512;
  short* outT0= qkvT1 + 1536*512;           // 512*512 bf16
  short* outT1= outT0 + 512*512;
  short* qkvT[2] = {qkvT0, qkvT1};
  short* outT[2] = {outT0, outT1};

  // weight transposes (WT[n][k], bf16) + data_x bf16
  k_transposeb<<<dim3(32,16), dim3(32,8), 0, stream>>>(fc1_w, fc1T, 1024, 512);
  k_transposeb<<<dim3(16,48), dim3(32,8), 0, stream>>>(qkvw[0], qkvT0, 512, 1536);
  k_transposeb<<<dim3(16,48), dim3(32,8), 0, stream>>>(qkvw[1], qkvT1, 512, 1536);
  k_transposeb<<<dim3(16,16), dim3(32,8), 0, stream>>>(outw[0], outT0, 512, 512);
  k_transposeb<<<dim3(16,16), dim3(32,8), 0, stream>>>(outw[1], outT1, 512, 512);
  k_f2b<<<8192, 256, 0, stream>>>(data_x, dxb, 16384*1024/8);

  k_copyrow<<<1, 512, 0, stream>>>(Ab, cls_tk);
  k_gemm_g<0><<<dim3(4, 128), 256, 0, stream>>>(dxb, 1024, fc1T, 1024, fc1_b,
                                                Ab + CDIM, nullptr, nullptr, 16384);
  float* base[2]  = {Ab, Bb};
  for(int L=0; L<2; L++){
    k_ln_pad<<<NPAD/4, 256, 0, stream>>>(base[L], ng[L], nb[L], lnX);
    k_gemm_g<1><<<dim3(12, 130), 256, 0, stream>>>(lnX, CDIM, qkvT[L], CDIM, nullptr,
                                                   Qb, Kb, Vb, NPAD);
    k_landmark<<<NHEAD*NLAND, 64, 0, stream>>>(Qb, qlb);
    k_landmark<<<NHEAD*NLAND, 64, 0, stream>>>(Kb, klb);
    k_a2<<<dim3(4, NHEAD), 256, 0, stream>>>(qlb, klb, a2b);
    k_colmax<<<NHEAD, 256, 0, stream>>>(a2b, hmax);
    k_scal<<<1, 64, 0, stream>>>(hmax, scal);
    k_zinit<<<dim3(256, NHEAD), 256, 0, stream>>>(a2b, scal, z0b);
    float* zc = z0b; float* zn = z1b;
    for(int it=0; it<6; it++){
      k_pgemm<0><<<dim3(4,4,NHEAD), 256, 0, stream>>>(a2b, zc, Xb_, 0.f, 1.f);
      k_pgemm<1><<<dim3(4,4,NHEAD), 256, 0, stream>>>(Xb_, Xb_, Tb_, 7.f, 1.f);
      k_pgemm<1><<<dim3(4,4,NHEAD), 256, 0, stream>>>(Xb_, Tb_, Ub_, 15.f, 1.f);
      k_pgemm<1><<<dim3(4,4,NHEAD), 256, 0, stream>>>(zc, Ub_, zn, 13.f, 0.25f);
      float* tmp = zc; zc = zn; zn = tmp;
    }
    // zc == z0b after 6 iterations
    k_a3v_mfma<<<dim3(NHEAD, NCHUNK), 256, 0, stream>>>(qlb, Kb, Vb, Fb, denP);
    k_a3v_comb<<<NHEAD*NLAND, 64, 0, stream>>>(Fb, denP, a3vb);
    k_sgemm2<0,1><<<dim3(1,4,NHEAD), 256, 0, stream>>>(zc, a3vb, w2tb, 256,64,256,
                                                       65536,16384,16384, 0.f, 1.f);
    k_a1_mfma<<<dim3(130, NHEAD), 256, 0, stream>>>(Qb, klb, w2tb, Fbf);
    k_resconv<<<dim3(260, NHEAD), 256, 0, stream>>>(Vb, resw[L], Fbf);
    k_gemm_g<2><<<dim3(4, 129), 256, 0, stream>>>(Fbf + (size_t)PAD0*CDIM, CDIM,
                                                  outT[L], CDIM, outb[L],
                                                  base[L], nullptr, nullptr, TOK);
    if(L == 0){
      k_ppeg2<<<dim3(64, 32), 256, 0, stream>>>(Ab + CDIM, w7, pb7, w5, pb5, w3, pb3,
                                                Bb + CDIM);
      k_copyrow<<<1, 512, 0, stream>>>(Bb, Ab);
    }
  }
  k_final<<<1, 512, 0, stream>>>(Bb, norm_g, norm_b, fc2_w, fc2_b, (float*)d_out);
}

// Round 14
// 1159.575 us; speedup vs baseline: 2.4843x; 1.0162x over previous
//
#include <hip/hip_runtime.h>
#include <hip/hip_bf16.h>

#define NPAD 16640
#define TOK  16385
#define CDIM 512
#define NHEAD 8
#define DHEAD 64
#define NLAND 256
#define LFAC  65
#define PAD0  255
#define NCHUNK 65     // 256-row chunks
#define CGRP 3        // chunks per block in a3v
#define NCG 22        // ceil(65/3)

typedef __attribute__((ext_vector_type(8))) short sh8;
typedef __attribute__((ext_vector_type(4))) float f4;

__device__ __forceinline__ float wave_sum(float v){
  #pragma unroll
  for(int o=32;o;o>>=1) v += __shfl_xor(v,o);
  return v;
}
__device__ __forceinline__ float wave_max(float v){
  #pragma unroll
  for(int o=32;o;o>>=1) v = fmaxf(v, __shfl_xor(v,o));
  return v;
}

__device__ __forceinline__ unsigned bfbits(float x){
  unsigned u = __float_as_uint(x);
  return (u + 0x7fffu + ((u >> 16) & 1u)) >> 16;
}
__device__ __forceinline__ float bf2f(short s){
  return __uint_as_float(((unsigned)(unsigned short)s) << 16);
}
__device__ __forceinline__ sh8 pack8f(float4 a, float4 b){
  sh8 r;
  r[0]=(short)bfbits(a.x); r[1]=(short)bfbits(a.y); r[2]=(short)bfbits(a.z); r[3]=(short)bfbits(a.w);
  r[4]=(short)bfbits(b.x); r[5]=(short)bfbits(b.y); r[6]=(short)bfbits(b.z); r[7]=(short)bfbits(b.w);
  return r;
}
#define MFMA16(a,b,c) __builtin_amdgcn_mfma_f32_16x16x32_bf16(a,b,c,0,0,0)

__device__ __forceinline__ void gload16(const void* g, void* l){
  __builtin_amdgcn_global_load_lds(
      (const __attribute__((address_space(1))) void*)g,
      (__attribute__((address_space(3))) void*)l, 16, 0, 0);
}

// ---------------- row copy (cls token) ----------------
__global__ void k_copyrow(float* dst, const float* __restrict__ src){
  dst[threadIdx.x] = src[threadIdx.x];
}

// ---------------- f32 -> bf16 convert ----------------
__global__ __launch_bounds__(256) void k_f2b(const float* __restrict__ in,
    short* __restrict__ out, int n8){
  int i = blockIdx.x*256 + threadIdx.x;
  if(i < n8){
    float4 a = *(const float4*)(in + (size_t)i*8);
    float4 b = *(const float4*)(in + (size_t)i*8 + 4);
    *(sh8*)(out + (size_t)i*8) = pack8f(a, b);
  }
}

// ---------------- layernorm + front pad -> bf16 ----------------
__global__ __launch_bounds__(256) void k_ln_pad(const float* __restrict__ A,
    const float* __restrict__ g, const float* __restrict__ b, short* __restrict__ B){
  int w = threadIdx.x >> 6, lane = threadIdx.x & 63;
  int row = blockIdx.x*4 + w;
  short* out = B + (size_t)row*CDIM;
  int c = lane*8;
  if(row < PAD0){
    sh8 z = {0,0,0,0,0,0,0,0};
    *(sh8*)(out + c) = z;
    return;
  }
  const float* x = A + (size_t)(row-PAD0)*CDIM;
  float4 v0 = *(const float4*)(x + c);
  float4 v1 = *(const float4*)(x + c + 4);
  float xs[8] = {v0.x,v0.y,v0.z,v0.w,v1.x,v1.y,v1.z,v1.w};
  float s = 0;
  #pragma unroll
  for(int i=0;i<8;i++) s += xs[i];
  s = wave_sum(s);
  float mu = s * (1.f/512.f);
  float vs = 0;
  #pragma unroll
  for(int i=0;i<8;i++){ float d = xs[i]-mu; vs += d*d; }
  vs = wave_sum(vs) * (1.f/512.f);
  float rs = rsqrtf(vs + 1e-5f);
  float4 g0 = *(const float4*)(g + c); float4 g1 = *(const float4*)(g + c + 4);
  float4 b0 = *(const float4*)(b + c); float4 b1 = *(const float4*)(b + c + 4);
  float gg[8] = {g0.x,g0.y,g0.z,g0.w,g1.x,g1.y,g1.z,g1.w};
  float bb[8] = {b0.x,b0.y,b0.z,b0.w,b1.x,b1.y,b1.z,b1.w};
  sh8 o;
  #pragma unroll
  for(int i=0;i<8;i++) o[i] = (short)bfbits((xs[i]-mu)*rs*gg[i] + bb[i]);
  *(sh8*)(out + c) = o;
}

// ---------------- gload-staged MFMA GEMM: C[M,N] = A[M,K] @ WT[N,K]^T ----------------
template<int MODE>
__global__ __launch_bounds__(256) void k_gemm_g(const short* __restrict__ A, int lda,
    const short* __restrict__ WT, int K, const float* __restrict__ bias,
    void* out0v, void* out1v, void* out2v, int M){
  __shared__ short As[2][128*32];
  __shared__ short Bs[2][128*32];
  int t = threadIdx.x, lane = t & 63, wv = t >> 6, g = lane >> 4, l15 = lane & 15;
  int nwg = gridDim.x * gridDim.y;
  int orig = blockIdx.y * gridDim.x + blockIdx.x;
  int qc = nwg >> 3, rc = nwg & 7, xcd = orig & 7, loc = orig >> 3;
  int wgid = (xcd < rc ? xcd*(qc+1) : rc*(qc+1) + (xcd - rc)*qc) + loc;
  int row0 = (wgid / gridDim.x) * 128, n0 = (wgid % gridDim.x) * 128;
  int wm = (wv>>1)*64, wn = (wv&1)*64;
  int mq = lane >> 2, slot = lane & 3;

  auto stage = [&](int buf, int k0){
    #pragma unroll
    for(int c=0;c<2;c++){
      int m = wv*32 + c*16 + mq;
      int swz = (((m&3) ^ ((m>>2)&3)) << 4);
      int gr = row0 + m; if(gr >= M) gr = M-1;
      const char* srcA = (const char*)(A + (size_t)gr*lda + k0) + ((slot*16) ^ swz);
      gload16(srcA, (char*)As[buf] + wv*2048 + c*1024);
      const char* srcB = (const char*)(WT + (size_t)(n0+m)*K + k0) + ((slot*16) ^ swz);
      gload16(srcB, (char*)Bs[buf] + wv*2048 + c*1024);
    }
  };

  f4 acc[4][4] = {};
  int nk = K >> 5;
  stage(0, 0);
  __syncthreads();
  int cur = 0;
  for(int i=0; i<nk; i++){
    if(i+1 < nk) stage(cur^1, (i+1) << 5);
    sh8 af[4], bf[4];
    #pragma unroll
    for(int mt=0; mt<4; mt++){
      int r = wm + mt*16 + l15;
      af[mt] = *(sh8*)((char*)As[cur] + r*64 + ((g*16) ^ (((r&3)^((r>>2)&3))<<4)));
    }
    #pragma unroll
    for(int nt=0; nt<4; nt++){
      int r = wn + nt*16 + l15;
      bf[nt] = *(sh8*)((char*)Bs[cur] + r*64 + ((g*16) ^ (((r&3)^((r>>2)&3))<<4)));
    }
    #pragma unroll
    for(int mt=0; mt<4; mt++)
      #pragma unroll
      for(int nt=0; nt<4; nt++)
        acc[mt][nt] = MFMA16(af[mt], bf[nt], acc[mt][nt]);
    __syncthreads();
    cur ^= 1;
  }
  #pragma unroll
  for(int mt=0; mt<4; mt++){
    #pragma unroll
    for(int r=0; r<4; r++){
      int gm = row0 + wm + mt*16 + g*4 + r;
      if(gm >= M) continue;
      #pragma unroll
      for(int nt=0; nt<4; nt++){
        int gn = n0 + wn + nt*16 + l15;
        float v = acc[mt][nt][r];
        if(MODE == 0){
          v += bias[gn];
          ((float*)out0v)[(size_t)gm*CDIM + gn] = v > 0.f ? v : 0.f;
        } else if(MODE == 1){
          int p = gn >> 9, rr = gn & 511;
          int hh = rr >> 6, dd = rr & 63;
          if(p == 0) v *= 0.125f;
          short* dst = (p==0) ? (short*)out0v : (p==1 ? (short*)out1v : (short*)out2v);
          dst[((size_t)hh*NPAD + gm)*DHEAD + dd] = (short)bfbits(v);
        } else {
          ((float*)out0v)[(size_t)gm*CDIM + gn] += v + bias[gn];
        }
      }
    }
  }
}

// ---------------- landmark means, Q and K in one dispatch ----------------
__global__ void k_landmark2(const short* __restrict__ Qb, const short* __restrict__ Kb,
    float* __restrict__ ql, float* __restrict__ kl){
  int bidx = blockIdx.x;               // [0,2*2048): first half Q, second half K
  int sel = bidx >> 11;
  int loc = bidx & 2047;               // h*256 + m
  int h = loc >> 8, m = loc & 255, d = threadIdx.x;
  const short* src = (sel ? Kb : Qb) + ((size_t)h*NPAD + (size_t)m*LFAC)*DHEAD + d;
  float s = 0;
  for(int j=0;j<LFAC;j++) s += bf2f(src[(size_t)j*DHEAD]);
  (sel ? kl : ql)[(size_t)loc*DHEAD + d] = s * (1.f/LFAC);
}

// ---------------- a2 = softmax(ql @ kl^T) ----------------
__global__ __launch_bounds__(256) void k_a2(const float* __restrict__ ql,
    const float* __restrict__ kl, float* __restrict__ a2){
  __shared__ __hip_bfloat16 klt[64*256];  // [d][m]
  int h = blockIdx.y;
  int t = threadIdx.x;
  const float* klh = kl + (size_t)h*NLAND*DHEAD;
  for(int r=0;r<64;r++){
    int idx = r*256 + t;
    int d = idx >> 8, m = idx & 255;
    klt[idx] = __float2bfloat16(klh[m*DHEAD + d]);
  }
  __syncthreads();
  int w = t >> 6, lane = t & 63;
  const float* qlh = ql + (size_t)h*NLAND*DHEAD;
  for(int rr=0; rr<16; rr++){
    int m = blockIdx.x*64 + w*16 + rr;
    const float* q = qlh + (size_t)m*DHEAD;
    float s[4] = {0,0,0,0};
    #pragma unroll
    for(int d=0; d<64; d++){
      float qv = q[d];
      #pragma unroll
      for(int qd=0; qd<4; qd++)
        s[qd] += qv * __bfloat162float(klt[d*256 + qd*64 + lane]);
    }
    float e[4], den = 0.f;
    #pragma unroll
    for(int qd=0; qd<4; qd++){ e[qd] = __expf(s[qd]); den += e[qd]; }
    den = wave_sum(den);
    float inv = 1.f/den;
    float* arow = a2 + ((size_t)h*NLAND + m)*NLAND;
    #pragma unroll
    for(int qd=0; qd<4; qd++) arow[qd*64 + lane] = e[qd]*inv;
  }
}

// ---------------- pinv init ----------------
__global__ void k_colmax(const float* __restrict__ a2, float* __restrict__ hmax){
  __shared__ float red[4];
  int h = blockIdx.x, t = threadIdx.x;
  const float* p = a2 + (size_t)h*65536 + t;
  float s = 0;
  for(int m=0;m<256;m++) s += p[(size_t)m*256];
  float mx = wave_max(s);
  if((t & 63) == 0) red[t>>6] = mx;
  __syncthreads();
  if(t == 0) hmax[h] = fmaxf(fmaxf(red[0],red[1]), fmaxf(red[2],red[3]));
}
// z0 = a2^T / max(hmax)   (global max computed inline)
__global__ void k_zinit(const float* __restrict__ a2, const float* __restrict__ hmax,
                        float* __restrict__ z){
  int h = blockIdx.y;
  int idx = blockIdx.x*256 + threadIdx.x;
  int m = idx >> 8, j = idx & 255;
  float mx = hmax[0];
  #pragma unroll
  for(int i=1;i<8;i++) mx = fmaxf(mx, hmax[i]);
  z[(size_t)h*65536 + idx] = a2[(size_t)h*65536 + (size_t)j*256 + m] / mx;
}

// ---------------- batched MFMA pinv GEMM: C = beta*(A @ (alpha*I-B)?) ----------------
template<int TRANS>
__global__ __launch_bounds__(256) void k_pgemm(const float* __restrict__ A,
    const float* __restrict__ B, float* __restrict__ C, float alpha, float beta){
  __shared__ short As[64*32];
  __shared__ short Bs[64*32];
  int bh = blockIdx.z;
  const float* Ah = A + (size_t)bh*65536;
  const float* Bh = B + (size_t)bh*65536;
  float* Ch = C + (size_t)bh*65536;
  int m0 = blockIdx.y*64, n0 = blockIdx.x*64;
  int t = threadIdx.x, lane = t & 63, wv = t >> 6, g = lane >> 4, l15 = lane & 15;
  f4 acc[4] = {};
  for(int k0=0; k0<256; k0+=32){
    {
      int m = t >> 2, kb = (t & 3)*8;
      float4 va = *(const float4*)(Ah + (size_t)(m0+m)*256 + k0 + kb);
      float4 vb = *(const float4*)(Ah + (size_t)(m0+m)*256 + k0 + kb + 4);
      int swz = (((m&3)^((m>>2)&3))<<4);
      *(sh8*)((char*)As + m*64 + ((kb*2)^swz)) = pack8f(va, vb);
    }
    {
      int kr = t >> 3, nb = (t & 7)*8;
      float4 wa = *(const float4*)(Bh + (size_t)(k0+kr)*256 + n0 + nb);
      float4 wb = *(const float4*)(Bh + (size_t)(k0+kr)*256 + n0 + nb + 4);
      float w8[8] = {wa.x,wa.y,wa.z,wa.w,wb.x,wb.y,wb.z,wb.w};
      #pragma unroll
      for(int e=0;e<8;e++){
        int n = nb + e;
        float val = w8[e];
        if(TRANS) val = ((k0+kr == n0+n) ? alpha : 0.f) - val;
        int swz = (((n&3)^((n>>2)&3))<<4);
        *(short*)((char*)Bs + n*64 + ((kr*2)^swz)) = (short)bfbits(val);
      }
    }
    __syncthreads();
    int rm = wv*16 + l15;
    sh8 af = *(sh8*)((char*)As + rm*64 + ((g*16) ^ (((rm&3)^((rm>>2)&3))<<4)));
    #pragma unroll
    for(int nt=0; nt<4; nt++){
      int n = nt*16 + l15;
      sh8 bf = *(sh8*)((char*)Bs + n*64 + ((g*16) ^ (((n&3)^((n>>2)&3))<<4)));
      acc[nt] = MFMA16(af, bf, acc[nt]);
    }
    __syncthreads();
  }
  #pragma unroll
  for(int nt=0; nt<4; nt++)
    #pragma unroll
    for(int r=0; r<4; r++)
      Ch[(size_t)(m0 + wv*16 + g*4 + r)*256 + n0 + nt*16 + l15] = acc[nt][r]*beta;
}

// ---------------- batched f32 GEMM 64x64 tile (w2^T only) ----------------
template<int TRANS, int OUTT>
__global__ __launch_bounds__(256) void k_sgemm2(const float* __restrict__ A,
    const float* __restrict__ B, float* __restrict__ C,
    int M, int N, int K, long sA, long sB, long sC, float alpha, float beta){
  __shared__ float As[32][68];
  __shared__ float Bs[32][68];
  int bh = blockIdx.z;
  const float* Ah = A + (size_t)bh*sA;
  const float* Bh = B + (size_t)bh*sB;
  float* Ch = C + (size_t)bh*sC;
  int m0 = blockIdx.y*64, n0 = blockIdx.x*64;
  int t = threadIdx.x, tx = t & 15, ty = t >> 4;
  float acc[4][4] = {};
  for(int k0=0; k0<K; k0+=32){
    #pragma unroll
    for(int u=0; u<2; u++){
      int idx = t + u*256;
      int r = idx >> 3, cb = (idx & 7) * 4;
      float4 va = *(const float4*)(Ah + (size_t)(m0+r)*K + k0 + cb);
      As[cb+0][r]=va.x; As[cb+1][r]=va.y; As[cb+2][r]=va.z; As[cb+3][r]=va.w;
      int kr = idx >> 4, nb = (idx & 15) * 4;
      float4 w = *(const float4*)(Bh + (size_t)(k0+kr)*N + n0 + nb);
      if(TRANS){
        int gk = k0 + kr;
        w.x = ((gk==n0+nb+0)?alpha:0.f) - w.x;
        w.y = ((gk==n0+nb+1)?alpha:0.f) - w.y;
        w.z = ((gk==n0+nb+2)?alpha:0.f) - w.z;
        w.w = ((gk==n0+nb+3)?alpha:0.f) - w.w;
      }
      *(float4*)&Bs[kr][nb] = w;
    }
    __syncthreads();
    #pragma unroll
    for(int k=0;k<32;k++){
      float a[4], b[4];
      *(float4*)a = *(const float4*)&As[k][ty*4];
      *(float4*)b = *(const float4*)&Bs[k][tx*4];
      #pragma unroll
      for(int i=0;i<4;i++)
        #pragma unroll
        for(int j=0;j<4;j++) acc[i][j] += a[i]*b[j];
    }
    __syncthreads();
  }
  #pragma unroll
  for(int i=0;i<4;i++){
    #pragma unroll
    for(int j=0;j<4;j++){
      int gm = m0 + ty*4 + i, gn = n0 + tx*4 + j;
      float v = acc[i][j] * beta;
      if(OUTT) Ch[(size_t)gn*M + gm] = v;
      else     Ch[(size_t)gm*N + gn] = v;
    }
  }
}

// ---------------- MFMA flash a1 (Q bf16, F out bf16) ----------------
__global__ __launch_bounds__(256) void k_a1_mfma(const short* __restrict__ Qb,
    const float* __restrict__ kl, const float* __restrict__ w2t, short* __restrict__ F){
  __shared__ short klL[128*64];
  __shared__ short w2L[64*128];
  __shared__ short pL[4][16*128];
  int h = blockIdx.y, n0 = blockIdx.x*128;
  int t = threadIdx.x, lane = t & 63, wv = t >> 6, g = lane >> 4, l15 = lane & 15;
  const float* klh = kl + (size_t)h*NLAND*DHEAD;
  const float* w2h = w2t + (size_t)h*DHEAD*NLAND;
  const short* qbase = Qb + (size_t)h*NPAD*DHEAD;
  sh8 aQ[2][2];
  #pragma unroll
  for(int st=0; st<2; st++)
    #pragma unroll
    for(int kk=0; kk<2; kk++)
      aQ[st][kk] = *(const sh8*)(qbase +
          (size_t)(n0 + wv*32 + st*16 + l15)*DHEAD + kk*32 + g*8);
  f4 accO[2][4] = {};
  float den[2][4] = {};
  short* pw = pL[wv];
  for(int half=0; half<2; half++){
    __syncthreads();
    #pragma unroll
    for(int it=0; it<4; it++){
      int gi = t + it*256;
      int m = gi >> 3, db = (gi & 7) * 8;
      const float* p = klh + (size_t)(half*128 + m)*DHEAD + db;
      *(sh8*)((char*)klL + m*128 + ((db*2) ^ ((m&7)<<4))) =
          pack8f(*(const float4*)p, *(const float4*)(p+4));
      int d = gi >> 4, mb = (gi & 15) * 8;
      const float* p2 = w2h + (size_t)d*NLAND + half*128 + mb;
      *(sh8*)((char*)w2L + d*256 + ((mb*2) ^ ((d&7)<<4))) =
          pack8f(*(const float4*)p2, *(const float4*)(p2+4));
    }
    __syncthreads();
    #pragma unroll
    for(int st=0; st<2; st++){
      #pragma unroll
      for(int mt=0; mt<8; mt++){
        f4 s = {};
        #pragma unroll
        for(int kk=0; kk<2; kk++){
          int m = mt*16 + l15;
          sh8 b = *(sh8*)((char*)klL + m*128 + ((kk*64 + g*16) ^ ((m&7)<<4)));
          s = MFMA16(aQ[st][kk], b, s);
        }
        #pragma unroll
        for(int r=0; r<4; r++){
          float e = __expf(s[r]);
          den[st][r] += e;
          int n = g*4 + r;
          *(short*)((char*)pw + n*256 + (((mt*16+l15)*2) ^ ((n&7)<<4))) = (short)bfbits(e);
        }
      }
      __syncthreads();
      #pragma unroll
      for(int ks=0; ks<4; ks++){
        sh8 aP = *(sh8*)((char*)pw + l15*256 + ((ks*64 + g*16) ^ ((l15&7)<<4)));
        #pragma unroll
        for(int dt=0; dt<4; dt++){
          int d = dt*16 + l15;
          sh8 bW = *(sh8*)((char*)w2L + d*256 + ((ks*64 + g*16) ^ ((d&7)<<4)));
          accO[st][dt] = MFMA16(aP, bW, accO[st][dt]);
        }
      }
      __syncthreads();
    }
  }
  #pragma unroll
  for(int st=0; st<2; st++)
    #pragma unroll
    for(int r=0; r<4; r++){
      float d_ = den[st][r];
      d_ += __shfl_xor(d_,1); d_ += __shfl_xor(d_,2);
      d_ += __shfl_xor(d_,4); d_ += __shfl_xor(d_,8);
      den[st][r] = 1.f/d_;
    }
  #pragma unroll
  for(int st=0; st<2; st++)
    #pragma unroll
    for(int dt=0; dt<4; dt++)
      #pragma unroll
      for(int r=0; r<4; r++){
        int row = n0 + wv*32 + st*16 + g*4 + r;
        F[(size_t)row*CDIM + h*DHEAD + dt*16 + l15] =
            (short)bfbits(accO[st][dt][r]*den[st][r]);
      }
}

// ---------------- MFMA flash a3v: CGRP chunks accumulated per block ----------------
__global__ __launch_bounds__(256) void k_a3v_mfma(const float* __restrict__ ql,
    const short* __restrict__ Kb, const short* __restrict__ Vb,
    float* __restrict__ numP, float* __restrict__ denP){
  __shared__ short kL[128*64];
  __shared__ short vL[64*128];
  __shared__ short pL[4][16*128];
  int h = blockIdx.x, cg = blockIdx.y;
  int t = threadIdx.x, lane = t & 63, wv = t >> 6, g = lane >> 4, l15 = lane & 15;
  const float* qlh = ql + (size_t)h*NLAND*DHEAD;
  sh8 aQ[4][2];
  #pragma unroll
  for(int st=0; st<4; st++)
    #pragma unroll
    for(int kk=0; kk<2; kk++){
      const float* p = qlh + (size_t)(wv*64 + st*16 + l15)*DHEAD + kk*32 + g*8;
      aQ[st][kk] = pack8f(*(const float4*)p, *(const float4*)(p+4));
    }
  f4 accO[4][4] = {};
  float den[4][4] = {};
  short* pw = pL[wv];
  for(int cc=0; cc<CGRP; cc++){
    int c = cg*CGRP + cc;
    if(c >= NCHUNK) break;
    for(int half=0; half<2; half++){
      const short* Kh = Kb + ((size_t)h*NPAD + (size_t)c*256 + half*128)*DHEAD;
      const short* Vh = Vb + ((size_t)h*NPAD + (size_t)c*256 + half*128)*DHEAD;
      __syncthreads();
      #pragma unroll
      for(int it=0; it<4; it++){
        int gi = t + it*256;
        int m = gi >> 3, db = (gi & 7) * 8;
        *(sh8*)((char*)kL + m*128 + ((db*2) ^ ((m&7)<<4))) =
            *(const sh8*)(Kh + (size_t)m*DHEAD + db);
      }
      #pragma unroll
      for(int it=0; it<4; it++){
        int idx = t + it*256;
        int m = idx & 127, dg = (idx >> 7) * 8;
        sh8 v = *(const sh8*)(Vh + (size_t)m*DHEAD + dg);
        #pragma unroll
        for(int i=0;i<8;i++){
          int d = dg + i;
          *(short*)((char*)vL + d*256 + ((m*2) ^ ((d&7)<<4))) = v[i];
        }
      }
      __syncthreads();
      #pragma unroll
      for(int st=0; st<4; st++){
        #pragma unroll
        for(int mt=0; mt<8; mt++){
          f4 s = {};
          #pragma unroll
          for(int kk=0; kk<2; kk++){
            int m = mt*16 + l15;
            sh8 b = *(sh8*)((char*)kL + m*128 + ((kk*64 + g*16) ^ ((m&7)<<4)));
            s = MFMA16(aQ[st][kk], b, s);
          }
          #pragma unroll
          for(int r=0; r<4; r++){
            float e = __expf(s[r]);
            den[st][r] += e;
            int n = g*4 + r;
            *(short*)((char*)pw + n*256 + (((mt*16+l15)*2) ^ ((n&7)<<4))) = (short)bfbits(e);
          }
        }
        __syncthreads();
        #pragma unroll
        for(int ks=0; ks<4; ks++){
          sh8 aP = *(sh8*)((char*)pw + l15*256 + ((ks*64 + g*16) ^ ((l15&7)<<4)));
          #pragma unroll
          for(int dt=0; dt<4; dt++){
            int d = dt*16 + l15;
            sh8 bV = *(sh8*)((char*)vL + d*256 + ((ks*64 + g*16) ^ ((d&7)<<4)));
            accO[st][dt] = MFMA16(aP, bV, accO[st][dt]);
          }
        }
        __syncthreads();
      }
    }
  }
  #pragma unroll
  for(int st=0; st<4; st++)
    #pragma unroll
    for(int r=0; r<4; r++){
      float d_ = den[st][r];
      d_ += __shfl_xor(d_,1); d_ += __shfl_xor(d_,2);
      d_ += __shfl_xor(d_,4); d_ += __shfl_xor(d_,8);
      den[st][r] = d_;
    }
  size_t base = ((size_t)h*NCG + cg)*NLAND;
  #pragma unroll
  for(int st=0; st<4; st++){
    #pragma unroll
    for(int r=0; r<4; r++){
      int row = wv*64 + st*16 + g*4 + r;
      if(l15 == 0) denP[base + row] = den[st][r];
      #pragma unroll
      for(int dt=0; dt<4; dt++)
        numP[(base + row)*DHEAD + dt*16 + l15] = accO[st][dt][r];
    }
  }
}

__global__ void k_a3v_comb(const float* __restrict__ numP, const float* __restrict__ denP,
                           float* __restrict__ a3v){
  int bidx = blockIdx.x;           // h*256 + m
  int h = bidx >> 8, m = bidx & 255;
  int d = threadIdx.x;
  float s = 0.f, den = 0.f;
  for(int c=0;c<NCG;c++){
    s += numP[(((size_t)h*NCG + c)*NLAND + m)*DHEAD + d];
    den += denP[((size_t)h*NCG + c)*NLAND + m];
  }
  a3v[((size_t)h*NLAND + m)*DHEAD + d] = s / den;
}

// ---------------- residual depthwise conv (k=33), register-FIR ----------------
__global__ __launch_bounds__(256) void k_resconv(const short* __restrict__ Vb,
    const float* __restrict__ rw, short* __restrict__ F){
  __shared__ float vs[96][64];
  int n0 = blockIdx.x*64, h = blockIdx.y;
  int t = threadIdx.x;
  const short* vh = Vb + (size_t)h*NPAD*DHEAD;
  #pragma unroll
  for(int i=0;i<3;i++){
    int idx = t + i*256;
    int r = idx >> 3, dg = (idx & 7)*8;
    int n = n0 - 16 + r;
    sh8 v = {0,0,0,0,0,0,0,0};
    if(n>=0 && n<NPAD) v = *(const sh8*)(vh + (size_t)n*DHEAD + dg);
    #pragma unroll
    for(int e=0;e<8;e++) vs[r][dg+e] = bf2f(v[e]);
  }
  float w[33];
  #pragma unroll
  for(int j=0;j<33;j++) w[j] = rw[h*33+j];
  __syncthreads();
  int d = t & 63, grp = t >> 6;
  float f0[16];
  #pragma unroll
  for(int rr=0;rr<16;rr++){
    int n = n0 + grp*16 + rr;
    f0[rr] = bf2f(F[(size_t)n*CDIM + h*DHEAD + d]);
  }
  float in[48];
  #pragma unroll
  for(int x=0;x<48;x++) in[x] = vs[grp*16 + x][d];
  #pragma unroll
  for(int rr=0;rr<16;rr++){
    float acc = 0.f;
    #pragma unroll
    for(int j=0;j<33;j++) acc += w[j]*in[rr+j];
    int n = n0 + grp*16 + rr;
    F[(size_t)n*CDIM + h*DHEAD + d] = (short)bfbits(f0[rr] + acc);
  }
}

// ---------------- weight transpose f32 -> bf16 ----------------
__global__ void k_transposeb(const float* __restrict__ in, short* __restrict__ out,
                             int R, int C){
  __shared__ float tile[32][33];
  int r0 = blockIdx.x*32, c0 = blockIdx.y*32;
  int tx = threadIdx.x, ty = threadIdx.y;
  #pragma unroll
  for(int r=0;r<4;r++) tile[ty + r*8][tx] = in[(size_t)(r0 + ty + r*8)*C + c0 + tx];
  __syncthreads();
  #pragma unroll
  for(int r=0;r<4;r++)
    out[(size_t)(c0 + ty + r*8)*R + r0 + tx] = (short)bfbits(tile[tx][ty + r*8]);
}

// ---------------- PPEG direct on row-major [n][c] (f32) ----------------
__global__ __launch_bounds__(256) void k_ppeg2(const float* __restrict__ X,
    const float* __restrict__ w7, const float* __restrict__ b7,
    const float* __restrict__ w5, const float* __restrict__ b5,
    const float* __restrict__ w3, const float* __restrict__ b3,
    float* __restrict__ Y){
  __shared__ float patch[484][20];
  int cg = blockIdx.y;
  int ti = blockIdx.x >> 3, tj = blockIdx.x & 7;
  int t = threadIdx.x;
  int i0 = ti*16 - 3, j0 = tj*16 - 3;
  for(int idx = t; idx < 1936; idx += 256){
    int p = idx >> 2, cq = (idx & 3) * 4;
    int gi = i0 + p/22, gj = j0 + p%22;
    float4 v = make_float4(0.f,0.f,0.f,0.f);
    if(gi>=0 && gi<128 && gj>=0 && gj<128)
      v = *(const float4*)(X + (size_t)(gi*128+gj)*CDIM + cg*16 + cq);
    *(float4*)&patch[p][cq] = v;
  }
  int c = t & 15, sg = t >> 4;
  int cglob = cg*16 + c;
  float wr[83];
  #pragma unroll
  for(int k=0;k<49;k++) wr[k] = w7[cglob*49+k];
  #pragma unroll
  for(int k=0;k<25;k++) wr[49+k] = w5[cglob*25+k];
  #pragma unroll
  for(int k=0;k<9;k++)  wr[74+k] = w3[cglob*9+k];
  float bsum = b7[cglob] + b5[cglob] + b3[cglob];
  __syncthreads();
  float acc[16];
  #pragma unroll
  for(int j=0;j<16;j++) acc[j] = patch[(sg+3)*22 + (j+3)][c] + bsum;
  #pragma unroll
  for(int a=0;a<7;a++)
    #pragma unroll
    for(int x=0;x<22;x++){
      float vv = patch[(sg+a)*22 + x][c];
      #pragma unroll
      for(int bq=0;bq<7;bq++){
        int j = x - bq;
        if(j>=0 && j<16) acc[j] += wr[a*7+bq]*vv;
      }
    }
  #pragma unroll
  for(int a=0;a<5;a++)
    #pragma unroll
    for(int x=1;x<21;x++){
      float vv = patch[(sg+a+1)*22 + x][c];
      #pragma unroll
      for(int bq=0;bq<5;bq++){
        int j = x - 1 - bq;
        if(j>=0 && j<16) acc[j] += wr[49+a*5+bq]*vv;
      }
    }
  #pragma unroll
  for(int a=0;a<3;a++)
    #pragma unroll
    for(int x=2;x<20;x++){
      float vv = patch[(sg+a+2)*22 + x][c];
      #pragma unroll
      for(int bq=0;bq<3;bq++){
        int j = x - 2 - bq;
        if(j>=0 && j<16) acc[j] += wr[74+a*3+bq]*vv;
      }
    }
  #pragma unroll
  for(int j=0;j<16;j++)
    Y[(size_t)((ti*16+sg)*128 + tj*16+j)*CDIM + cglob] = acc[j];
}

// ---------------- final LN(row0) + fc2 ----------------
__global__ __launch_bounds__(512) void k_final(const float* __restrict__ A,
    const float* __restrict__ g, const float* __restrict__ b,
    const float* __restrict__ w, const float* __restrict__ bias,
    float* __restrict__ outp){
  __shared__ float red[8];
  int t = threadIdx.x, wv = t >> 6;
  float x = A[t];
  float s = wave_sum(x);
  if((t & 63) == 0) red[wv] = s;
  __syncthreads();
  float mu = 0;
  #pragma unroll
  for(int i=0;i<8;i++) mu += red[i];
  mu *= (1.f/512.f);
  __syncthreads();
  float dx = x - mu;
  s = wave_sum(dx*dx);
  if((t & 63) == 0) red[wv] = s;
  __syncthreads();
  float var = 0;
  #pragma unroll
  for(int i=0;i<8;i++) var += red[i];
  var *= (1.f/512.f);
  float xn = dx * rsqrtf(var + 1e-5f) * g[t] + b[t];
  __syncthreads();
  for(int o=0;o<4;o++){
    s = wave_sum(xn * w[t*4 + o]);
    if((t & 63) == 0) red[wv] = s;
    __syncthreads();
    if(t == 0){
      float r = 0;
      #pragma unroll
      for(int i=0;i<8;i++) r += red[i];
      outp[o] = r + bias[o];
    }
    __syncthreads();
  }
}

extern "C" void kernel_launch(void* const* d_in, const int* in_sizes, int n_in,
                              void* d_out, int out_size, void* d_ws, size_t ws_size,
                              hipStream_t stream) {
  (void)in_sizes; (void)n_in; (void)out_size; (void)ws_size;
  const float* data_x = (const float*)d_in[0];
  const float* fc1_w  = (const float*)d_in[1];
  const float* fc1_b  = (const float*)d_in[2];
  const float* cls_tk = (const float*)d_in[3];
  const float* ng[2]  = {(const float*)d_in[4],  (const float*)d_in[16]};
  const float* nb[2]  = {(const float*)d_in[5],  (const float*)d_in[17]};
  const float* qkvw[2]= {(const float*)d_in[6],  (const float*)d_in[18]};
  const float* outw[2]= {(const float*)d_in[7],  (const float*)d_in[19]};
  const float* outb[2]= {(const float*)d_in[8],  (const float*)d_in[20]};
  const float* resw[2]= {(const float*)d_in[9],  (const float*)d_in[21]};
  const float* w7 = (const float*)d_in[10]; const float* pb7 = (const float*)d_in[11];
  const float* w5 = (const float*)d_in[12]; const float* pb5 = (const float*)d_in[13];
  const float* w3 = (const float*)d_in[14]; const float* pb3 = (const float*)d_in[15];
  const float* norm_g = (const float*)d_in[22];
  const float* norm_b = (const float*)d_in[23];
  const float* fc2_w  = (const float*)d_in[24];
  const float* fc2_b  = (const float*)d_in[25];

  float* ws = (float*)d_ws;
  float* Ab   = ws;                         // TOK*512 f32 (layer-0 h base)
  float* Bb   = Ab + (size_t)TOK*CDIM;      // TOK*512 f32 (post-ppeg h base)
  float* Fb   = Bb + (size_t)TOK*CDIM;      // a3v numP scratch (<= NPAD*512 f32)
  short* Fbf  = (short*)(Fb + (size_t)NPAD*CDIM);   // NPAD*512 bf16 pre-proj F
  short* lnX  = Fbf + (size_t)NPAD*CDIM;    // NPAD*512 bf16 (LN out)
  short* Qb   = lnX + (size_t)NPAD*CDIM;    // bf16 head-major
  short* Kb   = Qb  + (size_t)NPAD*CDIM;
  short* Vb   = Kb  + (size_t)NPAD*CDIM;
  short* dxb  = Vb  + (size_t)NPAD*CDIM;    // 16384*1024 bf16 data_x
  float* qlb  = (float*)(dxb + (size_t)16384*1024);
  float* klb  = qlb + NHEAD*NLAND*DHEAD;
  float* a2b  = klb + NHEAD*NLAND*DHEAD;    // 8*65536 f32
  float* z0b  = a2b + NHEAD*NLAND*NLAND;
  float* z1b  = z0b + NHEAD*NLAND*NLAND;
  float* Xb_  = z1b + NHEAD*NLAND*NLAND;
  float* Tb_  = Xb_ + NHEAD*NLAND*NLAND;
  float* Ub_  = Tb_ + NHEAD*NLAND*NLAND;
  float* a3vb = Ub_ + NHEAD*NLAND*NLAND;    // 8*256*64
  float* w2tb = a3vb + NHEAD*NLAND*DHEAD;   // 8*64*256
  float* denP = w2tb + NHEAD*DHEAD*NLAND;   // 8*22*256
  float* hmax = denP + NHEAD*NCG*NLAND;     // 8
  float* scal = hmax + 8;                   // 1 (unused)
  short* fc1T = (short*)(scal + 8);         // 512*1024 bf16
  short* qkvT0= fc1T + 512*1024;            // 1536*512 bf16
  short* qkvT1= qkvT0 + 1536*512;
  short* outT0= qkvT1 + 1536*512;           // 512*512 bf16
  short* outT1= outT0 + 512*512;
  short* qkvT[2] = {qkvT0, qkvT1};
  short* outT[2] = {outT0, outT1};

  k_transposeb<<<dim3(32,16), dim3(32,8), 0, stream>>>(fc1_w, fc1T, 1024, 512);
  k_transposeb<<<dim3(16,48), dim3(32,8), 0, stream>>>(qkvw[0], qkvT0, 512, 1536);
  k_transposeb<<<dim3(16,48), dim3(32,8), 0, stream>>>(qkvw[1], qkvT1, 512, 1536);
  k_transposeb<<<dim3(16,16), dim3(32,8), 0, stream>>>(outw[0], outT0, 512, 512);
  k_transposeb<<<dim3(16,16), dim3(32,8), 0, stream>>>(outw[1], outT1, 512, 512);
  k_f2b<<<8192, 256, 0, stream>>>(data_x, dxb, 16384*1024/8);

  k_copyrow<<<1, 512, 0, stream>>>(Ab, cls_tk);
  k_gemm_g<0><<<dim3(4, 128), 256, 0, stream>>>(dxb, 1024, fc1T, 1024, fc1_b,
                                                Ab + CDIM, nullptr, nullptr, 16384);
  float* base[2]  = {Ab, Bb};
  for(int L=0; L<2; L++){
    k_ln_pad<<<NPAD/4, 256, 0, stream>>>(base[L], ng[L], nb[L], lnX);
    k_gemm_g<1><<<dim3(12, 130), 256, 0, stream>>>(lnX, CDIM, qkvT[L], CDIM, nullptr,
                                                   Qb, Kb, Vb, NPAD);
    k_landmark2<<<2*NHEAD*NLAND, 64, 0, stream>>>(Qb, Kb, qlb, klb);
    k_a2<<<dim3(4, NHEAD), 256, 0, stream>>>(qlb, klb, a2b);
    k_colmax<<<NHEAD, 256, 0, stream>>>(a2b, hmax);
    k_zinit<<<dim3(256, NHEAD), 256, 0, stream>>>(a2b, hmax, z0b);
    float* zc = z0b; float* zn = z1b;
    for(int it=0; it<6; it++){
      k_pgemm<0><<<dim3(4,4,NHEAD), 256, 0, stream>>>(a2b, zc, Xb_, 0.f, 1.f);
      k_pgemm<1><<<dim3(4,4,NHEAD), 256, 0, stream>>>(Xb_, Xb_, Tb_, 7.f, 1.f);
      k_pgemm<1><<<dim3(4,4,NHEAD), 256, 0, stream>>>(Xb_, Tb_, Ub_, 15.f, 1.f);
      k_pgemm<1><<<dim3(4,4,NHEAD), 256, 0, stream>>>(zc, Ub_, zn, 13.f, 0.25f);
      float* tmp = zc; zc = zn; zn = tmp;
    }
    // zc == z0b after 6 iterations
    k_a3v_mfma<<<dim3(NHEAD, NCG), 256, 0, stream>>>(qlb, Kb, Vb, Fb, denP);
    k_a3v_comb<<<NHEAD*NLAND, 64, 0, stream>>>(Fb, denP, a3vb);
    k_sgemm2<0,1><<<dim3(1,4,NHEAD), 256, 0, stream>>>(zc, a3vb, w2tb, 256,64,256,
                                                       65536,16384,16384, 0.f, 1.f);
    k_a1_mfma<<<dim3(130, NHEAD), 256, 0, stream>>>(Qb, klb, w2tb, Fbf);
    k_resconv<<<dim3(260, NHEAD), 256, 0, stream>>>(Vb, resw[L], Fbf);
    k_gemm_g<2><<<dim3(4, 129), 256, 0, stream>>>(Fbf + (size_t)PAD0*CDIM, CDIM,
                                                  outT[L], CDIM, outb[L],
                                                  base[L], nullptr, nullptr, TOK);
    if(L == 0){
      k_ppeg2<<<dim3(64, 32), 256, 0, stream>>>(Ab + CDIM, w7, pb7, w5, pb5, w3, pb3,
                                                Bb + CDIM);
      k_copyrow<<<1, 512, 0, stream>>>(Bb, Ab);
    }
  }
  k_final<<<1, 512, 0, stream>>>(Bb, norm_g, norm_b, fc2_w, fc2_b, (float*)d_out);
}

// Round 15
// 1145.264 us; speedup vs baseline: 2.5154x; 1.0125x over previous
//
#include <hip/hip_runtime.h>
#include <hip/hip_bf16.h>

#define NPAD 16640
#define TOK  16385
#define CDIM 512
#define NHEAD 8
#define DHEAD 64
#define NLAND 256
#define LFAC  65
#define PAD0  255
#define NCHUNK 65     // 256-row chunks
#define CGRP 2        // chunks per block in a3v
#define NCG 33        // ceil(65/2)

typedef __attribute__((ext_vector_type(8))) short sh8;
typedef __attribute__((ext_vector_type(4))) float f4;

__device__ __forceinline__ float wave_sum(float v){
  #pragma unroll
  for(int o=32;o;o>>=1) v += __shfl_xor(v,o);
  return v;
}
__device__ __forceinline__ float wave_max(float v){
  #pragma unroll
  for(int o=32;o;o>>=1) v = fmaxf(v, __shfl_xor(v,o));
  return v;
}

__device__ __forceinline__ unsigned bfbits(float x){
  unsigned u = __float_as_uint(x);
  return (u + 0x7fffu + ((u >> 16) & 1u)) >> 16;
}
__device__ __forceinline__ float bf2f(short s){
  return __uint_as_float(((unsigned)(unsigned short)s) << 16);
}
__device__ __forceinline__ sh8 pack8f(float4 a, float4 b){
  sh8 r;
  r[0]=(short)bfbits(a.x); r[1]=(short)bfbits(a.y); r[2]=(short)bfbits(a.z); r[3]=(short)bfbits(a.w);
  r[4]=(short)bfbits(b.x); r[5]=(short)bfbits(b.y); r[6]=(short)bfbits(b.z); r[7]=(short)bfbits(b.w);
  return r;
}
#define MFMA16(a,b,c) __builtin_amdgcn_mfma_f32_16x16x32_bf16(a,b,c,0,0,0)

__device__ __forceinline__ void gload16(const void* g, void* l){
  __builtin_amdgcn_global_load_lds(
      (const __attribute__((address_space(1))) void*)g,
      (__attribute__((address_space(3))) void*)l, 16, 0, 0);
}

// ---------------- row copy (cls token) ----------------
__global__ void k_copyrow(float* dst, const float* __restrict__ src){
  dst[threadIdx.x] = src[threadIdx.x];
}

// ---------------- f32 -> bf16 convert ----------------
__global__ __launch_bounds__(256) void k_f2b(const float* __restrict__ in,
    short* __restrict__ out, int n8){
  int i = blockIdx.x*256 + threadIdx.x;
  if(i < n8){
    float4 a = *(const float4*)(in + (size_t)i*8);
    float4 b = *(const float4*)(in + (size_t)i*8 + 4);
    *(sh8*)(out + (size_t)i*8) = pack8f(a, b);
  }
}

// ---------------- layernorm + front pad -> bf16 ----------------
__global__ __launch_bounds__(256) void k_ln_pad(const float* __restrict__ A,
    const float* __restrict__ g, const float* __restrict__ b, short* __restrict__ B){
  int w = threadIdx.x >> 6, lane = threadIdx.x & 63;
  int row = blockIdx.x*4 + w;
  short* out = B + (size_t)row*CDIM;
  int c = lane*8;
  if(row < PAD0){
    sh8 z = {0,0,0,0,0,0,0,0};
    *(sh8*)(out + c) = z;
    return;
  }
  const float* x = A + (size_t)(row-PAD0)*CDIM;
  float4 v0 = *(const float4*)(x + c);
  float4 v1 = *(const float4*)(x + c + 4);
  float xs[8] = {v0.x,v0.y,v0.z,v0.w,v1.x,v1.y,v1.z,v1.w};
  float s = 0;
  #pragma unroll
  for(int i=0;i<8;i++) s += xs[i];
  s = wave_sum(s);
  float mu = s * (1.f/512.f);
  float vs = 0;
  #pragma unroll
  for(int i=0;i<8;i++){ float d = xs[i]-mu; vs += d*d; }
  vs = wave_sum(vs) * (1.f/512.f);
  float rs = rsqrtf(vs + 1e-5f);
  float4 g0 = *(const float4*)(g + c); float4 g1 = *(const float4*)(g + c + 4);
  float4 b0 = *(const float4*)(b + c); float4 b1 = *(const float4*)(b + c + 4);
  float gg[8] = {g0.x,g0.y,g0.z,g0.w,g1.x,g1.y,g1.z,g1.w};
  float bb[8] = {b0.x,b0.y,b0.z,b0.w,b1.x,b1.y,b1.z,b1.w};
  sh8 o;
  #pragma unroll
  for(int i=0;i<8;i++) o[i] = (short)bfbits((xs[i]-mu)*rs*gg[i] + bb[i]);
  *(sh8*)(out + c) = o;
}

// ---------------- gload-staged MFMA GEMM: C[M,N] = A[M,K] @ WT[N,K]^T ----------------
template<int MODE>
__global__ __launch_bounds__(256) void k_gemm_g(const short* __restrict__ A, int lda,
    const short* __restrict__ WT, int K, const float* __restrict__ bias,
    void* out0v, void* out1v, void* out2v, int M){
  __shared__ short As[2][128*32];
  __shared__ short Bs[2][128*32];
  int t = threadIdx.x, lane = t & 63, wv = t >> 6, g = lane >> 4, l15 = lane & 15;
  int nwg = gridDim.x * gridDim.y;
  int orig = blockIdx.y * gridDim.x + blockIdx.x;
  int qc = nwg >> 3, rc = nwg & 7, xcd = orig & 7, loc = orig >> 3;
  int wgid = (xcd < rc ? xcd*(qc+1) : rc*(qc+1) + (xcd - rc)*qc) + loc;
  int row0 = (wgid / gridDim.x) * 128, n0 = (wgid % gridDim.x) * 128;
  int wm = (wv>>1)*64, wn = (wv&1)*64;
  int mq = lane >> 2, slot = lane & 3;

  auto stage = [&](int buf, int k0){
    #pragma unroll
    for(int c=0;c<2;c++){
      int m = wv*32 + c*16 + mq;
      int swz = (((m&3) ^ ((m>>2)&3)) << 4);
      int gr = row0 + m; if(gr >= M) gr = M-1;
      const char* srcA = (const char*)(A + (size_t)gr*lda + k0) + ((slot*16) ^ swz);
      gload16(srcA, (char*)As[buf] + wv*2048 + c*1024);
      const char* srcB = (const char*)(WT + (size_t)(n0+m)*K + k0) + ((slot*16) ^ swz);
      gload16(srcB, (char*)Bs[buf] + wv*2048 + c*1024);
    }
  };

  f4 acc[4][4] = {};
  int nk = K >> 5;
  stage(0, 0);
  __syncthreads();
  int cur = 0;
  for(int i=0; i<nk; i++){
    if(i+1 < nk) stage(cur^1, (i+1) << 5);
    sh8 af[4], bf[4];
    #pragma unroll
    for(int mt=0; mt<4; mt++){
      int r = wm + mt*16 + l15;
      af[mt] = *(sh8*)((char*)As[cur] + r*64 + ((g*16) ^ (((r&3)^((r>>2)&3))<<4)));
    }
    #pragma unroll
    for(int nt=0; nt<4; nt++){
      int r = wn + nt*16 + l15;
      bf[nt] = *(sh8*)((char*)Bs[cur] + r*64 + ((g*16) ^ (((r&3)^((r>>2)&3))<<4)));
    }
    #pragma unroll
    for(int mt=0; mt<4; mt++)
      #pragma unroll
      for(int nt=0; nt<4; nt++)
        acc[mt][nt] = MFMA16(af[mt], bf[nt], acc[mt][nt]);
    __syncthreads();
    cur ^= 1;
  }
  #pragma unroll
  for(int mt=0; mt<4; mt++){
    #pragma unroll
    for(int r=0; r<4; r++){
      int gm = row0 + wm + mt*16 + g*4 + r;
      if(gm >= M) continue;
      #pragma unroll
      for(int nt=0; nt<4; nt++){
        int gn = n0 + wn + nt*16 + l15;
        float v = acc[mt][nt][r];
        if(MODE == 0){
          v += bias[gn];
          ((float*)out0v)[(size_t)gm*CDIM + gn] = v > 0.f ? v : 0.f;
        } else if(MODE == 1){
          int p = gn >> 9, rr = gn & 511;
          int hh = rr >> 6, dd = rr & 63;
          if(p == 0) v *= 0.125f;
          short* dst = (p==0) ? (short*)out0v : (p==1 ? (short*)out1v : (short*)out2v);
          dst[((size_t)hh*NPAD + gm)*DHEAD + dd] = (short)bfbits(v);
        } else {
          ((float*)out0v)[(size_t)gm*CDIM + gn] += v + bias[gn];
        }
      }
    }
  }
}

// ---------------- landmark means, Q and K in one dispatch ----------------
__global__ void k_landmark2(const short* __restrict__ Qb, const short* __restrict__ Kb,
    float* __restrict__ ql, float* __restrict__ kl){
  int bidx = blockIdx.x;
  int sel = bidx >> 11;
  int loc = bidx & 2047;
  int h = loc >> 8, m = loc & 255, d = threadIdx.x;
  const short* src = (sel ? Kb : Qb) + ((size_t)h*NPAD + (size_t)m*LFAC)*DHEAD + d;
  float s = 0;
  for(int j=0;j<LFAC;j++) s += bf2f(src[(size_t)j*DHEAD]);
  (sel ? kl : ql)[(size_t)loc*DHEAD + d] = s * (1.f/LFAC);
}

// ---------------- a2 = softmax(ql @ kl^T) ----------------
__global__ __launch_bounds__(256) void k_a2(const float* __restrict__ ql,
    const float* __restrict__ kl, float* __restrict__ a2){
  __shared__ __hip_bfloat16 klt[64*256];
  int h = blockIdx.y;
  int t = threadIdx.x;
  const float* klh = kl + (size_t)h*NLAND*DHEAD;
  for(int r=0;r<64;r++){
    int idx = r*256 + t;
    int d = idx >> 8, m = idx & 255;
    klt[idx] = __float2bfloat16(klh[m*DHEAD + d]);
  }
  __syncthreads();
  int w = t >> 6, lane = t & 63;
  const float* qlh = ql + (size_t)h*NLAND*DHEAD;
  for(int rr=0; rr<16; rr++){
    int m = blockIdx.x*64 + w*16 + rr;
    const float* q = qlh + (size_t)m*DHEAD;
    float s[4] = {0,0,0,0};
    #pragma unroll
    for(int d=0; d<64; d++){
      float qv = q[d];
      #pragma unroll
      for(int qd=0; qd<4; qd++)
        s[qd] += qv * __bfloat162float(klt[d*256 + qd*64 + lane]);
    }
    float e[4], den = 0.f;
    #pragma unroll
    for(int qd=0; qd<4; qd++){ e[qd] = __expf(s[qd]); den += e[qd]; }
    den = wave_sum(den);
    float inv = 1.f/den;
    float* arow = a2 + ((size_t)h*NLAND + m)*NLAND;
    #pragma unroll
    for(int qd=0; qd<4; qd++) arow[qd*64 + lane] = e[qd]*inv;
  }
}

// ---------------- pinv init ----------------
__global__ void k_colmax(const float* __restrict__ a2, float* __restrict__ hmax){
  __shared__ float red[4];
  int h = blockIdx.x, t = threadIdx.x;
  const float* p = a2 + (size_t)h*65536 + t;
  float s = 0;
  for(int m=0;m<256;m++) s += p[(size_t)m*256];
  float mx = wave_max(s);
  if((t & 63) == 0) red[t>>6] = mx;
  __syncthreads();
  if(t == 0) hmax[h] = fmaxf(fmaxf(red[0],red[1]), fmaxf(red[2],red[3]));
}
__global__ void k_zinit(const float* __restrict__ a2, const float* __restrict__ hmax,
                        float* __restrict__ z){
  int h = blockIdx.y;
  int idx = blockIdx.x*256 + threadIdx.x;
  int m = idx >> 8, j = idx & 255;
  float mx = hmax[0];
  #pragma unroll
  for(int i=1;i<8;i++) mx = fmaxf(mx, hmax[i]);
  z[(size_t)h*65536 + idx] = a2[(size_t)h*65536 + (size_t)j*256 + m] / mx;
}

// ---------------- batched MFMA pinv GEMM ----------------
template<int TRANS>
__global__ __launch_bounds__(256) void k_pgemm(const float* __restrict__ A,
    const float* __restrict__ B, float* __restrict__ C, float alpha, float beta){
  __shared__ short As[64*32];
  __shared__ short Bs[64*32];
  int bh = blockIdx.z;
  const float* Ah = A + (size_t)bh*65536;
  const float* Bh = B + (size_t)bh*65536;
  float* Ch = C + (size_t)bh*65536;
  int m0 = blockIdx.y*64, n0 = blockIdx.x*64;
  int t = threadIdx.x, lane = t & 63, wv = t >> 6, g = lane >> 4, l15 = lane & 15;
  f4 acc[4] = {};
  for(int k0=0; k0<256; k0+=32){
    {
      int m = t >> 2, kb = (t & 3)*8;
      float4 va = *(const float4*)(Ah + (size_t)(m0+m)*256 + k0 + kb);
      float4 vb = *(const float4*)(Ah + (size_t)(m0+m)*256 + k0 + kb + 4);
      int swz = (((m&3)^((m>>2)&3))<<4);
      *(sh8*)((char*)As + m*64 + ((kb*2)^swz)) = pack8f(va, vb);
    }
    {
      int kr = t >> 3, nb = (t & 7)*8;
      float4 wa = *(const float4*)(Bh + (size_t)(k0+kr)*256 + n0 + nb);
      float4 wb = *(const float4*)(Bh + (size_t)(k0+kr)*256 + n0 + nb + 4);
      float w8[8] = {wa.x,wa.y,wa.z,wa.w,wb.x,wb.y,wb.z,wb.w};
      #pragma unroll
      for(int e=0;e<8;e++){
        int n = nb + e;
        float val = w8[e];
        if(TRANS) val = ((k0+kr == n0+n) ? alpha : 0.f) - val;
        int swz = (((n&3)^((n>>2)&3))<<4);
        *(short*)((char*)Bs + n*64 + ((kr*2)^swz)) = (short)bfbits(val);
      }
    }
    __syncthreads();
    int rm = wv*16 + l15;
    sh8 af = *(sh8*)((char*)As + rm*64 + ((g*16) ^ (((rm&3)^((rm>>2)&3))<<4)));
    #pragma unroll
    for(int nt=0; nt<4; nt++){
      int n = nt*16 + l15;
      sh8 bf = *(sh8*)((char*)Bs + n*64 + ((g*16) ^ (((n&3)^((n>>2)&3))<<4)));
      acc[nt] = MFMA16(af, bf, acc[nt]);
    }
    __syncthreads();
  }
  #pragma unroll
  for(int nt=0; nt<4; nt++)
    #pragma unroll
    for(int r=0; r<4; r++)
      Ch[(size_t)(m0 + wv*16 + g*4 + r)*256 + n0 + nt*16 + l15] = acc[nt][r]*beta;
}

// ---------------- batched f32 GEMM 64x64 tile (w2^T only) ----------------
template<int TRANS, int OUTT>
__global__ __launch_bounds__(256) void k_sgemm2(const float* __restrict__ A,
    const float* __restrict__ B, float* __restrict__ C,
    int M, int N, int K, long sA, long sB, long sC, float alpha, float beta){
  __shared__ float As[32][68];
  __shared__ float Bs[32][68];
  int bh = blockIdx.z;
  const float* Ah = A + (size_t)bh*sA;
  const float* Bh = B + (size_t)bh*sB;
  float* Ch = C + (size_t)bh*sC;
  int m0 = blockIdx.y*64, n0 = blockIdx.x*64;
  int t = threadIdx.x, tx = t & 15, ty = t >> 4;
  float acc[4][4] = {};
  for(int k0=0; k0<K; k0+=32){
    #pragma unroll
    for(int u=0; u<2; u++){
      int idx = t + u*256;
      int r = idx >> 3, cb = (idx & 7) * 4;
      float4 va = *(const float4*)(Ah + (size_t)(m0+r)*K + k0 + cb);
      As[cb+0][r]=va.x; As[cb+1][r]=va.y; As[cb+2][r]=va.z; As[cb+3][r]=va.w;
      int kr = idx >> 4, nb = (idx & 15) * 4;
      float4 w = *(const float4*)(Bh + (size_t)(k0+kr)*N + n0 + nb);
      if(TRANS){
        int gk = k0 + kr;
        w.x = ((gk==n0+nb+0)?alpha:0.f) - w.x;
        w.y = ((gk==n0+nb+1)?alpha:0.f) - w.y;
        w.z = ((gk==n0+nb+2)?alpha:0.f) - w.z;
        w.w = ((gk==n0+nb+3)?alpha:0.f) - w.w;
      }
      *(float4*)&Bs[kr][nb] = w;
    }
    __syncthreads();
    #pragma unroll
    for(int k=0;k<32;k++){
      float a[4], b[4];
      *(float4*)a = *(const float4*)&As[k][ty*4];
      *(float4*)b = *(const float4*)&Bs[k][tx*4];
      #pragma unroll
      for(int i=0;i<4;i++)
        #pragma unroll
        for(int j=0;j<4;j++) acc[i][j] += a[i]*b[j];
    }
    __syncthreads();
  }
  #pragma unroll
  for(int i=0;i<4;i++){
    #pragma unroll
    for(int j=0;j<4;j++){
      int gm = m0 + ty*4 + i, gn = n0 + tx*4 + j;
      float v = acc[i][j] * beta;
      if(OUTT) Ch[(size_t)gn*M + gm] = v;
      else     Ch[(size_t)gm*N + gn] = v;
    }
  }
}

// ---------------- MFMA flash a1 (Q bf16, F out bf16), per-wave P (no inner barriers) --
__global__ __launch_bounds__(256) void k_a1_mfma(const short* __restrict__ Qb,
    const float* __restrict__ kl, const float* __restrict__ w2t, short* __restrict__ F){
  __shared__ short klL[128*64];
  __shared__ short w2L[64*128];
  __shared__ short pL[4][16*128];
  int h = blockIdx.y, n0 = blockIdx.x*128;
  int t = threadIdx.x, lane = t & 63, wv = t >> 6, g = lane >> 4, l15 = lane & 15;
  const float* klh = kl + (size_t)h*NLAND*DHEAD;
  const float* w2h = w2t + (size_t)h*DHEAD*NLAND;
  const short* qbase = Qb + (size_t)h*NPAD*DHEAD;
  sh8 aQ[2][2];
  #pragma unroll
  for(int st=0; st<2; st++)
    #pragma unroll
    for(int kk=0; kk<2; kk++)
      aQ[st][kk] = *(const sh8*)(qbase +
          (size_t)(n0 + wv*32 + st*16 + l15)*DHEAD + kk*32 + g*8);
  f4 accO[2][4] = {};
  float den[2][4] = {};
  short* pw = pL[wv];
  for(int half=0; half<2; half++){
    __syncthreads();             // all waves done with klL/w2L before restage
    #pragma unroll
    for(int it=0; it<4; it++){
      int gi = t + it*256;
      int m = gi >> 3, db = (gi & 7) * 8;
      const float* p = klh + (size_t)(half*128 + m)*DHEAD + db;
      *(sh8*)((char*)klL + m*128 + ((db*2) ^ ((m&7)<<4))) =
          pack8f(*(const float4*)p, *(const float4*)(p+4));
      int d = gi >> 4, mb = (gi & 15) * 8;
      const float* p2 = w2h + (size_t)d*NLAND + half*128 + mb;
      *(sh8*)((char*)w2L + d*256 + ((mb*2) ^ ((d&7)<<4))) =
          pack8f(*(const float4*)p2, *(const float4*)(p2+4));
    }
    __syncthreads();
    // P buffer pL[wv] is wave-private: DS ops in-order per wave, no barriers.
    #pragma unroll
    for(int st=0; st<2; st++){
      #pragma unroll
      for(int mt=0; mt<8; mt++){
        f4 s = {};
        #pragma unroll
        for(int kk=0; kk<2; kk++){
          int m = mt*16 + l15;
          sh8 b = *(sh8*)((char*)klL + m*128 + ((kk*64 + g*16) ^ ((m&7)<<4)));
          s = MFMA16(aQ[st][kk], b, s);
        }
        #pragma unroll
        for(int r=0; r<4; r++){
          float e = __expf(s[r]);
          den[st][r] += e;
          int n = g*4 + r;
          *(short*)((char*)pw + n*256 + (((mt*16+l15)*2) ^ ((n&7)<<4))) = (short)bfbits(e);
        }
      }
      #pragma unroll
      for(int ks=0; ks<4; ks++){
        sh8 aP = *(sh8*)((char*)pw + l15*256 + ((ks*64 + g*16) ^ ((l15&7)<<4)));
        #pragma unroll
        for(int dt=0; dt<4; dt++){
          int d = dt*16 + l15;
          sh8 bW = *(sh8*)((char*)w2L + d*256 + ((ks*64 + g*16) ^ ((d&7)<<4)));
          accO[st][dt] = MFMA16(aP, bW, accO[st][dt]);
        }
      }
    }
  }
  #pragma unroll
  for(int st=0; st<2; st++)
    #pragma unroll
    for(int r=0; r<4; r++){
      float d_ = den[st][r];
      d_ += __shfl_xor(d_,1); d_ += __shfl_xor(d_,2);
      d_ += __shfl_xor(d_,4); d_ += __shfl_xor(d_,8);
      den[st][r] = 1.f/d_;
    }
  #pragma unroll
  for(int st=0; st<2; st++)
    #pragma unroll
    for(int dt=0; dt<4; dt++)
      #pragma unroll
      for(int r=0; r<4; r++){
        int row = n0 + wv*32 + st*16 + g*4 + r;
        F[(size_t)row*CDIM + h*DHEAD + dt*16 + l15] =
            (short)bfbits(accO[st][dt][r]*den[st][r]);
      }
}

// ---------------- MFMA flash a3v: CGRP chunks/block, no inner barriers ----------------
__global__ __launch_bounds__(256) void k_a3v_mfma(const float* __restrict__ ql,
    const short* __restrict__ Kb, const short* __restrict__ Vb,
    float* __restrict__ numP, float* __restrict__ denP){
  __shared__ short kL[128*64];
  __shared__ short vL[64*128];
  __shared__ short pL[4][16*128];
  int h = blockIdx.x, cg = blockIdx.y;
  int t = threadIdx.x, lane = t & 63, wv = t >> 6, g = lane >> 4, l15 = lane & 15;
  const float* qlh = ql + (size_t)h*NLAND*DHEAD;
  sh8 aQ[4][2];
  #pragma unroll
  for(int st=0; st<4; st++)
    #pragma unroll
    for(int kk=0; kk<2; kk++){
      const float* p = qlh + (size_t)(wv*64 + st*16 + l15)*DHEAD + kk*32 + g*8;
      aQ[st][kk] = pack8f(*(const float4*)p, *(const float4*)(p+4));
    }
  f4 accO[4][4] = {};
  float den[4][4] = {};
  short* pw = pL[wv];
  for(int cc=0; cc<CGRP; cc++){
    int c = cg*CGRP + cc;
    if(c >= NCHUNK) break;
    for(int half=0; half<2; half++){
      const short* Kh = Kb + ((size_t)h*NPAD + (size_t)c*256 + half*128)*DHEAD;
      const short* Vh = Vb + ((size_t)h*NPAD + (size_t)c*256 + half*128)*DHEAD;
      __syncthreads();           // all waves done reading kL/vL
      #pragma unroll
      for(int it=0; it<4; it++){
        int gi = t + it*256;
        int m = gi >> 3, db = (gi & 7) * 8;
        *(sh8*)((char*)kL + m*128 + ((db*2) ^ ((m&7)<<4))) =
            *(const sh8*)(Kh + (size_t)m*DHEAD + db);
      }
      #pragma unroll
      for(int it=0; it<4; it++){
        int idx = t + it*256;
        int m = idx & 127, dg = (idx >> 7) * 8;
        sh8 v = *(const sh8*)(Vh + (size_t)m*DHEAD + dg);
        #pragma unroll
        for(int i=0;i<8;i++){
          int d = dg + i;
          *(short*)((char*)vL + d*256 + ((m*2) ^ ((d&7)<<4))) = v[i];
        }
      }
      __syncthreads();
      // pw is wave-private; DS in-order per wave -> no inner barriers needed.
      #pragma unroll
      for(int st=0; st<4; st++){
        #pragma unroll
        for(int mt=0; mt<8; mt++){
          f4 s = {};
          #pragma unroll
          for(int kk=0; kk<2; kk++){
            int m = mt*16 + l15;
            sh8 b = *(sh8*)((char*)kL + m*128 + ((kk*64 + g*16) ^ ((m&7)<<4)));
            s = MFMA16(aQ[st][kk], b, s);
          }
          #pragma unroll
          for(int r=0; r<4; r++){
            float e = __expf(s[r]);
            den[st][r] += e;
            int n = g*4 + r;
            *(short*)((char*)pw + n*256 + (((mt*16+l15)*2) ^ ((n&7)<<4))) = (short)bfbits(e);
          }
        }
        #pragma unroll
        for(int ks=0; ks<4; ks++){
          sh8 aP = *(sh8*)((char*)pw + l15*256 + ((ks*64 + g*16) ^ ((l15&7)<<4)));
          #pragma unroll
          for(int dt=0; dt<4; dt++){
            int d = dt*16 + l15;
            sh8 bV = *(sh8*)((char*)vL + d*256 + ((ks*64 + g*16) ^ ((d&7)<<4)));
            accO[st][dt] = MFMA16(aP, bV, accO[st][dt]);
          }
        }
      }
    }
  }
  #pragma unroll
  for(int st=0; st<4; st++)
    #pragma unroll
    for(int r=0; r<4; r++){
      float d_ = den[st][r];
      d_ += __shfl_xor(d_,1); d_ += __shfl_xor(d_,2);
      d_ += __shfl_xor(d_,4); d_ += __shfl_xor(d_,8);
      den[st][r] = d_;
    }
  size_t base = ((size_t)h*NCG + cg)*NLAND;
  #pragma unroll
  for(int st=0; st<4; st++){
    #pragma unroll
    for(int r=0; r<4; r++){
      int row = wv*64 + st*16 + g*4 + r;
      if(l15 == 0) denP[base + row] = den[st][r];
      #pragma unroll
      for(int dt=0; dt<4; dt++)
        numP[(base + row)*DHEAD + dt*16 + l15] = accO[st][dt][r];
    }
  }
}

__global__ void k_a3v_comb(const float* __restrict__ numP, const float* __restrict__ denP,
                           float* __restrict__ a3v){
  int bidx = blockIdx.x;
  int h = bidx >> 8, m = bidx & 255;
  int d = threadIdx.x;
  float s = 0.f, den = 0.f;
  for(int c=0;c<NCG;c++){
    s += numP[(((size_t)h*NCG + c)*NLAND + m)*DHEAD + d];
    den += denP[((size_t)h*NCG + c)*NLAND + m];
  }
  a3v[((size_t)h*NLAND + m)*DHEAD + d] = s / den;
}

// ---------------- residual depthwise conv (k=33), register-FIR ----------------
__global__ __launch_bounds__(256) void k_resconv(const short* __restrict__ Vb,
    const float* __restrict__ rw, short* __restrict__ F){
  __shared__ float vs[96][64];
  int n0 = blockIdx.x*64, h = blockIdx.y;
  int t = threadIdx.x;
  const short* vh = Vb + (size_t)h*NPAD*DHEAD;
  #pragma unroll
  for(int i=0;i<3;i++){
    int idx = t + i*256;
    int r = idx >> 3, dg = (idx & 7)*8;
    int n = n0 - 16 + r;
    sh8 v = {0,0,0,0,0,0,0,0};
    if(n>=0 && n<NPAD) v = *(const sh8*)(vh + (size_t)n*DHEAD + dg);
    #pragma unroll
    for(int e=0;e<8;e++) vs[r][dg+e] = bf2f(v[e]);
  }
  float w[33];
  #pragma unroll
  for(int j=0;j<33;j++) w[j] = rw[h*33+j];
  __syncthreads();
  int d = t & 63, grp = t >> 6;
  float f0[16];
  #pragma unroll
  for(int rr=0;rr<16;rr++){
    int n = n0 + grp*16 + rr;
    f0[rr] = bf2f(F[(size_t)n*CDIM + h*DHEAD + d]);
  }
  float in[48];
  #pragma unroll
  for(int x=0;x<48;x++) in[x] = vs[grp*16 + x][d];
  #pragma unroll
  for(int rr=0;rr<16;rr++){
    float acc = 0.f;
    #pragma unroll
    for(int j=0;j<33;j++) acc += w[j]*in[rr+j];
    int n = n0 + grp*16 + rr;
    F[(size_t)n*CDIM + h*DHEAD + d] = (short)bfbits(f0[rr] + acc);
  }
}

// ---------------- weight transpose f32 -> bf16 ----------------
__global__ void k_transposeb(const float* __restrict__ in, short* __restrict__ out,
                             int R, int C){
  __shared__ float tile[32][33];
  int r0 = blockIdx.x*32, c0 = blockIdx.y*32;
  int tx = threadIdx.x, ty = threadIdx.y;
  #pragma unroll
  for(int r=0;r<4;r++) tile[ty + r*8][tx] = in[(size_t)(r0 + ty + r*8)*C + c0 + tx];
  __syncthreads();
  #pragma unroll
  for(int r=0;r<4;r++)
    out[(size_t)(c0 + ty + r*8)*R + r0 + tx] = (short)bfbits(tile[tx][ty + r*8]);
}

// ---------------- PPEG direct on row-major [n][c] (f32) ----------------
__global__ __launch_bounds__(256) void k_ppeg2(const float* __restrict__ X,
    const float* __restrict__ w7, const float* __restrict__ b7,
    const float* __restrict__ w5, const float* __restrict__ b5,
    const float* __restrict__ w3, const float* __restrict__ b3,
    float* __restrict__ Y){
  __shared__ float patch[484][20];
  int cg = blockIdx.y;
  int ti = blockIdx.x >> 3, tj = blockIdx.x & 7;
  int t = threadIdx.x;
  int i0 = ti*16 - 3, j0 = tj*16 - 3;
  for(int idx = t; idx < 1936; idx += 256){
    int p = idx >> 2, cq = (idx & 3) * 4;
    int gi = i0 + p/22, gj = j0 + p%22;
    float4 v = make_float4(0.f,0.f,0.f,0.f);
    if(gi>=0 && gi<128 && gj>=0 && gj<128)
      v = *(const float4*)(X + (size_t)(gi*128+gj)*CDIM + cg*16 + cq);
    *(float4*)&patch[p][cq] = v;
  }
  int c = t & 15, sg = t >> 4;
  int cglob = cg*16 + c;
  float wr[83];
  #pragma unroll
  for(int k=0;k<49;k++) wr[k] = w7[cglob*49+k];
  #pragma unroll
  for(int k=0;k<25;k++) wr[49+k] = w5[cglob*25+k];
  #pragma unroll
  for(int k=0;k<9;k++)  wr[74+k] = w3[cglob*9+k];
  float bsum = b7[cglob] + b5[cglob] + b3[cglob];
  __syncthreads();
  float acc[16];
  #pragma unroll
  for(int j=0;j<16;j++) acc[j] = patch[(sg+3)*22 + (j+3)][c] + bsum;
  #pragma unroll
  for(int a=0;a<7;a++)
    #pragma unroll
    for(int x=0;x<22;x++){
      float vv = patch[(sg+a)*22 + x][c];
      #pragma unroll
      for(int bq=0;bq<7;bq++){
        int j = x - bq;
        if(j>=0 && j<16) acc[j] += wr[a*7+bq]*vv;
      }
    }
  #pragma unroll
  for(int a=0;a<5;a++)
    #pragma unroll
    for(int x=1;x<21;x++){
      float vv = patch[(sg+a+1)*22 + x][c];
      #pragma unroll
      for(int bq=0;bq<5;bq++){
        int j = x - 1 - bq;
        if(j>=0 && j<16) acc[j] += wr[49+a*5+bq]*vv;
      }
    }
  #pragma unroll
  for(int a=0;a<3;a++)
    #pragma unroll
    for(int x=2;x<20;x++){
      float vv = patch[(sg+a+2)*22 + x][c];
      #pragma unroll
      for(int bq=0;bq<3;bq++){
        int j = x - 2 - bq;
        if(j>=0 && j<16) acc[j] += wr[74+a*3+bq]*vv;
      }
    }
  #pragma unroll
  for(int j=0;j<16;j++)
    Y[(size_t)((ti*16+sg)*128 + tj*16+j)*CDIM + cglob] = acc[j];
}

// ---------------- final LN(row0) + fc2 ----------------
__global__ __launch_bounds__(512) void k_final(const float* __restrict__ A,
    const float* __restrict__ g, const float* __restrict__ b,
    const float* __restrict__ w, const float* __restrict__ bias,
    float* __restrict__ outp){
  __shared__ float red[8];
  int t = threadIdx.x, wv = t >> 6;
  float x = A[t];
  float s = wave_sum(x);
  if((t & 63) == 0) red[wv] = s;
  __syncthreads();
  float mu = 0;
  #pragma unroll
  for(int i=0;i<8;i++) mu += red[i];
  mu *= (1.f/512.f);
  __syncthreads();
  float dx = x - mu;
  s = wave_sum(dx*dx);
  if((t & 63) == 0) red[wv] = s;
  __syncthreads();
  float var = 0;
  #pragma unroll
  for(int i=0;i<8;i++) var += red[i];
  var *= (1.f/512.f);
  float xn = dx * rsqrtf(var + 1e-5f) * g[t] + b[t];
  __syncthreads();
  for(int o=0;o<4;o++){
    s = wave_sum(xn * w[t*4 + o]);
    if((t & 63) == 0) red[wv] = s;
    __syncthreads();
    if(t == 0){
      float r = 0;
      #pragma unroll
      for(int i=0;i<8;i++) r += red[i];
      outp[o] = r + bias[o];
    }
    __syncthreads();
  }
}

extern "C" void kernel_launch(void* const* d_in, const int* in_sizes, int n_in,
                              void* d_out, int out_size, void* d_ws, size_t ws_size,
                              hipStream_t stream) {
  (void)in_sizes; (void)n_in; (void)out_size; (void)ws_size;
  const float* data_x = (const float*)d_in[0];
  const float* fc1_w  = (const float*)d_in[1];
  const float* fc1_b  = (const float*)d_in[2];
  const float* cls_tk = (const float*)d_in[3];
  const float* ng[2]  = {(const float*)d_in[4],  (const float*)d_in[16]};
  const float* nb[2]  = {(const float*)d_in[5],  (const float*)d_in[17]};
  const float* qkvw[2]= {(const float*)d_in[6],  (const float*)d_in[18]};
  const float* outw[2]= {(const float*)d_in[7],  (const float*)d_in[19]};
  const float* outb[2]= {(const float*)d_in[8],  (const float*)d_in[20]};
  const float* resw[2]= {(const float*)d_in[9],  (const float*)d_in[21]};
  const float* w7 = (const float*)d_in[10]; const float* pb7 = (const float*)d_in[11];
  const float* w5 = (const float*)d_in[12]; const float* pb5 = (const float*)d_in[13];
  const float* w3 = (const float*)d_in[14]; const float* pb3 = (const float*)d_in[15];
  const float* norm_g = (const float*)d_in[22];
  const float* norm_b = (const float*)d_in[23];
  const float* fc2_w  = (const float*)d_in[24];
  const float* fc2_b  = (const float*)d_in[25];

  float* ws = (float*)d_ws;
  float* Ab   = ws;
  float* Bb   = Ab + (size_t)TOK*CDIM;
  float* Fb   = Bb + (size_t)TOK*CDIM;
  short* Fbf  = (short*)(Fb + (size_t)NPAD*CDIM);
  short* lnX  = Fbf + (size_t)NPAD*CDIM;
  short* Qb   = lnX + (size_t)NPAD*CDIM;
  short* Kb   = Qb  + (size_t)NPAD*CDIM;
  short* Vb   = Kb  + (size_t)NPAD*CDIM;
  short* dxb  = Vb  + (size_t)NPAD*CDIM;
  float* qlb  = (float*)(dxb + (size_t)16384*1024);
  float* klb  = qlb + NHEAD*NLAND*DHEAD;
  float* a2b  = klb + NHEAD*NLAND*DHEAD;
  float* z0b  = a2b + NHEAD*NLAND*NLAND;
  float* z1b  = z0b + NHEAD*NLAND*NLAND;
  float* Xb_  = z1b + NHEAD*NLAND*NLAND;
  float* Tb_  = Xb_ + NHEAD*NLAND*NLAND;
  float* Ub_  = Tb_ + NHEAD*NLAND*NLAND;
  float* a3vb = Ub_ + NHEAD*NLAND*NLAND;
  float* w2tb = a3vb + NHEAD*NLAND*DHEAD;
  float* denP = w2tb + NHEAD*DHEAD*NLAND;   // 8*33*256
  float* hmax = denP + NHEAD*NCG*NLAND;
  float* scal = hmax + 8;
  short* fc1T = (short*)(scal + 8);
  short* qkvT0= fc1T + 512*1024;
  short* qkvT1= qkvT0 + 1536*512;
  short* outT0= qkvT1 + 1536*512;
  short* outT1= outT0 + 512*512;
  short* qkvT[2] = {qkvT0, qkvT1};
  short* outT[2] = {outT0, outT1};

  k_transposeb<<<dim3(32,16), dim3(32,8), 0, stream>>>(fc1_w, fc1T, 1024, 512);
  k_transposeb<<<dim3(16,48), dim3(32,8), 0, stream>>>(qkvw[0], qkvT0, 512, 1536);
  k_transposeb<<<dim3(16,48), dim3(32,8), 0, stream>>>(qkvw[1], qkvT1, 512, 1536);
  k_transposeb<<<dim3(16,16), dim3(32,8), 0, stream>>>(outw[0], outT0, 512, 512);
  k_transposeb<<<dim3(16,16), dim3(32,8), 0, stream>>>(outw[1], outT1, 512, 512);
  k_f2b<<<8192, 256, 0, stream>>>(data_x, dxb, 16384*1024/8);

  k_copyrow<<<1, 512, 0, stream>>>(Ab, cls_tk);
  k_gemm_g<0><<<dim3(4, 128), 256, 0, stream>>>(dxb, 1024, fc1T, 1024, fc1_b,
                                                Ab + CDIM, nullptr, nullptr, 16384);
  float* base[2]  = {Ab, Bb};
  for(int L=0; L<2; L++){
    k_ln_pad<<<NPAD/4, 256, 0, stream>>>(base[L], ng[L], nb[L], lnX);
    k_gemm_g<1><<<dim3(12, 130), 256, 0, stream>>>(lnX, CDIM, qkvT[L], CDIM, nullptr,
                                                   Qb, Kb, Vb, NPAD);
    k_landmark2<<<2*NHEAD*NLAND, 64, 0, stream>>>(Qb, Kb, qlb, klb);
    k_a2<<<dim3(4, NHEAD), 256, 0, stream>>>(qlb, klb, a2b);
    k_colmax<<<NHEAD, 256, 0, stream>>>(a2b, hmax);
    k_zinit<<<dim3(256, NHEAD), 256, 0, stream>>>(a2b, hmax, z0b);
    float* zc = z0b; float* zn = z1b;
    for(int it=0; it<6; it++){
      k_pgemm<0><<<dim3(4,4,NHEAD), 256, 0, stream>>>(a2b, zc, Xb_, 0.f, 1.f);
      k_pgemm<1><<<dim3(4,4,NHEAD), 256, 0, stream>>>(Xb_, Xb_, Tb_, 7.f, 1.f);
      k_pgemm<1><<<dim3(4,4,NHEAD), 256, 0, stream>>>(Xb_, Tb_, Ub_, 15.f, 1.f);
      k_pgemm<1><<<dim3(4,4,NHEAD), 256, 0, stream>>>(zc, Ub_, zn, 13.f, 0.25f);
      float* tmp = zc; zc = zn; zn = tmp;
    }
    k_a3v_mfma<<<dim3(NHEAD, NCG), 256, 0, stream>>>(qlb, Kb, Vb, Fb, denP);
    k_a3v_comb<<<NHEAD*NLAND, 64, 0, stream>>>(Fb, denP, a3vb);
    k_sgemm2<0,1><<<dim3(1,4,NHEAD), 256, 0, stream>>>(zc, a3vb, w2tb, 256,64,256,
                                                       65536,16384,16384, 0.f, 1.f);
    k_a1_mfma<<<dim3(130, NHEAD), 256, 0, stream>>>(Qb, klb, w2tb, Fbf);
    k_resconv<<<dim3(260, NHEAD), 256, 0, stream>>>(Vb, resw[L], Fbf);
    k_gemm_g<2><<<dim3(4, 129), 256, 0, stream>>>(Fbf + (size_t)PAD0*CDIM, CDIM,
                                                  outT[L], CDIM, outb[L],
                                                  base[L], nullptr, nullptr, TOK);
    if(L == 0){
      k_ppeg2<<<dim3(64, 32), 256, 0, stream>>>(Ab + CDIM, w7, pb7, w5, pb5, w3, pb3,
                                                Bb + CDIM);
      k_copyrow<<<1, 512, 0, stream>>>(Bb, Ab);
    }
  }
  k_final<<<1, 512, 0, stream>>>(Bb, norm_g, norm_b, fc2_w, fc2_b, (float*)d_out);
}

// Round 16
// 1038.731 us; speedup vs baseline: 2.7734x; 1.1026x over previous
//
#include <hip/hip_runtime.h>
#include <hip/hip_bf16.h>

#define NPAD 16640
#define TOK  16385
#define CDIM 512
#define NHEAD 8
#define DHEAD 64
#define NLAND 256
#define LFAC  65
#define PAD0  255
#define NCHUNK 65     // 256-row chunks
#define CGRP 2        // chunks per block in a3v
#define NCG 33        // ceil(65/2)

typedef __attribute__((ext_vector_type(8))) short sh8;
typedef __attribute__((ext_vector_type(4))) float f4;

__device__ __forceinline__ float wave_sum(float v){
  #pragma unroll
  for(int o=32;o;o>>=1) v += __shfl_xor(v,o);
  return v;
}
__device__ __forceinline__ float wave_max(float v){
  #pragma unroll
  for(int o=32;o;o>>=1) v = fmaxf(v, __shfl_xor(v,o));
  return v;
}

__device__ __forceinline__ unsigned bfbits(float x){
  unsigned u = __float_as_uint(x);
  return (u + 0x7fffu + ((u >> 16) & 1u)) >> 16;
}
__device__ __forceinline__ float bf2f(short s){
  return __uint_as_float(((unsigned)(unsigned short)s) << 16);
}
__device__ __forceinline__ sh8 pack8f(float4 a, float4 b){
  sh8 r;
  r[0]=(short)bfbits(a.x); r[1]=(short)bfbits(a.y); r[2]=(short)bfbits(a.z); r[3]=(short)bfbits(a.w);
  r[4]=(short)bfbits(b.x); r[5]=(short)bfbits(b.y); r[6]=(short)bfbits(b.z); r[7]=(short)bfbits(b.w);
  return r;
}
#define MFMA16(a,b,c) __builtin_amdgcn_mfma_f32_16x16x32_bf16(a,b,c,0,0,0)

__device__ __forceinline__ void gload16(const void* g, void* l){
  __builtin_amdgcn_global_load_lds(
      (const __attribute__((address_space(1))) void*)g,
      (__attribute__((address_space(3))) void*)l, 16, 0, 0);
}

// ---------------- row copy (cls token) ----------------
__global__ void k_copyrow(float* dst, const float* __restrict__ src){
  dst[threadIdx.x] = src[threadIdx.x];
}

// ---------------- f32 -> bf16 convert ----------------
__global__ __launch_bounds__(256) void k_f2b(const float* __restrict__ in,
    short* __restrict__ out, int n8){
  int i = blockIdx.x*256 + threadIdx.x;
  if(i < n8){
    float4 a = *(const float4*)(in + (size_t)i*8);
    float4 b = *(const float4*)(in + (size_t)i*8 + 4);
    *(sh8*)(out + (size_t)i*8) = pack8f(a, b);
  }
}

// ---------------- layernorm + front pad -> bf16 ----------------
__global__ __launch_bounds__(256) void k_ln_pad(const float* __restrict__ A,
    const float* __restrict__ g, const float* __restrict__ b, short* __restrict__ B){
  int w = threadIdx.x >> 6, lane = threadIdx.x & 63;
  int row = blockIdx.x*4 + w;
  short* out = B + (size_t)row*CDIM;
  int c = lane*8;
  if(row < PAD0){
    sh8 z = {0,0,0,0,0,0,0,0};
    *(sh8*)(out + c) = z;
    return;
  }
  const float* x = A + (size_t)(row-PAD0)*CDIM;
  float4 v0 = *(const float4*)(x + c);
  float4 v1 = *(const float4*)(x + c + 4);
  float xs[8] = {v0.x,v0.y,v0.z,v0.w,v1.x,v1.y,v1.z,v1.w};
  float s = 0;
  #pragma unroll
  for(int i=0;i<8;i++) s += xs[i];
  s = wave_sum(s);
  float mu = s * (1.f/512.f);
  float vs = 0;
  #pragma unroll
  for(int i=0;i<8;i++){ float d = xs[i]-mu; vs += d*d; }
  vs = wave_sum(vs) * (1.f/512.f);
  float rs = rsqrtf(vs + 1e-5f);
  float4 g0 = *(const float4*)(g + c); float4 g1 = *(const float4*)(g + c + 4);
  float4 b0 = *(const float4*)(b + c); float4 b1 = *(const float4*)(b + c + 4);
  float gg[8] = {g0.x,g0.y,g0.z,g0.w,g1.x,g1.y,g1.z,g1.w};
  float bb[8] = {b0.x,b0.y,b0.z,b0.w,b1.x,b1.y,b1.z,b1.w};
  sh8 o;
  #pragma unroll
  for(int i=0;i<8;i++) o[i] = (short)bfbits((xs[i]-mu)*rs*gg[i] + bb[i]);
  *(sh8*)(out + c) = o;
}

// ---------------- gload-staged MFMA GEMM: C[M,N] = A[M,K] @ WT[N,K]^T ----------------
template<int MODE>
__global__ __launch_bounds__(256) void k_gemm_g(const short* __restrict__ A, int lda,
    const short* __restrict__ WT, int K, const float* __restrict__ bias,
    void* out0v, void* out1v, void* out2v, int M){
  __shared__ short As[2][128*32];
  __shared__ short Bs[2][128*32];
  int t = threadIdx.x, lane = t & 63, wv = t >> 6, g = lane >> 4, l15 = lane & 15;
  int nwg = gridDim.x * gridDim.y;
  int orig = blockIdx.y * gridDim.x + blockIdx.x;
  int qc = nwg >> 3, rc = nwg & 7, xcd = orig & 7, loc = orig >> 3;
  int wgid = (xcd < rc ? xcd*(qc+1) : rc*(qc+1) + (xcd - rc)*qc) + loc;
  int row0 = (wgid / gridDim.x) * 128, n0 = (wgid % gridDim.x) * 128;
  int wm = (wv>>1)*64, wn = (wv&1)*64;
  int mq = lane >> 2, slot = lane & 3;

  auto stage = [&](int buf, int k0){
    #pragma unroll
    for(int c=0;c<2;c++){
      int m = wv*32 + c*16 + mq;
      int swz = (((m&3) ^ ((m>>2)&3)) << 4);
      int gr = row0 + m; if(gr >= M) gr = M-1;
      const char* srcA = (const char*)(A + (size_t)gr*lda + k0) + ((slot*16) ^ swz);
      gload16(srcA, (char*)As[buf] + wv*2048 + c*1024);
      const char* srcB = (const char*)(WT + (size_t)(n0+m)*K + k0) + ((slot*16) ^ swz);
      gload16(srcB, (char*)Bs[buf] + wv*2048 + c*1024);
    }
  };

  f4 acc[4][4] = {};
  int nk = K >> 5;
  stage(0, 0);
  __syncthreads();
  int cur = 0;
  for(int i=0; i<nk; i++){
    if(i+1 < nk) stage(cur^1, (i+1) << 5);
    sh8 af[4], bf[4];
    #pragma unroll
    for(int mt=0; mt<4; mt++){
      int r = wm + mt*16 + l15;
      af[mt] = *(sh8*)((char*)As[cur] + r*64 + ((g*16) ^ (((r&3)^((r>>2)&3))<<4)));
    }
    #pragma unroll
    for(int nt=0; nt<4; nt++){
      int r = wn + nt*16 + l15;
      bf[nt] = *(sh8*)((char*)Bs[cur] + r*64 + ((g*16) ^ (((r&3)^((r>>2)&3))<<4)));
    }
    #pragma unroll
    for(int mt=0; mt<4; mt++)
      #pragma unroll
      for(int nt=0; nt<4; nt++)
        acc[mt][nt] = MFMA16(af[mt], bf[nt], acc[mt][nt]);
    __syncthreads();
    cur ^= 1;
  }
  #pragma unroll
  for(int mt=0; mt<4; mt++){
    #pragma unroll
    for(int r=0; r<4; r++){
      int gm = row0 + wm + mt*16 + g*4 + r;
      if(gm >= M) continue;
      #pragma unroll
      for(int nt=0; nt<4; nt++){
        int gn = n0 + wn + nt*16 + l15;
        float v = acc[mt][nt][r];
        if(MODE == 0){
          v += bias[gn];
          ((float*)out0v)[(size_t)gm*CDIM + gn] = v > 0.f ? v : 0.f;
        } else if(MODE == 1){
          int p = gn >> 9, rr = gn & 511;
          int hh = rr >> 6, dd = rr & 63;
          if(p == 0) v *= 0.125f;
          short* dst = (p==0) ? (short*)out0v : (p==1 ? (short*)out1v : (short*)out2v);
          dst[((size_t)hh*NPAD + gm)*DHEAD + dd] = (short)bfbits(v);
        } else {
          ((float*)out0v)[(size_t)gm*CDIM + gn] += v + bias[gn];
        }
      }
    }
  }
}

// ---------------- landmark means, Q and K in one dispatch ----------------
__global__ void k_landmark2(const short* __restrict__ Qb, const short* __restrict__ Kb,
    float* __restrict__ ql, float* __restrict__ kl){
  int bidx = blockIdx.x;
  int sel = bidx >> 11;
  int loc = bidx & 2047;
  int h = loc >> 8, m = loc & 255, d = threadIdx.x;
  const short* src = (sel ? Kb : Qb) + ((size_t)h*NPAD + (size_t)m*LFAC)*DHEAD + d;
  float s = 0;
  for(int j=0;j<LFAC;j++) s += bf2f(src[(size_t)j*DHEAD]);
  (sel ? kl : ql)[(size_t)loc*DHEAD + d] = s * (1.f/LFAC);
}

// ---------------- a2 = softmax(ql @ kl^T), f32 + bf16 outputs ----------------
__global__ __launch_bounds__(256) void k_a2(const float* __restrict__ ql,
    const float* __restrict__ kl, float* __restrict__ a2, short* __restrict__ a2bf){
  __shared__ __hip_bfloat16 klt[64*256];
  int h = blockIdx.y;
  int t = threadIdx.x;
  const float* klh = kl + (size_t)h*NLAND*DHEAD;
  for(int r=0;r<64;r++){
    int idx = r*256 + t;
    int d = idx >> 8, m = idx & 255;
    klt[idx] = __float2bfloat16(klh[m*DHEAD + d]);
  }
  __syncthreads();
  int w = t >> 6, lane = t & 63;
  const float* qlh = ql + (size_t)h*NLAND*DHEAD;
  for(int rr=0; rr<16; rr++){
    int m = blockIdx.x*64 + w*16 + rr;
    const float* q = qlh + (size_t)m*DHEAD;
    float s[4] = {0,0,0,0};
    #pragma unroll
    for(int d=0; d<64; d++){
      float qv = q[d];
      #pragma unroll
      for(int qd=0; qd<4; qd++)
        s[qd] += qv * __bfloat162float(klt[d*256 + qd*64 + lane]);
    }
    float e[4], den = 0.f;
    #pragma unroll
    for(int qd=0; qd<4; qd++){ e[qd] = __expf(s[qd]); den += e[qd]; }
    den = wave_sum(den);
    float inv = 1.f/den;
    size_t rowo = ((size_t)h*NLAND + m)*NLAND;
    #pragma unroll
    for(int qd=0; qd<4; qd++){
      float v = e[qd]*inv;
      a2[rowo + qd*64 + lane] = v;
      a2bf[rowo + qd*64 + lane] = (short)bfbits(v);
    }
  }
}

// ---------------- pinv init ----------------
__global__ void k_colmax(const float* __restrict__ a2, float* __restrict__ hmax){
  __shared__ float red[4];
  int h = blockIdx.x, t = threadIdx.x;
  const float* p = a2 + (size_t)h*65536 + t;
  float s = 0;
  for(int m=0;m<256;m++) s += p[(size_t)m*256];
  float mx = wave_max(s);
  if((t & 63) == 0) red[t>>6] = mx;
  __syncthreads();
  if(t == 0) hmax[h] = fmaxf(fmaxf(red[0],red[1]), fmaxf(red[2],red[3]));
}
// z0 (bf16) = a2^T / max(hmax)
__global__ void k_zinit(const float* __restrict__ a2, const float* __restrict__ hmax,
                        short* __restrict__ z){
  int h = blockIdx.y;
  int idx = blockIdx.x*256 + threadIdx.x;
  int m = idx >> 8, j = idx & 255;
  float mx = hmax[0];
  #pragma unroll
  for(int i=1;i<8;i++) mx = fmaxf(mx, hmax[i]);
  z[(size_t)h*65536 + idx] = (short)bfbits(a2[(size_t)h*65536 + (size_t)j*256 + m] / mx);
}

// ---------------- batched MFMA pinv GEMM, bf16 I/O ----------------
// C = beta*(A @ (alpha*I-B)?) ; F32OUT writes f32 (final z for w2 gemm)
template<int TRANS, int F32OUT>
__global__ __launch_bounds__(256) void k_pgemm(const short* __restrict__ A,
    const short* __restrict__ B, short* __restrict__ C, float* __restrict__ Cf,
    float alpha, float beta){
  __shared__ short As[64*32];
  __shared__ short Bs[64*32];
  int bh = blockIdx.z;
  const short* Ah = A + (size_t)bh*65536;
  const short* Bh = B + (size_t)bh*65536;
  int m0 = blockIdx.y*64, n0 = blockIdx.x*64;
  int t = threadIdx.x, lane = t & 63, wv = t >> 6, g = lane >> 4, l15 = lane & 15;
  f4 acc[4] = {};
  for(int k0=0; k0<256; k0+=32){
    {
      int m = t >> 2, kb = (t & 3)*8;
      sh8 av = *(const sh8*)(Ah + (size_t)(m0+m)*256 + k0 + kb);
      int swz = (((m&3)^((m>>2)&3))<<4);
      *(sh8*)((char*)As + m*64 + ((kb*2)^swz)) = av;
    }
    {
      int kr = t >> 3, nb = (t & 7)*8;
      sh8 bv = *(const sh8*)(Bh + (size_t)(k0+kr)*256 + n0 + nb);
      #pragma unroll
      for(int e=0;e<8;e++){
        int n = nb + e;
        short sv = bv[e];
        if(TRANS){
          float f = ((k0+kr == n0+n) ? alpha : 0.f) - bf2f(sv);
          sv = (short)bfbits(f);
        }
        int swz = (((n&3)^((n>>2)&3))<<4);
        *(short*)((char*)Bs + n*64 + ((kr*2)^swz)) = sv;
      }
    }
    __syncthreads();
    int rm = wv*16 + l15;
    sh8 af = *(sh8*)((char*)As + rm*64 + ((g*16) ^ (((rm&3)^((rm>>2)&3))<<4)));
    #pragma unroll
    for(int nt=0; nt<4; nt++){
      int n = nt*16 + l15;
      sh8 bf = *(sh8*)((char*)Bs + n*64 + ((g*16) ^ (((n&3)^((n>>2)&3))<<4)));
      acc[nt] = MFMA16(af, bf, acc[nt]);
    }
    __syncthreads();
  }
  size_t hoff = (size_t)bh*65536;
  #pragma unroll
  for(int nt=0; nt<4; nt++)
    #pragma unroll
    for(int r=0; r<4; r++){
      size_t idx = hoff + (size_t)(m0 + wv*16 + g*4 + r)*256 + n0 + nt*16 + l15;
      float v = acc[nt][r]*beta;
      if(F32OUT) Cf[idx] = v;
      else       C[idx] = (short)bfbits(v);
    }
}

// ---------------- batched f32 GEMM 64x64 tile (w2^T only) ----------------
template<int TRANS, int OUTT>
__global__ __launch_bounds__(256) void k_sgemm2(const float* __restrict__ A,
    const float* __restrict__ B, float* __restrict__ C,
    int M, int N, int K, long sA, long sB, long sC, float alpha, float beta){
  __shared__ float As[32][68];
  __shared__ float Bs[32][68];
  int bh = blockIdx.z;
  const float* Ah = A + (size_t)bh*sA;
  const float* Bh = B + (size_t)bh*sB;
  float* Ch = C + (size_t)bh*sC;
  int m0 = blockIdx.y*64, n0 = blockIdx.x*64;
  int t = threadIdx.x, tx = t & 15, ty = t >> 4;
  float acc[4][4] = {};
  for(int k0=0; k0<K; k0+=32){
    #pragma unroll
    for(int u=0; u<2; u++){
      int idx = t + u*256;
      int r = idx >> 3, cb = (idx & 7) * 4;
      float4 va = *(const float4*)(Ah + (size_t)(m0+r)*K + k0 + cb);
      As[cb+0][r]=va.x; As[cb+1][r]=va.y; As[cb+2][r]=va.z; As[cb+3][r]=va.w;
      int kr = idx >> 4, nb = (idx & 15) * 4;
      float4 w = *(const float4*)(Bh + (size_t)(k0+kr)*N + n0 + nb);
      if(TRANS){
        int gk = k0 + kr;
        w.x = ((gk==n0+nb+0)?alpha:0.f) - w.x;
        w.y = ((gk==n0+nb+1)?alpha:0.f) - w.y;
        w.z = ((gk==n0+nb+2)?alpha:0.f) - w.z;
        w.w = ((gk==n0+nb+3)?alpha:0.f) - w.w;
      }
      *(float4*)&Bs[kr][nb] = w;
    }
    __syncthreads();
    #pragma unroll
    for(int k=0;k<32;k++){
      float a[4], b[4];
      *(float4*)a = *(const float4*)&As[k][ty*4];
      *(float4*)b = *(const float4*)&Bs[k][tx*4];
      #pragma unroll
      for(int i=0;i<4;i++)
        #pragma unroll
        for(int j=0;j<4;j++) acc[i][j] += a[i]*b[j];
    }
    __syncthreads();
  }
  #pragma unroll
  for(int i=0;i<4;i++){
    #pragma unroll
    for(int j=0;j<4;j++){
      int gm = m0 + ty*4 + i, gn = n0 + tx*4 + j;
      float v = acc[i][j] * beta;
      if(OUTT) Ch[(size_t)gn*M + gm] = v;
      else     Ch[(size_t)gm*N + gn] = v;
    }
  }
}

// ---------------- MFMA flash a1 (Q bf16, F out bf16), per-wave P ----------------
__global__ __launch_bounds__(256) void k_a1_mfma(const short* __restrict__ Qb,
    const float* __restrict__ kl, const float* __restrict__ w2t, short* __restrict__ F){
  __shared__ short klL[128*64];
  __shared__ short w2L[64*128];
  __shared__ short pL[4][16*128];
  int h = blockIdx.y, n0 = blockIdx.x*128;
  int t = threadIdx.x, lane = t & 63, wv = t >> 6, g = lane >> 4, l15 = lane & 15;
  const float* klh = kl + (size_t)h*NLAND*DHEAD;
  const float* w2h = w2t + (size_t)h*DHEAD*NLAND;
  const short* qbase = Qb + (size_t)h*NPAD*DHEAD;
  sh8 aQ[2][2];
  #pragma unroll
  for(int st=0; st<2; st++)
    #pragma unroll
    for(int kk=0; kk<2; kk++)
      aQ[st][kk] = *(const sh8*)(qbase +
          (size_t)(n0 + wv*32 + st*16 + l15)*DHEAD + kk*32 + g*8);
  f4 accO[2][4] = {};
  float den[2][4] = {};
  short* pw = pL[wv];
  for(int half=0; half<2; half++){
    __syncthreads();
    #pragma unroll
    for(int it=0; it<4; it++){
      int gi = t + it*256;
      int m = gi >> 3, db = (gi & 7) * 8;
      const float* p = klh + (size_t)(half*128 + m)*DHEAD + db;
      *(sh8*)((char*)klL + m*128 + ((db*2) ^ ((m&7)<<4))) =
          pack8f(*(const float4*)p, *(const float4*)(p+4));
      int d = gi >> 4, mb = (gi & 15) * 8;
      const float* p2 = w2h + (size_t)d*NLAND + half*128 + mb;
      *(sh8*)((char*)w2L + d*256 + ((mb*2) ^ ((d&7)<<4))) =
          pack8f(*(const float4*)p2, *(const float4*)(p2+4));
    }
    __syncthreads();
    #pragma unroll
    for(int st=0; st<2; st++){
      #pragma unroll
      for(int mt=0; mt<8; mt++){
        f4 s = {};
        #pragma unroll
        for(int kk=0; kk<2; kk++){
          int m = mt*16 + l15;
          sh8 b = *(sh8*)((char*)klL + m*128 + ((kk*64 + g*16) ^ ((m&7)<<4)));
          s = MFMA16(aQ[st][kk], b, s);
        }
        #pragma unroll
        for(int r=0; r<4; r++){
          float e = __expf(s[r]);
          den[st][r] += e;
          int n = g*4 + r;
          *(short*)((char*)pw + n*256 + (((mt*16+l15)*2) ^ ((n&7)<<4))) = (short)bfbits(e);
        }
      }
      #pragma unroll
      for(int ks=0; ks<4; ks++){
        sh8 aP = *(sh8*)((char*)pw + l15*256 + ((ks*64 + g*16) ^ ((l15&7)<<4)));
        #pragma unroll
        for(int dt=0; dt<4; dt++){
          int d = dt*16 + l15;
          sh8 bW = *(sh8*)((char*)w2L + d*256 + ((ks*64 + g*16) ^ ((d&7)<<4)));
          accO[st][dt] = MFMA16(aP, bW, accO[st][dt]);
        }
      }
    }
  }
  #pragma unroll
  for(int st=0; st<2; st++)
    #pragma unroll
    for(int r=0; r<4; r++){
      float d_ = den[st][r];
      d_ += __shfl_xor(d_,1); d_ += __shfl_xor(d_,2);
      d_ += __shfl_xor(d_,4); d_ += __shfl_xor(d_,8);
      den[st][r] = 1.f/d_;
    }
  #pragma unroll
  for(int st=0; st<2; st++)
    #pragma unroll
    for(int dt=0; dt<4; dt++)
      #pragma unroll
      for(int r=0; r<4; r++){
        int row = n0 + wv*32 + st*16 + g*4 + r;
        F[(size_t)row*CDIM + h*DHEAD + dt*16 + l15] =
            (short)bfbits(accO[st][dt][r]*den[st][r]);
      }
}

// ---------------- MFMA flash a3v: CGRP chunks/block, packed V staging ----------------
__global__ __launch_bounds__(256) void k_a3v_mfma(const float* __restrict__ ql,
    const short* __restrict__ Kb, const short* __restrict__ Vb,
    float* __restrict__ numP, float* __restrict__ denP){
  __shared__ short kL[128*64];
  __shared__ short vL[64*128];
  __shared__ short pL[4][16*128];
  int h = blockIdx.x, cg = blockIdx.y;
  int t = threadIdx.x, lane = t & 63, wv = t >> 6, g = lane >> 4, l15 = lane & 15;
  const float* qlh = ql + (size_t)h*NLAND*DHEAD;
  sh8 aQ[4][2];
  #pragma unroll
  for(int st=0; st<4; st++)
    #pragma unroll
    for(int kk=0; kk<2; kk++){
      const float* p = qlh + (size_t)(wv*64 + st*16 + l15)*DHEAD + kk*32 + g*8;
      aQ[st][kk] = pack8f(*(const float4*)p, *(const float4*)(p+4));
    }
  f4 accO[4][4] = {};
  float den[4][4] = {};
  short* pw = pL[wv];
  for(int cc=0; cc<CGRP; cc++){
    int c = cg*CGRP + cc;
    if(c >= NCHUNK) break;
    for(int half=0; half<2; half++){
      const short* Kh = Kb + ((size_t)h*NPAD + (size_t)c*256 + half*128)*DHEAD;
      const short* Vh = Vb + ((size_t)h*NPAD + (size_t)c*256 + half*128)*DHEAD;
      __syncthreads();
      #pragma unroll
      for(int it=0; it<4; it++){
        int gi = t + it*256;
        int m = gi >> 3, db = (gi & 7) * 8;
        *(sh8*)((char*)kL + m*128 + ((db*2) ^ ((m&7)<<4))) =
            *(const sh8*)(Kh + (size_t)m*DHEAD + db);
      }
      // V staging: 2 rows/thread packed into u32 writes (same layout+swizzle)
      #pragma unroll
      for(int it=0; it<2; it++){
        int idx = t + it*256;                 // 512 units: 64 row-pairs x 8 d-groups
        int mp = (idx & 63)*2, dg = (idx >> 6)*8;
        sh8 v0 = *(const sh8*)(Vh + (size_t)mp*DHEAD + dg);
        sh8 v1 = *(const sh8*)(Vh + (size_t)(mp+1)*DHEAD + dg);
        #pragma unroll
        for(int i=0;i<8;i++){
          int d = dg + i;
          unsigned pk = ((unsigned)(unsigned short)v0[i]) |
                        (((unsigned)(unsigned short)v1[i]) << 16);
          *(unsigned*)((char*)vL + d*256 + ((mp*2) ^ ((d&7)<<4))) = pk;
        }
      }
      __syncthreads();
      #pragma unroll
      for(int st=0; st<4; st++){
        #pragma unroll
        for(int mt=0; mt<8; mt++){
          f4 s = {};
          #pragma unroll
          for(int kk=0; kk<2; kk++){
            int m = mt*16 + l15;
            sh8 b = *(sh8*)((char*)kL + m*128 + ((kk*64 + g*16) ^ ((m&7)<<4)));
            s = MFMA16(aQ[st][kk], b, s);
          }
          #pragma unroll
          for(int r=0; r<4; r++){
            float e = __expf(s[r]);
            den[st][r] += e;
            int n = g*4 + r;
            *(short*)((char*)pw + n*256 + (((mt*16+l15)*2) ^ ((n&7)<<4))) = (short)bfbits(e);
          }
        }
        #pragma unroll
        for(int ks=0; ks<4; ks++){
          sh8 aP = *(sh8*)((char*)pw + l15*256 + ((ks*64 + g*16) ^ ((l15&7)<<4)));
          #pragma unroll
          for(int dt=0; dt<4; dt++){
            int d = dt*16 + l15;
            sh8 bV = *(sh8*)((char*)vL + d*256 + ((ks*64 + g*16) ^ ((d&7)<<4)));
            accO[st][dt] = MFMA16(aP, bV, accO[st][dt]);
          }
        }
      }
    }
  }
  #pragma unroll
  for(int st=0; st<4; st++)
    #pragma unroll
    for(int r=0; r<4; r++){
      float d_ = den[st][r];
      d_ += __shfl_xor(d_,1); d_ += __shfl_xor(d_,2);
      d_ += __shfl_xor(d_,4); d_ += __shfl_xor(d_,8);
      den[st][r] = d_;
    }
  size_t base = ((size_t)h*NCG + cg)*NLAND;
  #pragma unroll
  for(int st=0; st<4; st++){
    #pragma unroll
    for(int r=0; r<4; r++){
      int row = wv*64 + st*16 + g*4 + r;
      if(l15 == 0) denP[base + row] = den[st][r];
      #pragma unroll
      for(int dt=0; dt<4; dt++)
        numP[(base + row)*DHEAD + dt*16 + l15] = accO[st][dt][r];
    }
  }
}

__global__ void k_a3v_comb(const float* __restrict__ numP, const float* __restrict__ denP,
                           float* __restrict__ a3v){
  int bidx = blockIdx.x;
  int h = bidx >> 8, m = bidx & 255;
  int d = threadIdx.x;
  float s = 0.f, den = 0.f;
  for(int c=0;c<NCG;c++){
    s += numP[(((size_t)h*NCG + c)*NLAND + m)*DHEAD + d];
    den += denP[((size_t)h*NCG + c)*NLAND + m];
  }
  a3v[((size_t)h*NLAND + m)*DHEAD + d] = s / den;
}

// ---------------- residual depthwise conv (k=33), register-FIR ----------------
__global__ __launch_bounds__(256) void k_resconv(const short* __restrict__ Vb,
    const float* __restrict__ rw, short* __restrict__ F){
  __shared__ float vs[96][64];
  int n0 = blockIdx.x*64, h = blockIdx.y;
  int t = threadIdx.x;
  const short* vh = Vb + (size_t)h*NPAD*DHEAD;
  #pragma unroll
  for(int i=0;i<3;i++){
    int idx = t + i*256;
    int r = idx >> 3, dg = (idx & 7)*8;
    int n = n0 - 16 + r;
    sh8 v = {0,0,0,0,0,0,0,0};
    if(n>=0 && n<NPAD) v = *(const sh8*)(vh + (size_t)n*DHEAD + dg);
    #pragma unroll
    for(int e=0;e<8;e++) vs[r][dg+e] = bf2f(v[e]);
  }
  float w[33];
  #pragma unroll
  for(int j=0;j<33;j++) w[j] = rw[h*33+j];
  __syncthreads();
  int d = t & 63, grp = t >> 6;
  float f0[16];
  #pragma unroll
  for(int rr=0;rr<16;rr++){
    int n = n0 + grp*16 + rr;
    f0[rr] = bf2f(F[(size_t)n*CDIM + h*DHEAD + d]);
  }
  float in[48];
  #pragma unroll
  for(int x=0;x<48;x++) in[x] = vs[grp*16 + x][d];
  #pragma unroll
  for(int rr=0;rr<16;rr++){
    float acc = 0.f;
    #pragma unroll
    for(int j=0;j<33;j++) acc += w[j]*in[rr+j];
    int n = n0 + grp*16 + rr;
    F[(size_t)n*CDIM + h*DHEAD + d] = (short)bfbits(f0[rr] + acc);
  }
}

// ---------------- weight transpose f32 -> bf16 ----------------
__global__ void k_transposeb(const float* __restrict__ in, short* __restrict__ out,
                             int R, int C){
  __shared__ float tile[32][33];
  int r0 = blockIdx.x*32, c0 = blockIdx.y*32;
  int tx = threadIdx.x, ty = threadIdx.y;
  #pragma unroll
  for(int r=0;r<4;r++) tile[ty + r*8][tx] = in[(size_t)(r0 + ty + r*8)*C + c0 + tx];
  __syncthreads();
  #pragma unroll
  for(int r=0;r<4;r++)
    out[(size_t)(c0 + ty + r*8)*R + r0 + tx] = (short)bfbits(tile[tx][ty + r*8]);
}

// ---------------- PPEG direct on row-major [n][c] (f32) ----------------
__global__ __launch_bounds__(256) void k_ppeg2(const float* __restrict__ X,
    const float* __restrict__ w7, const float* __restrict__ b7,
    const float* __restrict__ w5, const float* __restrict__ b5,
    const float* __restrict__ w3, const float* __restrict__ b3,
    float* __restrict__ Y){
  __shared__ float patch[484][20];
  int cg = blockIdx.y;
  int ti = blockIdx.x >> 3, tj = blockIdx.x & 7;
  int t = threadIdx.x;
  int i0 = ti*16 - 3, j0 = tj*16 - 3;
  for(int idx = t; idx < 1936; idx += 256){
    int p = idx >> 2, cq = (idx & 3) * 4;
    int gi = i0 + p/22, gj = j0 + p%22;
    float4 v = make_float4(0.f,0.f,0.f,0.f);
    if(gi>=0 && gi<128 && gj>=0 && gj<128)
      v = *(const float4*)(X + (size_t)(gi*128+gj)*CDIM + cg*16 + cq);
    *(float4*)&patch[p][cq] = v;
  }
  int c = t & 15, sg = t >> 4;
  int cglob = cg*16 + c;
  float wr[83];
  #pragma unroll
  for(int k=0;k<49;k++) wr[k] = w7[cglob*49+k];
  #pragma unroll
  for(int k=0;k<25;k++) wr[49+k] = w5[cglob*25+k];
  #pragma unroll
  for(int k=0;k<9;k++)  wr[74+k] = w3[cglob*9+k];
  float bsum = b7[cglob] + b5[cglob] + b3[cglob];
  __syncthreads();
  float acc[16];
  #pragma unroll
  for(int j=0;j<16;j++) acc[j] = patch[(sg+3)*22 + (j+3)][c] + bsum;
  #pragma unroll
  for(int a=0;a<7;a++)
    #pragma unroll
    for(int x=0;x<22;x++){
      float vv = patch[(sg+a)*22 + x][c];
      #pragma unroll
      for(int bq=0;bq<7;bq++){
        int j = x - bq;
        if(j>=0 && j<16) acc[j] += wr[a*7+bq]*vv;
      }
    }
  #pragma unroll
  for(int a=0;a<5;a++)
    #pragma unroll
    for(int x=1;x<21;x++){
      float vv = patch[(sg+a+1)*22 + x][c];
      #pragma unroll
      for(int bq=0;bq<5;bq++){
        int j = x - 1 - bq;
        if(j>=0 && j<16) acc[j] += wr[49+a*5+bq]*vv;
      }
    }
  #pragma unroll
  for(int a=0;a<3;a++)
    #pragma unroll
    for(int x=2;x<20;x++){
      float vv = patch[(sg+a+2)*22 + x][c];
      #pragma unroll
      for(int bq=0;bq<3;bq++){
        int j = x - 2 - bq;
        if(j>=0 && j<16) acc[j] += wr[74+a*3+bq]*vv;
      }
    }
  #pragma unroll
  for(int j=0;j<16;j++)
    Y[(size_t)((ti*16+sg)*128 + tj*16+j)*CDIM + cglob] = acc[j];
}

// ---------------- final LN(row0) + fc2 ----------------
__global__ __launch_bounds__(512) void k_final(const float* __restrict__ A,
    const float* __restrict__ g, const float* __restrict__ b,
    const float* __restrict__ w, const float* __restrict__ bias,
    float* __restrict__ outp){
  __shared__ float red[8];
  int t = threadIdx.x, wv = t >> 6;
  float x = A[t];
  float s = wave_sum(x);
  if((t & 63) == 0) red[wv] = s;
  __syncthreads();
  float mu = 0;
  #pragma unroll
  for(int i=0;i<8;i++) mu += red[i];
  mu *= (1.f/512.f);
  __syncthreads();
  float dx = x - mu;
  s = wave_sum(dx*dx);
  if((t & 63) == 0) red[wv] = s;
  __syncthreads();
  float var = 0;
  #pragma unroll
  for(int i=0;i<8;i++) var += red[i];
  var *= (1.f/512.f);
  float xn = dx * rsqrtf(var + 1e-5f) * g[t] + b[t];
  __syncthreads();
  for(int o=0;o<4;o++){
    s = wave_sum(xn * w[t*4 + o]);
    if((t & 63) == 0) red[wv] = s;
    __syncthreads();
    if(t == 0){
      float r = 0;
      #pragma unroll
      for(int i=0;i<8;i++) r += red[i];
      outp[o] = r + bias[o];
    }
    __syncthreads();
  }
}

extern "C" void kernel_launch(void* const* d_in, const int* in_sizes, int n_in,
                              void* d_out, int out_size, void* d_ws, size_t ws_size,
                              hipStream_t stream) {
  (void)in_sizes; (void)n_in; (void)out_size; (void)ws_size;
  const float* data_x = (const float*)d_in[0];
  const float* fc1_w  = (const float*)d_in[1];
  const float* fc1_b  = (const float*)d_in[2];
  const float* cls_tk = (const float*)d_in[3];
  const float* ng[2]  = {(const float*)d_in[4],  (const float*)d_in[16]};
  const float* nb[2]  = {(const float*)d_in[5],  (const float*)d_in[17]};
  const float* qkvw[2]= {(const float*)d_in[6],  (const float*)d_in[18]};
  const float* outw[2]= {(const float*)d_in[7],  (const float*)d_in[19]};
  const float* outb[2]= {(const float*)d_in[8],  (const float*)d_in[20]};
  const float* resw[2]= {(const float*)d_in[9],  (const float*)d_in[21]};
  const float* w7 = (const float*)d_in[10]; const float* pb7 = (const float*)d_in[11];
  const float* w5 = (const float*)d_in[12]; const float* pb5 = (const float*)d_in[13];
  const float* w3 = (const float*)d_in[14]; const float* pb3 = (const float*)d_in[15];
  const float* norm_g = (const float*)d_in[22];
  const float* norm_b = (const float*)d_in[23];
  const float* fc2_w  = (const float*)d_in[24];
  const float* fc2_b  = (const float*)d_in[25];

  float* ws = (float*)d_ws;
  float* Ab   = ws;
  float* Bb   = Ab + (size_t)TOK*CDIM;
  float* Fb   = Bb + (size_t)TOK*CDIM;
  short* Fbf  = (short*)(Fb + (size_t)NPAD*CDIM);
  short* lnX  = Fbf + (size_t)NPAD*CDIM;
  short* Qb   = lnX + (size_t)NPAD*CDIM;
  short* Kb   = Qb  + (size_t)NPAD*CDIM;
  short* Vb   = Kb  + (size_t)NPAD*CDIM;
  short* dxb  = Vb  + (size_t)NPAD*CDIM;
  float* qlb  = (float*)(dxb + (size_t)16384*1024);
  float* klb  = qlb + NHEAD*NLAND*DHEAD;
  float* a2b  = klb + NHEAD*NLAND*DHEAD;    // 8*65536 f32
  float* z0b  = a2b + NHEAD*NLAND*NLAND;    // carved: zb0/zb1 bf16
  float* z1b  = z0b + NHEAD*NLAND*NLAND;    // carved: xb/tb bf16
  float* Xb_  = z1b + NHEAD*NLAND*NLAND;    // carved: ub bf16 + a2bf
  float* Tb_  = Xb_ + NHEAD*NLAND*NLAND;    // zf (final z f32)
  float* Ub_  = Tb_ + NHEAD*NLAND*NLAND;    // unused
  float* a3vb = Ub_ + NHEAD*NLAND*NLAND;
  float* w2tb = a3vb + NHEAD*NLAND*DHEAD;
  float* denP = w2tb + NHEAD*DHEAD*NLAND;   // 8*33*256
  float* hmax = denP + NHEAD*NCG*NLAND;
  float* scal = hmax + 8;
  short* fc1T = (short*)(scal + 8);
  short* qkvT0= fc1T + 512*1024;
  short* qkvT1= qkvT0 + 1536*512;
  short* outT0= qkvT1 + 1536*512;
  short* outT1= outT0 + 512*512;
  short* qkvT[2] = {qkvT0, qkvT1};
  short* outT[2] = {outT0, outT1};

  const int HB = NHEAD*NLAND*NLAND;         // 524288
  short* zb0  = (short*)z0b;  short* zb1  = zb0 + HB;
  short* xb   = (short*)z1b;  short* tb   = xb + HB;
  short* ub   = (short*)Xb_;  short* a2bf = ub + HB;
  float* zf   = Tb_;

  k_transposeb<<<dim3(32,16), dim3(32,8), 0, stream>>>(fc1_w, fc1T, 1024, 512);
  k_transposeb<<<dim3(16,48), dim3(32,8), 0, stream>>>(qkvw[0], qkvT0, 512, 1536);
  k_transposeb<<<dim3(16,48), dim3(32,8), 0, stream>>>(qkvw[1], qkvT1, 512, 1536);
  k_transposeb<<<dim3(16,16), dim3(32,8), 0, stream>>>(outw[0], outT0, 512, 512);
  k_transposeb<<<dim3(16,16), dim3(32,8), 0, stream>>>(outw[1], outT1, 512, 512);
  k_f2b<<<8192, 256, 0, stream>>>(data_x, dxb, 16384*1024/8);

  k_copyrow<<<1, 512, 0, stream>>>(Ab, cls_tk);
  k_gemm_g<0><<<dim3(4, 128), 256, 0, stream>>>(dxb, 1024, fc1T, 1024, fc1_b,
                                                Ab + CDIM, nullptr, nullptr, 16384);
  float* base[2]  = {Ab, Bb};
  for(int L=0; L<2; L++){
    k_ln_pad<<<NPAD/4, 256, 0, stream>>>(base[L], ng[L], nb[L], lnX);
    k_gemm_g<1><<<dim3(12, 130), 256, 0, stream>>>(lnX, CDIM, qkvT[L], CDIM, nullptr,
                                                   Qb, Kb, Vb, NPAD);
    k_landmark2<<<2*NHEAD*NLAND, 64, 0, stream>>>(Qb, Kb, qlb, klb);
    k_a2<<<dim3(4, NHEAD), 256, 0, stream>>>(qlb, klb, a2b, a2bf);
    k_colmax<<<NHEAD, 256, 0, stream>>>(a2b, hmax);
    k_zinit<<<dim3(256, NHEAD), 256, 0, stream>>>(a2b, hmax, zb0);
    short* zc = zb0; short* zn = zb1;
    for(int it=0; it<6; it++){
      k_pgemm<0,0><<<dim3(4,4,NHEAD), 256, 0, stream>>>(a2bf, zc, xb, nullptr, 0.f, 1.f);
      k_pgemm<1,0><<<dim3(4,4,NHEAD), 256, 0, stream>>>(xb, xb, tb, nullptr, 7.f, 1.f);
      k_pgemm<1,0><<<dim3(4,4,NHEAD), 256, 0, stream>>>(xb, tb, ub, nullptr, 15.f, 1.f);
      if(it < 5){
        k_pgemm<1,0><<<dim3(4,4,NHEAD), 256, 0, stream>>>(zc, ub, zn, nullptr, 13.f, 0.25f);
        short* tmp = zc; zc = zn; zn = tmp;
      } else {
        k_pgemm<1,1><<<dim3(4,4,NHEAD), 256, 0, stream>>>(zc, ub, nullptr, zf, 13.f, 0.25f);
      }
    }
    k_a3v_mfma<<<dim3(NHEAD, NCG), 256, 0, stream>>>(qlb, Kb, Vb, Fb, denP);
    k_a3v_comb<<<NHEAD*NLAND, 64, 0, stream>>>(Fb, denP, a3vb);
    k_sgemm2<0,1><<<dim3(1,4,NHEAD), 256, 0, stream>>>(zf, a3vb, w2tb, 256,64,256,
                                                       65536,16384,16384, 0.f, 1.f);
    k_a1_mfma<<<dim3(130, NHEAD), 256, 0, stream>>>(Qb, klb, w2tb, Fbf);
    k_resconv<<<dim3(260, NHEAD), 256, 0, stream>>>(Vb, resw[L], Fbf);
    k_gemm_g<2><<<dim3(4, 129), 256, 0, stream>>>(Fbf + (size_t)PAD0*CDIM, CDIM,
                                                  outT[L], CDIM, outb[L],
                                                  base[L], nullptr, nullptr, TOK);
    if(L == 0){
      k_ppeg2<<<dim3(64, 32), 256, 0, stream>>>(Ab + CDIM, w7, pb7, w5, pb5, w3, pb3,
                                                Bb + CDIM);
      k_copyrow<<<1, 512, 0, stream>>>(Bb, Ab);
    }
  }
  k_final<<<1, 512, 0, stream>>>(Bb, norm_g, norm_b, fc2_w, fc2_b, (float*)d_out);
}

// Round 17
// 945.393 us; speedup vs baseline: 3.0472x; 1.0987x over previous
//
#include <hip/hip_runtime.h>
#include <hip/hip_bf16.h>

#define NPAD 16640
#define TOK  16385
#define CDIM 512
#define NHEAD 8
#define DHEAD 64
#define NLAND 256
#define LFAC  65
#define PAD0  255
#define NCHUNK 65     // 256-row chunks
#define CGRP 2        // chunks per block in a3v
#define NCG 33        // ceil(65/2)

typedef __attribute__((ext_vector_type(8))) short sh8;
typedef __attribute__((ext_vector_type(4))) float f4;

__device__ __forceinline__ float wave_sum(float v){
  #pragma unroll
  for(int o=32;o;o>>=1) v += __shfl_xor(v,o);
  return v;
}
__device__ __forceinline__ float wave_max(float v){
  #pragma unroll
  for(int o=32;o;o>>=1) v = fmaxf(v, __shfl_xor(v,o));
  return v;
}

__device__ __forceinline__ unsigned bfbits(float x){
  unsigned u = __float_as_uint(x);
  return (u + 0x7fffu + ((u >> 16) & 1u)) >> 16;
}
__device__ __forceinline__ float bf2f(short s){
  return __uint_as_float(((unsigned)(unsigned short)s) << 16);
}
__device__ __forceinline__ sh8 pack8f(float4 a, float4 b){
  sh8 r;
  r[0]=(short)bfbits(a.x); r[1]=(short)bfbits(a.y); r[2]=(short)bfbits(a.z); r[3]=(short)bfbits(a.w);
  r[4]=(short)bfbits(b.x); r[5]=(short)bfbits(b.y); r[6]=(short)bfbits(b.z); r[7]=(short)bfbits(b.w);
  return r;
}
#define MFMA16(a,b,c) __builtin_amdgcn_mfma_f32_16x16x32_bf16(a,b,c,0,0,0)

__device__ __forceinline__ void gload16(const void* g, void* l){
  __builtin_amdgcn_global_load_lds(
      (const __attribute__((address_space(1))) void*)g,
      (__attribute__((address_space(3))) void*)l, 16, 0, 0);
}

// ---------------- row copy (cls token) ----------------
__global__ void k_copyrow(float* dst, const float* __restrict__ src){
  dst[threadIdx.x] = src[threadIdx.x];
}

// ---------------- f32 -> bf16 convert ----------------
__global__ __launch_bounds__(256) void k_f2b(const float* __restrict__ in,
    short* __restrict__ out, int n8){
  int i = blockIdx.x*256 + threadIdx.x;
  if(i < n8){
    float4 a = *(const float4*)(in + (size_t)i*8);
    float4 b = *(const float4*)(in + (size_t)i*8 + 4);
    *(sh8*)(out + (size_t)i*8) = pack8f(a, b);
  }
}

// ---------------- layernorm + front pad -> bf16 ----------------
__global__ __launch_bounds__(256) void k_ln_pad(const float* __restrict__ A,
    const float* __restrict__ g, const float* __restrict__ b, short* __restrict__ B){
  int w = threadIdx.x >> 6, lane = threadIdx.x & 63;
  int row = blockIdx.x*4 + w;
  short* out = B + (size_t)row*CDIM;
  int c = lane*8;
  if(row < PAD0){
    sh8 z = {0,0,0,0,0,0,0,0};
    *(sh8*)(out + c) = z;
    return;
  }
  const float* x = A + (size_t)(row-PAD0)*CDIM;
  float4 v0 = *(const float4*)(x + c);
  float4 v1 = *(const float4*)(x + c + 4);
  float xs[8] = {v0.x,v0.y,v0.z,v0.w,v1.x,v1.y,v1.z,v1.w};
  float s = 0;
  #pragma unroll
  for(int i=0;i<8;i++) s += xs[i];
  s = wave_sum(s);
  float mu = s * (1.f/512.f);
  float vs = 0;
  #pragma unroll
  for(int i=0;i<8;i++){ float d = xs[i]-mu; vs += d*d; }
  vs = wave_sum(vs) * (1.f/512.f);
  float rs = rsqrtf(vs + 1e-5f);
  float4 g0 = *(const float4*)(g + c); float4 g1 = *(const float4*)(g + c + 4);
  float4 b0 = *(const float4*)(b + c); float4 b1 = *(const float4*)(b + c + 4);
  float gg[8] = {g0.x,g0.y,g0.z,g0.w,g1.x,g1.y,g1.z,g1.w};
  float bb[8] = {b0.x,b0.y,b0.z,b0.w,b1.x,b1.y,b1.z,b1.w};
  sh8 o;
  #pragma unroll
  for(int i=0;i<8;i++) o[i] = (short)bfbits((xs[i]-mu)*rs*gg[i] + bb[i]);
  *(sh8*)(out + c) = o;
}

// ---------------- gload-staged MFMA GEMM: C[M,N] = A[M,K] @ WT[N,K]^T ----------------
template<int MODE>
__global__ __launch_bounds__(256) void k_gemm_g(const short* __restrict__ A, int lda,
    const short* __restrict__ WT, int K, const float* __restrict__ bias,
    void* out0v, void* out1v, void* out2v, int M){
  __shared__ short As[2][128*32];
  __shared__ short Bs[2][128*32];
  int t = threadIdx.x, lane = t & 63, wv = t >> 6, g = lane >> 4, l15 = lane & 15;
  int nwg = gridDim.x * gridDim.y;
  int orig = blockIdx.y * gridDim.x + blockIdx.x;
  int qc = nwg >> 3, rc = nwg & 7, xcd = orig & 7, loc = orig >> 3;
  int wgid = (xcd < rc ? xcd*(qc+1) : rc*(qc+1) + (xcd - rc)*qc) + loc;
  int row0 = (wgid / gridDim.x) * 128, n0 = (wgid % gridDim.x) * 128;
  int wm = (wv>>1)*64, wn = (wv&1)*64;
  int mq = lane >> 2, slot = lane & 3;

  auto stage = [&](int buf, int k0){
    #pragma unroll
    for(int c=0;c<2;c++){
      int m = wv*32 + c*16 + mq;
      int swz = (((m&3) ^ ((m>>2)&3)) << 4);
      int gr = row0 + m; if(gr >= M) gr = M-1;
      const char* srcA = (const char*)(A + (size_t)gr*lda + k0) + ((slot*16) ^ swz);
      gload16(srcA, (char*)As[buf] + wv*2048 + c*1024);
      const char* srcB = (const char*)(WT + (size_t)(n0+m)*K + k0) + ((slot*16) ^ swz);
      gload16(srcB, (char*)Bs[buf] + wv*2048 + c*1024);
    }
  };

  f4 acc[4][4] = {};
  int nk = K >> 5;
  stage(0, 0);
  __syncthreads();
  int cur = 0;
  for(int i=0; i<nk; i++){
    if(i+1 < nk) stage(cur^1, (i+1) << 5);
    sh8 af[4], bf[4];
    #pragma unroll
    for(int mt=0; mt<4; mt++){
      int r = wm + mt*16 + l15;
      af[mt] = *(sh8*)((char*)As[cur] + r*64 + ((g*16) ^ (((r&3)^((r>>2)&3))<<4)));
    }
    #pragma unroll
    for(int nt=0; nt<4; nt++){
      int r = wn + nt*16 + l15;
      bf[nt] = *(sh8*)((char*)Bs[cur] + r*64 + ((g*16) ^ (((r&3)^((r>>2)&3))<<4)));
    }
    #pragma unroll
    for(int mt=0; mt<4; mt++)
      #pragma unroll
      for(int nt=0; nt<4; nt++)
        acc[mt][nt] = MFMA16(af[mt], bf[nt], acc[mt][nt]);
    __syncthreads();
    cur ^= 1;
  }
  #pragma unroll
  for(int mt=0; mt<4; mt++){
    #pragma unroll
    for(int r=0; r<4; r++){
      int gm = row0 + wm + mt*16 + g*4 + r;
      if(gm >= M) continue;
      #pragma unroll
      for(int nt=0; nt<4; nt++){
        int gn = n0 + wn + nt*16 + l15;
        float v = acc[mt][nt][r];
        if(MODE == 0){
          v += bias[gn];
          ((float*)out0v)[(size_t)gm*CDIM + gn] = v > 0.f ? v : 0.f;
        } else if(MODE == 1){
          int p = gn >> 9, rr = gn & 511;
          int hh = rr >> 6, dd = rr & 63;
          if(p == 0) v *= 0.125f;
          short* dst = (p==0) ? (short*)out0v : (p==1 ? (short*)out1v : (short*)out2v);
          dst[((size_t)hh*NPAD + gm)*DHEAD + dd] = (short)bfbits(v);
        } else {
          ((float*)out0v)[(size_t)gm*CDIM + gn] += v + bias[gn];
        }
      }
    }
  }
}

// ---------------- landmark means, Q and K in one dispatch ----------------
__global__ void k_landmark2(const short* __restrict__ Qb, const short* __restrict__ Kb,
    float* __restrict__ ql, float* __restrict__ kl){
  int bidx = blockIdx.x;
  int sel = bidx >> 11;
  int loc = bidx & 2047;
  int h = loc >> 8, m = loc & 255, d = threadIdx.x;
  const short* src = (sel ? Kb : Qb) + ((size_t)h*NPAD + (size_t)m*LFAC)*DHEAD + d;
  float s = 0;
  for(int j=0;j<LFAC;j++) s += bf2f(src[(size_t)j*DHEAD]);
  (sel ? kl : ql)[(size_t)loc*DHEAD + d] = s * (1.f/LFAC);
}

// ---------------- a2 = softmax(ql @ kl^T), MFMA ----------------
// grid (4 row-quarters, NHEAD). kl staged bf16 LDS; Q frags from global.
__global__ __launch_bounds__(256) void k_a2_mfma(const float* __restrict__ ql,
    const float* __restrict__ kl, float* __restrict__ a2, short* __restrict__ a2bf){
  __shared__ short klL[256*64];   // [n][d] bf16, 128B rows, XOR swizzle
  int q = blockIdx.x, h = blockIdx.y;
  int t = threadIdx.x, lane = t & 63, wv = t >> 6, g = lane >> 4, l15 = lane & 15;
  const float* qlh = ql + (size_t)h*NLAND*DHEAD;
  const float* klh = kl + (size_t)h*NLAND*DHEAD;
  #pragma unroll
  for(int i=0;i<8;i++){
    int gi = t + i*256;               // 2048 granules of 8
    int n = gi >> 3, db = (gi & 7)*8;
    float4 a = *(const float4*)(klh + (size_t)n*DHEAD + db);
    float4 b = *(const float4*)(klh + (size_t)n*DHEAD + db + 4);
    *(sh8*)((char*)klL + n*128 + ((db*2) ^ ((n&7)<<4))) = pack8f(a, b);
  }
  __syncthreads();
  int row0 = q*64 + wv*16;
  sh8 aQ[2];
  #pragma unroll
  for(int kk=0; kk<2; kk++){
    const float* p = qlh + (size_t)(row0 + l15)*DHEAD + kk*32 + g*8;
    aQ[kk] = pack8f(*(const float4*)p, *(const float4*)(p+4));
  }
  f4 acc[16];
  #pragma unroll
  for(int nt=0; nt<16; nt++){
    f4 s = {};
    #pragma unroll
    for(int kk=0; kk<2; kk++){
      int n = nt*16 + l15;
      sh8 b = *(sh8*)((char*)klL + n*128 + ((kk*64 + g*16) ^ ((n&7)<<4)));
      s = MFMA16(aQ[kk], b, s);
    }
    acc[nt] = s;
  }
  float den[4] = {0,0,0,0};
  #pragma unroll
  for(int nt=0; nt<16; nt++)
    #pragma unroll
    for(int r=0; r<4; r++){
      float e = __expf(acc[nt][r]);
      acc[nt][r] = e;
      den[r] += e;
    }
  #pragma unroll
  for(int r=0; r<4; r++){
    float d_ = den[r];
    d_ += __shfl_xor(d_,1); d_ += __shfl_xor(d_,2);
    d_ += __shfl_xor(d_,4); d_ += __shfl_xor(d_,8);
    den[r] = 1.f/d_;
  }
  #pragma unroll
  for(int nt=0; nt<16; nt++)
    #pragma unroll
    for(int r=0; r<4; r++){
      int row = row0 + g*4 + r;
      int col = nt*16 + l15;
      float v = acc[nt][r]*den[r];
      size_t idx = ((size_t)h*NLAND + row)*NLAND + col;
      a2[idx] = v;
      a2bf[idx] = (short)bfbits(v);
    }
}

// ---------------- pinv init ----------------
__global__ void k_colmax(const float* __restrict__ a2, float* __restrict__ hmax){
  __shared__ float red[4];
  int h = blockIdx.x, t = threadIdx.x;
  const float* p = a2 + (size_t)h*65536 + t;
  float s = 0;
  for(int m=0;m<256;m++) s += p[(size_t)m*256];
  float mx = wave_max(s);
  if((t & 63) == 0) red[t>>6] = mx;
  __syncthreads();
  if(t == 0) hmax[h] = fmaxf(fmaxf(red[0],red[1]), fmaxf(red[2],red[3]));
}
// z0 (bf16) = a2^T / max(hmax)
__global__ void k_zinit(const float* __restrict__ a2, const float* __restrict__ hmax,
                        short* __restrict__ z){
  int h = blockIdx.y;
  int idx = blockIdx.x*256 + threadIdx.x;
  int m = idx >> 8, j = idx & 255;
  float mx = hmax[0];
  #pragma unroll
  for(int i=1;i<8;i++) mx = fmaxf(mx, hmax[i]);
  z[(size_t)h*65536 + idx] = (short)bfbits(a2[(size_t)h*65536 + (size_t)j*256 + m] / mx);
}

// ---------------- batched MFMA pinv GEMM, bf16 I/O ----------------
template<int TRANS, int F32OUT>
__global__ __launch_bounds__(256) void k_pgemm(const short* __restrict__ A,
    const short* __restrict__ B, short* __restrict__ C, float* __restrict__ Cf,
    float alpha, float beta){
  __shared__ short As[64*32];
  __shared__ short Bs[64*32];
  int bh = blockIdx.z;
  const short* Ah = A + (size_t)bh*65536;
  const short* Bh = B + (size_t)bh*65536;
  int m0 = blockIdx.y*64, n0 = blockIdx.x*64;
  int t = threadIdx.x, lane = t & 63, wv = t >> 6, g = lane >> 4, l15 = lane & 15;
  f4 acc[4] = {};
  for(int k0=0; k0<256; k0+=32){
    {
      int m = t >> 2, kb = (t & 3)*8;
      sh8 av = *(const sh8*)(Ah + (size_t)(m0+m)*256 + k0 + kb);
      int swz = (((m&3)^((m>>2)&3))<<4);
      *(sh8*)((char*)As + m*64 + ((kb*2)^swz)) = av;
    }
    {
      int kr = t >> 3, nb = (t & 7)*8;
      sh8 bv = *(const sh8*)(Bh + (size_t)(k0+kr)*256 + n0 + nb);
      #pragma unroll
      for(int e=0;e<8;e++){
        int n = nb + e;
        short sv = bv[e];
        if(TRANS){
          float f = ((k0+kr == n0+n) ? alpha : 0.f) - bf2f(sv);
          sv = (short)bfbits(f);
        }
        int swz = (((n&3)^((n>>2)&3))<<4);
        *(short*)((char*)Bs + n*64 + ((kr*2)^swz)) = sv;
      }
    }
    __syncthreads();
    int rm = wv*16 + l15;
    sh8 af = *(sh8*)((char*)As + rm*64 + ((g*16) ^ (((rm&3)^((rm>>2)&3))<<4)));
    #pragma unroll
    for(int nt=0; nt<4; nt++){
      int n = nt*16 + l15;
      sh8 bf = *(sh8*)((char*)Bs + n*64 + ((g*16) ^ (((n&3)^((n>>2)&3))<<4)));
      acc[nt] = MFMA16(af, bf, acc[nt]);
    }
    __syncthreads();
  }
  size_t hoff = (size_t)bh*65536;
  #pragma unroll
  for(int nt=0; nt<4; nt++)
    #pragma unroll
    for(int r=0; r<4; r++){
      size_t idx = hoff + (size_t)(m0 + wv*16 + g*4 + r)*256 + n0 + nt*16 + l15;
      float v = acc[nt][r]*beta;
      if(F32OUT) Cf[idx] = v;
      else       C[idx] = (short)bfbits(v);
    }
}

// ---------------- batched f32 GEMM 64x64 tile (w2^T only) ----------------
template<int TRANS, int OUTT>
__global__ __launch_bounds__(256) void k_sgemm2(const float* __restrict__ A,
    const float* __restrict__ B, float* __restrict__ C,
    int M, int N, int K, long sA, long sB, long sC, float alpha, float beta){
  __shared__ float As[32][68];
  __shared__ float Bs[32][68];
  int bh = blockIdx.z;
  const float* Ah = A + (size_t)bh*sA;
  const float* Bh = B + (size_t)bh*sB;
  float* Ch = C + (size_t)bh*sC;
  int m0 = blockIdx.y*64, n0 = blockIdx.x*64;
  int t = threadIdx.x, tx = t & 15, ty = t >> 4;
  float acc[4][4] = {};
  for(int k0=0; k0<K; k0+=32){
    #pragma unroll
    for(int u=0; u<2; u++){
      int idx = t + u*256;
      int r = idx >> 3, cb = (idx & 7) * 4;
      float4 va = *(const float4*)(Ah + (size_t)(m0+r)*K + k0 + cb);
      As[cb+0][r]=va.x; As[cb+1][r]=va.y; As[cb+2][r]=va.z; As[cb+3][r]=va.w;
      int kr = idx >> 4, nb = (idx & 15) * 4;
      float4 w = *(const float4*)(Bh + (size_t)(k0+kr)*N + n0 + nb);
      if(TRANS){
        int gk = k0 + kr;
        w.x = ((gk==n0+nb+0)?alpha:0.f) - w.x;
        w.y = ((gk==n0+nb+1)?alpha:0.f) - w.y;
        w.z = ((gk==n0+nb+2)?alpha:0.f) - w.z;
        w.w = ((gk==n0+nb+3)?alpha:0.f) - w.w;
      }
      *(float4*)&Bs[kr][nb] = w;
    }
    __syncthreads();
    #pragma unroll
    for(int k=0;k<32;k++){
      float a[4], b[4];
      *(float4*)a = *(const float4*)&As[k][ty*4];
      *(float4*)b = *(const float4*)&Bs[k][tx*4];
      #pragma unroll
      for(int i=0;i<4;i++)
        #pragma unroll
        for(int j=0;j<4;j++) acc[i][j] += a[i]*b[j];
    }
    __syncthreads();
  }
  #pragma unroll
  for(int i=0;i<4;i++){
    #pragma unroll
    for(int j=0;j<4;j++){
      int gm = m0 + ty*4 + i, gn = n0 + tx*4 + j;
      float v = acc[i][j] * beta;
      if(OUTT) Ch[(size_t)gn*M + gm] = v;
      else     Ch[(size_t)gm*N + gn] = v;
    }
  }
}

// ---------------- MFMA flash a1 (Q bf16, F out bf16), per-wave P ----------------
__global__ __launch_bounds__(256) void k_a1_mfma(const short* __restrict__ Qb,
    const float* __restrict__ kl, const float* __restrict__ w2t, short* __restrict__ F){
  __shared__ short klL[128*64];
  __shared__ short w2L[64*128];
  __shared__ short pL[4][16*128];
  int h = blockIdx.y, n0 = blockIdx.x*128;
  int t = threadIdx.x, lane = t & 63, wv = t >> 6, g = lane >> 4, l15 = lane & 15;
  const float* klh = kl + (size_t)h*NLAND*DHEAD;
  const float* w2h = w2t + (size_t)h*DHEAD*NLAND;
  const short* qbase = Qb + (size_t)h*NPAD*DHEAD;
  sh8 aQ[2][2];
  #pragma unroll
  for(int st=0; st<2; st++)
    #pragma unroll
    for(int kk=0; kk<2; kk++)
      aQ[st][kk] = *(const sh8*)(qbase +
          (size_t)(n0 + wv*32 + st*16 + l15)*DHEAD + kk*32 + g*8);
  f4 accO[2][4] = {};
  float den[2][4] = {};
  short* pw = pL[wv];
  for(int half=0; half<2; half++){
    __syncthreads();
    #pragma unroll
    for(int it=0; it<4; it++){
      int gi = t + it*256;
      int m = gi >> 3, db = (gi & 7) * 8;
      const float* p = klh + (size_t)(half*128 + m)*DHEAD + db;
      *(sh8*)((char*)klL + m*128 + ((db*2) ^ ((m&7)<<4))) =
          pack8f(*(const float4*)p, *(const float4*)(p+4));
      int d = gi >> 4, mb = (gi & 15) * 8;
      const float* p2 = w2h + (size_t)d*NLAND + half*128 + mb;
      *(sh8*)((char*)w2L + d*256 + ((mb*2) ^ ((d&7)<<4))) =
          pack8f(*(const float4*)p2, *(const float4*)(p2+4));
    }
    __syncthreads();
    #pragma unroll
    for(int st=0; st<2; st++){
      #pragma unroll
      for(int mt=0; mt<8; mt++){
        f4 s = {};
        #pragma unroll
        for(int kk=0; kk<2; kk++){
          int m = mt*16 + l15;
          sh8 b = *(sh8*)((char*)klL + m*128 + ((kk*64 + g*16) ^ ((m&7)<<4)));
          s = MFMA16(aQ[st][kk], b, s);
        }
        #pragma unroll
        for(int r=0; r<4; r++){
          float e = __expf(s[r]);
          den[st][r] += e;
          int n = g*4 + r;
          *(short*)((char*)pw + n*256 + (((mt*16+l15)*2) ^ ((n&7)<<4))) = (short)bfbits(e);
        }
      }
      #pragma unroll
      for(int ks=0; ks<4; ks++){
        sh8 aP = *(sh8*)((char*)pw + l15*256 + ((ks*64 + g*16) ^ ((l15&7)<<4)));
        #pragma unroll
        for(int dt=0; dt<4; dt++){
          int d = dt*16 + l15;
          sh8 bW = *(sh8*)((char*)w2L + d*256 + ((ks*64 + g*16) ^ ((d&7)<<4)));
          accO[st][dt] = MFMA16(aP, bW, accO[st][dt]);
        }
      }
    }
  }
  #pragma unroll
  for(int st=0; st<2; st++)
    #pragma unroll
    for(int r=0; r<4; r++){
      float d_ = den[st][r];
      d_ += __shfl_xor(d_,1); d_ += __shfl_xor(d_,2);
      d_ += __shfl_xor(d_,4); d_ += __shfl_xor(d_,8);
      den[st][r] = 1.f/d_;
    }
  #pragma unroll
  for(int st=0; st<2; st++)
    #pragma unroll
    for(int dt=0; dt<4; dt++)
      #pragma unroll
      for(int r=0; r<4; r++){
        int row = n0 + wv*32 + st*16 + g*4 + r;
        F[(size_t)row*CDIM + h*DHEAD + dt*16 + l15] =
            (short)bfbits(accO[st][dt][r]*den[st][r]);
      }
}

// ---------------- MFMA flash a3v: CGRP chunks/block, packed V staging ----------------
__global__ __launch_bounds__(256) void k_a3v_mfma(const float* __restrict__ ql,
    const short* __restrict__ Kb, const short* __restrict__ Vb,
    float* __restrict__ numP, float* __restrict__ denP){
  __shared__ short kL[128*64];
  __shared__ short vL[64*128];
  __shared__ short pL[4][16*128];
  int h = blockIdx.x, cg = blockIdx.y;
  int t = threadIdx.x, lane = t & 63, wv = t >> 6, g = lane >> 4, l15 = lane & 15;
  const float* qlh = ql + (size_t)h*NLAND*DHEAD;
  sh8 aQ[4][2];
  #pragma unroll
  for(int st=0; st<4; st++)
    #pragma unroll
    for(int kk=0; kk<2; kk++){
      const float* p = qlh + (size_t)(wv*64 + st*16 + l15)*DHEAD + kk*32 + g*8;
      aQ[st][kk] = pack8f(*(const float4*)p, *(const float4*)(p+4));
    }
  f4 accO[4][4] = {};
  float den[4][4] = {};
  short* pw = pL[wv];
  for(int cc=0; cc<CGRP; cc++){
    int c = cg*CGRP + cc;
    if(c >= NCHUNK) break;
    for(int half=0; half<2; half++){
      const short* Kh = Kb + ((size_t)h*NPAD + (size_t)c*256 + half*128)*DHEAD;
      const short* Vh = Vb + ((size_t)h*NPAD + (size_t)c*256 + half*128)*DHEAD;
      __syncthreads();
      #pragma unroll
      for(int it=0; it<4; it++){
        int gi = t + it*256;
        int m = gi >> 3, db = (gi & 7) * 8;
        *(sh8*)((char*)kL + m*128 + ((db*2) ^ ((m&7)<<4))) =
            *(const sh8*)(Kh + (size_t)m*DHEAD + db);
      }
      #pragma unroll
      for(int it=0; it<2; it++){
        int idx = t + it*256;
        int mp = (idx & 63)*2, dg = (idx >> 6)*8;
        sh8 v0 = *(const sh8*)(Vh + (size_t)mp*DHEAD + dg);
        sh8 v1 = *(const sh8*)(Vh + (size_t)(mp+1)*DHEAD + dg);
        #pragma unroll
        for(int i=0;i<8;i++){
          int d = dg + i;
          unsigned pk = ((unsigned)(unsigned short)v0[i]) |
                        (((unsigned)(unsigned short)v1[i]) << 16);
          *(unsigned*)((char*)vL + d*256 + ((mp*2) ^ ((d&7)<<4))) = pk;
        }
      }
      __syncthreads();
      #pragma unroll
      for(int st=0; st<4; st++){
        #pragma unroll
        for(int mt=0; mt<8; mt++){
          f4 s = {};
          #pragma unroll
          for(int kk=0; kk<2; kk++){
            int m = mt*16 + l15;
            sh8 b = *(sh8*)((char*)kL + m*128 + ((kk*64 + g*16) ^ ((m&7)<<4)));
            s = MFMA16(aQ[st][kk], b, s);
          }
          #pragma unroll
          for(int r=0; r<4; r++){
            float e = __expf(s[r]);
            den[st][r] += e;
            int n = g*4 + r;
            *(short*)((char*)pw + n*256 + (((mt*16+l15)*2) ^ ((n&7)<<4))) = (short)bfbits(e);
          }
        }
        #pragma unroll
        for(int ks=0; ks<4; ks++){
          sh8 aP = *(sh8*)((char*)pw + l15*256 + ((ks*64 + g*16) ^ ((l15&7)<<4)));
          #pragma unroll
          for(int dt=0; dt<4; dt++){
            int d = dt*16 + l15;
            sh8 bV = *(sh8*)((char*)vL + d*256 + ((ks*64 + g*16) ^ ((d&7)<<4)));
            accO[st][dt] = MFMA16(aP, bV, accO[st][dt]);
          }
        }
      }
    }
  }
  #pragma unroll
  for(int st=0; st<4; st++)
    #pragma unroll
    for(int r=0; r<4; r++){
      float d_ = den[st][r];
      d_ += __shfl_xor(d_,1); d_ += __shfl_xor(d_,2);
      d_ += __shfl_xor(d_,4); d_ += __shfl_xor(d_,8);
      den[st][r] = d_;
    }
  size_t base = ((size_t)h*NCG + cg)*NLAND;
  #pragma unroll
  for(int st=0; st<4; st++){
    #pragma unroll
    for(int r=0; r<4; r++){
      int row = wv*64 + st*16 + g*4 + r;
      if(l15 == 0) denP[base + row] = den[st][r];
      #pragma unroll
      for(int dt=0; dt<4; dt++)
        numP[(base + row)*DHEAD + dt*16 + l15] = accO[st][dt][r];
    }
  }
}

__global__ void k_a3v_comb(const float* __restrict__ numP, const float* __restrict__ denP,
                           float* __restrict__ a3v){
  int bidx = blockIdx.x;
  int h = bidx >> 8, m = bidx & 255;
  int d = threadIdx.x;
  float s = 0.f, den = 0.f;
  for(int c=0;c<NCG;c++){
    s += numP[(((size_t)h*NCG + c)*NLAND + m)*DHEAD + d];
    den += denP[((size_t)h*NCG + c)*NLAND + m];
  }
  a3v[((size_t)h*NLAND + m)*DHEAD + d] = s / den;
}

// ---------------- residual depthwise conv (k=33), register-FIR ----------------
__global__ __launch_bounds__(256) void k_resconv(const short* __restrict__ Vb,
    const float* __restrict__ rw, short* __restrict__ F){
  __shared__ float vs[96][64];
  int n0 = blockIdx.x*64, h = blockIdx.y;
  int t = threadIdx.x;
  const short* vh = Vb + (size_t)h*NPAD*DHEAD;
  #pragma unroll
  for(int i=0;i<3;i++){
    int idx = t + i*256;
    int r = idx >> 3, dg = (idx & 7)*8;
    int n = n0 - 16 + r;
    sh8 v = {0,0,0,0,0,0,0,0};
    if(n>=0 && n<NPAD) v = *(const sh8*)(vh + (size_t)n*DHEAD + dg);
    #pragma unroll
    for(int e=0;e<8;e++) vs[r][dg+e] = bf2f(v[e]);
  }
  float w[33];
  #pragma unroll
  for(int j=0;j<33;j++) w[j] = rw[h*33+j];
  __syncthreads();
  int d = t & 63, grp = t >> 6;
  float f0[16];
  #pragma unroll
  for(int rr=0;rr<16;rr++){
    int n = n0 + grp*16 + rr;
    f0[rr] = bf2f(F[(size_t)n*CDIM + h*DHEAD + d]);
  }
  float in[48];
  #pragma unroll
  for(int x=0;x<48;x++) in[x] = vs[grp*16 + x][d];
  #pragma unroll
  for(int rr=0;rr<16;rr++){
    float acc = 0.f;
    #pragma unroll
    for(int j=0;j<33;j++) acc += w[j]*in[rr+j];
    int n = n0 + grp*16 + rr;
    F[(size_t)n*CDIM + h*DHEAD + d] = (short)bfbits(f0[rr] + acc);
  }
}

// ---------------- weight transpose f32 -> bf16 ----------------
__global__ void k_transposeb(const float* __restrict__ in, short* __restrict__ out,
                             int R, int C){
  __shared__ float tile[32][33];
  int r0 = blockIdx.x*32, c0 = blockIdx.y*32;
  int tx = threadIdx.x, ty = threadIdx.y;
  #pragma unroll
  for(int r=0;r<4;r++) tile[ty + r*8][tx] = in[(size_t)(r0 + ty + r*8)*C + c0 + tx];
  __syncthreads();
  #pragma unroll
  for(int r=0;r<4;r++)
    out[(size_t)(c0 + ty + r*8)*R + r0 + tx] = (short)bfbits(tile[tx][ty + r*8]);
}

// ---------------- PPEG direct on row-major [n][c] (f32) ----------------
__global__ __launch_bounds__(256) void k_ppeg2(const float* __restrict__ X,
    const float* __restrict__ w7, const float* __restrict__ b7,
    const float* __restrict__ w5, const float* __restrict__ b5,
    const float* __restrict__ w3, const float* __restrict__ b3,
    float* __restrict__ Y){
  __shared__ float patch[484][20];
  int cg = blockIdx.y;
  int ti = blockIdx.x >> 3, tj = blockIdx.x & 7;
  int t = threadIdx.x;
  int i0 = ti*16 - 3, j0 = tj*16 - 3;
  for(int idx = t; idx < 1936; idx += 256){
    int p = idx >> 2, cq = (idx & 3) * 4;
    int gi = i0 + p/22, gj = j0 + p%22;
    float4 v = make_float4(0.f,0.f,0.f,0.f);
    if(gi>=0 && gi<128 && gj>=0 && gj<128)
      v = *(const float4*)(X + (size_t)(gi*128+gj)*CDIM + cg*16 + cq);
    *(float4*)&patch[p][cq] = v;
  }
  int c = t & 15, sg = t >> 4;
  int cglob = cg*16 + c;
  float wr[83];
  #pragma unroll
  for(int k=0;k<49;k++) wr[k] = w7[cglob*49+k];
  #pragma unroll
  for(int k=0;k<25;k++) wr[49+k] = w5[cglob*25+k];
  #pragma unroll
  for(int k=0;k<9;k++)  wr[74+k] = w3[cglob*9+k];
  float bsum = b7[cglob] + b5[cglob] + b3[cglob];
  __syncthreads();
  float acc[16];
  #pragma unroll
  for(int j=0;j<16;j++) acc[j] = patch[(sg+3)*22 + (j+3)][c] + bsum;
  #pragma unroll
  for(int a=0;a<7;a++)
    #pragma unroll
    for(int x=0;x<22;x++){
      float vv = patch[(sg+a)*22 + x][c];
      #pragma unroll
      for(int bq=0;bq<7;bq++){
        int j = x - bq;
        if(j>=0 && j<16) acc[j] += wr[a*7+bq]*vv;
      }
    }
  #pragma unroll
  for(int a=0;a<5;a++)
    #pragma unroll
    for(int x=1;x<21;x++){
      float vv = patch[(sg+a+1)*22 + x][c];
      #pragma unroll
      for(int bq=0;bq<5;bq++){
        int j = x - 1 - bq;
        if(j>=0 && j<16) acc[j] += wr[49+a*5+bq]*vv;
      }
    }
  #pragma unroll
  for(int a=0;a<3;a++)
    #pragma unroll
    for(int x=2;x<20;x++){
      float vv = patch[(sg+a+2)*22 + x][c];
      #pragma unroll
      for(int bq=0;bq<3;bq++){
        int j = x - 2 - bq;
        if(j>=0 && j<16) acc[j] += wr[74+a*3+bq]*vv;
      }
    }
  #pragma unroll
  for(int j=0;j<16;j++)
    Y[(size_t)((ti*16+sg)*128 + tj*16+j)*CDIM + cglob] = acc[j];
}

// ---------------- final LN(row0) + fc2 ----------------
__global__ __launch_bounds__(512) void k_final(const float* __restrict__ A,
    const float* __restrict__ g, const float* __restrict__ b,
    const float* __restrict__ w, const float* __restrict__ bias,
    float* __restrict__ outp){
  __shared__ float red[8];
  int t = threadIdx.x, wv = t >> 6;
  float x = A[t];
  float s = wave_sum(x);
  if((t & 63) == 0) red[wv] = s;
  __syncthreads();
  float mu = 0;
  #pragma unroll
  for(int i=0;i<8;i++) mu += red[i];
  mu *= (1.f/512.f);
  __syncthreads();
  float dx = x - mu;
  s = wave_sum(dx*dx);
  if((t & 63) == 0) red[wv] = s;
  __syncthreads();
  float var = 0;
  #pragma unroll
  for(int i=0;i<8;i++) var += red[i];
  var *= (1.f/512.f);
  float xn = dx * rsqrtf(var + 1e-5f) * g[t] + b[t];
  __syncthreads();
  for(int o=0;o<4;o++){
    s = wave_sum(xn * w[t*4 + o]);
    if((t & 63) == 0) red[wv] = s;
    __syncthreads();
    if(t == 0){
      float r = 0;
      #pragma unroll
      for(int i=0;i<8;i++) r += red[i];
      outp[o] = r + bias[o];
    }
    __syncthreads();
  }
}

extern "C" void kernel_launch(void* const* d_in, const int* in_sizes, int n_in,
                              void* d_out, int out_size, void* d_ws, size_t ws_size,
                              hipStream_t stream) {
  (void)in_sizes; (void)n_in; (void)out_size; (void)ws_size;
  const float* data_x = (const float*)d_in[0];
  const float* fc1_w  = (const float*)d_in[1];
  const float* fc1_b  = (const float*)d_in[2];
  const float* cls_tk = (const float*)d_in[3];
  const float* ng[2]  = {(const float*)d_in[4],  (const float*)d_in[16]};
  const float* nb[2]  = {(const float*)d_in[5],  (const float*)d_in[17]};
  const float* qkvw[2]= {(const float*)d_in[6],  (const float*)d_in[18]};
  const float* outw[2]= {(const float*)d_in[7],  (const float*)d_in[19]};
  const float* outb[2]= {(const float*)d_in[8],  (const float*)d_in[20]};
  const float* resw[2]= {(const float*)d_in[9],  (const float*)d_in[21]};
  const float* w7 = (const float*)d_in[10]; const float* pb7 = (const float*)d_in[11];
  const float* w5 = (const float*)d_in[12]; const float* pb5 = (const float*)d_in[13];
  const float* w3 = (const float*)d_in[14]; const float* pb3 = (const float*)d_in[15];
  const float* norm_g = (const float*)d_in[22];
  const float* norm_b = (const float*)d_in[23];
  const float* fc2_w  = (const float*)d_in[24];
  const float* fc2_b  = (const float*)d_in[25];

  float* ws = (float*)d_ws;
  float* Ab   = ws;
  float* Bb   = Ab + (size_t)TOK*CDIM;
  float* Fb   = Bb + (size_t)TOK*CDIM;
  short* Fbf  = (short*)(Fb + (size_t)NPAD*CDIM);
  short* lnX  = Fbf + (size_t)NPAD*CDIM;
  short* Qb   = lnX + (size_t)NPAD*CDIM;
  short* Kb   = Qb  + (size_t)NPAD*CDIM;
  short* Vb   = Kb  + (size_t)NPAD*CDIM;
  short* dxb  = Vb  + (size_t)NPAD*CDIM;
  float* qlb  = (float*)(dxb + (size_t)16384*1024);
  float* klb  = qlb + NHEAD*NLAND*DHEAD;
  float* a2b  = klb + NHEAD*NLAND*DHEAD;
  float* z0b  = a2b + NHEAD*NLAND*NLAND;
  float* z1b  = z0b + NHEAD*NLAND*NLAND;
  float* Xb_  = z1b + NHEAD*NLAND*NLAND;
  float* Tb_  = Xb_ + NHEAD*NLAND*NLAND;
  float* Ub_  = Tb_ + NHEAD*NLAND*NLAND;
  float* a3vb = Ub_ + NHEAD*NLAND*NLAND;
  float* w2tb = a3vb + NHEAD*NLAND*DHEAD;
  float* denP = w2tb + NHEAD*DHEAD*NLAND;
  float* hmax = denP + NHEAD*NCG*NLAND;
  float* scal = hmax + 8;
  short* fc1T = (short*)(scal + 8);
  short* qkvT0= fc1T + 512*1024;
  short* qkvT1= qkvT0 + 1536*512;
  short* outT0= qkvT1 + 1536*512;
  short* outT1= outT0 + 512*512;
  short* qkvT[2] = {qkvT0, qkvT1};
  short* outT[2] = {outT0, outT1};

  const int HB = NHEAD*NLAND*NLAND;
  short* zb0  = (short*)z0b;  short* zb1  = zb0 + HB;
  short* xb   = (short*)z1b;  short* tb   = xb + HB;
  short* ub   = (short*)Xb_;  short* a2bf = ub + HB;
  float* zf   = Tb_;

  k_transposeb<<<dim3(32,16), dim3(32,8), 0, stream>>>(fc1_w, fc1T, 1024, 512);
  k_transposeb<<<dim3(16,48), dim3(32,8), 0, stream>>>(qkvw[0], qkvT0, 512, 1536);
  k_transposeb<<<dim3(16,48), dim3(32,8), 0, stream>>>(qkvw[1], qkvT1, 512, 1536);
  k_transposeb<<<dim3(16,16), dim3(32,8), 0, stream>>>(outw[0], outT0, 512, 512);
  k_transposeb<<<dim3(16,16), dim3(32,8), 0, stream>>>(outw[1], outT1, 512, 512);
  k_f2b<<<8192, 256, 0, stream>>>(data_x, dxb, 16384*1024/8);

  k_copyrow<<<1, 512, 0, stream>>>(Ab, cls_tk);
  k_gemm_g<0><<<dim3(4, 128), 256, 0, stream>>>(dxb, 1024, fc1T, 1024, fc1_b,
                                                Ab + CDIM, nullptr, nullptr, 16384);
  float* base[2]  = {Ab, Bb};
  for(int L=0; L<2; L++){
    k_ln_pad<<<NPAD/4, 256, 0, stream>>>(base[L], ng[L], nb[L], lnX);
    k_gemm_g<1><<<dim3(12, 130), 256, 0, stream>>>(lnX, CDIM, qkvT[L], CDIM, nullptr,
                                                   Qb, Kb, Vb, NPAD);
    k_landmark2<<<2*NHEAD*NLAND, 64, 0, stream>>>(Qb, Kb, qlb, klb);
    k_a2_mfma<<<dim3(4, NHEAD), 256, 0, stream>>>(qlb, klb, a2b, a2bf);
    k_colmax<<<NHEAD, 256, 0, stream>>>(a2b, hmax);
    k_zinit<<<dim3(256, NHEAD), 256, 0, stream>>>(a2b, hmax, zb0);
    short* zc = zb0; short* zn = zb1;
    for(int it=0; it<6; it++){
      k_pgemm<0,0><<<dim3(4,4,NHEAD), 256, 0, stream>>>(a2bf, zc, xb, nullptr, 0.f, 1.f);
      k_pgemm<1,0><<<dim3(4,4,NHEAD), 256, 0, stream>>>(xb, xb, tb, nullptr, 7.f, 1.f);
      k_pgemm<1,0><<<dim3(4,4,NHEAD), 256, 0, stream>>>(xb, tb, ub, nullptr, 15.f, 1.f);
      if(it < 5){
        k_pgemm<1,0><<<dim3(4,4,NHEAD), 256, 0, stream>>>(zc, ub, zn, nullptr, 13.f, 0.25f);
        short* tmp = zc; zc = zn; zn = tmp;
      } else {
        k_pgemm<1,1><<<dim3(4,4,NHEAD), 256, 0, stream>>>(zc, ub, nullptr, zf, 13.f, 0.25f);
      }
    }
    k_a3v_mfma<<<dim3(NHEAD, NCG), 256, 0, stream>>>(qlb, Kb, Vb, Fb, denP);
    k_a3v_comb<<<NHEAD*NLAND, 64, 0, stream>>>(Fb, denP, a3vb);
    k_sgemm2<0,1><<<dim3(1,4,NHEAD), 256, 0, stream>>>(zf, a3vb, w2tb, 256,64,256,
                                                       65536,16384,16384, 0.f, 1.f);
    k_a1_mfma<<<dim3(130, NHEAD), 256, 0, stream>>>(Qb, klb, w2tb, Fbf);
    k_resconv<<<dim3(260, NHEAD), 256, 0, stream>>>(Vb, resw[L], Fbf);
    k_gemm_g<2><<<dim3(4, 129), 256, 0, stream>>>(Fbf + (size_t)PAD0*CDIM, CDIM,
                                                  outT[L], CDIM, outb[L],
                                                  base[L], nullptr, nullptr, TOK);
    if(L == 0){
      k_ppeg2<<<dim3(64, 32), 256, 0, stream>>>(Ab + CDIM, w7, pb7, w5, pb5, w3, pb3,
                                                Bb + CDIM);
      k_copyrow<<<1, 512, 0, stream>>>(Bb, Ab);
    }
  }
  k_final<<<1, 512, 0, stream>>>(Bb, norm_g, norm_b, fc2_w, fc2_b, (float*)d_out);
}

// Round 18
// 933.875 us; speedup vs baseline: 3.0847x; 1.0123x over previous
//
#include <hip/hip_runtime.h>
#include <hip/hip_bf16.h>

#define NPAD 16640
#define TOK  16385
#define CDIM 512
#define NHEAD 8
#define DHEAD 64
#define NLAND 256
#define LFAC  65
#define PAD0  255
#define NCHUNK 65     // 256-row chunks
#define CGRP 2        // chunks per block in a3v
#define NCG 33        // ceil(65/2)

typedef __attribute__((ext_vector_type(8))) short sh8;
typedef __attribute__((ext_vector_type(4))) float f4;

__device__ __forceinline__ float wave_sum(float v){
  #pragma unroll
  for(int o=32;o;o>>=1) v += __shfl_xor(v,o);
  return v;
}
__device__ __forceinline__ float wave_max(float v){
  #pragma unroll
  for(int o=32;o;o>>=1) v = fmaxf(v, __shfl_xor(v,o));
  return v;
}

__device__ __forceinline__ unsigned bfbits(float x){
  unsigned u = __float_as_uint(x);
  return (u + 0x7fffu + ((u >> 16) & 1u)) >> 16;
}
__device__ __forceinline__ float bf2f(short s){
  return __uint_as_float(((unsigned)(unsigned short)s) << 16);
}
__device__ __forceinline__ sh8 pack8f(float4 a, float4 b){
  sh8 r;
  r[0]=(short)bfbits(a.x); r[1]=(short)bfbits(a.y); r[2]=(short)bfbits(a.z); r[3]=(short)bfbits(a.w);
  r[4]=(short)bfbits(b.x); r[5]=(short)bfbits(b.y); r[6]=(short)bfbits(b.z); r[7]=(short)bfbits(b.w);
  return r;
}
#define MFMA16(a,b,c) __builtin_amdgcn_mfma_f32_16x16x32_bf16(a,b,c,0,0,0)

__device__ __forceinline__ void gload16(const void* g, void* l){
  __builtin_amdgcn_global_load_lds(
      (const __attribute__((address_space(1))) void*)g,
      (__attribute__((address_space(3))) void*)l, 16, 0, 0);
}

// ---------------- row copy (cls token) ----------------
__global__ void k_copyrow(float* dst, const float* __restrict__ src){
  dst[threadIdx.x] = src[threadIdx.x];
}

// ---------------- f32 -> bf16 convert ----------------
__global__ __launch_bounds__(256) void k_f2b(const float* __restrict__ in,
    short* __restrict__ out, int n8){
  int i = blockIdx.x*256 + threadIdx.x;
  if(i < n8){
    float4 a = *(const float4*)(in + (size_t)i*8);
    float4 b = *(const float4*)(in + (size_t)i*8 + 4);
    *(sh8*)(out + (size_t)i*8) = pack8f(a, b);
  }
}

// ---------------- layernorm + front pad -> bf16 ----------------
__global__ __launch_bounds__(256) void k_ln_pad(const float* __restrict__ A,
    const float* __restrict__ g, const float* __restrict__ b, short* __restrict__ B){
  int w = threadIdx.x >> 6, lane = threadIdx.x & 63;
  int row = blockIdx.x*4 + w;
  short* out = B + (size_t)row*CDIM;
  int c = lane*8;
  if(row < PAD0){
    sh8 z = {0,0,0,0,0,0,0,0};
    *(sh8*)(out + c) = z;
    return;
  }
  const float* x = A + (size_t)(row-PAD0)*CDIM;
  float4 v0 = *(const float4*)(x + c);
  float4 v1 = *(const float4*)(x + c + 4);
  float xs[8] = {v0.x,v0.y,v0.z,v0.w,v1.x,v1.y,v1.z,v1.w};
  float s = 0;
  #pragma unroll
  for(int i=0;i<8;i++) s += xs[i];
  s = wave_sum(s);
  float mu = s * (1.f/512.f);
  float vs = 0;
  #pragma unroll
  for(int i=0;i<8;i++){ float d = xs[i]-mu; vs += d*d; }
  vs = wave_sum(vs) * (1.f/512.f);
  float rs = rsqrtf(vs + 1e-5f);
  float4 g0 = *(const float4*)(g + c); float4 g1 = *(const float4*)(g + c + 4);
  float4 b0 = *(const float4*)(b + c); float4 b1 = *(const float4*)(b + c + 4);
  float gg[8] = {g0.x,g0.y,g0.z,g0.w,g1.x,g1.y,g1.z,g1.w};
  float bb[8] = {b0.x,b0.y,b0.z,b0.w,b1.x,b1.y,b1.z,b1.w};
  sh8 o;
  #pragma unroll
  for(int i=0;i<8;i++) o[i] = (short)bfbits((xs[i]-mu)*rs*gg[i] + bb[i]);
  *(sh8*)(out + c) = o;
}

// ---------------- gload-staged MFMA GEMM: C[M,N] = A[M,K] @ WT[N,K]^T ----------------
template<int MODE>
__global__ __launch_bounds__(256) void k_gemm_g(const short* __restrict__ A, int lda,
    const short* __restrict__ WT, int K, const float* __restrict__ bias,
    void* out0v, void* out1v, void* out2v, int M){
  __shared__ short As[2][128*32];
  __shared__ short Bs[2][128*32];
  int t = threadIdx.x, lane = t & 63, wv = t >> 6, g = lane >> 4, l15 = lane & 15;
  int nwg = gridDim.x * gridDim.y;
  int orig = blockIdx.y * gridDim.x + blockIdx.x;
  int qc = nwg >> 3, rc = nwg & 7, xcd = orig & 7, loc = orig >> 3;
  int wgid = (xcd < rc ? xcd*(qc+1) : rc*(qc+1) + (xcd - rc)*qc) + loc;
  int row0 = (wgid / gridDim.x) * 128, n0 = (wgid % gridDim.x) * 128;
  int wm = (wv>>1)*64, wn = (wv&1)*64;
  int mq = lane >> 2, slot = lane & 3;

  auto stage = [&](int buf, int k0){
    #pragma unroll
    for(int c=0;c<2;c++){
      int m = wv*32 + c*16 + mq;
      int swz = (((m&3) ^ ((m>>2)&3)) << 4);
      int gr = row0 + m; if(gr >= M) gr = M-1;
      const char* srcA = (const char*)(A + (size_t)gr*lda + k0) + ((slot*16) ^ swz);
      gload16(srcA, (char*)As[buf] + wv*2048 + c*1024);
      const char* srcB = (const char*)(WT + (size_t)(n0+m)*K + k0) + ((slot*16) ^ swz);
      gload16(srcB, (char*)Bs[buf] + wv*2048 + c*1024);
    }
  };

  f4 acc[4][4] = {};
  int nk = K >> 5;
  stage(0, 0);
  __syncthreads();
  int cur = 0;
  for(int i=0; i<nk; i++){
    if(i+1 < nk) stage(cur^1, (i+1) << 5);
    sh8 af[4], bf[4];
    #pragma unroll
    for(int mt=0; mt<4; mt++){
      int r = wm + mt*16 + l15;
      af[mt] = *(sh8*)((char*)As[cur] + r*64 + ((g*16) ^ (((r&3)^((r>>2)&3))<<4)));
    }
    #pragma unroll
    for(int nt=0; nt<4; nt++){
      int r = wn + nt*16 + l15;
      bf[nt] = *(sh8*)((char*)Bs[cur] + r*64 + ((g*16) ^ (((r&3)^((r>>2)&3))<<4)));
    }
    #pragma unroll
    for(int mt=0; mt<4; mt++)
      #pragma unroll
      for(int nt=0; nt<4; nt++)
        acc[mt][nt] = MFMA16(af[mt], bf[nt], acc[mt][nt]);
    __syncthreads();
    cur ^= 1;
  }
  #pragma unroll
  for(int mt=0; mt<4; mt++){
    #pragma unroll
    for(int r=0; r<4; r++){
      int gm = row0 + wm + mt*16 + g*4 + r;
      if(gm >= M) continue;
      #pragma unroll
      for(int nt=0; nt<4; nt++){
        int gn = n0 + wn + nt*16 + l15;
        float v = acc[mt][nt][r];
        if(MODE == 0){
          v += bias[gn];
          ((float*)out0v)[(size_t)gm*CDIM + gn] = v > 0.f ? v : 0.f;
        } else if(MODE == 1){
          int p = gn >> 9, rr = gn & 511;
          int hh = rr >> 6, dd = rr & 63;
          if(p == 0) v *= 0.125f;
          short* dst = (p==0) ? (short*)out0v : (p==1 ? (short*)out1v : (short*)out2v);
          dst[((size_t)hh*NPAD + gm)*DHEAD + dd] = (short)bfbits(v);
        } else {
          ((float*)out0v)[(size_t)gm*CDIM + gn] += v + bias[gn];
        }
      }
    }
  }
}

// ---------------- landmark means, Q and K in one dispatch ----------------
__global__ void k_landmark2(const short* __restrict__ Qb, const short* __restrict__ Kb,
    float* __restrict__ ql, float* __restrict__ kl){
  int bidx = blockIdx.x;
  int sel = bidx >> 11;
  int loc = bidx & 2047;
  int h = loc >> 8, m = loc & 255, d = threadIdx.x;
  const short* src = (sel ? Kb : Qb) + ((size_t)h*NPAD + (size_t)m*LFAC)*DHEAD + d;
  float s = 0;
  for(int j=0;j<LFAC;j++) s += bf2f(src[(size_t)j*DHEAD]);
  (sel ? kl : ql)[(size_t)loc*DHEAD + d] = s * (1.f/LFAC);
}

// ---------------- a2 = softmax(ql @ kl^T), MFMA ----------------
__global__ __launch_bounds__(256) void k_a2_mfma(const float* __restrict__ ql,
    const float* __restrict__ kl, float* __restrict__ a2, short* __restrict__ a2bf){
  __shared__ short klL[256*64];   // [n][d] bf16, 128B rows, XOR swizzle
  int q = blockIdx.x, h = blockIdx.y;
  int t = threadIdx.x, lane = t & 63, wv = t >> 6, g = lane >> 4, l15 = lane & 15;
  const float* qlh = ql + (size_t)h*NLAND*DHEAD;
  const float* klh = kl + (size_t)h*NLAND*DHEAD;
  #pragma unroll
  for(int i=0;i<8;i++){
    int gi = t + i*256;
    int n = gi >> 3, db = (gi & 7)*8;
    float4 a = *(const float4*)(klh + (size_t)n*DHEAD + db);
    float4 b = *(const float4*)(klh + (size_t)n*DHEAD + db + 4);
    *(sh8*)((char*)klL + n*128 + ((db*2) ^ ((n&7)<<4))) = pack8f(a, b);
  }
  __syncthreads();
  int row0 = q*64 + wv*16;
  sh8 aQ[2];
  #pragma unroll
  for(int kk=0; kk<2; kk++){
    const float* p = qlh + (size_t)(row0 + l15)*DHEAD + kk*32 + g*8;
    aQ[kk] = pack8f(*(const float4*)p, *(const float4*)(p+4));
  }
  f4 acc[16];
  #pragma unroll
  for(int nt=0; nt<16; nt++){
    f4 s = {};
    #pragma unroll
    for(int kk=0; kk<2; kk++){
      int n = nt*16 + l15;
      sh8 b = *(sh8*)((char*)klL + n*128 + ((kk*64 + g*16) ^ ((n&7)<<4)));
      s = MFMA16(aQ[kk], b, s);
    }
    acc[nt] = s;
  }
  float den[4] = {0,0,0,0};
  #pragma unroll
  for(int nt=0; nt<16; nt++)
    #pragma unroll
    for(int r=0; r<4; r++){
      float e = __expf(acc[nt][r]);
      acc[nt][r] = e;
      den[r] += e;
    }
  #pragma unroll
  for(int r=0; r<4; r++){
    float d_ = den[r];
    d_ += __shfl_xor(d_,1); d_ += __shfl_xor(d_,2);
    d_ += __shfl_xor(d_,4); d_ += __shfl_xor(d_,8);
    den[r] = 1.f/d_;
  }
  #pragma unroll
  for(int nt=0; nt<16; nt++)
    #pragma unroll
    for(int r=0; r<4; r++){
      int row = row0 + g*4 + r;
      int col = nt*16 + l15;
      float v = acc[nt][r]*den[r];
      size_t idx = ((size_t)h*NLAND + row)*NLAND + col;
      a2[idx] = v;
      a2bf[idx] = (short)bfbits(v);
    }
}

// ---------------- pinv init ----------------
__global__ void k_colmax(const float* __restrict__ a2, float* __restrict__ hmax){
  __shared__ float red[4];
  int h = blockIdx.x, t = threadIdx.x;
  const float* p = a2 + (size_t)h*65536 + t;
  float s = 0;
  for(int m=0;m<256;m++) s += p[(size_t)m*256];
  float mx = wave_max(s);
  if((t & 63) == 0) red[t>>6] = mx;
  __syncthreads();
  if(t == 0) hmax[h] = fmaxf(fmaxf(red[0],red[1]), fmaxf(red[2],red[3]));
}
// z0 (bf16) = a2^T / max(hmax)
__global__ void k_zinit(const float* __restrict__ a2, const float* __restrict__ hmax,
                        short* __restrict__ z){
  int h = blockIdx.y;
  int idx = blockIdx.x*256 + threadIdx.x;
  int m = idx >> 8, j = idx & 255;
  float mx = hmax[0];
  #pragma unroll
  for(int i=1;i<8;i++) mx = fmaxf(mx, hmax[i]);
  z[(size_t)h*65536 + idx] = (short)bfbits(a2[(size_t)h*65536 + (size_t)j*256 + m] / mx);
}

// ---------------- batched MFMA pinv GEMM, bf16 I/O ----------------
template<int TRANS, int F32OUT>
__global__ __launch_bounds__(256) void k_pgemm(const short* __restrict__ A,
    const short* __restrict__ B, short* __restrict__ C, float* __restrict__ Cf,
    float alpha, float beta){
  __shared__ short As[64*32];
  __shared__ short Bs[64*32];
  int bh = blockIdx.z;
  const short* Ah = A + (size_t)bh*65536;
  const short* Bh = B + (size_t)bh*65536;
  int m0 = blockIdx.y*64, n0 = blockIdx.x*64;
  int t = threadIdx.x, lane = t & 63, wv = t >> 6, g = lane >> 4, l15 = lane & 15;
  f4 acc[4] = {};
  for(int k0=0; k0<256; k0+=32){
    {
      int m = t >> 2, kb = (t & 3)*8;
      sh8 av = *(const sh8*)(Ah + (size_t)(m0+m)*256 + k0 + kb);
      int swz = (((m&3)^((m>>2)&3))<<4);
      *(sh8*)((char*)As + m*64 + ((kb*2)^swz)) = av;
    }
    {
      int kr = t >> 3, nb = (t & 7)*8;
      sh8 bv = *(const sh8*)(Bh + (size_t)(k0+kr)*256 + n0 + nb);
      #pragma unroll
      for(int e=0;e<8;e++){
        int n = nb + e;
        short sv = bv[e];
        if(TRANS){
          float f = ((k0+kr == n0+n) ? alpha : 0.f) - bf2f(sv);
          sv = (short)bfbits(f);
        }
        int swz = (((n&3)^((n>>2)&3))<<4);
        *(short*)((char*)Bs + n*64 + ((kr*2)^swz)) = sv;
      }
    }
    __syncthreads();
    int rm = wv*16 + l15;
    sh8 af = *(sh8*)((char*)As + rm*64 + ((g*16) ^ (((rm&3)^((rm>>2)&3))<<4)));
    #pragma unroll
    for(int nt=0; nt<4; nt++){
      int n = nt*16 + l15;
      sh8 bf = *(sh8*)((char*)Bs + n*64 + ((g*16) ^ (((n&3)^((n>>2)&3))<<4)));
      acc[nt] = MFMA16(af, bf, acc[nt]);
    }
    __syncthreads();
  }
  size_t hoff = (size_t)bh*65536;
  #pragma unroll
  for(int nt=0; nt<4; nt++)
    #pragma unroll
    for(int r=0; r<4; r++){
      size_t idx = hoff + (size_t)(m0 + wv*16 + g*4 + r)*256 + n0 + nt*16 + l15;
      float v = acc[nt][r]*beta;
      if(F32OUT) Cf[idx] = v;
      else       C[idx] = (short)bfbits(v);
    }
}

// ---------------- batched f32 GEMM 64x64 tile (w2^T only) ----------------
template<int TRANS, int OUTT>
__global__ __launch_bounds__(256) void k_sgemm2(const float* __restrict__ A,
    const float* __restrict__ B, float* __restrict__ C,
    int M, int N, int K, long sA, long sB, long sC, float alpha, float beta){
  __shared__ float As[32][68];
  __shared__ float Bs[32][68];
  int bh = blockIdx.z;
  const float* Ah = A + (size_t)bh*sA;
  const float* Bh = B + (size_t)bh*sB;
  float* Ch = C + (size_t)bh*sC;
  int m0 = blockIdx.y*64, n0 = blockIdx.x*64;
  int t = threadIdx.x, tx = t & 15, ty = t >> 4;
  float acc[4][4] = {};
  for(int k0=0; k0<K; k0+=32){
    #pragma unroll
    for(int u=0; u<2; u++){
      int idx = t + u*256;
      int r = idx >> 3, cb = (idx & 7) * 4;
      float4 va = *(const float4*)(Ah + (size_t)(m0+r)*K + k0 + cb);
      As[cb+0][r]=va.x; As[cb+1][r]=va.y; As[cb+2][r]=va.z; As[cb+3][r]=va.w;
      int kr = idx >> 4, nb = (idx & 15) * 4;
      float4 w = *(const float4*)(Bh + (size_t)(k0+kr)*N + n0 + nb);
      if(TRANS){
        int gk = k0 + kr;
        w.x = ((gk==n0+nb+0)?alpha:0.f) - w.x;
        w.y = ((gk==n0+nb+1)?alpha:0.f) - w.y;
        w.z = ((gk==n0+nb+2)?alpha:0.f) - w.z;
        w.w = ((gk==n0+nb+3)?alpha:0.f) - w.w;
      }
      *(float4*)&Bs[kr][nb] = w;
    }
    __syncthreads();
    #pragma unroll
    for(int k=0;k<32;k++){
      float a[4], b[4];
      *(float4*)a = *(const float4*)&As[k][ty*4];
      *(float4*)b = *(const float4*)&Bs[k][tx*4];
      #pragma unroll
      for(int i=0;i<4;i++)
        #pragma unroll
        for(int j=0;j<4;j++) acc[i][j] += a[i]*b[j];
    }
    __syncthreads();
  }
  #pragma unroll
  for(int i=0;i<4;i++){
    #pragma unroll
    for(int j=0;j<4;j++){
      int gm = m0 + ty*4 + i, gn = n0 + tx*4 + j;
      float v = acc[i][j] * beta;
      if(OUTT) Ch[(size_t)gn*M + gm] = v;
      else     Ch[(size_t)gm*N + gn] = v;
    }
  }
}

// ---------------- MFMA flash a1 (Q bf16, F out bf16), per-wave P ----------------
__global__ __launch_bounds__(256) void k_a1_mfma(const short* __restrict__ Qb,
    const float* __restrict__ kl, const float* __restrict__ w2t, short* __restrict__ F){
  __shared__ short klL[128*64];
  __shared__ short w2L[64*128];
  __shared__ short pL[4][16*128];
  int h = blockIdx.y, n0 = blockIdx.x*128;
  int t = threadIdx.x, lane = t & 63, wv = t >> 6, g = lane >> 4, l15 = lane & 15;
  const float* klh = kl + (size_t)h*NLAND*DHEAD;
  const float* w2h = w2t + (size_t)h*DHEAD*NLAND;
  const short* qbase = Qb + (size_t)h*NPAD*DHEAD;
  sh8 aQ[2][2];
  #pragma unroll
  for(int st=0; st<2; st++)
    #pragma unroll
    for(int kk=0; kk<2; kk++)
      aQ[st][kk] = *(const sh8*)(qbase +
          (size_t)(n0 + wv*32 + st*16 + l15)*DHEAD + kk*32 + g*8);
  f4 accO[2][4] = {};
  float den[2][4] = {};
  short* pw = pL[wv];
  for(int half=0; half<2; half++){
    __syncthreads();
    #pragma unroll
    for(int it=0; it<4; it++){
      int gi = t + it*256;
      int m = gi >> 3, db = (gi & 7) * 8;
      const float* p = klh + (size_t)(half*128 + m)*DHEAD + db;
      *(sh8*)((char*)klL + m*128 + ((db*2) ^ ((m&7)<<4))) =
          pack8f(*(const float4*)p, *(const float4*)(p+4));
      int d = gi >> 4, mb = (gi & 15) * 8;
      const float* p2 = w2h + (size_t)d*NLAND + half*128 + mb;
      *(sh8*)((char*)w2L + d*256 + ((mb*2) ^ ((d&7)<<4))) =
          pack8f(*(const float4*)p2, *(const float4*)(p2+4));
    }
    __syncthreads();
    #pragma unroll
    for(int st=0; st<2; st++){
      #pragma unroll
      for(int mt=0; mt<8; mt++){
        f4 s = {};
        #pragma unroll
        for(int kk=0; kk<2; kk++){
          int m = mt*16 + l15;
          sh8 b = *(sh8*)((char*)klL + m*128 + ((kk*64 + g*16) ^ ((m&7)<<4)));
          s = MFMA16(aQ[st][kk], b, s);
        }
        #pragma unroll
        for(int r=0; r<4; r++){
          float e = __expf(s[r]);
          den[st][r] += e;
          int n = g*4 + r;
          *(short*)((char*)pw + n*256 + (((mt*16+l15)*2) ^ ((n&7)<<4))) = (short)bfbits(e);
        }
      }
      #pragma unroll
      for(int ks=0; ks<4; ks++){
        sh8 aP = *(sh8*)((char*)pw + l15*256 + ((ks*64 + g*16) ^ ((l15&7)<<4)));
        #pragma unroll
        for(int dt=0; dt<4; dt++){
          int d = dt*16 + l15;
          sh8 bW = *(sh8*)((char*)w2L + d*256 + ((ks*64 + g*16) ^ ((d&7)<<4)));
          accO[st][dt] = MFMA16(aP, bW, accO[st][dt]);
        }
      }
    }
  }
  #pragma unroll
  for(int st=0; st<2; st++)
    #pragma unroll
    for(int r=0; r<4; r++){
      float d_ = den[st][r];
      d_ += __shfl_xor(d_,1); d_ += __shfl_xor(d_,2);
      d_ += __shfl_xor(d_,4); d_ += __shfl_xor(d_,8);
      den[st][r] = 1.f/d_;
    }
  #pragma unroll
  for(int st=0; st<2; st++)
    #pragma unroll
    for(int dt=0; dt<4; dt++)
      #pragma unroll
      for(int r=0; r<4; r++){
        int row = n0 + wv*32 + st*16 + g*4 + r;
        F[(size_t)row*CDIM + h*DHEAD + dt*16 + l15] =
            (short)bfbits(accO[st][dt][r]*den[st][r]);
      }
}

// ---------------- MFMA flash a3v: async-stage split (T14) ----------------
// Per phase: write prefetched K/V regs -> LDS, issue next phase's loads,
// barrier, compute. Load latency hides under previous phase's compute.
__global__ __launch_bounds__(256) void k_a3v_mfma(const float* __restrict__ ql,
    const short* __restrict__ Kb, const short* __restrict__ Vb,
    float* __restrict__ numP, float* __restrict__ denP){
  __shared__ short kL[128*64];
  __shared__ short vL[64*128];
  __shared__ short pL[4][16*128];
  int h = blockIdx.x, cg = blockIdx.y;
  int t = threadIdx.x, lane = t & 63, wv = t >> 6, g = lane >> 4, l15 = lane & 15;
  const float* qlh = ql + (size_t)h*NLAND*DHEAD;
  sh8 aQ[4][2];
  #pragma unroll
  for(int st=0; st<4; st++)
    #pragma unroll
    for(int kk=0; kk<2; kk++){
      const float* p = qlh + (size_t)(wv*64 + st*16 + l15)*DHEAD + kk*32 + g*8;
      aQ[st][kk] = pack8f(*(const float4*)p, *(const float4*)(p+4));
    }
  f4 accO[4][4] = {};
  float den[4][4] = {};
  short* pw = pL[wv];

  // per-thread staging addresses (phase-invariant offsets)
  int km[4], kdb[4];
  #pragma unroll
  for(int it=0; it<4; it++){
    int gi = t + it*256;
    km[it] = gi >> 3; kdb[it] = (gi & 7) * 8;
  }
  int vmp[2], vdg[2];
  #pragma unroll
  for(int it=0; it<2; it++){
    int idx = t + it*256;
    vmp[it] = (idx & 63)*2; vdg[it] = (idx >> 6)*8;
  }

  sh8 kreg[4], vreg[4];
  auto ldregs = [&](int ph){
    int c = cg*CGRP + (ph >> 1), half = ph & 1;
    const short* Kh = Kb + ((size_t)h*NPAD + (size_t)c*256 + half*128)*DHEAD;
    const short* Vh = Vb + ((size_t)h*NPAD + (size_t)c*256 + half*128)*DHEAD;
    #pragma unroll
    for(int it=0; it<4; it++)
      kreg[it] = *(const sh8*)(Kh + (size_t)km[it]*DHEAD + kdb[it]);
    #pragma unroll
    for(int it=0; it<2; it++){
      vreg[2*it]   = *(const sh8*)(Vh + (size_t)vmp[it]*DHEAD + vdg[it]);
      vreg[2*it+1] = *(const sh8*)(Vh + (size_t)(vmp[it]+1)*DHEAD + vdg[it]);
    }
  };

  int nph = 2*CGRP;
  if(cg*CGRP + ((nph-1) >> 1) >= NCHUNK) nph = 2;   // last (odd) group: 1 chunk
  ldregs(0);
  for(int ph=0; ph<nph; ph++){
    __syncthreads();             // all waves done reading kL/vL from prev phase
    #pragma unroll
    for(int it=0; it<4; it++)
      *(sh8*)((char*)kL + km[it]*128 + ((kdb[it]*2) ^ ((km[it]&7)<<4))) = kreg[it];
    #pragma unroll
    for(int it=0; it<2; it++){
      sh8 v0 = vreg[2*it], v1 = vreg[2*it+1];
      int mp = vmp[it], dg = vdg[it];
      #pragma unroll
      for(int i=0;i<8;i++){
        int d = dg + i;
        unsigned pk = ((unsigned)(unsigned short)v0[i]) |
                      (((unsigned)(unsigned short)v1[i]) << 16);
        *(unsigned*)((char*)vL + d*256 + ((mp*2) ^ ((d&7)<<4))) = pk;
      }
    }
    if(ph+1 < nph) ldregs(ph+1);   // latency flies under this phase's compute
    __syncthreads();
    #pragma unroll
    for(int st=0; st<4; st++){
      #pragma unroll
      for(int mt=0; mt<8; mt++){
        f4 s = {};
        #pragma unroll
        for(int kk=0; kk<2; kk++){
          int m = mt*16 + l15;
          sh8 b = *(sh8*)((char*)kL + m*128 + ((kk*64 + g*16) ^ ((m&7)<<4)));
          s = MFMA16(aQ[st][kk], b, s);
        }
        #pragma unroll
        for(int r=0; r<4; r++){
          float e = __expf(s[r]);
          den[st][r] += e;
          int n = g*4 + r;
          *(short*)((char*)pw + n*256 + (((mt*16+l15)*2) ^ ((n&7)<<4))) = (short)bfbits(e);
        }
      }
      #pragma unroll
      for(int ks=0; ks<4; ks++){
        sh8 aP = *(sh8*)((char*)pw + l15*256 + ((ks*64 + g*16) ^ ((l15&7)<<4)));
        #pragma unroll
        for(int dt=0; dt<4; dt++){
          int d = dt*16 + l15;
          sh8 bV = *(sh8*)((char*)vL + d*256 + ((ks*64 + g*16) ^ ((d&7)<<4)));
          accO[st][dt] = MFMA16(aP, bV, accO[st][dt]);
        }
      }
    }
  }
  #pragma unroll
  for(int st=0; st<4; st++)
    #pragma unroll
    for(int r=0; r<4; r++){
      float d_ = den[st][r];
      d_ += __shfl_xor(d_,1); d_ += __shfl_xor(d_,2);
      d_ += __shfl_xor(d_,4); d_ += __shfl_xor(d_,8);
      den[st][r] = d_;
    }
  size_t base = ((size_t)h*NCG + cg)*NLAND;
  #pragma unroll
  for(int st=0; st<4; st++){
    #pragma unroll
    for(int r=0; r<4; r++){
      int row = wv*64 + st*16 + g*4 + r;
      if(l15 == 0) denP[base + row] = den[st][r];
      #pragma unroll
      for(int dt=0; dt<4; dt++)
        numP[(base + row)*DHEAD + dt*16 + l15] = accO[st][dt][r];
    }
  }
}

__global__ void k_a3v_comb(const float* __restrict__ numP, const float* __restrict__ denP,
                           float* __restrict__ a3v){
  int bidx = blockIdx.x;
  int h = bidx >> 8, m = bidx & 255;
  int d = threadIdx.x;
  float s = 0.f, den = 0.f;
  for(int c=0;c<NCG;c++){
    s += numP[(((size_t)h*NCG + c)*NLAND + m)*DHEAD + d];
    den += denP[((size_t)h*NCG + c)*NLAND + m];
  }
  a3v[((size_t)h*NLAND + m)*DHEAD + d] = s / den;
}

// ---------------- residual depthwise conv (k=33), register-FIR ----------------
__global__ __launch_bounds__(256) void k_resconv(const short* __restrict__ Vb,
    const float* __restrict__ rw, short* __restrict__ F){
  __shared__ float vs[96][64];
  int n0 = blockIdx.x*64, h = blockIdx.y;
  int t = threadIdx.x;
  const short* vh = Vb + (size_t)h*NPAD*DHEAD;
  #pragma unroll
  for(int i=0;i<3;i++){
    int idx = t + i*256;
    int r = idx >> 3, dg = (idx & 7)*8;
    int n = n0 - 16 + r;
    sh8 v = {0,0,0,0,0,0,0,0};
    if(n>=0 && n<NPAD) v = *(const sh8*)(vh + (size_t)n*DHEAD + dg);
    #pragma unroll
    for(int e=0;e<8;e++) vs[r][dg+e] = bf2f(v[e]);
  }
  float w[33];
  #pragma unroll
  for(int j=0;j<33;j++) w[j] = rw[h*33+j];
  __syncthreads();
  int d = t & 63, grp = t >> 6;
  float f0[16];
  #pragma unroll
  for(int rr=0;rr<16;rr++){
    int n = n0 + grp*16 + rr;
    f0[rr] = bf2f(F[(size_t)n*CDIM + h*DHEAD + d]);
  }
  float in[48];
  #pragma unroll
  for(int x=0;x<48;x++) in[x] = vs[grp*16 + x][d];
  #pragma unroll
  for(int rr=0;rr<16;rr++){
    float acc = 0.f;
    #pragma unroll
    for(int j=0;j<33;j++) acc += w[j]*in[rr+j];
    int n = n0 + grp*16 + rr;
    F[(size_t)n*CDIM + h*DHEAD + d] = (short)bfbits(f0[rr] + acc);
  }
}

// ---------------- weight transpose f32 -> bf16 ----------------
__global__ void k_transposeb(const float* __restrict__ in, short* __restrict__ out,
                             int R, int C){
  __shared__ float tile[32][33];
  int r0 = blockIdx.x*32, c0 = blockIdx.y*32;
  int tx = threadIdx.x, ty = threadIdx.y;
  #pragma unroll
  for(int r=0;r<4;r++) tile[ty + r*8][tx] = in[(size_t)(r0 + ty + r*8)*C + c0 + tx];
  __syncthreads();
  #pragma unroll
  for(int r=0;r<4;r++)
    out[(size_t)(c0 + ty + r*8)*R + r0 + tx] = (short)bfbits(tile[tx][ty + r*8]);
}

// ---------------- PPEG direct on row-major [n][c] (f32) ----------------
__global__ __launch_bounds__(256) void k_ppeg2(const float* __restrict__ X,
    const float* __restrict__ w7, const float* __restrict__ b7,
    const float* __restrict__ w5, const float* __restrict__ b5,
    const float* __restrict__ w3, const float* __restrict__ b3,
    float* __restrict__ Y){
  __shared__ float patch[484][20];
  int cg = blockIdx.y;
  int ti = blockIdx.x >> 3, tj = blockIdx.x & 7;
  int t = threadIdx.x;
  int i0 = ti*16 - 3, j0 = tj*16 - 3;
  for(int idx = t; idx < 1936; idx += 256){
    int p = idx >> 2, cq = (idx & 3) * 4;
    int gi = i0 + p/22, gj = j0 + p%22;
    float4 v = make_float4(0.f,0.f,0.f,0.f);
    if(gi>=0 && gi<128 && gj>=0 && gj<128)
      v = *(const float4*)(X + (size_t)(gi*128+gj)*CDIM + cg*16 + cq);
    *(float4*)&patch[p][cq] = v;
  }
  int c = t & 15, sg = t >> 4;
  int cglob = cg*16 + c;
  float wr[83];
  #pragma unroll
  for(int k=0;k<49;k++) wr[k] = w7[cglob*49+k];
  #pragma unroll
  for(int k=0;k<25;k++) wr[49+k] = w5[cglob*25+k];
  #pragma unroll
  for(int k=0;k<9;k++)  wr[74+k] = w3[cglob*9+k];
  float bsum = b7[cglob] + b5[cglob] + b3[cglob];
  __syncthreads();
  float acc[16];
  #pragma unroll
  for(int j=0;j<16;j++) acc[j] = patch[(sg+3)*22 + (j+3)][c] + bsum;
  #pragma unroll
  for(int a=0;a<7;a++)
    #pragma unroll
    for(int x=0;x<22;x++){
      float vv = patch[(sg+a)*22 + x][c];
      #pragma unroll
      for(int bq=0;bq<7;bq++){
        int j = x - bq;
        if(j>=0 && j<16) acc[j] += wr[a*7+bq]*vv;
      }
    }
  #pragma unroll
  for(int a=0;a<5;a++)
    #pragma unroll
    for(int x=1;x<21;x++){
      float vv = patch[(sg+a+1)*22 + x][c];
      #pragma unroll
      for(int bq=0;bq<5;bq++){
        int j = x - 1 - bq;
        if(j>=0 && j<16) acc[j] += wr[49+a*5+bq]*vv;
      }
    }
  #pragma unroll
  for(int a=0;a<3;a++)
    #pragma unroll
    for(int x=2;x<20;x++){
      float vv = patch[(sg+a+2)*22 + x][c];
      #pragma unroll
      for(int bq=0;bq<3;bq++){
        int j = x - 2 - bq;
        if(j>=0 && j<16) acc[j] += wr[74+a*3+bq]*vv;
      }
    }
  #pragma unroll
  for(int j=0;j<16;j++)
    Y[(size_t)((ti*16+sg)*128 + tj*16+j)*CDIM + cglob] = acc[j];
}

// ---------------- final LN(row0) + fc2 ----------------
__global__ __launch_bounds__(512) void k_final(const float* __restrict__ A,
    const float* __restrict__ g, const float* __restrict__ b,
    const float* __restrict__ w, const float* __restrict__ bias,
    float* __restrict__ outp){
  __shared__ float red[8];
  int t = threadIdx.x, wv = t >> 6;
  float x = A[t];
  float s = wave_sum(x);
  if((t & 63) == 0) red[wv] = s;
  __syncthreads();
  float mu = 0;
  #pragma unroll
  for(int i=0;i<8;i++) mu += red[i];
  mu *= (1.f/512.f);
  __syncthreads();
  float dx = x - mu;
  s = wave_sum(dx*dx);
  if((t & 63) == 0) red[wv] = s;
  __syncthreads();
  float var = 0;
  #pragma unroll
  for(int i=0;i<8;i++) var += red[i];
  var *= (1.f/512.f);
  float xn = dx * rsqrtf(var + 1e-5f) * g[t] + b[t];
  __syncthreads();
  for(int o=0;o<4;o++){
    s = wave_sum(xn * w[t*4 + o]);
    if((t & 63) == 0) red[wv] = s;
    __syncthreads();
    if(t == 0){
      float r = 0;
      #pragma unroll
      for(int i=0;i<8;i++) r += red[i];
      outp[o] = r + bias[o];
    }
    __syncthreads();
  }
}

extern "C" void kernel_launch(void* const* d_in, const int* in_sizes, int n_in,
                              void* d_out, int out_size, void* d_ws, size_t ws_size,
                              hipStream_t stream) {
  (void)in_sizes; (void)n_in; (void)out_size; (void)ws_size;
  const float* data_x = (const float*)d_in[0];
  const float* fc1_w  = (const float*)d_in[1];
  const float* fc1_b  = (const float*)d_in[2];
  const float* cls_tk = (const float*)d_in[3];
  const float* ng[2]  = {(const float*)d_in[4],  (const float*)d_in[16]};
  const float* nb[2]  = {(const float*)d_in[5],  (const float*)d_in[17]};
  const float* qkvw[2]= {(const float*)d_in[6],  (const float*)d_in[18]};
  const float* outw[2]= {(const float*)d_in[7],  (const float*)d_in[19]};
  const float* outb[2]= {(const float*)d_in[8],  (const float*)d_in[20]};
  const float* resw[2]= {(const float*)d_in[9],  (const float*)d_in[21]};
  const float* w7 = (const float*)d_in[10]; const float* pb7 = (const float*)d_in[11];
  const float* w5 = (const float*)d_in[12]; const float* pb5 = (const float*)d_in[13];
  const float* w3 = (const float*)d_in[14]; const float* pb3 = (const float*)d_in[15];
  const float* norm_g = (const float*)d_in[22];
  const float* norm_b = (const float*)d_in[23];
  const float* fc2_w  = (const float*)d_in[24];
  const float* fc2_b  = (const float*)d_in[25];

  float* ws = (float*)d_ws;
  float* Ab   = ws;
  float* Bb   = Ab + (size_t)TOK*CDIM;
  float* Fb   = Bb + (size_t)TOK*CDIM;
  short* Fbf  = (short*)(Fb + (size_t)NPAD*CDIM);
  short* lnX  = Fbf + (size_t)NPAD*CDIM;
  short* Qb   = lnX + (size_t)NPAD*CDIM;
  short* Kb   = Qb  + (size_t)NPAD*CDIM;
  short* Vb   = Kb  + (size_t)NPAD*CDIM;
  short* dxb  = Vb  + (size_t)NPAD*CDIM;
  float* qlb  = (float*)(dxb + (size_t)16384*1024);
  float* klb  = qlb + NHEAD*NLAND*DHEAD;
  float* a2b  = klb + NHEAD*NLAND*DHEAD;
  float* z0b  = a2b + NHEAD*NLAND*NLAND;
  float* z1b  = z0b + NHEAD*NLAND*NLAND;
  float* Xb_  = z1b + NHEAD*NLAND*NLAND;
  float* Tb_  = Xb_ + NHEAD*NLAND*NLAND;
  float* Ub_  = Tb_ + NHEAD*NLAND*NLAND;
  float* a3vb = Ub_ + NHEAD*NLAND*NLAND;
  float* w2tb = a3vb + NHEAD*NLAND*DHEAD;
  float* denP = w2tb + NHEAD*DHEAD*NLAND;
  float* hmax = denP + NHEAD*NCG*NLAND;
  float* scal = hmax + 8;
  short* fc1T = (short*)(scal + 8);
  short* qkvT0= fc1T + 512*1024;
  short* qkvT1= qkvT0 + 1536*512;
  short* outT0= qkvT1 + 1536*512;
  short* outT1= outT0 + 512*512;
  short* qkvT[2] = {qkvT0, qkvT1};
  short* outT[2] = {outT0, outT1};

  const int HB = NHEAD*NLAND*NLAND;
  short* zb0  = (short*)z0b;  short* zb1  = zb0 + HB;
  short* xb   = (short*)z1b;  short* tb   = xb + HB;
  short* ub   = (short*)Xb_;  short* a2bf = ub + HB;
  float* zf   = Tb_;

  k_transposeb<<<dim3(32,16), dim3(32,8), 0, stream>>>(fc1_w, fc1T, 1024, 512);
  k_transposeb<<<dim3(16,48), dim3(32,8), 0, stream>>>(qkvw[0], qkvT0, 512, 1536);
  k_transposeb<<<dim3(16,48), dim3(32,8), 0, stream>>>(qkvw[1], qkvT1, 512, 1536);
  k_transposeb<<<dim3(16,16), dim3(32,8), 0, stream>>>(outw[0], outT0, 512, 512);
  k_transposeb<<<dim3(16,16), dim3(32,8), 0, stream>>>(outw[1], outT1, 512, 512);
  k_f2b<<<8192, 256, 0, stream>>>(data_x, dxb, 16384*1024/8);

  k_copyrow<<<1, 512, 0, stream>>>(Ab, cls_tk);
  k_gemm_g<0><<<dim3(4, 128), 256, 0, stream>>>(dxb, 1024, fc1T, 1024, fc1_b,
                                                Ab + CDIM, nullptr, nullptr, 16384);
  float* base[2]  = {Ab, Bb};
  for(int L=0; L<2; L++){
    k_ln_pad<<<NPAD/4, 256, 0, stream>>>(base[L], ng[L], nb[L], lnX);
    k_gemm_g<1><<<dim3(12, 130), 256, 0, stream>>>(lnX, CDIM, qkvT[L], CDIM, nullptr,
                                                   Qb, Kb, Vb, NPAD);
    k_landmark2<<<2*NHEAD*NLAND, 64, 0, stream>>>(Qb, Kb, qlb, klb);
    k_a2_mfma<<<dim3(4, NHEAD), 256, 0, stream>>>(qlb, klb, a2b, a2bf);
    k_colmax<<<NHEAD, 256, 0, stream>>>(a2b, hmax);
    k_zinit<<<dim3(256, NHEAD), 256, 0, stream>>>(a2b, hmax, zb0);
    short* zc = zb0; short* zn = zb1;
    for(int it=0; it<6; it++){
      k_pgemm<0,0><<<dim3(4,4,NHEAD), 256, 0, stream>>>(a2bf, zc, xb, nullptr, 0.f, 1.f);
      k_pgemm<1,0><<<dim3(4,4,NHEAD), 256, 0, stream>>>(xb, xb, tb, nullptr, 7.f, 1.f);
      k_pgemm<1,0><<<dim3(4,4,NHEAD), 256, 0, stream>>>(xb, tb, ub, nullptr, 15.f, 1.f);
      if(it < 5){
        k_pgemm<1,0><<<dim3(4,4,NHEAD), 256, 0, stream>>>(zc, ub, zn, nullptr, 13.f, 0.25f);
        short* tmp = zc; zc = zn; zn = tmp;
      } else {
        k_pgemm<1,1><<<dim3(4,4,NHEAD), 256, 0, stream>>>(zc, ub, nullptr, zf, 13.f, 0.25f);
      }
    }
    k_a3v_mfma<<<dim3(NHEAD, NCG), 256, 0, stream>>>(qlb, Kb, Vb, Fb, denP);
    k_a3v_comb<<<NHEAD*NLAND, 64, 0, stream>>>(Fb, denP, a3vb);
    k_sgemm2<0,1><<<dim3(1,4,NHEAD), 256, 0, stream>>>(zf, a3vb, w2tb, 256,64,256,
                                                       65536,16384,16384, 0.f, 1.f);
    k_a1_mfma<<<dim3(130, NHEAD), 256, 0, stream>>>(Qb, klb, w2tb, Fbf);
    k_resconv<<<dim3(260, NHEAD), 256, 0, stream>>>(Vb, resw[L], Fbf);
    k_gemm_g<2><<<dim3(4, 129), 256, 0, stream>>>(Fbf + (size_t)PAD0*CDIM, CDIM,
                                                  outT[L], CDIM, outb[L],
                                                  base[L], nullptr, nullptr, TOK);
    if(L == 0){
      k_ppeg2<<<dim3(64, 32), 256, 0, stream>>>(Ab + CDIM, w7, pb7, w5, pb5, w3, pb3,
                                                Bb + CDIM);
      k_copyrow<<<1, 512, 0, stream>>>(Bb, Ab);
    }
  }
  k_final<<<1, 512, 0, stream>>>(Bb, norm_g, norm_b, fc2_w, fc2_b, (float*)d_out);
}

// Round 19
// 930.060 us; speedup vs baseline: 3.0974x; 1.0041x over previous
//
#include <hip/hip_runtime.h>
#include <hip/hip_bf16.h>

#define NPAD 16640
#define TOK  16385
#define CDIM 512
#define NHEAD 8
#define DHEAD 64
#define NLAND 256
#define LFAC  65
#define PAD0  255
#define NCHUNK 65     // 256-row chunks
#define CGRP 2        // chunks per block in a3v
#define NCG 33        // ceil(65/2)

typedef __attribute__((ext_vector_type(8))) short sh8;
typedef __attribute__((ext_vector_type(4))) float f4;

__device__ __forceinline__ float wave_sum(float v){
  #pragma unroll
  for(int o=32;o;o>>=1) v += __shfl_xor(v,o);
  return v;
}
__device__ __forceinline__ float wave_max(float v){
  #pragma unroll
  for(int o=32;o;o>>=1) v = fmaxf(v, __shfl_xor(v,o));
  return v;
}

__device__ __forceinline__ unsigned bfbits(float x){
  unsigned u = __float_as_uint(x);
  return (u + 0x7fffu + ((u >> 16) & 1u)) >> 16;
}
__device__ __forceinline__ float bf2f(short s){
  return __uint_as_float(((unsigned)(unsigned short)s) << 16);
}
__device__ __forceinline__ sh8 pack8f(float4 a, float4 b){
  sh8 r;
  r[0]=(short)bfbits(a.x); r[1]=(short)bfbits(a.y); r[2]=(short)bfbits(a.z); r[3]=(short)bfbits(a.w);
  r[4]=(short)bfbits(b.x); r[5]=(short)bfbits(b.y); r[6]=(short)bfbits(b.z); r[7]=(short)bfbits(b.w);
  return r;
}
#define MFMA16(a,b,c) __builtin_amdgcn_mfma_f32_16x16x32_bf16(a,b,c,0,0,0)

__device__ __forceinline__ void gload16(const void* g, void* l){
  __builtin_amdgcn_global_load_lds(
      (const __attribute__((address_space(1))) void*)g,
      (__attribute__((address_space(3))) void*)l, 16, 0, 0);
}

// lgkm-only barrier: drains LDS ops but leaves global prefetch (vmcnt) in flight
#define BAR_LGKM() do{ \
  asm volatile("s_waitcnt lgkmcnt(0)" ::: "memory"); \
  __builtin_amdgcn_s_barrier(); \
}while(0)

// ---------------- row copy (cls token) ----------------
__global__ void k_copyrow(float* dst, const float* __restrict__ src){
  dst[threadIdx.x] = src[threadIdx.x];
}

// ---------------- f32 -> bf16 convert ----------------
__global__ __launch_bounds__(256) void k_f2b(const float* __restrict__ in,
    short* __restrict__ out, int n8){
  int i = blockIdx.x*256 + threadIdx.x;
  if(i < n8){
    float4 a = *(const float4*)(in + (size_t)i*8);
    float4 b = *(const float4*)(in + (size_t)i*8 + 4);
    *(sh8*)(out + (size_t)i*8) = pack8f(a, b);
  }
}

// ---------------- layernorm + front pad -> bf16 ----------------
__global__ __launch_bounds__(256) void k_ln_pad(const float* __restrict__ A,
    const float* __restrict__ g, const float* __restrict__ b, short* __restrict__ B){
  int w = threadIdx.x >> 6, lane = threadIdx.x & 63;
  int row = blockIdx.x*4 + w;
  short* out = B + (size_t)row*CDIM;
  int c = lane*8;
  if(row < PAD0){
    sh8 z = {0,0,0,0,0,0,0,0};
    *(sh8*)(out + c) = z;
    return;
  }
  const float* x = A + (size_t)(row-PAD0)*CDIM;
  float4 v0 = *(const float4*)(x + c);
  float4 v1 = *(const float4*)(x + c + 4);
  float xs[8] = {v0.x,v0.y,v0.z,v0.w,v1.x,v1.y,v1.z,v1.w};
  float s = 0;
  #pragma unroll
  for(int i=0;i<8;i++) s += xs[i];
  s = wave_sum(s);
  float mu = s * (1.f/512.f);
  float vs = 0;
  #pragma unroll
  for(int i=0;i<8;i++){ float d = xs[i]-mu; vs += d*d; }
  vs = wave_sum(vs) * (1.f/512.f);
  float rs = rsqrtf(vs + 1e-5f);
  float4 g0 = *(const float4*)(g + c); float4 g1 = *(const float4*)(g + c + 4);
  float4 b0 = *(const float4*)(b + c); float4 b1 = *(const float4*)(b + c + 4);
  float gg[8] = {g0.x,g0.y,g0.z,g0.w,g1.x,g1.y,g1.z,g1.w};
  float bb[8] = {b0.x,b0.y,b0.z,b0.w,b1.x,b1.y,b1.z,b1.w};
  sh8 o;
  #pragma unroll
  for(int i=0;i<8;i++) o[i] = (short)bfbits((xs[i]-mu)*rs*gg[i] + bb[i]);
  *(sh8*)(out + c) = o;
}

// ---------------- gload-staged MFMA GEMM: C[M,N] = A[M,K] @ WT[N,K]^T ----------------
template<int MODE>
__global__ __launch_bounds__(256) void k_gemm_g(const short* __restrict__ A, int lda,
    const short* __restrict__ WT, int K, const float* __restrict__ bias,
    void* out0v, void* out1v, void* out2v, int M){
  __shared__ short As[2][128*32];
  __shared__ short Bs[2][128*32];
  int t = threadIdx.x, lane = t & 63, wv = t >> 6, g = lane >> 4, l15 = lane & 15;
  int nwg = gridDim.x * gridDim.y;
  int orig = blockIdx.y * gridDim.x + blockIdx.x;
  int qc = nwg >> 3, rc = nwg & 7, xcd = orig & 7, loc = orig >> 3;
  int wgid = (xcd < rc ? xcd*(qc+1) : rc*(qc+1) + (xcd - rc)*qc) + loc;
  int row0 = (wgid / gridDim.x) * 128, n0 = (wgid % gridDim.x) * 128;
  int wm = (wv>>1)*64, wn = (wv&1)*64;
  int mq = lane >> 2, slot = lane & 3;

  auto stage = [&](int buf, int k0){
    #pragma unroll
    for(int c=0;c<2;c++){
      int m = wv*32 + c*16 + mq;
      int swz = (((m&3) ^ ((m>>2)&3)) << 4);
      int gr = row0 + m; if(gr >= M) gr = M-1;
      const char* srcA = (const char*)(A + (size_t)gr*lda + k0) + ((slot*16) ^ swz);
      gload16(srcA, (char*)As[buf] + wv*2048 + c*1024);
      const char* srcB = (const char*)(WT + (size_t)(n0+m)*K + k0) + ((slot*16) ^ swz);
      gload16(srcB, (char*)Bs[buf] + wv*2048 + c*1024);
    }
  };

  f4 acc[4][4] = {};
  int nk = K >> 5;
  stage(0, 0);
  __syncthreads();
  int cur = 0;
  for(int i=0; i<nk; i++){
    if(i+1 < nk) stage(cur^1, (i+1) << 5);
    sh8 af[4], bf[4];
    #pragma unroll
    for(int mt=0; mt<4; mt++){
      int r = wm + mt*16 + l15;
      af[mt] = *(sh8*)((char*)As[cur] + r*64 + ((g*16) ^ (((r&3)^((r>>2)&3))<<4)));
    }
    #pragma unroll
    for(int nt=0; nt<4; nt++){
      int r = wn + nt*16 + l15;
      bf[nt] = *(sh8*)((char*)Bs[cur] + r*64 + ((g*16) ^ (((r&3)^((r>>2)&3))<<4)));
    }
    #pragma unroll
    for(int mt=0; mt<4; mt++)
      #pragma unroll
      for(int nt=0; nt<4; nt++)
        acc[mt][nt] = MFMA16(af[mt], bf[nt], acc[mt][nt]);
    __syncthreads();
    cur ^= 1;
  }
  #pragma unroll
  for(int mt=0; mt<4; mt++){
    #pragma unroll
    for(int r=0; r<4; r++){
      int gm = row0 + wm + mt*16 + g*4 + r;
      if(gm >= M) continue;
      #pragma unroll
      for(int nt=0; nt<4; nt++){
        int gn = n0 + wn + nt*16 + l15;
        float v = acc[mt][nt][r];
        if(MODE == 0){
          v += bias[gn];
          ((float*)out0v)[(size_t)gm*CDIM + gn] = v > 0.f ? v : 0.f;
        } else if(MODE == 1){
          int p = gn >> 9, rr = gn & 511;
          int hh = rr >> 6, dd = rr & 63;
          if(p == 0) v *= 0.125f;
          short* dst = (p==0) ? (short*)out0v : (p==1 ? (short*)out1v : (short*)out2v);
          dst[((size_t)hh*NPAD + gm)*DHEAD + dd] = (short)bfbits(v);
        } else {
          ((float*)out0v)[(size_t)gm*CDIM + gn] += v + bias[gn];
        }
      }
    }
  }
}

// ---------------- landmark means, Q and K in one dispatch ----------------
__global__ void k_landmark2(const short* __restrict__ Qb, const short* __restrict__ Kb,
    float* __restrict__ ql, float* __restrict__ kl){
  int bidx = blockIdx.x;
  int sel = bidx >> 11;
  int loc = bidx & 2047;
  int h = loc >> 8, m = loc & 255, d = threadIdx.x;
  const short* src = (sel ? Kb : Qb) + ((size_t)h*NPAD + (size_t)m*LFAC)*DHEAD + d;
  float s = 0;
  for(int j=0;j<LFAC;j++) s += bf2f(src[(size_t)j*DHEAD]);
  (sel ? kl : ql)[(size_t)loc*DHEAD + d] = s * (1.f/LFAC);
}

// ---------------- a2 = softmax(ql @ kl^T), MFMA ----------------
__global__ __launch_bounds__(256) void k_a2_mfma(const float* __restrict__ ql,
    const float* __restrict__ kl, float* __restrict__ a2, short* __restrict__ a2bf){
  __shared__ short klL[256*64];   // [n][d] bf16, 128B rows, XOR swizzle
  int q = blockIdx.x, h = blockIdx.y;
  int t = threadIdx.x, lane = t & 63, wv = t >> 6, g = lane >> 4, l15 = lane & 15;
  const float* qlh = ql + (size_t)h*NLAND*DHEAD;
  const float* klh = kl + (size_t)h*NLAND*DHEAD;
  #pragma unroll
  for(int i=0;i<8;i++){
    int gi = t + i*256;
    int n = gi >> 3, db = (gi & 7)*8;
    float4 a = *(const float4*)(klh + (size_t)n*DHEAD + db);
    float4 b = *(const float4*)(klh + (size_t)n*DHEAD + db + 4);
    *(sh8*)((char*)klL + n*128 + ((db*2) ^ ((n&7)<<4))) = pack8f(a, b);
  }
  __syncthreads();
  int row0 = q*64 + wv*16;
  sh8 aQ[2];
  #pragma unroll
  for(int kk=0; kk<2; kk++){
    const float* p = qlh + (size_t)(row0 + l15)*DHEAD + kk*32 + g*8;
    aQ[kk] = pack8f(*(const float4*)p, *(const float4*)(p+4));
  }
  f4 acc[16];
  #pragma unroll
  for(int nt=0; nt<16; nt++){
    f4 s = {};
    #pragma unroll
    for(int kk=0; kk<2; kk++){
      int n = nt*16 + l15;
      sh8 b = *(sh8*)((char*)klL + n*128 + ((kk*64 + g*16) ^ ((n&7)<<4)));
      s = MFMA16(aQ[kk], b, s);
    }
    acc[nt] = s;
  }
  float den[4] = {0,0,0,0};
  #pragma unroll
  for(int nt=0; nt<16; nt++)
    #pragma unroll
    for(int r=0; r<4; r++){
      float e = __expf(acc[nt][r]);
      acc[nt][r] = e;
      den[r] += e;
    }
  #pragma unroll
  for(int r=0; r<4; r++){
    float d_ = den[r];
    d_ += __shfl_xor(d_,1); d_ += __shfl_xor(d_,2);
    d_ += __shfl_xor(d_,4); d_ += __shfl_xor(d_,8);
    den[r] = 1.f/d_;
  }
  #pragma unroll
  for(int nt=0; nt<16; nt++)
    #pragma unroll
    for(int r=0; r<4; r++){
      int row = row0 + g*4 + r;
      int col = nt*16 + l15;
      float v = acc[nt][r]*den[r];
      size_t idx = ((size_t)h*NLAND + row)*NLAND + col;
      a2[idx] = v;
      a2bf[idx] = (short)bfbits(v);
    }
}

// ---------------- pinv init ----------------
__global__ void k_colmax(const float* __restrict__ a2, float* __restrict__ hmax){
  __shared__ float red[4];
  int h = blockIdx.x, t = threadIdx.x;
  const float* p = a2 + (size_t)h*65536 + t;
  float s = 0;
  for(int m=0;m<256;m++) s += p[(size_t)m*256];
  float mx = wave_max(s);
  if((t & 63) == 0) red[t>>6] = mx;
  __syncthreads();
  if(t == 0) hmax[h] = fmaxf(fmaxf(red[0],red[1]), fmaxf(red[2],red[3]));
}
// z0 (bf16) = a2^T / max(hmax)
__global__ void k_zinit(const float* __restrict__ a2, const float* __restrict__ hmax,
                        short* __restrict__ z){
  int h = blockIdx.y;
  int idx = blockIdx.x*256 + threadIdx.x;
  int m = idx >> 8, j = idx & 255;
  float mx = hmax[0];
  #pragma unroll
  for(int i=1;i<8;i++) mx = fmaxf(mx, hmax[i]);
  z[(size_t)h*65536 + idx] = (short)bfbits(a2[(size_t)h*65536 + (size_t)j*256 + m] / mx);
}

// ---------------- batched MFMA pinv GEMM, bf16 I/O ----------------
template<int TRANS, int F32OUT>
__global__ __launch_bounds__(256) void k_pgemm(const short* __restrict__ A,
    const short* __restrict__ B, short* __restrict__ C, float* __restrict__ Cf,
    float alpha, float beta){
  __shared__ short As[64*32];
  __shared__ short Bs[64*32];
  int bh = blockIdx.z;
  const short* Ah = A + (size_t)bh*65536;
  const short* Bh = B + (size_t)bh*65536;
  int m0 = blockIdx.y*64, n0 = blockIdx.x*64;
  int t = threadIdx.x, lane = t & 63, wv = t >> 6, g = lane >> 4, l15 = lane & 15;
  f4 acc[4] = {};
  for(int k0=0; k0<256; k0+=32){
    {
      int m = t >> 2, kb = (t & 3)*8;
      sh8 av = *(const sh8*)(Ah + (size_t)(m0+m)*256 + k0 + kb);
      int swz = (((m&3)^((m>>2)&3))<<4);
      *(sh8*)((char*)As + m*64 + ((kb*2)^swz)) = av;
    }
    {
      int kr = t >> 3, nb = (t & 7)*8;
      sh8 bv = *(const sh8*)(Bh + (size_t)(k0+kr)*256 + n0 + nb);
      #pragma unroll
      for(int e=0;e<8;e++){
        int n = nb + e;
        short sv = bv[e];
        if(TRANS){
          float f = ((k0+kr == n0+n) ? alpha : 0.f) - bf2f(sv);
          sv = (short)bfbits(f);
        }
        int swz = (((n&3)^((n>>2)&3))<<4);
        *(short*)((char*)Bs + n*64 + ((kr*2)^swz)) = sv;
      }
    }
    __syncthreads();
    int rm = wv*16 + l15;
    sh8 af = *(sh8*)((char*)As + rm*64 + ((g*16) ^ (((rm&3)^((rm>>2)&3))<<4)));
    #pragma unroll
    for(int nt=0; nt<4; nt++){
      int n = nt*16 + l15;
      sh8 bf = *(sh8*)((char*)Bs + n*64 + ((g*16) ^ (((n&3)^((n>>2)&3))<<4)));
      acc[nt] = MFMA16(af, bf, acc[nt]);
    }
    __syncthreads();
  }
  size_t hoff = (size_t)bh*65536;
  #pragma unroll
  for(int nt=0; nt<4; nt++)
    #pragma unroll
    for(int r=0; r<4; r++){
      size_t idx = hoff + (size_t)(m0 + wv*16 + g*4 + r)*256 + n0 + nt*16 + l15;
      float v = acc[nt][r]*beta;
      if(F32OUT) Cf[idx] = v;
      else       C[idx] = (short)bfbits(v);
    }
}

// ---------------- batched f32 GEMM 64x64 tile (w2^T only) ----------------
template<int TRANS, int OUTT>
__global__ __launch_bounds__(256) void k_sgemm2(const float* __restrict__ A,
    const float* __restrict__ B, float* __restrict__ C,
    int M, int N, int K, long sA, long sB, long sC, float alpha, float beta){
  __shared__ float As[32][68];
  __shared__ float Bs[32][68];
  int bh = blockIdx.z;
  const float* Ah = A + (size_t)bh*sA;
  const float* Bh = B + (size_t)bh*sB;
  float* Ch = C + (size_t)bh*sC;
  int m0 = blockIdx.y*64, n0 = blockIdx.x*64;
  int t = threadIdx.x, tx = t & 15, ty = t >> 4;
  float acc[4][4] = {};
  for(int k0=0; k0<K; k0+=32){
    #pragma unroll
    for(int u=0; u<2; u++){
      int idx = t + u*256;
      int r = idx >> 3, cb = (idx & 7) * 4;
      float4 va = *(const float4*)(Ah + (size_t)(m0+r)*K + k0 + cb);
      As[cb+0][r]=va.x; As[cb+1][r]=va.y; As[cb+2][r]=va.z; As[cb+3][r]=va.w;
      int kr = idx >> 4, nb = (idx & 15) * 4;
      float4 w = *(const float4*)(Bh + (size_t)(k0+kr)*N + n0 + nb);
      if(TRANS){
        int gk = k0 + kr;
        w.x = ((gk==n0+nb+0)?alpha:0.f) - w.x;
        w.y = ((gk==n0+nb+1)?alpha:0.f) - w.y;
        w.z = ((gk==n0+nb+2)?alpha:0.f) - w.z;
        w.w = ((gk==n0+nb+3)?alpha:0.f) - w.w;
      }
      *(float4*)&Bs[kr][nb] = w;
    }
    __syncthreads();
    #pragma unroll
    for(int k=0;k<32;k++){
      float a[4], b[4];
      *(float4*)a = *(const float4*)&As[k][ty*4];
      *(float4*)b = *(const float4*)&Bs[k][tx*4];
      #pragma unroll
      for(int i=0;i<4;i++)
        #pragma unroll
        for(int j=0;j<4;j++) acc[i][j] += a[i]*b[j];
    }
    __syncthreads();
  }
  #pragma unroll
  for(int i=0;i<4;i++){
    #pragma unroll
    for(int j=0;j<4;j++){
      int gm = m0 + ty*4 + i, gn = n0 + tx*4 + j;
      float v = acc[i][j] * beta;
      if(OUTT) Ch[(size_t)gn*M + gm] = v;
      else     Ch[(size_t)gm*N + gn] = v;
    }
  }
}

// ---------------- MFMA flash a1 (Q bf16, F out bf16), per-wave P ----------------
__global__ __launch_bounds__(256) void k_a1_mfma(const short* __restrict__ Qb,
    const float* __restrict__ kl, const float* __restrict__ w2t, short* __restrict__ F){
  __shared__ short klL[128*64];
  __shared__ short w2L[64*128];
  __shared__ short pL[4][16*128];
  int h = blockIdx.y, n0 = blockIdx.x*128;
  int t = threadIdx.x, lane = t & 63, wv = t >> 6, g = lane >> 4, l15 = lane & 15;
  const float* klh = kl + (size_t)h*NLAND*DHEAD;
  const float* w2h = w2t + (size_t)h*DHEAD*NLAND;
  const short* qbase = Qb + (size_t)h*NPAD*DHEAD;
  sh8 aQ[2][2];
  #pragma unroll
  for(int st=0; st<2; st++)
    #pragma unroll
    for(int kk=0; kk<2; kk++)
      aQ[st][kk] = *(const sh8*)(qbase +
          (size_t)(n0 + wv*32 + st*16 + l15)*DHEAD + kk*32 + g*8);
  f4 accO[2][4] = {};
  float den[2][4] = {};
  short* pw = pL[wv];
  for(int half=0; half<2; half++){
    __syncthreads();
    #pragma unroll
    for(int it=0; it<4; it++){
      int gi = t + it*256;
      int m = gi >> 3, db = (gi & 7) * 8;
      const float* p = klh + (size_t)(half*128 + m)*DHEAD + db;
      *(sh8*)((char*)klL + m*128 + ((db*2) ^ ((m&7)<<4))) =
          pack8f(*(const float4*)p, *(const float4*)(p+4));
      int d = gi >> 4, mb = (gi & 15) * 8;
      const float* p2 = w2h + (size_t)d*NLAND + half*128 + mb;
      *(sh8*)((char*)w2L + d*256 + ((mb*2) ^ ((d&7)<<4))) =
          pack8f(*(const float4*)p2, *(const float4*)(p2+4));
    }
    __syncthreads();
    #pragma unroll
    for(int st=0; st<2; st++){
      #pragma unroll
      for(int mt=0; mt<8; mt++){
        f4 s = {};
        #pragma unroll
        for(int kk=0; kk<2; kk++){
          int m = mt*16 + l15;
          sh8 b = *(sh8*)((char*)klL + m*128 + ((kk*64 + g*16) ^ ((m&7)<<4)));
          s = MFMA16(aQ[st][kk], b, s);
        }
        #pragma unroll
        for(int r=0; r<4; r++){
          float e = __expf(s[r]);
          den[st][r] += e;
          int n = g*4 + r;
          *(short*)((char*)pw + n*256 + (((mt*16+l15)*2) ^ ((n&7)<<4))) = (short)bfbits(e);
        }
      }
      #pragma unroll
      for(int ks=0; ks<4; ks++){
        sh8 aP = *(sh8*)((char*)pw + l15*256 + ((ks*64 + g*16) ^ ((l15&7)<<4)));
        #pragma unroll
        for(int dt=0; dt<4; dt++){
          int d = dt*16 + l15;
          sh8 bW = *(sh8*)((char*)w2L + d*256 + ((ks*64 + g*16) ^ ((d&7)<<4)));
          accO[st][dt] = MFMA16(aP, bW, accO[st][dt]);
        }
      }
    }
  }
  #pragma unroll
  for(int st=0; st<2; st++)
    #pragma unroll
    for(int r=0; r<4; r++){
      float d_ = den[st][r];
      d_ += __shfl_xor(d_,1); d_ += __shfl_xor(d_,2);
      d_ += __shfl_xor(d_,4); d_ += __shfl_xor(d_,8);
      den[st][r] = 1.f/d_;
    }
  #pragma unroll
  for(int st=0; st<2; st++)
    #pragma unroll
    for(int dt=0; dt<4; dt++)
      #pragma unroll
      for(int r=0; r<4; r++){
        int row = n0 + wv*32 + st*16 + g*4 + r;
        F[(size_t)row*CDIM + h*DHEAD + dt*16 + l15] =
            (short)bfbits(accO[st][dt][r]*den[st][r]);
      }
}

// ---------------- MFMA flash a3v: 8 waves (st split), lgkm-only barriers ----------
// Each wave handles 2 row-groups (halved serial chain); register K/V prefetch
// survives the barrier because vmcnt is NOT drained (BAR_LGKM).
__global__ __launch_bounds__(512) void k_a3v_mfma(const float* __restrict__ ql,
    const short* __restrict__ Kb, const short* __restrict__ Vb,
    float* __restrict__ numP, float* __restrict__ denP){
  __shared__ short kL[128*64];
  __shared__ short vL[64*128];
  __shared__ short pL[8][16*128];
  int h = blockIdx.x, cg = blockIdx.y;
  int t = threadIdx.x, lane = t & 63, wv = t >> 6, g = lane >> 4, l15 = lane & 15;
  int r0 = (wv & 3)*64 + (wv >> 2)*32;      // 8 waves cover 256 rows in 32-row slices
  const float* qlh = ql + (size_t)h*NLAND*DHEAD;
  sh8 aQ[2][2];
  #pragma unroll
  for(int st=0; st<2; st++)
    #pragma unroll
    for(int kk=0; kk<2; kk++){
      const float* p = qlh + (size_t)(r0 + st*16 + l15)*DHEAD + kk*32 + g*8;
      aQ[st][kk] = pack8f(*(const float4*)p, *(const float4*)(p+4));
    }
  f4 accO[2][4] = {};
  float den[2][4] = {};
  short* pw = pL[wv];

  // staging addresses (512 threads)
  int km[2], kdb[2];
  #pragma unroll
  for(int it=0; it<2; it++){
    int gi = t + it*512;
    km[it] = gi >> 3; kdb[it] = (gi & 7) * 8;
  }
  int vmp = (t & 63)*2, vdg = (t >> 6)*8;

  sh8 kreg[2], vreg[2];
  auto ldregs = [&](int ph){
    int c = cg*CGRP + (ph >> 1), half = ph & 1;
    const short* Kh = Kb + ((size_t)h*NPAD + (size_t)c*256 + half*128)*DHEAD;
    const short* Vh = Vb + ((size_t)h*NPAD + (size_t)c*256 + half*128)*DHEAD;
    #pragma unroll
    for(int it=0; it<2; it++)
      kreg[it] = *(const sh8*)(Kh + (size_t)km[it]*DHEAD + kdb[it]);
    vreg[0] = *(const sh8*)(Vh + (size_t)vmp*DHEAD + vdg);
    vreg[1] = *(const sh8*)(Vh + (size_t)(vmp+1)*DHEAD + vdg);
  };

  int nph = 2*CGRP;
  if(cg*CGRP + ((nph-1) >> 1) >= NCHUNK) nph = 2;   // last (odd) group: 1 chunk
  ldregs(0);
  for(int ph=0; ph<nph; ph++){
    BAR_LGKM();                  // prev-phase LDS reads drained; vm prefetch stays live
    #pragma unroll
    for(int it=0; it<2; it++)
      *(sh8*)((char*)kL + km[it]*128 + ((kdb[it]*2) ^ ((km[it]&7)<<4))) = kreg[it];
    {
      sh8 v0 = vreg[0], v1 = vreg[1];
      #pragma unroll
      for(int i=0;i<8;i++){
        int d = vdg + i;
        unsigned pk = ((unsigned)(unsigned short)v0[i]) |
                      (((unsigned)(unsigned short)v1[i]) << 16);
        *(unsigned*)((char*)vL + d*256 + ((vmp*2) ^ ((d&7)<<4))) = pk;
      }
    }
    if(ph+1 < nph) ldregs(ph+1);   // in flight across the next barrier
    BAR_LGKM();                  // staging writes visible to all waves
    #pragma unroll
    for(int st=0; st<2; st++){
      #pragma unroll
      for(int mt=0; mt<8; mt++){
        f4 s = {};
        #pragma unroll
        for(int kk=0; kk<2; kk++){
          int m = mt*16 + l15;
          sh8 b = *(sh8*)((char*)kL + m*128 + ((kk*64 + g*16) ^ ((m&7)<<4)));
          s = MFMA16(aQ[st][kk], b, s);
        }
        #pragma unroll
        for(int r=0; r<4; r++){
          float e = __expf(s[r]);
          den[st][r] += e;
          int n = g*4 + r;
          *(short*)((char*)pw + n*256 + (((mt*16+l15)*2) ^ ((n&7)<<4))) = (short)bfbits(e);
        }
      }
      #pragma unroll
      for(int ks=0; ks<4; ks++){
        sh8 aP = *(sh8*)((char*)pw + l15*256 + ((ks*64 + g*16) ^ ((l15&7)<<4)));
        #pragma unroll
        for(int dt=0; dt<4; dt++){
          int d = dt*16 + l15;
          sh8 bV = *(sh8*)((char*)vL + d*256 + ((ks*64 + g*16) ^ ((d&7)<<4)));
          accO[st][dt] = MFMA16(aP, bV, accO[st][dt]);
        }
      }
    }
  }
  #pragma unroll
  for(int st=0; st<2; st++)
    #pragma unroll
    for(int r=0; r<4; r++){
      float d_ = den[st][r];
      d_ += __shfl_xor(d_,1); d_ += __shfl_xor(d_,2);
      d_ += __shfl_xor(d_,4); d_ += __shfl_xor(d_,8);
      den[st][r] = d_;
    }
  size_t base = ((size_t)h*NCG + cg)*NLAND;
  #pragma unroll
  for(int st=0; st<2; st++){
    #pragma unroll
    for(int r=0; r<4; r++){
      int row = r0 + st*16 + g*4 + r;
      if(l15 == 0) denP[base + row] = den[st][r];
      #pragma unroll
      for(int dt=0; dt<4; dt++)
        numP[(base + row)*DHEAD + dt*16 + l15] = accO[st][dt][r];
    }
  }
}

__global__ void k_a3v_comb(const float* __restrict__ numP, const float* __restrict__ denP,
                           float* __restrict__ a3v){
  int bidx = blockIdx.x;
  int h = bidx >> 8, m = bidx & 255;
  int d = threadIdx.x;
  float s = 0.f, den = 0.f;
  for(int c=0;c<NCG;c++){
    s += numP[(((size_t)h*NCG + c)*NLAND + m)*DHEAD + d];
    den += denP[((size_t)h*NCG + c)*NLAND + m];
  }
  a3v[((size_t)h*NLAND + m)*DHEAD + d] = s / den;
}

// ---------------- residual depthwise conv (k=33), register-FIR ----------------
__global__ __launch_bounds__(256) void k_resconv(const short* __restrict__ Vb,
    const float* __restrict__ rw, short* __restrict__ F){
  __shared__ float vs[96][64];
  int n0 = blockIdx.x*64, h = blockIdx.y;
  int t = threadIdx.x;
  const short* vh = Vb + (size_t)h*NPAD*DHEAD;
  #pragma unroll
  for(int i=0;i<3;i++){
    int idx = t + i*256;
    int r = idx >> 3, dg = (idx & 7)*8;
    int n = n0 - 16 + r;
    sh8 v = {0,0,0,0,0,0,0,0};
    if(n>=0 && n<NPAD) v = *(const sh8*)(vh + (size_t)n*DHEAD + dg);
    #pragma unroll
    for(int e=0;e<8;e++) vs[r][dg+e] = bf2f(v[e]);
  }
  float w[33];
  #pragma unroll
  for(int j=0;j<33;j++) w[j] = rw[h*33+j];
  __syncthreads();
  int d = t & 63, grp = t >> 6;
  float f0[16];
  #pragma unroll
  for(int rr=0;rr<16;rr++){
    int n = n0 + grp*16 + rr;
    f0[rr] = bf2f(F[(size_t)n*CDIM + h*DHEAD + d]);
  }
  float in[48];
  #pragma unroll
  for(int x=0;x<48;x++) in[x] = vs[grp*16 + x][d];
  #pragma unroll
  for(int rr=0;rr<16;rr++){
    float acc = 0.f;
    #pragma unroll
    for(int j=0;j<33;j++) acc += w[j]*in[rr+j];
    int n = n0 + grp*16 + rr;
    F[(size_t)n*CDIM + h*DHEAD + d] = (short)bfbits(f0[rr] + acc);
  }
}

// ---------------- weight transpose f32 -> bf16 ----------------
__global__ void k_transposeb(const float* __restrict__ in, short* __restrict__ out,
                             int R, int C){
  __shared__ float tile[32][33];
  int r0 = blockIdx.x*32, c0 = blockIdx.y*32;
  int tx = threadIdx.x, ty = threadIdx.y;
  #pragma unroll
  for(int r=0;r<4;r++) tile[ty + r*8][tx] = in[(size_t)(r0 + ty + r*8)*C + c0 + tx];
  __syncthreads();
  #pragma unroll
  for(int r=0;r<4;r++)
    out[(size_t)(c0 + ty + r*8)*R + r0 + tx] = (short)bfbits(tile[tx][ty + r*8]);
}

// ---------------- PPEG direct on row-major [n][c] (f32) ----------------
__global__ __launch_bounds__(256) void k_ppeg2(const float* __restrict__ X,
    const float* __restrict__ w7, const float* __restrict__ b7,
    const float* __restrict__ w5, const float* __restrict__ b5,
    const float* __restrict__ w3, const float* __restrict__ b3,
    float* __restrict__ Y){
  __shared__ float patch[484][20];
  int cg = blockIdx.y;
  int ti = blockIdx.x >> 3, tj = blockIdx.x & 7;
  int t = threadIdx.x;
  int i0 = ti*16 - 3, j0 = tj*16 - 3;
  for(int idx = t; idx < 1936; idx += 256){
    int p = idx >> 2, cq = (idx & 3) * 4;
    int gi = i0 + p/22, gj = j0 + p%22;
    float4 v = make_float4(0.f,0.f,0.f,0.f);
    if(gi>=0 && gi<128 && gj>=0 && gj<128)
      v = *(const float4*)(X + (size_t)(gi*128+gj)*CDIM + cg*16 + cq);
    *(float4*)&patch[p][cq] = v;
  }
  int c = t & 15, sg = t >> 4;
  int cglob = cg*16 + c;
  float wr[83];
  #pragma unroll
  for(int k=0;k<49;k++) wr[k] = w7[cglob*49+k];
  #pragma unroll
  for(int k=0;k<25;k++) wr[49+k] = w5[cglob*25+k];
  #pragma unroll
  for(int k=0;k<9;k++)  wr[74+k] = w3[cglob*9+k];
  float bsum = b7[cglob] + b5[cglob] + b3[cglob];
  __syncthreads();
  float acc[16];
  #pragma unroll
  for(int j=0;j<16;j++) acc[j] = patch[(sg+3)*22 + (j+3)][c] + bsum;
  #pragma unroll
  for(int a=0;a<7;a++)
    #pragma unroll
    for(int x=0;x<22;x++){
      float vv = patch[(sg+a)*22 + x][c];
      #pragma unroll
      for(int bq=0;bq<7;bq++){
        int j = x - bq;
        if(j>=0 && j<16) acc[j] += wr[a*7+bq]*vv;
      }
    }
  #pragma unroll
  for(int a=0;a<5;a++)
    #pragma unroll
    for(int x=1;x<21;x++){
      float vv = patch[(sg+a+1)*22 + x][c];
      #pragma unroll
      for(int bq=0;bq<5;bq++){
        int j = x - 1 - bq;
        if(j>=0 && j<16) acc[j] += wr[49+a*5+bq]*vv;
      }
    }
  #pragma unroll
  for(int a=0;a<3;a++)
    #pragma unroll
    for(int x=2;x<20;x++){
      float vv = patch[(sg+a+2)*22 + x][c];
      #pragma unroll
      for(int bq=0;bq<3;bq++){
        int j = x - 2 - bq;
        if(j>=0 && j<16) acc[j] += wr[74+a*3+bq]*vv;
      }
    }
  #pragma unroll
  for(int j=0;j<16;j++)
    Y[(size_t)((ti*16+sg)*128 + tj*16+j)*CDIM + cglob] = acc[j];
}

// ---------------- final LN(row0) + fc2 ----------------
__global__ __launch_bounds__(512) void k_final(const float* __restrict__ A,
    const float* __restrict__ g, const float* __restrict__ b,
    const float* __restrict__ w, const float* __restrict__ bias,
    float* __restrict__ outp){
  __shared__ float red[8];
  int t = threadIdx.x, wv = t >> 6;
  float x = A[t];
  float s = wave_sum(x);
  if((t & 63) == 0) red[wv] = s;
  __syncthreads();
  float mu = 0;
  #pragma unroll
  for(int i=0;i<8;i++) mu += red[i];
  mu *= (1.f/512.f);
  __syncthreads();
  float dx = x - mu;
  s = wave_sum(dx*dx);
  if((t & 63) == 0) red[wv] = s;
  __syncthreads();
  float var = 0;
  #pragma unroll
  for(int i=0;i<8;i++) var += red[i];
  var *= (1.f/512.f);
  float xn = dx * rsqrtf(var + 1e-5f) * g[t] + b[t];
  __syncthreads();
  for(int o=0;o<4;o++){
    s = wave_sum(xn * w[t*4 + o]);
    if((t & 63) == 0) red[wv] = s;
    __syncthreads();
    if(t == 0){
      float r = 0;
      #pragma unroll
      for(int i=0;i<8;i++) r += red[i];
      outp[o] = r + bias[o];
    }
    __syncthreads();
  }
}

extern "C" void kernel_launch(void* const* d_in, const int* in_sizes, int n_in,
                              void* d_out, int out_size, void* d_ws, size_t ws_size,
                              hipStream_t stream) {
  (void)in_sizes; (void)n_in; (void)out_size; (void)ws_size;
  const float* data_x = (const float*)d_in[0];
  const float* fc1_w  = (const float*)d_in[1];
  const float* fc1_b  = (const float*)d_in[2];
  const float* cls_tk = (const float*)d_in[3];
  const float* ng[2]  = {(const float*)d_in[4],  (const float*)d_in[16]};
  const float* nb[2]  = {(const float*)d_in[5],  (const float*)d_in[17]};
  const float* qkvw[2]= {(const float*)d_in[6],  (const float*)d_in[18]};
  const float* outw[2]= {(const float*)d_in[7],  (const float*)d_in[19]};
  const float* outb[2]= {(const float*)d_in[8],  (const float*)d_in[20]};
  const float* resw[2]= {(const float*)d_in[9],  (const float*)d_in[21]};
  const float* w7 = (const float*)d_in[10]; const float* pb7 = (const float*)d_in[11];
  const float* w5 = (const float*)d_in[12]; const float* pb5 = (const float*)d_in[13];
  const float* w3 = (const float*)d_in[14]; const float* pb3 = (const float*)d_in[15];
  const float* norm_g = (const float*)d_in[22];
  const float* norm_b = (const float*)d_in[23];
  const float* fc2_w  = (const float*)d_in[24];
  const float* fc2_b  = (const float*)d_in[25];

  float* ws = (float*)d_ws;
  float* Ab   = ws;
  float* Bb   = Ab + (size_t)TOK*CDIM;
  float* Fb   = Bb + (size_t)TOK*CDIM;
  short* Fbf  = (short*)(Fb + (size_t)NPAD*CDIM);
  short* lnX  = Fbf + (size_t)NPAD*CDIM;
  short* Qb   = lnX + (size_t)NPAD*CDIM;
  short* Kb   = Qb  + (size_t)NPAD*CDIM;
  short* Vb   = Kb  + (size_t)NPAD*CDIM;
  short* dxb  = Vb  + (size_t)NPAD*CDIM;
  float* qlb  = (float*)(dxb + (size_t)16384*1024);
  float* klb  = qlb + NHEAD*NLAND*DHEAD;
  float* a2b  = klb + NHEAD*NLAND*DHEAD;
  float* z0b  = a2b + NHEAD*NLAND*NLAND;
  float* z1b  = z0b + NHEAD*NLAND*NLAND;
  float* Xb_  = z1b + NHEAD*NLAND*NLAND;
  float* Tb_  = Xb_ + NHEAD*NLAND*NLAND;
  float* Ub_  = Tb_ + NHEAD*NLAND*NLAND;
  float* a3vb = Ub_ + NHEAD*NLAND*NLAND;
  float* w2tb = a3vb + NHEAD*NLAND*DHEAD;
  float* denP = w2tb + NHEAD*DHEAD*NLAND;
  float* hmax = denP + NHEAD*NCG*NLAND;
  float* scal = hmax + 8;
  short* fc1T = (short*)(scal + 8);
  short* qkvT0= fc1T + 512*1024;
  short* qkvT1= qkvT0 + 1536*512;
  short* outT0= qkvT1 + 1536*512;
  short* outT1= outT0 + 512*512;
  short* qkvT[2] = {qkvT0, qkvT1};
  short* outT[2] = {outT0, outT1};

  const int HB = NHEAD*NLAND*NLAND;
  short* zb0  = (short*)z0b;  short* zb1  = zb0 + HB;
  short* xb   = (short*)z1b;  short* tb   = xb + HB;
  short* ub   = (short*)Xb_;  short* a2bf = ub + HB;
  float* zf   = Tb_;

  k_transposeb<<<dim3(32,16), dim3(32,8), 0, stream>>>(fc1_w, fc1T, 1024, 512);
  k_transposeb<<<dim3(16,48), dim3(32,8), 0, stream>>>(qkvw[0], qkvT0, 512, 1536);
  k_transposeb<<<dim3(16,48), dim3(32,8), 0, stream>>>(qkvw[1], qkvT1, 512, 1536);
  k_transposeb<<<dim3(16,16), dim3(32,8), 0, stream>>>(outw[0], outT0, 512, 512);
  k_transposeb<<<dim3(16,16), dim3(32,8), 0, stream>>>(outw[1], outT1, 512, 512);
  k_f2b<<<8192, 256, 0, stream>>>(data_x, dxb, 16384*1024/8);

  k_copyrow<<<1, 512, 0, stream>>>(Ab, cls_tk);
  k_gemm_g<0><<<dim3(4, 128), 256, 0, stream>>>(dxb, 1024, fc1T, 1024, fc1_b,
                                                Ab + CDIM, nullptr, nullptr, 16384);
  float* base[2]  = {Ab, Bb};
  for(int L=0; L<2; L++){
    k_ln_pad<<<NPAD/4, 256, 0, stream>>>(base[L], ng[L], nb[L], lnX);
    k_gemm_g<1><<<dim3(12, 130), 256, 0, stream>>>(lnX, CDIM, qkvT[L], CDIM, nullptr,
                                                   Qb, Kb, Vb, NPAD);
    k_landmark2<<<2*NHEAD*NLAND, 64, 0, stream>>>(Qb, Kb, qlb, klb);
    k_a2_mfma<<<dim3(4, NHEAD), 256, 0, stream>>>(qlb, klb, a2b, a2bf);
    k_colmax<<<NHEAD, 256, 0, stream>>>(a2b, hmax);
    k_zinit<<<dim3(256, NHEAD), 256, 0, stream>>>(a2b, hmax, zb0);
    short* zc = zb0; short* zn = zb1;
    for(int it=0; it<6; it++){
      k_pgemm<0,0><<<dim3(4,4,NHEAD), 256, 0, stream>>>(a2bf, zc, xb, nullptr, 0.f, 1.f);
      k_pgemm<1,0><<<dim3(4,4,NHEAD), 256, 0, stream>>>(xb, xb, tb, nullptr, 7.f, 1.f);
      k_pgemm<1,0><<<dim3(4,4,NHEAD), 256, 0, stream>>>(xb, tb, ub, nullptr, 15.f, 1.f);
      if(it < 5){
        k_pgemm<1,0><<<dim3(4,4,NHEAD), 256, 0, stream>>>(zc, ub, zn, nullptr, 13.f, 0.25f);
        short* tmp = zc; zc = zn; zn = tmp;
      } else {
        k_pgemm<1,1><<<dim3(4,4,NHEAD), 256, 0, stream>>>(zc, ub, nullptr, zf, 13.f, 0.25f);
      }
    }
    k_a3v_mfma<<<dim3(NHEAD, NCG), 512, 0, stream>>>(qlb, Kb, Vb, Fb, denP);
    k_a3v_comb<<<NHEAD*NLAND, 64, 0, stream>>>(Fb, denP, a3vb);
    k_sgemm2<0,1><<<dim3(1,4,NHEAD), 256, 0, stream>>>(zf, a3vb, w2tb, 256,64,256,
                                                       65536,16384,16384, 0.f, 1.f);
    k_a1_mfma<<<dim3(130, NHEAD), 256, 0, stream>>>(Qb, klb, w2tb, Fbf);
    k_resconv<<<dim3(260, NHEAD), 256, 0, stream>>>(Vb, resw[L], Fbf);
    k_gemm_g<2><<<dim3(4, 129), 256, 0, stream>>>(Fbf + (size_t)PAD0*CDIM, CDIM,
                                                  outT[L], CDIM, outb[L],
                                                  base[L], nullptr, nullptr, TOK);
    if(L == 0){
      k_ppeg2<<<dim3(64, 32), 256, 0, stream>>>(Ab + CDIM, w7, pb7, w5, pb5, w3, pb3,
                                                Bb + CDIM);
      k_copyrow<<<1, 512, 0, stream>>>(Bb, Ab);
    }
  }
  k_final<<<1, 512, 0, stream>>>(Bb, norm_g, norm_b, fc2_w, fc2_b, (float*)d_out);
}